// Round 1
// baseline (2460.778 us; speedup 1.0000x reference)
//
#include <hip/hip_runtime.h>
#include <hip/hip_bf16.h>
#include <math.h>

// Problem constants
#define LL   512
#define DD   512
#define DII  1024
#define NST  16
#define BB   8
#define MM   4096   // B*L tokens

__device__ __forceinline__ float sigmoidf_(float x){ return 1.0f/(1.0f+expf(-x)); }
__device__ __forceinline__ float siluf_(float x){ return x*sigmoidf_(x); }
__device__ __forceinline__ float softplusf_(float x){ return x > 20.0f ? x : log1pf(expf(x)); }

// ---------------------------------------------------------------------------
// Generic fp32 GEMM: C[M,N] = act(A[M,K] @ W[N,K]^T + bias) fused with
// optional residual (C = resid + rscale*val) and row-reversal on A-read
// (rev_in) or C-write (rev_out), where rows are (b*L + l) and reversal maps
// l -> L-1-l within each batch. Tile 64x64, K-step 16, 256 threads, 4x4/thread.
// ---------------------------------------------------------------------------
__global__ void __launch_bounds__(256) gemm_kernel(
    const float* __restrict__ A, int lda,
    const float* __restrict__ W, int ldw,
    const float* __restrict__ bias,
    float* __restrict__ C, int ldc,
    const float* __restrict__ resid, int ldr, float rscale,
    int Ktot, int act, int rev_in, int rev_out)
{
    __shared__ float As[16][64];
    __shared__ float Ws[16][64];
    const int tid = threadIdx.x;
    const int tx = tid & 15, ty = tid >> 4;
    const int rowBase = blockIdx.y << 6;
    const int colBase = blockIdx.x << 6;

    const int lm = tid >> 2;          // 0..63 (tile row for A / tile col for W)
    const int kq = (tid & 3) << 2;    // 0,4,8,12

    int arow = rowBase + lm;
    if (rev_in) { int b = arow >> 9, l = arow & (LL-1); arow = (b << 9) + (LL-1-l); }
    const float* Aptr = A + (size_t)arow * lda + kq;
    const float* Wptr = W + (size_t)(colBase + lm) * ldw + kq;

    float acc[4][4] = {};
    for (int k0 = 0; k0 < Ktot; k0 += 16) {
        float4 av = *(const float4*)(Aptr + k0);
        float4 wv = *(const float4*)(Wptr + k0);
        As[kq+0][lm]=av.x; As[kq+1][lm]=av.y; As[kq+2][lm]=av.z; As[kq+3][lm]=av.w;
        Ws[kq+0][lm]=wv.x; Ws[kq+1][lm]=wv.y; Ws[kq+2][lm]=wv.z; Ws[kq+3][lm]=wv.w;
        __syncthreads();
        #pragma unroll
        for (int kk = 0; kk < 16; kk++) {
            float a[4], w[4];
            #pragma unroll
            for (int i = 0; i < 4; i++) a[i] = As[kk][(ty<<2)+i];
            #pragma unroll
            for (int j = 0; j < 4; j++) w[j] = Ws[kk][(tx<<2)+j];
            #pragma unroll
            for (int i = 0; i < 4; i++)
                #pragma unroll
                for (int j = 0; j < 4; j++)
                    acc[i][j] += a[i]*w[j];
        }
        __syncthreads();
    }

    #pragma unroll
    for (int i = 0; i < 4; i++) {
        int orow = rowBase + (ty<<2) + i;
        if (rev_out) { int b = orow >> 9, l = orow & (LL-1); orow = (b << 9) + (LL-1-l); }
        #pragma unroll
        for (int j = 0; j < 4; j++) {
            int col = colBase + (tx<<2) + j;
            float v = acc[i][j];
            if (bias) v += bias[col];
            if (act == 1) v = siluf_(v);
            else if (act == 2) v = softplusf_(v);
            if (resid) v = resid[(size_t)orow*ldr + col] + rscale*v;
            C[(size_t)orow*ldc + col] = v;
        }
    }
}

// ---------------------------------------------------------------------------
// LayerNorm over last dim (512). One block (128 thr) per row; float4 loads.
// ---------------------------------------------------------------------------
__global__ void __launch_bounds__(128) ln_kernel(
    const float* __restrict__ x, const float* __restrict__ g,
    const float* __restrict__ bta, float* __restrict__ out)
{
    const int row = blockIdx.x;
    const int t = threadIdx.x;
    float4 v = ((const float4*)(x + (size_t)row*DD))[t];
    float s = v.x+v.y+v.z+v.w;
    float q = v.x*v.x+v.y*v.y+v.z*v.z+v.w*v.w;
    #pragma unroll
    for (int off = 32; off >= 1; off >>= 1) {
        s += __shfl_down(s, off);
        q += __shfl_down(q, off);
    }
    __shared__ float sh[4];
    if ((t & 63) == 0) { sh[(t>>6)*2] = s; sh[(t>>6)*2+1] = q; }
    __syncthreads();
    float mean = (sh[0]+sh[2]) * (1.0f/DD);
    float var  = (sh[1]+sh[3]) * (1.0f/DD) - mean*mean;
    float rstd = rsqrtf(var + 1e-5f);
    float4 gg = ((const float4*)g)[t];
    float4 bb = ((const float4*)bta)[t];
    float4 o;
    o.x = (v.x-mean)*rstd*gg.x + bb.x;
    o.y = (v.y-mean)*rstd*gg.y + bb.y;
    o.z = (v.z-mean)*rstd*gg.z + bb.z;
    o.w = (v.w-mean)*rstd*gg.w + bb.w;
    ((float4*)(out + (size_t)row*DD))[t] = o;
}

// ---------------------------------------------------------------------------
// Mamba causal depthwise conv (K=4, pad left 3) + bias + SiLU.
// xi = xz[:, :, :DII]. Thread -> channel fastest => coalesced.
// ---------------------------------------------------------------------------
__global__ void __launch_bounds__(256) mamba_conv_kernel(
    const float* __restrict__ xz, const float* __restrict__ cw,
    const float* __restrict__ cb, float* __restrict__ xc)
{
    const int idx = blockIdx.x*256 + threadIdx.x;   // B*L*DII total
    const int c = idx & (DII-1);
    const int row = idx >> 10;                      // b*L + l
    const int l = row & (LL-1);
    float4 w = ((const float4*)cw)[c];
    const float* wf = (const float*)&w;
    float acc = cb[c];
    #pragma unroll
    for (int t = 0; t < 4; t++) {
        int ll = l - 3 + t;
        if (ll >= 0) acc += wf[t] * xz[((size_t)(row - l + ll))*2048 + c];
    }
    xc[idx] = siluf_(acc);
}

// ---------------------------------------------------------------------------
// Selective scan. 16 lanes = 16 states per (b,d); shfl_xor reduce for the
// C-contraction; lane n==0 writes ys[b,l,d].
// ---------------------------------------------------------------------------
__global__ void __launch_bounds__(256) scan_kernel(
    const float* __restrict__ dt, const float* __restrict__ xc,
    const float* __restrict__ xdb, const float* __restrict__ Alog,
    float* __restrict__ ys)
{
    const int gtid = blockIdx.x*256 + threadIdx.x;
    const int n = gtid & (NST-1);
    const int gid = gtid >> 4;          // b*DII + d
    const int d = gid & (DII-1);
    const int b = gid >> 10;
    const float Acoef = -expf(Alog[d*NST + n]);
    float h = 0.0f;
    const float* dtp = dt  + (size_t)b*LL*DII + d;
    const float* xcp = xc  + (size_t)b*LL*DII + d;
    const float* xbp = xdb + (size_t)b*LL*64 + 32 + n;  // B at +0, C at +16
    float* ysp = ys + (size_t)b*LL*DII + d;
    for (int l = 0; l < LL; l++) {
        float dtv = dtp[(size_t)l*DII];
        float xcv = xcp[(size_t)l*DII];
        float Bv  = xbp[(size_t)l*64];
        float Cv  = xbp[(size_t)l*64 + 16];
        h = __expf(dtv*Acoef)*h + dtv*Bv*xcv;
        float acc = h*Cv;
        acc += __shfl_xor(acc, 1);
        acc += __shfl_xor(acc, 2);
        acc += __shfl_xor(acc, 4);
        acc += __shfl_xor(acc, 8);
        if (n == 0) ysp[(size_t)l*DII] = acc;
    }
}

// ---------------------------------------------------------------------------
// y = (ys + Dp*xc) * silu(z), z = xz[:, :, DII:]. In-place on ys.
// ---------------------------------------------------------------------------
__global__ void __launch_bounds__(256) ycombine_kernel(
    float* __restrict__ ys, const float* __restrict__ xc,
    const float* __restrict__ xz, const float* __restrict__ Dp)
{
    const int idx = blockIdx.x*256 + threadIdx.x;   // B*L*DII
    const int d = idx & (DII-1);
    const int row = idx >> 10;
    float z = xz[(size_t)row*2048 + DII + d];
    ys[idx] = (ys[idx] + Dp[d]*xc[idx]) * siluf_(z);
}

// ---------------------------------------------------------------------------
// GLU: out[row,c] = pw1[row,c] * sigmoid(pw1[row,512+c])
// ---------------------------------------------------------------------------
__global__ void __launch_bounds__(256) glu_kernel(
    const float* __restrict__ pw1, float* __restrict__ out)
{
    const int idx = blockIdx.x*256 + threadIdx.x;   // B*L*DD
    const int c = idx & (DD-1);
    const int row = idx >> 9;
    float a = pw1[(size_t)row*1024 + c];
    float g = pw1[(size_t)row*1024 + DD + c];
    out[idx] = a * sigmoidf_(g);
}

// ---------------------------------------------------------------------------
// Fused 3x depthwise conv (15/31/63, symmetric zero-pad) avg + BN + SiLU.
// Token-major [b,l,c]; thread -> c fastest => every tap load is coalesced.
// ---------------------------------------------------------------------------
__global__ void __launch_bounds__(256) multiconv_kernel(
    const float* __restrict__ gin,
    const float* __restrict__ w15, const float* __restrict__ w31,
    const float* __restrict__ w63,
    const float* __restrict__ bn_g, const float* __restrict__ bn_b,
    const float* __restrict__ bn_m, const float* __restrict__ bn_v,
    float* __restrict__ out)
{
    const int idx = blockIdx.x*256 + threadIdx.x;   // B*L*DD
    const int c = idx & (DD-1);
    const int l = (idx >> 9) & (LL-1);
    const int b = idx >> 18;
    float s15 = 0.f, s31 = 0.f, s63 = 0.f;
    #pragma unroll
    for (int off = -31; off <= 31; off++) {
        int ll = l + off;
        float v = (ll >= 0 && ll < LL) ? gin[(((size_t)(b<<9)+ll)<<9) + c] : 0.f;
        s63 += w63[c*63 + off + 31] * v;
        if (off >= -15 && off <= 15) s31 += w31[c*31 + off + 15] * v;
        if (off >= -7  && off <= 7 ) s15 += w15[c*15 + off + 7 ] * v;
    }
    float m = (s15 + s31 + s63) * (1.0f/3.0f);
    m = (m - bn_m[c]) * rsqrtf(bn_v[c] + 1e-5f) * bn_g[c] + bn_b[c];
    out[idx] = siluf_(m);
}

// ---------------------------------------------------------------------------
extern "C" void kernel_launch(void* const* d_in, const int* in_sizes, int n_in,
                              void* d_out, int out_size, void* d_ws, size_t ws_size,
                              hipStream_t stream)
{
    const float* x        = (const float*)d_in[0];
    const float* ff1_ln_g = (const float*)d_in[1];
    const float* ff1_ln_b = (const float*)d_in[2];
    const float* ff1_w1   = (const float*)d_in[3];
    const float* ff1_b1   = (const float*)d_in[4];
    const float* ff1_w2   = (const float*)d_in[5];
    const float* ff1_b2   = (const float*)d_in[6];
    const float* ff2_ln_g = (const float*)d_in[7];
    const float* ff2_ln_b = (const float*)d_in[8];
    const float* ff2_w1   = (const float*)d_in[9];
    const float* ff2_b1   = (const float*)d_in[10];
    const float* ff2_w2   = (const float*)d_in[11];
    const float* ff2_b2   = (const float*)d_in[12];
    const float* m_win    = (const float*)d_in[13];
    const float* m_convw  = (const float*)d_in[14];
    const float* m_convb  = (const float*)d_in[15];
    const float* m_wx     = (const float*)d_in[16];
    const float* m_wdt    = (const float*)d_in[17];
    const float* m_bdt    = (const float*)d_in[18];
    const float* m_Alog   = (const float*)d_in[19];
    const float* m_Dp     = (const float*)d_in[20];
    const float* m_wout   = (const float*)d_in[21];
    const float* bi_wo    = (const float*)d_in[22];
    const float* bi_bo    = (const float*)d_in[23];
    const float* cv_ln_g  = (const float*)d_in[24];
    const float* cv_ln_b  = (const float*)d_in[25];
    const float* cv_pw1_w = (const float*)d_in[26];
    const float* cv_pw1_b = (const float*)d_in[27];
    const float* cv_dw15  = (const float*)d_in[28];
    const float* cv_dw31  = (const float*)d_in[29];
    const float* cv_dw63  = (const float*)d_in[30];
    const float* cv_bn_g  = (const float*)d_in[31];
    const float* cv_bn_b  = (const float*)d_in[32];
    const float* cv_bn_m  = (const float*)d_in[33];
    const float* cv_bn_v  = (const float*)d_in[34];
    const float* cv_pw2_w = (const float*)d_in[35];
    const float* cv_pw2_b = (const float*)d_in[36];
    const float* ln_g     = (const float*)d_in[37];
    const float* ln_b     = (const float*)d_in[38];

    // Workspace layout (floats). Total = 4096*7232 floats = 118.5 MB.
    float* ws   = (float*)d_ws;
    float* h    = ws;                              // [MM*512]  residual stream
    float* lnb  = h    + (size_t)MM*DD;            // [MM*512]  LN output
    float* bigA = lnb  + (size_t)MM*DD;            // [MM*2048] ffn hidden / xz / pw1
    float* xcb  = bigA + (size_t)MM*2048;          // [MM*1024] conv-act x
    float* dtb  = xcb  + (size_t)MM*DII;           // [MM*1024] dt (also GLU out)
    float* ysb  = dtb  + (size_t)MM*DII;           // [MM*1024] scan out (also conv out)
    float* xdbb = ysb  + (size_t)MM*DII;           // [MM*64]   dt/B/C projections
    float* catb = xdbb + (size_t)MM*64;            // [MM*1024] fwd|rev concat
    size_t need = ((size_t)(catb + (size_t)MM*DII - ws)) * sizeof(float);
    if (ws_size < need) return;  // workspace too small -> clean failure

    dim3 blk(256);
    auto gemm = [&](const float* A, int lda, const float* W, int ldw,
                    const float* bias, float* C, int ldc,
                    const float* res, int ldr, float rs,
                    int M, int N, int K, int act, int ri, int ro) {
        dim3 g(N/64, M/64);
        hipLaunchKernelGGL(gemm_kernel, g, blk, 0, stream,
                           A, lda, W, ldw, bias, C, ldc, res, ldr, rs, K, act, ri, ro);
    };

    // ---- FFN1: h = x + 0.5*(silu(LN(x)@w1^T+b1)@w2^T+b2)
    hipLaunchKernelGGL(ln_kernel, dim3(MM), dim3(128), 0, stream, x, ff1_ln_g, ff1_ln_b, lnb);
    gemm(lnb, 512, ff1_w1, 512, ff1_b1, bigA, 2048, nullptr, 0, 0.f, MM, 2048, 512, 1, 0, 0);
    gemm(bigA, 2048, ff1_w2, 2048, ff1_b2, h, 512, x, 512, 0.5f, MM, 512, 2048, 0, 0, 0);

    // ---- BiMamba: two directions, concat into catb, project with bi_wo
    for (int dir = 0; dir < 2; dir++) {
        const float* win   = m_win   + (size_t)dir*2048*512;
        const float* convw = m_convw + (size_t)dir*DII*4;
        const float* convb = m_convb + (size_t)dir*DII;
        const float* wx    = m_wx    + (size_t)dir*64*DII;
        const float* wdt   = m_wdt   + (size_t)dir*DII*32;
        const float* bdt   = m_bdt   + (size_t)dir*DII;
        const float* Alog  = m_Alog  + (size_t)dir*DII*NST;
        const float* Dp    = m_Dp    + (size_t)dir*DII;
        const float* wout  = m_wout  + (size_t)dir*DD*DII;

        // xz = h(reversed for dir=1) @ win^T  [MM, 2048]
        gemm(h, 512, win, 512, nullptr, bigA, 2048, nullptr, 0, 0.f, MM, 2048, 512, 0, dir, 0);
        // xc = silu(causal dwconv(xi) + convb)
        hipLaunchKernelGGL(mamba_conv_kernel, dim3(MM*DII/256), blk, 0, stream, bigA, convw, convb, xcb);
        // xdb = xc @ wx^T  [MM, 64]
        gemm(xcb, DII, wx, DII, nullptr, xdbb, 64, nullptr, 0, 0.f, MM, 64, DII, 0, 0, 0);
        // dt = softplus(xdb[:, :32] @ wdt^T + bdt)  [MM, 1024]
        gemm(xdbb, 64, wdt, 32, bdt, dtb, DII, nullptr, 0, 0.f, MM, DII, 32, 2, 0, 0);
        // selective scan -> ysb
        hipLaunchKernelGGL(scan_kernel, dim3(BB*DII*NST/256), blk, 0, stream, dtb, xcb, xdbb, Alog, ysb);
        // y = (ys + Dp*xc) * silu(z)
        hipLaunchKernelGGL(ycombine_kernel, dim3(MM*DII/256), blk, 0, stream, ysb, xcb, bigA, Dp);
        // out-proj into cat half (reverse rows back for dir=1)
        gemm(ysb, DII, wout, DII, nullptr, catb + dir*DD, 2*DD, nullptr, 0, 0.f, MM, DD, DII, 0, 0, dir);
    }
    // h += cat @ bi_wo^T + bi_bo
    gemm(catb, 1024, bi_wo, 1024, bi_bo, h, 512, h, 512, 1.0f, MM, 512, 1024, 0, 0, 0);

    // ---- ConvMod
    hipLaunchKernelGGL(ln_kernel, dim3(MM), dim3(128), 0, stream, h, cv_ln_g, cv_ln_b, lnb);
    gemm(lnb, 512, cv_pw1_w, 512, cv_pw1_b, bigA, 1024, nullptr, 0, 0.f, MM, 1024, 512, 0, 0, 0);
    hipLaunchKernelGGL(glu_kernel, dim3(MM*DD/256), blk, 0, stream, bigA, dtb);
    hipLaunchKernelGGL(multiconv_kernel, dim3(MM*DD/256), blk, 0, stream, dtb,
                       cv_dw15, cv_dw31, cv_dw63, cv_bn_g, cv_bn_b, cv_bn_m, cv_bn_v, ysb);
    gemm(ysb, 512, cv_pw2_w, 512, cv_pw2_b, h, 512, h, 512, 1.0f, MM, 512, 512, 0, 0, 0);

    // ---- FFN2
    hipLaunchKernelGGL(ln_kernel, dim3(MM), dim3(128), 0, stream, h, ff2_ln_g, ff2_ln_b, lnb);
    gemm(lnb, 512, ff2_w1, 512, ff2_b1, bigA, 2048, nullptr, 0, 0.f, MM, 2048, 512, 1, 0, 0);
    gemm(bigA, 2048, ff2_w2, 2048, ff2_b2, h, 512, h, 512, 0.5f, MM, 512, 2048, 0, 0, 0);

    // ---- Final LN -> d_out
    hipLaunchKernelGGL(ln_kernel, dim3(MM), dim3(128), 0, stream, h, ln_g, ln_b, (float*)d_out);
}

// Round 2
// 1818.883 us; speedup vs baseline: 1.3529x; 1.3529x over previous
//
#include <hip/hip_runtime.h>
#include <hip/hip_bf16.h>
#include <math.h>

// Problem constants
#define LL   512
#define DD   512
#define DII  1024
#define NST  16
#define BB   8
#define MM   4096   // B*L tokens

__device__ __forceinline__ float sigmoidf_(float x){ return 1.0f/(1.0f+expf(-x)); }
__device__ __forceinline__ float siluf_(float x){ return x*sigmoidf_(x); }
__device__ __forceinline__ float softplusf_(float x){ return x > 20.0f ? x : log1pf(expf(x)); }

// ---------------------------------------------------------------------------
// Generic fp32 GEMM: C[M,N] = act(A[M,K] @ W[N,K]^T + bias) fused with
// optional residual (C = resid + rscale*val) and row-reversal on A-read
// (rev_in) or C-write (rev_out). Tile 64x64, K-step 16, 256 thr, 4x4/thread.
// ---------------------------------------------------------------------------
__global__ void __launch_bounds__(256) gemm_kernel(
    const float* __restrict__ A, int lda,
    const float* __restrict__ W, int ldw,
    const float* __restrict__ bias,
    float* __restrict__ C, int ldc,
    const float* __restrict__ resid, int ldr, float rscale,
    int Ktot, int act, int rev_in, int rev_out)
{
    __shared__ float As[16][64];
    __shared__ float Ws[16][64];
    const int tid = threadIdx.x;
    const int tx = tid & 15, ty = tid >> 4;
    const int rowBase = blockIdx.y << 6;
    const int colBase = blockIdx.x << 6;

    const int lm = tid >> 2;          // 0..63
    const int kq = (tid & 3) << 2;    // 0,4,8,12

    int arow = rowBase + lm;
    if (rev_in) { int b = arow >> 9, l = arow & (LL-1); arow = (b << 9) + (LL-1-l); }
    const float* Aptr = A + (size_t)arow * lda + kq;
    const float* Wptr = W + (size_t)(colBase + lm) * ldw + kq;

    float acc[4][4] = {};
    for (int k0 = 0; k0 < Ktot; k0 += 16) {
        float4 av = *(const float4*)(Aptr + k0);
        float4 wv = *(const float4*)(Wptr + k0);
        As[kq+0][lm]=av.x; As[kq+1][lm]=av.y; As[kq+2][lm]=av.z; As[kq+3][lm]=av.w;
        Ws[kq+0][lm]=wv.x; Ws[kq+1][lm]=wv.y; Ws[kq+2][lm]=wv.z; Ws[kq+3][lm]=wv.w;
        __syncthreads();
        #pragma unroll
        for (int kk = 0; kk < 16; kk++) {
            float a[4], w[4];
            #pragma unroll
            for (int i = 0; i < 4; i++) a[i] = As[kk][(ty<<2)+i];
            #pragma unroll
            for (int j = 0; j < 4; j++) w[j] = Ws[kk][(tx<<2)+j];
            #pragma unroll
            for (int i = 0; i < 4; i++)
                #pragma unroll
                for (int j = 0; j < 4; j++)
                    acc[i][j] += a[i]*w[j];
        }
        __syncthreads();
    }

    #pragma unroll
    for (int i = 0; i < 4; i++) {
        int orow = rowBase + (ty<<2) + i;
        if (rev_out) { int b = orow >> 9, l = orow & (LL-1); orow = (b << 9) + (LL-1-l); }
        #pragma unroll
        for (int j = 0; j < 4; j++) {
            int col = colBase + (tx<<2) + j;
            float v = acc[i][j];
            if (bias) v += bias[col];
            if (act == 1) v = siluf_(v);
            else if (act == 2) v = softplusf_(v);
            if (resid) v = resid[(size_t)orow*ldr + col] + rscale*v;
            C[(size_t)orow*ldc + col] = v;
        }
    }
}

// ---------------------------------------------------------------------------
// LayerNorm over last dim (512). One block (128 thr) per row; float4 loads.
// ---------------------------------------------------------------------------
__global__ void __launch_bounds__(128) ln_kernel(
    const float* __restrict__ x, const float* __restrict__ g,
    const float* __restrict__ bta, float* __restrict__ out)
{
    const int row = blockIdx.x;
    const int t = threadIdx.x;
    float4 v = ((const float4*)(x + (size_t)row*DD))[t];
    float s = v.x+v.y+v.z+v.w;
    float q = v.x*v.x+v.y*v.y+v.z*v.z+v.w*v.w;
    #pragma unroll
    for (int off = 32; off >= 1; off >>= 1) {
        s += __shfl_down(s, off);
        q += __shfl_down(q, off);
    }
    __shared__ float sh[4];
    if ((t & 63) == 0) { sh[(t>>6)*2] = s; sh[(t>>6)*2+1] = q; }
    __syncthreads();
    float mean = (sh[0]+sh[2]) * (1.0f/DD);
    float var  = (sh[1]+sh[3]) * (1.0f/DD) - mean*mean;
    float rstd = rsqrtf(var + 1e-5f);
    float4 gg = ((const float4*)g)[t];
    float4 bb = ((const float4*)bta)[t];
    float4 o;
    o.x = (v.x-mean)*rstd*gg.x + bb.x;
    o.y = (v.y-mean)*rstd*gg.y + bb.y;
    o.z = (v.z-mean)*rstd*gg.z + bb.z;
    o.w = (v.w-mean)*rstd*gg.w + bb.w;
    ((float4*)(out + (size_t)row*DD))[t] = o;
}

// ---------------------------------------------------------------------------
// Mamba causal depthwise conv (K=4, pad left 3) + bias + SiLU.
// ---------------------------------------------------------------------------
__global__ void __launch_bounds__(256) mamba_conv_kernel(
    const float* __restrict__ xz, const float* __restrict__ cw,
    const float* __restrict__ cb, float* __restrict__ xc)
{
    const int idx = blockIdx.x*256 + threadIdx.x;   // B*L*DII total
    const int c = idx & (DII-1);
    const int row = idx >> 10;                      // b*L + l
    const int l = row & (LL-1);
    float4 w = ((const float4*)cw)[c];
    const float* wf = (const float*)&w;
    float acc = cb[c];
    #pragma unroll
    for (int t = 0; t < 4; t++) {
        int ll = l - 3 + t;
        if (ll >= 0) acc += wf[t] * xz[((size_t)(row - l + ll))*2048 + c];
    }
    xc[idx] = siluf_(acc);
}

// ---------------------------------------------------------------------------
// Selective scan. 16 lanes = 16 states per (b,d).
// ---------------------------------------------------------------------------
__global__ void __launch_bounds__(256) scan_kernel(
    const float* __restrict__ dt, const float* __restrict__ xc,
    const float* __restrict__ xdb, const float* __restrict__ Alog,
    float* __restrict__ ys)
{
    const int gtid = blockIdx.x*256 + threadIdx.x;
    const int n = gtid & (NST-1);
    const int gid = gtid >> 4;          // b*DII + d
    const int d = gid & (DII-1);
    const int b = gid >> 10;
    const float Acoef = -expf(Alog[d*NST + n]);
    float h = 0.0f;
    const float* dtp = dt  + (size_t)b*LL*DII + d;
    const float* xcp = xc  + (size_t)b*LL*DII + d;
    const float* xbp = xdb + (size_t)b*LL*64 + 32 + n;  // B at +0, C at +16
    float* ysp = ys + (size_t)b*LL*DII + d;
    for (int l = 0; l < LL; l++) {
        float dtv = dtp[(size_t)l*DII];
        float xcv = xcp[(size_t)l*DII];
        float Bv  = xbp[(size_t)l*64];
        float Cv  = xbp[(size_t)l*64 + 16];
        h = __expf(dtv*Acoef)*h + dtv*Bv*xcv;
        float acc = h*Cv;
        acc += __shfl_xor(acc, 1);
        acc += __shfl_xor(acc, 2);
        acc += __shfl_xor(acc, 4);
        acc += __shfl_xor(acc, 8);
        if (n == 0) ysp[(size_t)l*DII] = acc;
    }
}

// ---------------------------------------------------------------------------
// y = (ys + Dp*xc) * silu(z). In-place on ys.
// ---------------------------------------------------------------------------
__global__ void __launch_bounds__(256) ycombine_kernel(
    float* __restrict__ ys, const float* __restrict__ xc,
    const float* __restrict__ xz, const float* __restrict__ Dp)
{
    const int idx = blockIdx.x*256 + threadIdx.x;   // B*L*DII
    const int d = idx & (DII-1);
    const int row = idx >> 10;
    float z = xz[(size_t)row*2048 + DII + d];
    ys[idx] = (ys[idx] + Dp[d]*xc[idx]) * siluf_(z);
}

// ---------------------------------------------------------------------------
// GLU + transpose: reads pw1 out [b*L, 1024] token-major, computes
// a*sigmoid(g), writes channel-major [b, c, l]. 64x64 LDS tile per block.
// grid (c_tile=8, l_tile=8, b=8), 256 threads.
// ---------------------------------------------------------------------------
__global__ void __launch_bounds__(256) glu_transpose_kernel(
    const float* __restrict__ pw1, float* __restrict__ out_t)
{
    __shared__ float sh[64][65];
    const int c0 = blockIdx.x << 6;
    const int l0 = blockIdx.y << 6;
    const int b  = blockIdx.z;
    const int t  = threadIdx.x;
    const int c4 = (t & 15) << 2;
    const int r  = t >> 4;            // 0..15
    #pragma unroll
    for (int i = 0; i < 4; i++) {
        int lrow = r + i*16;
        size_t row = (size_t)(b << 9) + l0 + lrow;
        float4 a = *(const float4*)(pw1 + row*1024 + c0 + c4);
        float4 g = *(const float4*)(pw1 + row*1024 + 512 + c0 + c4);
        sh[lrow][c4+0] = a.x * sigmoidf_(g.x);
        sh[lrow][c4+1] = a.y * sigmoidf_(g.y);
        sh[lrow][c4+2] = a.z * sigmoidf_(g.z);
        sh[lrow][c4+3] = a.w * sigmoidf_(g.w);
    }
    __syncthreads();
    #pragma unroll
    for (int i = 0; i < 4; i++) {
        int crow = r + i*16;
        float4 o;
        o.x = sh[c4+0][crow];
        o.y = sh[c4+1][crow];
        o.z = sh[c4+2][crow];
        o.w = sh[c4+3][crow];
        *(float4*)(out_t + ((size_t)(b << 9) + c0 + crow)*512 + l0 + c4) = o;
    }
}

// ---------------------------------------------------------------------------
// Channel-major fused 3x dwconv (15/31/63) avg + BN + SiLU.
// One block per (b,c): c is BLOCK-UNIFORM -> all 109 weights + BN params are
// scalar (SGPR) loads, zero per-lane gathers. Sequence + 31-halo in LDS;
// taps are stride-1 conflict-free LDS reads. in/out layout [b, c, l].
// ---------------------------------------------------------------------------
__global__ void __launch_bounds__(256) multiconv_t_kernel(
    const float* __restrict__ gin_t,
    const float* __restrict__ w15, const float* __restrict__ w31,
    const float* __restrict__ w63,
    const float* __restrict__ bn_g, const float* __restrict__ bn_b,
    const float* __restrict__ bn_m, const float* __restrict__ bn_v,
    float* __restrict__ out_t)
{
    __shared__ float sh[574];               // 31 halo | 512 | 31 halo
    const int c = blockIdx.x & (DD-1);
    const int b = blockIdx.x >> 9;
    const int t = threadIdx.x;
    const float* rowp = gin_t + ((size_t)(b << 9) + c)*512;
    sh[31 + t]       = rowp[t];
    sh[31 + t + 256] = rowp[t + 256];
    if (t < 31) { sh[t] = 0.f; sh[543 + t] = 0.f; }
    __syncthreads();

    const float bnscale = rsqrtf(bn_v[c] + 1e-5f) * bn_g[c];
    const float bnm = bn_m[c], bnb = bn_b[c];
    float* outp = out_t + ((size_t)(b << 9) + c)*512;
    #pragma unroll
    for (int half = 0; half < 2; half++) {
        int l = t + half*256;
        float s63 = 0.f, s31 = 0.f, s15 = 0.f;
        #pragma unroll
        for (int k = 0; k < 63; k++) s63 += w63[c*63 + k] * sh[l + k];
        #pragma unroll
        for (int k = 0; k < 31; k++) s31 += w31[c*31 + k] * sh[l + 16 + k];
        #pragma unroll
        for (int k = 0; k < 15; k++) s15 += w15[c*15 + k] * sh[l + 24 + k];
        float m = (s15 + s31 + s63) * (1.0f/3.0f);
        m = (m - bnm) * bnscale + bnb;
        outp[l] = siluf_(m);
    }
}

// ---------------------------------------------------------------------------
// Transpose [b, c, l] -> [b, l, c]. 64x64 LDS tiles.
// grid (l_tile=8, c_tile=8, b=8), 256 threads.
// ---------------------------------------------------------------------------
__global__ void __launch_bounds__(256) transpose_bcl_kernel(
    const float* __restrict__ in_t, float* __restrict__ out)
{
    __shared__ float sh[64][65];
    const int l0 = blockIdx.x << 6;
    const int c0 = blockIdx.y << 6;
    const int b  = blockIdx.z;
    const int t  = threadIdx.x;
    const int l4 = (t & 15) << 2;
    const int r  = t >> 4;
    #pragma unroll
    for (int i = 0; i < 4; i++) {
        int crow = r + i*16;
        float4 v = *(const float4*)(in_t + ((size_t)(b << 9) + c0 + crow)*512 + l0 + l4);
        sh[crow][l4+0] = v.x; sh[crow][l4+1] = v.y;
        sh[crow][l4+2] = v.z; sh[crow][l4+3] = v.w;
    }
    __syncthreads();
    #pragma unroll
    for (int i = 0; i < 4; i++) {
        int lrow = r + i*16;
        float4 o;
        o.x = sh[l4+0][lrow];
        o.y = sh[l4+1][lrow];
        o.z = sh[l4+2][lrow];
        o.w = sh[l4+3][lrow];
        *(float4*)(out + ((size_t)(b << 9) + l0 + lrow)*512 + c0 + l4) = o;
    }
}

// ---------------------------------------------------------------------------
extern "C" void kernel_launch(void* const* d_in, const int* in_sizes, int n_in,
                              void* d_out, int out_size, void* d_ws, size_t ws_size,
                              hipStream_t stream)
{
    const float* x        = (const float*)d_in[0];
    const float* ff1_ln_g = (const float*)d_in[1];
    const float* ff1_ln_b = (const float*)d_in[2];
    const float* ff1_w1   = (const float*)d_in[3];
    const float* ff1_b1   = (const float*)d_in[4];
    const float* ff1_w2   = (const float*)d_in[5];
    const float* ff1_b2   = (const float*)d_in[6];
    const float* ff2_ln_g = (const float*)d_in[7];
    const float* ff2_ln_b = (const float*)d_in[8];
    const float* ff2_w1   = (const float*)d_in[9];
    const float* ff2_b1   = (const float*)d_in[10];
    const float* ff2_w2   = (const float*)d_in[11];
    const float* ff2_b2   = (const float*)d_in[12];
    const float* m_win    = (const float*)d_in[13];
    const float* m_convw  = (const float*)d_in[14];
    const float* m_convb  = (const float*)d_in[15];
    const float* m_wx     = (const float*)d_in[16];
    const float* m_wdt    = (const float*)d_in[17];
    const float* m_bdt    = (const float*)d_in[18];
    const float* m_Alog   = (const float*)d_in[19];
    const float* m_Dp     = (const float*)d_in[20];
    const float* m_wout   = (const float*)d_in[21];
    const float* bi_wo    = (const float*)d_in[22];
    const float* bi_bo    = (const float*)d_in[23];
    const float* cv_ln_g  = (const float*)d_in[24];
    const float* cv_ln_b  = (const float*)d_in[25];
    const float* cv_pw1_w = (const float*)d_in[26];
    const float* cv_pw1_b = (const float*)d_in[27];
    const float* cv_dw15  = (const float*)d_in[28];
    const float* cv_dw31  = (const float*)d_in[29];
    const float* cv_dw63  = (const float*)d_in[30];
    const float* cv_bn_g  = (const float*)d_in[31];
    const float* cv_bn_b  = (const float*)d_in[32];
    const float* cv_bn_m  = (const float*)d_in[33];
    const float* cv_bn_v  = (const float*)d_in[34];
    const float* cv_pw2_w = (const float*)d_in[35];
    const float* cv_pw2_b = (const float*)d_in[36];
    const float* ln_g     = (const float*)d_in[37];
    const float* ln_b     = (const float*)d_in[38];

    // Workspace layout (floats). Total = 4096*7232 floats = 118.5 MB.
    float* ws   = (float*)d_ws;
    float* h    = ws;                              // [MM*512]  residual stream
    float* lnb  = h    + (size_t)MM*DD;            // [MM*512]  LN out / conv out
    float* bigA = lnb  + (size_t)MM*DD;            // [MM*2048] ffn hidden / xz / pw1
    float* xcb  = bigA + (size_t)MM*2048;          // [MM*1024] conv-act x
    float* dtb  = xcb  + (size_t)MM*DII;           // [MM*1024] dt / GLU-transposed
    float* ysb  = dtb  + (size_t)MM*DII;           // [MM*1024] scan out / conv-t out
    float* xdbb = ysb  + (size_t)MM*DII;           // [MM*64]   dt/B/C projections
    float* catb = xdbb + (size_t)MM*64;            // [MM*1024] fwd|rev concat
    size_t need = ((size_t)(catb + (size_t)MM*DII - ws)) * sizeof(float);
    if (ws_size < need) return;

    dim3 blk(256);
    auto gemm = [&](const float* A, int lda, const float* W, int ldw,
                    const float* bias, float* C, int ldc,
                    const float* res, int ldr, float rs,
                    int M, int N, int K, int act, int ri, int ro) {
        dim3 g(N/64, M/64);
        hipLaunchKernelGGL(gemm_kernel, g, blk, 0, stream,
                           A, lda, W, ldw, bias, C, ldc, res, ldr, rs, K, act, ri, ro);
    };

    // ---- FFN1: h = x + 0.5*(silu(LN(x)@w1^T+b1)@w2^T+b2)
    hipLaunchKernelGGL(ln_kernel, dim3(MM), dim3(128), 0, stream, x, ff1_ln_g, ff1_ln_b, lnb);
    gemm(lnb, 512, ff1_w1, 512, ff1_b1, bigA, 2048, nullptr, 0, 0.f, MM, 2048, 512, 1, 0, 0);
    gemm(bigA, 2048, ff1_w2, 2048, ff1_b2, h, 512, x, 512, 0.5f, MM, 512, 2048, 0, 0, 0);

    // ---- BiMamba
    for (int dir = 0; dir < 2; dir++) {
        const float* win   = m_win   + (size_t)dir*2048*512;
        const float* convw = m_convw + (size_t)dir*DII*4;
        const float* convb = m_convb + (size_t)dir*DII;
        const float* wx    = m_wx    + (size_t)dir*64*DII;
        const float* wdt   = m_wdt   + (size_t)dir*DII*32;
        const float* bdt   = m_bdt   + (size_t)dir*DII;
        const float* Alog  = m_Alog  + (size_t)dir*DII*NST;
        const float* Dp    = m_Dp    + (size_t)dir*DII;
        const float* wout  = m_wout  + (size_t)dir*DD*DII;

        gemm(h, 512, win, 512, nullptr, bigA, 2048, nullptr, 0, 0.f, MM, 2048, 512, 0, dir, 0);
        hipLaunchKernelGGL(mamba_conv_kernel, dim3(MM*DII/256), blk, 0, stream, bigA, convw, convb, xcb);
        gemm(xcb, DII, wx, DII, nullptr, xdbb, 64, nullptr, 0, 0.f, MM, 64, DII, 0, 0, 0);
        gemm(xdbb, 64, wdt, 32, bdt, dtb, DII, nullptr, 0, 0.f, MM, DII, 32, 2, 0, 0);
        hipLaunchKernelGGL(scan_kernel, dim3(BB*DII*NST/256), blk, 0, stream, dtb, xcb, xdbb, Alog, ysb);
        hipLaunchKernelGGL(ycombine_kernel, dim3(MM*DII/256), blk, 0, stream, ysb, xcb, bigA, Dp);
        gemm(ysb, DII, wout, DII, nullptr, catb + dir*DD, 2*DD, nullptr, 0, 0.f, MM, DD, DII, 0, 0, dir);
    }
    gemm(catb, 1024, bi_wo, 1024, bi_bo, h, 512, h, 512, 1.0f, MM, 512, 1024, 0, 0, 0);

    // ---- ConvMod (channel-major path: GLU+T -> conv -> T-back)
    hipLaunchKernelGGL(ln_kernel, dim3(MM), dim3(128), 0, stream, h, cv_ln_g, cv_ln_b, lnb);
    gemm(lnb, 512, cv_pw1_w, 512, cv_pw1_b, bigA, 1024, nullptr, 0, 0.f, MM, 1024, 512, 0, 0, 0);
    hipLaunchKernelGGL(glu_transpose_kernel, dim3(8,8,8), blk, 0, stream, bigA, dtb);
    hipLaunchKernelGGL(multiconv_t_kernel, dim3(BB*DD), blk, 0, stream, dtb,
                       cv_dw15, cv_dw31, cv_dw63, cv_bn_g, cv_bn_b, cv_bn_m, cv_bn_v, ysb);
    hipLaunchKernelGGL(transpose_bcl_kernel, dim3(8,8,8), blk, 0, stream, ysb, lnb);
    gemm(lnb, 512, cv_pw2_w, 512, cv_pw2_b, h, 512, h, 512, 1.0f, MM, 512, 512, 0, 0, 0);

    // ---- FFN2
    hipLaunchKernelGGL(ln_kernel, dim3(MM), dim3(128), 0, stream, h, ff2_ln_g, ff2_ln_b, lnb);
    gemm(lnb, 512, ff2_w1, 512, ff2_b1, bigA, 2048, nullptr, 0, 0.f, MM, 2048, 512, 1, 0, 0);
    gemm(bigA, 2048, ff2_w2, 2048, ff2_b2, h, 512, h, 512, 0.5f, MM, 512, 2048, 0, 0, 0);

    // ---- Final LN -> d_out
    hipLaunchKernelGGL(ln_kernel, dim3(MM), dim3(128), 0, stream, h, ln_g, ln_b, (float*)d_out);
}

// Round 3
// 1198.875 us; speedup vs baseline: 2.0526x; 1.5172x over previous
//
#include <hip/hip_runtime.h>
#include <hip/hip_bf16.h>
#include <math.h>

// Problem constants
#define LL   512
#define DD   512
#define DII  1024
#define NST  16
#define BB   8
#define MM   4096   // B*L tokens
#define CH   32     // scan chunk length

typedef __attribute__((ext_vector_type(8))) short bf16x8;
typedef __attribute__((ext_vector_type(4))) float f32x4;

__device__ __forceinline__ float sigmoidf_(float x){ return 1.0f/(1.0f+expf(-x)); }
__device__ __forceinline__ float siluf_(float x){ return x*sigmoidf_(x); }
__device__ __forceinline__ float softplusf_(float x){ return x > 20.0f ? x : log1pf(expf(x)); }

__device__ __forceinline__ short f2bf(float f) {         // fp32 -> bf16 RNE
    union { float f; unsigned u; } v; v.f = f;
    unsigned r = v.u + 0x7fffu + ((v.u >> 16) & 1u);
    return (short)(r >> 16);
}
__device__ __forceinline__ bf16x8 pack_bf8(float4 v0, float4 v1) {
    union { bf16x8 v; short e[8]; } pk;
    pk.e[0]=f2bf(v0.x); pk.e[1]=f2bf(v0.y); pk.e[2]=f2bf(v0.z); pk.e[3]=f2bf(v0.w);
    pk.e[4]=f2bf(v1.x); pk.e[5]=f2bf(v1.y); pk.e[6]=f2bf(v1.z); pk.e[7]=f2bf(v1.w);
    return pk.v;
}

// ---------------------------------------------------------------------------
// bf16 MFMA GEMM: C[M,N] = act(A[M,K] @ W[N,K]^T + bias) (+ resid, rev).
// Tile 128 x BN, BK=32, 256 threads = 4 waves. A/W staged fp32->bf16 into
// LDS rows padded to 40 shorts (80B stride -> 2-way bank alias, free).
// MFMA 16x16x32_bf16; C/D layout: col=lane&15, row=(lane>>4)*4+reg (m89).
// ---------------------------------------------------------------------------
template<int BN>
__global__ void __launch_bounds__(256) gemm_bf16_kernel(
    const float* __restrict__ A, int lda,
    const float* __restrict__ W, int ldw,
    const float* __restrict__ bias,
    float* __restrict__ C, int ldc,
    const float* __restrict__ resid, int ldr, float rscale,
    int Ktot, int act, int rev_in, int rev_out)
{
    constexpr int WN = BN / 64;        // waves along N (2 for BN=128, 1 for BN=64)
    constexpr int WM = 4 / WN;         // waves along M
    constexpr int TM = 128 / WM;       // wave tile M (64 or 32)
    constexpr int FM = TM / 16;        // M fragments per wave (4 or 2)

    __shared__ short As[128][40];
    __shared__ short Ws[BN][40];

    const int tid  = threadIdx.x;
    const int lane = tid & 63;
    const int w    = tid >> 6;
    const int rowBase = blockIdx.y << 7;
    const int colBase = blockIdx.x * BN;
    const int wm = (w / WN) * TM;
    const int wn = (w % WN) * 64;
    const int fr  = lane & 15;
    const int fkb = (lane >> 4) << 3;   // k elem offset 0,8,16,24

    f32x4 acc[FM][4] = {};

    for (int k0 = 0; k0 < Ktot; k0 += 32) {
        // stage A: 128x32 = 512 8-elem segments
        for (int s = tid; s < 512; s += 256) {
            int r = s >> 2, c8 = (s & 3) << 3;
            int arow = rowBase + r;
            if (rev_in) { int bb = arow >> 9, l = arow & (LL-1); arow = (bb<<9)+(LL-1-l); }
            const float* ap = A + (size_t)arow*lda + k0 + c8;
            float4 v0 = *(const float4*)ap;
            float4 v1 = *(const float4*)(ap + 4);
            *(bf16x8*)&As[r][c8] = pack_bf8(v0, v1);
        }
        // stage W: BNx32 = BN*4 segments
        for (int s = tid; s < BN*4; s += 256) {
            int r = s >> 2, c8 = (s & 3) << 3;
            const float* wp = W + (size_t)(colBase + r)*ldw + k0 + c8;
            float4 v0 = *(const float4*)wp;
            float4 v1 = *(const float4*)(wp + 4);
            *(bf16x8*)&Ws[r][c8] = pack_bf8(v0, v1);
        }
        __syncthreads();
        bf16x8 af[FM], bfr[4];
        #pragma unroll
        for (int mi = 0; mi < FM; mi++) af[mi]  = *(const bf16x8*)&As[wm + mi*16 + fr][fkb];
        #pragma unroll
        for (int ni = 0; ni < 4;  ni++) bfr[ni] = *(const bf16x8*)&Ws[wn + ni*16 + fr][fkb];
        #pragma unroll
        for (int mi = 0; mi < FM; mi++)
            #pragma unroll
            for (int ni = 0; ni < 4; ni++)
                acc[mi][ni] = __builtin_amdgcn_mfma_f32_16x16x32_bf16(af[mi], bfr[ni], acc[mi][ni], 0, 0, 0);
        __syncthreads();
    }

    #pragma unroll
    for (int mi = 0; mi < FM; mi++) {
        #pragma unroll
        for (int r = 0; r < 4; r++) {
            int orow = rowBase + wm + mi*16 + ((lane>>4)<<2) + r;
            if (rev_out) { int bb = orow >> 9, l = orow & (LL-1); orow = (bb<<9)+(LL-1-l); }
            #pragma unroll
            for (int ni = 0; ni < 4; ni++) {
                int gcol = colBase + wn + ni*16 + fr;
                float v = acc[mi][ni][r];
                if (bias) v += bias[gcol];
                if (act == 1) v = siluf_(v);
                else if (act == 2) v = softplusf_(v);
                if (resid) v = resid[(size_t)orow*ldr + gcol] + rscale*v;
                C[(size_t)orow*ldc + gcol] = v;
            }
        }
    }
}

// ---------------------------------------------------------------------------
// fp32 fallback GEMM (used only for the tiny N=64 xdb projection).
// ---------------------------------------------------------------------------
__global__ void __launch_bounds__(256) gemm_kernel(
    const float* __restrict__ A, int lda,
    const float* __restrict__ W, int ldw,
    const float* __restrict__ bias,
    float* __restrict__ C, int ldc,
    const float* __restrict__ resid, int ldr, float rscale,
    int Ktot, int act, int rev_in, int rev_out)
{
    __shared__ float As[16][64];
    __shared__ float Wsm[16][64];
    const int tid = threadIdx.x;
    const int tx = tid & 15, ty = tid >> 4;
    const int rowBase = blockIdx.y << 6;
    const int colBase = blockIdx.x << 6;
    const int lm = tid >> 2;
    const int kq = (tid & 3) << 2;

    int arow = rowBase + lm;
    if (rev_in) { int b = arow >> 9, l = arow & (LL-1); arow = (b << 9) + (LL-1-l); }
    const float* Aptr = A + (size_t)arow * lda + kq;
    const float* Wptr = W + (size_t)(colBase + lm) * ldw + kq;

    float acc[4][4] = {};
    for (int k0 = 0; k0 < Ktot; k0 += 16) {
        float4 av = *(const float4*)(Aptr + k0);
        float4 wv = *(const float4*)(Wptr + k0);
        As[kq+0][lm]=av.x; As[kq+1][lm]=av.y; As[kq+2][lm]=av.z; As[kq+3][lm]=av.w;
        Wsm[kq+0][lm]=wv.x; Wsm[kq+1][lm]=wv.y; Wsm[kq+2][lm]=wv.z; Wsm[kq+3][lm]=wv.w;
        __syncthreads();
        #pragma unroll
        for (int kk = 0; kk < 16; kk++) {
            float a[4], wv2[4];
            #pragma unroll
            for (int i = 0; i < 4; i++) a[i] = As[kk][(ty<<2)+i];
            #pragma unroll
            for (int j = 0; j < 4; j++) wv2[j] = Wsm[kk][(tx<<2)+j];
            #pragma unroll
            for (int i = 0; i < 4; i++)
                #pragma unroll
                for (int j = 0; j < 4; j++)
                    acc[i][j] += a[i]*wv2[j];
        }
        __syncthreads();
    }
    #pragma unroll
    for (int i = 0; i < 4; i++) {
        int orow = rowBase + (ty<<2) + i;
        if (rev_out) { int b = orow >> 9, l = orow & (LL-1); orow = (b << 9) + (LL-1-l); }
        #pragma unroll
        for (int j = 0; j < 4; j++) {
            int col = colBase + (tx<<2) + j;
            float v = acc[i][j];
            if (bias) v += bias[col];
            if (act == 1) v = siluf_(v);
            else if (act == 2) v = softplusf_(v);
            if (resid) v = resid[(size_t)orow*ldr + col] + rscale*v;
            C[(size_t)orow*ldc + col] = v;
        }
    }
}

// ---------------------------------------------------------------------------
// LayerNorm over last dim (512).
// ---------------------------------------------------------------------------
__global__ void __launch_bounds__(128) ln_kernel(
    const float* __restrict__ x, const float* __restrict__ g,
    const float* __restrict__ bta, float* __restrict__ out)
{
    const int row = blockIdx.x;
    const int t = threadIdx.x;
    float4 v = ((const float4*)(x + (size_t)row*DD))[t];
    float s = v.x+v.y+v.z+v.w;
    float q = v.x*v.x+v.y*v.y+v.z*v.z+v.w*v.w;
    #pragma unroll
    for (int off = 32; off >= 1; off >>= 1) {
        s += __shfl_down(s, off);
        q += __shfl_down(q, off);
    }
    __shared__ float sh[4];
    if ((t & 63) == 0) { sh[(t>>6)*2] = s; sh[(t>>6)*2+1] = q; }
    __syncthreads();
    float mean = (sh[0]+sh[2]) * (1.0f/DD);
    float var  = (sh[1]+sh[3]) * (1.0f/DD) - mean*mean;
    float rstd = rsqrtf(var + 1e-5f);
    float4 gg = ((const float4*)g)[t];
    float4 bb = ((const float4*)bta)[t];
    float4 o;
    o.x = (v.x-mean)*rstd*gg.x + bb.x;
    o.y = (v.y-mean)*rstd*gg.y + bb.y;
    o.z = (v.z-mean)*rstd*gg.z + bb.z;
    o.w = (v.w-mean)*rstd*gg.w + bb.w;
    ((float4*)(out + (size_t)row*DD))[t] = o;
}

// ---------------------------------------------------------------------------
// Mamba causal depthwise conv (K=4, pad left 3) + bias + SiLU.
// ---------------------------------------------------------------------------
__global__ void __launch_bounds__(256) mamba_conv_kernel(
    const float* __restrict__ xz, const float* __restrict__ cw,
    const float* __restrict__ cb, float* __restrict__ xc)
{
    const int idx = blockIdx.x*256 + threadIdx.x;
    const int c = idx & (DII-1);
    const int row = idx >> 10;
    const int l = row & (LL-1);
    float4 w = ((const float4*)cw)[c];
    const float* wf = (const float*)&w;
    float acc = cb[c];
    #pragma unroll
    for (int t = 0; t < 4; t++) {
        int ll = l - 3 + t;
        if (ll >= 0) acc += wf[t] * xz[((size_t)(row - l + ll))*2048 + c];
    }
    xc[idx] = siluf_(acc);
}

// ---------------------------------------------------------------------------
// Selective scan v2: chunked double-buffered LDS staging + fused ycombine.
// Block = 256 thr = 16 groups x 16 lanes; group j owns channel d0+j, lane = n.
// Per chunk (CH=32 l-steps): cooperative float4 loads of dt/xc/B/C into LDS,
// serial recurrence out of LDS, y written back fused with (+Dp*xc)*silu(z).
// ---------------------------------------------------------------------------
__global__ void __launch_bounds__(256) scan_kernel(
    const float* __restrict__ dt, const float* __restrict__ xc,
    const float* __restrict__ xdb, const float* __restrict__ Alog,
    const float* __restrict__ xz, const float* __restrict__ Dp,
    float* __restrict__ ys)
{
    __shared__ float s_dt[2][CH][16];
    __shared__ float s_xc[2][CH][16];
    __shared__ float s_bc[2][CH][32];
    __shared__ float s_y[CH][16];

    const int t   = threadIdx.x;
    const int gid0 = blockIdx.x << 4;
    const int b   = gid0 >> 10;
    const int d0  = gid0 & (DII-1);
    const int j   = t >> 4;           // group -> channel d0+j
    const int n   = t & 15;           // state index / write col
    const float Af  = -__expf(Alog[(d0 + j)*NST + n]);
    const float Dpv = Dp[d0 + n];

    // staging roles
    const int is_xc = (t >= 128);
    const int sl  = (t & 127) >> 2;   // 0..31
    const int sf  = (t & 3) << 2;     // 0,4,8,12
    const int bl  = t >> 3;           // 0..31
    const int bf4 = (t & 7) << 2;     // 0..28
    const int wl  = t >> 4;           // write row 0..15 (and +16)

    const float* dx_base = (is_xc ? xc : dt) + (size_t)b*LL*DII + d0 + sf;
    const float* bc_base = xdb + (size_t)b*LL*64 + 32 + bf4;
    const float* z_base  = xz  + (size_t)b*LL*2048 + DII + d0 + n;
    float*       ys_base = ys  + (size_t)b*LL*DII + d0 + n;

    const int NCH = LL / CH;
    float4 vdx, vbc; float rz0, rz1;
    // prologue: load + commit chunk 0
    vdx = *(const float4*)(dx_base + (size_t)(0*CH + sl)*DII);
    vbc = *(const float4*)(bc_base + (size_t)(0*CH + bl)*64);
    rz0 = z_base[(size_t)(0*CH + wl)*2048];
    rz1 = z_base[(size_t)(0*CH + wl + 16)*2048];
    if (is_xc) *(float4*)&s_xc[0][sl][sf] = vdx; else *(float4*)&s_dt[0][sl][sf] = vdx;
    *(float4*)&s_bc[0][bl][bf4] = vbc;
    __syncthreads();

    float hstate = 0.f;
    for (int c = 0; c < NCH; ++c) {
        const int p = c & 1;
        float4 nA, nB; float nz0 = 0.f, nz1 = 0.f;
        if (c + 1 < NCH) {
            nA  = *(const float4*)(dx_base + (size_t)((c+1)*CH + sl)*DII);
            nB  = *(const float4*)(bc_base + (size_t)((c+1)*CH + bl)*64);
            nz0 = z_base[(size_t)((c+1)*CH + wl)*2048];
            nz1 = z_base[(size_t)((c+1)*CH + wl + 16)*2048];
        }
        #pragma unroll 8
        for (int l = 0; l < CH; ++l) {
            float dtv = s_dt[p][l][j];
            float xcv = s_xc[p][l][j];
            float Bv  = s_bc[p][l][n];
            float Cv  = s_bc[p][l][16 + n];
            float dA  = __expf(dtv * Af);
            hstate = dA*hstate + (dtv*Bv)*xcv;
            float acc = hstate*Cv;
            acc += __shfl_xor(acc, 1);
            acc += __shfl_xor(acc, 2);
            acc += __shfl_xor(acc, 4);
            acc += __shfl_xor(acc, 8);
            if (n == 0) s_y[l][j] = acc;
        }
        __syncthreads();
        // fused output: y = (ys + Dp*xc) * silu(z)
        {
            float y0 = (s_y[wl][n]      + Dpv * s_xc[p][wl][n])      * siluf_(rz0);
            float y1 = (s_y[wl + 16][n] + Dpv * s_xc[p][wl + 16][n]) * siluf_(rz1);
            ys_base[(size_t)(c*CH + wl)*DII]      = y0;
            ys_base[(size_t)(c*CH + wl + 16)*DII] = y1;
        }
        if (c + 1 < NCH) {
            const int q = p ^ 1;
            if (is_xc) *(float4*)&s_xc[q][sl][sf] = nA; else *(float4*)&s_dt[q][sl][sf] = nA;
            *(float4*)&s_bc[q][bl][bf4] = nB;
            rz0 = nz0; rz1 = nz1;
        }
        __syncthreads();
    }
}

// ---------------------------------------------------------------------------
// GLU + transpose to [b, c, l].
// ---------------------------------------------------------------------------
__global__ void __launch_bounds__(256) glu_transpose_kernel(
    const float* __restrict__ pw1, float* __restrict__ out_t)
{
    __shared__ float sh[64][65];
    const int c0 = blockIdx.x << 6;
    const int l0 = blockIdx.y << 6;
    const int b  = blockIdx.z;
    const int t  = threadIdx.x;
    const int c4 = (t & 15) << 2;
    const int r  = t >> 4;
    #pragma unroll
    for (int i = 0; i < 4; i++) {
        int lrow = r + i*16;
        size_t row = (size_t)(b << 9) + l0 + lrow;
        float4 a = *(const float4*)(pw1 + row*1024 + c0 + c4);
        float4 g = *(const float4*)(pw1 + row*1024 + 512 + c0 + c4);
        sh[lrow][c4+0] = a.x * sigmoidf_(g.x);
        sh[lrow][c4+1] = a.y * sigmoidf_(g.y);
        sh[lrow][c4+2] = a.z * sigmoidf_(g.z);
        sh[lrow][c4+3] = a.w * sigmoidf_(g.w);
    }
    __syncthreads();
    #pragma unroll
    for (int i = 0; i < 4; i++) {
        int crow = r + i*16;
        float4 o;
        o.x = sh[c4+0][crow];
        o.y = sh[c4+1][crow];
        o.z = sh[c4+2][crow];
        o.w = sh[c4+3][crow];
        *(float4*)(out_t + ((size_t)(b << 9) + c0 + crow)*512 + l0 + c4) = o;
    }
}

// ---------------------------------------------------------------------------
// Channel-major fused 3x dwconv avg + BN + SiLU (weights via SGPR).
// ---------------------------------------------------------------------------
__global__ void __launch_bounds__(256) multiconv_t_kernel(
    const float* __restrict__ gin_t,
    const float* __restrict__ w15, const float* __restrict__ w31,
    const float* __restrict__ w63,
    const float* __restrict__ bn_g, const float* __restrict__ bn_b,
    const float* __restrict__ bn_m, const float* __restrict__ bn_v,
    float* __restrict__ out_t)
{
    __shared__ float sh[574];
    const int c = blockIdx.x & (DD-1);
    const int b = blockIdx.x >> 9;
    const int t = threadIdx.x;
    const float* rowp = gin_t + ((size_t)(b << 9) + c)*512;
    sh[31 + t]       = rowp[t];
    sh[31 + t + 256] = rowp[t + 256];
    if (t < 31) { sh[t] = 0.f; sh[543 + t] = 0.f; }
    __syncthreads();

    const float bnscale = rsqrtf(bn_v[c] + 1e-5f) * bn_g[c];
    const float bnm = bn_m[c], bnb = bn_b[c];
    float* outp = out_t + ((size_t)(b << 9) + c)*512;
    #pragma unroll
    for (int half = 0; half < 2; half++) {
        int l = t + half*256;
        float s63 = 0.f, s31 = 0.f, s15 = 0.f;
        #pragma unroll
        for (int k = 0; k < 63; k++) s63 += w63[c*63 + k] * sh[l + k];
        #pragma unroll
        for (int k = 0; k < 31; k++) s31 += w31[c*31 + k] * sh[l + 16 + k];
        #pragma unroll
        for (int k = 0; k < 15; k++) s15 += w15[c*15 + k] * sh[l + 24 + k];
        float m = (s15 + s31 + s63) * (1.0f/3.0f);
        m = (m - bnm) * bnscale + bnb;
        outp[l] = siluf_(m);
    }
}

// ---------------------------------------------------------------------------
// Transpose [b, c, l] -> [b, l, c].
// ---------------------------------------------------------------------------
__global__ void __launch_bounds__(256) transpose_bcl_kernel(
    const float* __restrict__ in_t, float* __restrict__ out)
{
    __shared__ float sh[64][65];
    const int l0 = blockIdx.x << 6;
    const int c0 = blockIdx.y << 6;
    const int b  = blockIdx.z;
    const int t  = threadIdx.x;
    const int l4 = (t & 15) << 2;
    const int r  = t >> 4;
    #pragma unroll
    for (int i = 0; i < 4; i++) {
        int crow = r + i*16;
        float4 v = *(const float4*)(in_t + ((size_t)(b << 9) + c0 + crow)*512 + l0 + l4);
        sh[crow][l4+0] = v.x; sh[crow][l4+1] = v.y;
        sh[crow][l4+2] = v.z; sh[crow][l4+3] = v.w;
    }
    __syncthreads();
    #pragma unroll
    for (int i = 0; i < 4; i++) {
        int lrow = r + i*16;
        float4 o;
        o.x = sh[l4+0][lrow];
        o.y = sh[l4+1][lrow];
        o.z = sh[l4+2][lrow];
        o.w = sh[l4+3][lrow];
        *(float4*)(out + ((size_t)(b << 9) + l0 + lrow)*512 + c0 + l4) = o;
    }
}

// ---------------------------------------------------------------------------
extern "C" void kernel_launch(void* const* d_in, const int* in_sizes, int n_in,
                              void* d_out, int out_size, void* d_ws, size_t ws_size,
                              hipStream_t stream)
{
    const float* x        = (const float*)d_in[0];
    const float* ff1_ln_g = (const float*)d_in[1];
    const float* ff1_ln_b = (const float*)d_in[2];
    const float* ff1_w1   = (const float*)d_in[3];
    const float* ff1_b1   = (const float*)d_in[4];
    const float* ff1_w2   = (const float*)d_in[5];
    const float* ff1_b2   = (const float*)d_in[6];
    const float* ff2_ln_g = (const float*)d_in[7];
    const float* ff2_ln_b = (const float*)d_in[8];
    const float* ff2_w1   = (const float*)d_in[9];
    const float* ff2_b1   = (const float*)d_in[10];
    const float* ff2_w2   = (const float*)d_in[11];
    const float* ff2_b2   = (const float*)d_in[12];
    const float* m_win    = (const float*)d_in[13];
    const float* m_convw  = (const float*)d_in[14];
    const float* m_convb  = (const float*)d_in[15];
    const float* m_wx     = (const float*)d_in[16];
    const float* m_wdt    = (const float*)d_in[17];
    const float* m_bdt    = (const float*)d_in[18];
    const float* m_Alog   = (const float*)d_in[19];
    const float* m_Dp     = (const float*)d_in[20];
    const float* m_wout   = (const float*)d_in[21];
    const float* bi_wo    = (const float*)d_in[22];
    const float* bi_bo    = (const float*)d_in[23];
    const float* cv_ln_g  = (const float*)d_in[24];
    const float* cv_ln_b  = (const float*)d_in[25];
    const float* cv_pw1_w = (const float*)d_in[26];
    const float* cv_pw1_b = (const float*)d_in[27];
    const float* cv_dw15  = (const float*)d_in[28];
    const float* cv_dw31  = (const float*)d_in[29];
    const float* cv_dw63  = (const float*)d_in[30];
    const float* cv_bn_g  = (const float*)d_in[31];
    const float* cv_bn_b  = (const float*)d_in[32];
    const float* cv_bn_m  = (const float*)d_in[33];
    const float* cv_bn_v  = (const float*)d_in[34];
    const float* cv_pw2_w = (const float*)d_in[35];
    const float* cv_pw2_b = (const float*)d_in[36];
    const float* ln_g     = (const float*)d_in[37];
    const float* ln_b     = (const float*)d_in[38];

    float* ws   = (float*)d_ws;
    float* h    = ws;                              // [MM*512]
    float* lnb  = h    + (size_t)MM*DD;            // [MM*512]
    float* bigA = lnb  + (size_t)MM*DD;            // [MM*2048]
    float* xcb  = bigA + (size_t)MM*2048;          // [MM*1024]
    float* dtb  = xcb  + (size_t)MM*DII;           // [MM*1024]
    float* ysb  = dtb  + (size_t)MM*DII;           // [MM*1024]
    float* xdbb = ysb  + (size_t)MM*DII;           // [MM*64]
    float* catb = xdbb + (size_t)MM*64;            // [MM*1024]
    size_t need = ((size_t)(catb + (size_t)MM*DII - ws)) * sizeof(float);
    if (ws_size < need) return;

    dim3 blk(256);
    auto gemm = [&](const float* A, int lda, const float* W, int ldw,
                    const float* bias, float* C, int ldc,
                    const float* res, int ldr, float rs,
                    int M, int N, int K, int act, int ri, int ro) {
        if (N >= 1024 && (N & 127) == 0 && (K & 31) == 0) {
            dim3 g(N/128, M/128);
            gemm_bf16_kernel<128><<<g, blk, 0, stream>>>(A, lda, W, ldw, bias, C, ldc, res, ldr, rs, K, act, ri, ro);
        } else if (N == 512 && (K & 31) == 0) {
            dim3 g(N/64, M/128);
            gemm_bf16_kernel<64><<<g, blk, 0, stream>>>(A, lda, W, ldw, bias, C, ldc, res, ldr, rs, K, act, ri, ro);
        } else {
            dim3 g(N/64, M/64);
            gemm_kernel<<<g, blk, 0, stream>>>(A, lda, W, ldw, bias, C, ldc, res, ldr, rs, K, act, ri, ro);
        }
    };

    // ---- FFN1
    hipLaunchKernelGGL(ln_kernel, dim3(MM), dim3(128), 0, stream, x, ff1_ln_g, ff1_ln_b, lnb);
    gemm(lnb, 512, ff1_w1, 512, ff1_b1, bigA, 2048, nullptr, 0, 0.f, MM, 2048, 512, 1, 0, 0);
    gemm(bigA, 2048, ff1_w2, 2048, ff1_b2, h, 512, x, 512, 0.5f, MM, 512, 2048, 0, 0, 0);

    // ---- BiMamba
    for (int dir = 0; dir < 2; dir++) {
        const float* win   = m_win   + (size_t)dir*2048*512;
        const float* convw = m_convw + (size_t)dir*DII*4;
        const float* convb = m_convb + (size_t)dir*DII;
        const float* wx    = m_wx    + (size_t)dir*64*DII;
        const float* wdt   = m_wdt   + (size_t)dir*DII*32;
        const float* bdt   = m_bdt   + (size_t)dir*DII;
        const float* Alog  = m_Alog  + (size_t)dir*DII*NST;
        const float* Dp    = m_Dp    + (size_t)dir*DII;
        const float* wout  = m_wout  + (size_t)dir*DD*DII;

        gemm(h, 512, win, 512, nullptr, bigA, 2048, nullptr, 0, 0.f, MM, 2048, 512, 0, dir, 0);
        hipLaunchKernelGGL(mamba_conv_kernel, dim3(MM*DII/256), blk, 0, stream, bigA, convw, convb, xcb);
        gemm(xcb, DII, wx, DII, nullptr, xdbb, 64, nullptr, 0, 0.f, MM, 64, DII, 0, 0, 0);
        gemm(xdbb, 64, wdt, 32, bdt, dtb, DII, nullptr, 0, 0.f, MM, DII, 32, 2, 0, 0);
        hipLaunchKernelGGL(scan_kernel, dim3(BB*DII/16), blk, 0, stream, dtb, xcb, xdbb, Alog, bigA, Dp, ysb);
        gemm(ysb, DII, wout, DII, nullptr, catb + dir*DD, 2*DD, nullptr, 0, 0.f, MM, DD, DII, 0, 0, dir);
    }
    gemm(catb, 1024, bi_wo, 1024, bi_bo, h, 512, h, 512, 1.0f, MM, 512, 1024, 0, 0, 0);

    // ---- ConvMod
    hipLaunchKernelGGL(ln_kernel, dim3(MM), dim3(128), 0, stream, h, cv_ln_g, cv_ln_b, lnb);
    gemm(lnb, 512, cv_pw1_w, 512, cv_pw1_b, bigA, 1024, nullptr, 0, 0.f, MM, 1024, 512, 0, 0, 0);
    hipLaunchKernelGGL(glu_transpose_kernel, dim3(8,8,8), blk, 0, stream, bigA, dtb);
    hipLaunchKernelGGL(multiconv_t_kernel, dim3(BB*DD), blk, 0, stream, dtb,
                       cv_dw15, cv_dw31, cv_dw63, cv_bn_g, cv_bn_b, cv_bn_m, cv_bn_v, ysb);
    hipLaunchKernelGGL(transpose_bcl_kernel, dim3(8,8,8), blk, 0, stream, ysb, lnb);
    gemm(lnb, 512, cv_pw2_w, 512, cv_pw2_b, h, 512, h, 512, 1.0f, MM, 512, 512, 0, 0, 0);

    // ---- FFN2
    hipLaunchKernelGGL(ln_kernel, dim3(MM), dim3(128), 0, stream, h, ff2_ln_g, ff2_ln_b, lnb);
    gemm(lnb, 512, ff2_w1, 512, ff2_b1, bigA, 2048, nullptr, 0, 0.f, MM, 2048, 512, 1, 0, 0);
    gemm(bigA, 2048, ff2_w2, 2048, ff2_b2, h, 512, h, 512, 0.5f, MM, 512, 2048, 0, 0, 0);

    // ---- Final LN -> d_out
    hipLaunchKernelGGL(ln_kernel, dim3(MM), dim3(128), 0, stream, h, ln_g, ln_b, (float*)d_out);
}

// Round 4
// 785.336 us; speedup vs baseline: 3.1334x; 1.5266x over previous
//
#include <hip/hip_runtime.h>
#include <hip/hip_bf16.h>
#include <math.h>

#define LL   512
#define DD   512
#define DII  1024
#define NST  16
#define BB   8
#define MM   4096
#define CH   32
#define MB_  (1024*1024)

typedef __attribute__((ext_vector_type(8))) short bf16x8;
typedef __attribute__((ext_vector_type(4))) float f32x4;

__device__ __forceinline__ float sigmoidf_(float x){ return 1.0f/(1.0f+expf(-x)); }
__device__ __forceinline__ float siluf_(float x){ return x*sigmoidf_(x); }
__device__ __forceinline__ float softplusf_(float x){ return x > 20.0f ? x : log1pf(expf(x)); }

__device__ __forceinline__ short f2bf(float f) {
    union { float f; unsigned u; } v; v.f = f;
    unsigned r = v.u + 0x7fffu + ((v.u >> 16) & 1u);
    return (short)(r >> 16);
}
__device__ __forceinline__ float bf2f(short s) {
    union { unsigned u; float f; } v; v.u = ((unsigned)(unsigned short)s) << 16;
    return v.f;
}
__device__ __forceinline__ bf16x8 pack_bf8(float4 v0, float4 v1) {
    union { bf16x8 v; short e[8]; } pk;
    pk.e[0]=f2bf(v0.x); pk.e[1]=f2bf(v0.y); pk.e[2]=f2bf(v0.z); pk.e[3]=f2bf(v0.w);
    pk.e[4]=f2bf(v1.x); pk.e[5]=f2bf(v1.y); pk.e[6]=f2bf(v1.z); pk.e[7]=f2bf(v1.w);
    return pk.v;
}
__device__ __forceinline__ void gl_lds16(const short* g, short* l) {
    __builtin_amdgcn_global_load_lds(
        (const __attribute__((address_space(1))) void*)g,
        (__attribute__((address_space(3))) void*)l, 16, 0, 0);
}

// ---------------------------------------------------------------------------
// Batched fp32 -> bf16 weight conversion (one launch, 10 segments).
// ---------------------------------------------------------------------------
struct WcvtArgs { const float* s[10]; short* d[10]; int n[10]; };
__global__ void __launch_bounds__(256) wcvt_kernel(WcvtArgs a) {
    const int seg = blockIdx.y;
    const int i = (blockIdx.x*256 + threadIdx.x) * 8;
    if (i >= a.n[seg]) return;
    const float* s = a.s[seg] + i;
    float4 v0 = *(const float4*)s;
    float4 v1 = *(const float4*)(s + 4);
    *(bf16x8*)(a.d[seg] + i) = pack_bf8(v0, v1);
}

// ---------------------------------------------------------------------------
// bf16 GEMM v3 (m97 structure): C = A[M,K]bf16 @ W[N,K]^T bf16.
// 128 x BN tile, BK=32, 256 thr = 4 waves, global_load_lds(16B) staging into
// linear LDS, mfma_f32_16x16x32_bf16. Split-K via gridDim.z -> fp32 partials
// (epilogue then in reduce_kernel); else fused epilogue with fp32/bf16 out.
// ---------------------------------------------------------------------------
template<int BN>
__global__ void __launch_bounds__(256) gemm3_kernel(
    const short* __restrict__ A, int lda,
    const short* __restrict__ W, int ldw,
    const float* __restrict__ bias,
    float* __restrict__ outF, short* __restrict__ outB, int ldc,
    const float* __restrict__ resid, int ldr, float rscale,
    int kLen, int act, int rev_in,
    float* __restrict__ partial, size_t pstride, int N)
{
    constexpr int WN = BN / 64;          // 2 (BN=128) or 1 (BN=64)
    constexpr int WM = 4 / WN;
    constexpr int TM = 128 / WM;         // 64 or 32
    constexpr int FM = TM / 16;          // 4 or 2
    constexpr int WRND = BN / 64;        // W staging rounds

    __shared__ short As[128*32];
    __shared__ short Ws[BN*32];

    const int tid = threadIdx.x, lane = tid & 63, wid = tid >> 6;
    const int rowBase = blockIdx.y << 7;
    const int colBase = blockIdx.x * BN;
    const int kBase = blockIdx.z * kLen;

    int arow[2], ac8[2];
    #pragma unroll
    for (int r = 0; r < 2; r++) {
        int u = (r*4 + wid)*64 + lane;
        int rr = rowBase + (u >> 2);
        if (rev_in) { int bb = rr >> 9, l = rr & 511; rr = (bb << 9) + (511 - l); }
        arow[r] = rr; ac8[r] = (u & 3) << 3;
    }
    int wrow[WRND], wc8[WRND];
    #pragma unroll
    for (int r = 0; r < WRND; r++) {
        int u = (r*4 + wid)*64 + lane;
        wrow[r] = colBase + (u >> 2); wc8[r] = (u & 3) << 3;
    }
    const int fr = lane & 15, fkb = (lane >> 4) << 3;
    const int wm = (wid / WN) * TM, wn = (wid % WN) * 64;

    f32x4 acc[FM][4] = {};

    for (int k0 = kBase; k0 < kBase + kLen; k0 += 32) {
        #pragma unroll
        for (int r = 0; r < 2; r++)
            gl_lds16(A + (size_t)arow[r]*lda + k0 + ac8[r], As + (r*4 + wid)*512);
        #pragma unroll
        for (int r = 0; r < WRND; r++)
            gl_lds16(W + (size_t)wrow[r]*ldw + k0 + wc8[r], Ws + (r*4 + wid)*512);
        __syncthreads();
        bf16x8 af[FM], bfr[4];
        #pragma unroll
        for (int mi = 0; mi < FM; mi++) af[mi]  = *(const bf16x8*)&As[(wm + mi*16 + fr)*32 + fkb];
        #pragma unroll
        for (int ni = 0; ni < 4;  ni++) bfr[ni] = *(const bf16x8*)&Ws[(wn + ni*16 + fr)*32 + fkb];
        #pragma unroll
        for (int mi = 0; mi < FM; mi++)
            #pragma unroll
            for (int ni = 0; ni < 4; ni++)
                acc[mi][ni] = __builtin_amdgcn_mfma_f32_16x16x32_bf16(af[mi], bfr[ni], acc[mi][ni], 0, 0, 0);
        __syncthreads();
    }

    if (partial) {
        float* pp = partial + (size_t)blockIdx.z * pstride;
        #pragma unroll
        for (int mi = 0; mi < FM; mi++)
            #pragma unroll
            for (int r = 0; r < 4; r++) {
                int orow = rowBase + wm + mi*16 + ((lane>>4)<<2) + r;
                #pragma unroll
                for (int ni = 0; ni < 4; ni++)
                    pp[(size_t)orow*N + colBase + wn + ni*16 + fr] = acc[mi][ni][r];
            }
    } else {
        #pragma unroll
        for (int mi = 0; mi < FM; mi++)
            #pragma unroll
            for (int r = 0; r < 4; r++) {
                int orow = rowBase + wm + mi*16 + ((lane>>4)<<2) + r;
                #pragma unroll
                for (int ni = 0; ni < 4; ni++) {
                    int gcol = colBase + wn + ni*16 + fr;
                    float v = acc[mi][ni][r];
                    if (bias) v += bias[gcol];
                    if (act == 1) v = siluf_(v);
                    else if (act == 2) v = softplusf_(v);
                    if (resid) v = resid[(size_t)orow*ldr + gcol] + rscale*v;
                    if (outF) outF[(size_t)orow*ldc + gcol] = v;
                    if (outB) outB[(size_t)orow*ldc + gcol] = f2bf(v);
                }
            }
    }
}

// ---------------------------------------------------------------------------
// Split-K reduce + epilogue: sum S partials, bias/act/resid/rev, f32/bf16 out.
// ---------------------------------------------------------------------------
__global__ void __launch_bounds__(256) reduce_kernel(
    const float* __restrict__ part, int S, size_t pstride, int N,
    const float* __restrict__ bias, int act,
    const float* __restrict__ resid, int ldr, float rscale,
    float* __restrict__ outF, short* __restrict__ outB, int ldc,
    int colOff, int rev_out)
{
    const int i4 = blockIdx.x*256 + threadIdx.x;
    const int row = i4 / (N >> 2);
    const int c4  = (i4 - row*(N >> 2)) << 2;
    float4 s = *(const float4*)(part + (size_t)row*N + c4);
    for (int z = 1; z < S; z++) {
        float4 t = *(const float4*)(part + (size_t)z*pstride + (size_t)row*N + c4);
        s.x += t.x; s.y += t.y; s.z += t.z; s.w += t.w;
    }
    if (bias) { float4 b = *(const float4*)(bias + c4); s.x+=b.x; s.y+=b.y; s.z+=b.z; s.w+=b.w; }
    if (act == 1) { s.x=siluf_(s.x); s.y=siluf_(s.y); s.z=siluf_(s.z); s.w=siluf_(s.w); }
    else if (act == 2) { s.x=softplusf_(s.x); s.y=softplusf_(s.y); s.z=softplusf_(s.z); s.w=softplusf_(s.w); }
    int orow = row;
    if (rev_out) { int b = row >> 9, l = row & 511; orow = (b << 9) + (511 - l); }
    if (resid) {
        float4 rr = *(const float4*)(resid + (size_t)orow*ldr + colOff + c4);
        s.x = rr.x + rscale*s.x; s.y = rr.y + rscale*s.y;
        s.z = rr.z + rscale*s.z; s.w = rr.w + rscale*s.w;
    }
    if (outF) *(float4*)(outF + (size_t)orow*ldc + colOff + c4) = s;
    if (outB) {
        short4 o; o.x=f2bf(s.x); o.y=f2bf(s.y); o.z=f2bf(s.z); o.w=f2bf(s.w);
        *(short4*)(outB + (size_t)orow*ldc + colOff + c4) = o;
    }
}

// ---------------------------------------------------------------------------
// fp32 fallback GEMM (only the K=32 dt projection).
// ---------------------------------------------------------------------------
__global__ void __launch_bounds__(256) gemm_kernel(
    const float* __restrict__ A, int lda,
    const float* __restrict__ W, int ldw,
    const float* __restrict__ bias,
    float* __restrict__ C, int ldc,
    int Ktot, int act)
{
    __shared__ float As[16][64];
    __shared__ float Wsm[16][64];
    const int tid = threadIdx.x;
    const int tx = tid & 15, ty = tid >> 4;
    const int rowBase = blockIdx.y << 6;
    const int colBase = blockIdx.x << 6;
    const int lm = tid >> 2;
    const int kq = (tid & 3) << 2;

    const float* Aptr = A + (size_t)(rowBase + lm)*lda + kq;
    const float* Wptr = W + (size_t)(colBase + lm)*ldw + kq;

    float acc[4][4] = {};
    for (int k0 = 0; k0 < Ktot; k0 += 16) {
        float4 av = *(const float4*)(Aptr + k0);
        float4 wv = *(const float4*)(Wptr + k0);
        As[kq+0][lm]=av.x; As[kq+1][lm]=av.y; As[kq+2][lm]=av.z; As[kq+3][lm]=av.w;
        Wsm[kq+0][lm]=wv.x; Wsm[kq+1][lm]=wv.y; Wsm[kq+2][lm]=wv.z; Wsm[kq+3][lm]=wv.w;
        __syncthreads();
        #pragma unroll
        for (int kk = 0; kk < 16; kk++) {
            float a[4], w2[4];
            #pragma unroll
            for (int i = 0; i < 4; i++) a[i] = As[kk][(ty<<2)+i];
            #pragma unroll
            for (int j = 0; j < 4; j++) w2[j] = Wsm[kk][(tx<<2)+j];
            #pragma unroll
            for (int i = 0; i < 4; i++)
                #pragma unroll
                for (int j = 0; j < 4; j++)
                    acc[i][j] += a[i]*w2[j];
        }
        __syncthreads();
    }
    #pragma unroll
    for (int i = 0; i < 4; i++) {
        int orow = rowBase + (ty<<2) + i;
        #pragma unroll
        for (int j = 0; j < 4; j++) {
            int col = colBase + (tx<<2) + j;
            float v = acc[i][j];
            if (bias) v += bias[col];
            if (act == 2) v = softplusf_(v);
            C[(size_t)orow*ldc + col] = v;
        }
    }
}

// ---------------------------------------------------------------------------
// LayerNorm over 512; writes fp32 and/or bf16.
// ---------------------------------------------------------------------------
__global__ void __launch_bounds__(128) ln_kernel(
    const float* __restrict__ x, const float* __restrict__ g,
    const float* __restrict__ bta, float* __restrict__ outF,
    short* __restrict__ outB)
{
    const int row = blockIdx.x;
    const int t = threadIdx.x;
    float4 v = ((const float4*)(x + (size_t)row*DD))[t];
    float s = v.x+v.y+v.z+v.w;
    float q = v.x*v.x+v.y*v.y+v.z*v.z+v.w*v.w;
    #pragma unroll
    for (int off = 32; off >= 1; off >>= 1) {
        s += __shfl_down(s, off);
        q += __shfl_down(q, off);
    }
    __shared__ float sh[4];
    if ((t & 63) == 0) { sh[(t>>6)*2] = s; sh[(t>>6)*2+1] = q; }
    __syncthreads();
    float mean = (sh[0]+sh[2]) * (1.0f/DD);
    float var  = (sh[1]+sh[3]) * (1.0f/DD) - mean*mean;
    float rstd = rsqrtf(var + 1e-5f);
    float4 gg = ((const float4*)g)[t];
    float4 bb = ((const float4*)bta)[t];
    float4 o;
    o.x = (v.x-mean)*rstd*gg.x + bb.x;
    o.y = (v.y-mean)*rstd*gg.y + bb.y;
    o.z = (v.z-mean)*rstd*gg.z + bb.z;
    o.w = (v.w-mean)*rstd*gg.w + bb.w;
    if (outF) ((float4*)(outF + (size_t)row*DD))[t] = o;
    if (outB) {
        short4 ob; ob.x=f2bf(o.x); ob.y=f2bf(o.y); ob.z=f2bf(o.z); ob.w=f2bf(o.w);
        *(short4*)(outB + (size_t)row*DD + t*4) = ob;
    }
}

// ---------------------------------------------------------------------------
// Mamba causal dwconv (K=4) + bias + SiLU; xi layout [MM][1024].
// Writes fp32 (scan) + bf16 (wx GEMM).
// ---------------------------------------------------------------------------
__global__ void __launch_bounds__(256) mamba_conv_kernel(
    const float* __restrict__ xi, const float* __restrict__ cw,
    const float* __restrict__ cb, float* __restrict__ xc,
    short* __restrict__ xcb16)
{
    const int idx = blockIdx.x*256 + threadIdx.x;
    const int c = idx & (DII-1);
    const int row = idx >> 10;
    const int l = row & (LL-1);
    float4 w = ((const float4*)cw)[c];
    const float* wf = (const float*)&w;
    float acc = cb[c];
    #pragma unroll
    for (int t = 0; t < 4; t++) {
        int ll = l - 3 + t;
        if (ll >= 0) acc += wf[t] * xi[((size_t)(row - l + ll))*DII + c];
    }
    float v = siluf_(acc);
    xc[idx] = v;
    xcb16[idx] = f2bf(v);
}

// ---------------------------------------------------------------------------
// Selective scan (chunked dbuf LDS) + fused ycombine. z bf16 in, ys bf16 out.
// ---------------------------------------------------------------------------
__global__ void __launch_bounds__(256) scan_kernel(
    const float* __restrict__ dt, const float* __restrict__ xc,
    const float* __restrict__ xdb, const float* __restrict__ Alog,
    const short* __restrict__ zb, const float* __restrict__ Dp,
    short* __restrict__ ys)
{
    __shared__ float s_dt[2][CH][16];
    __shared__ float s_xc[2][CH][16];
    __shared__ float s_bc[2][CH][32];
    __shared__ float s_y[CH][16];

    const int t   = threadIdx.x;
    const int gid0 = blockIdx.x << 4;
    const int b   = gid0 >> 10;
    const int d0  = gid0 & (DII-1);
    const int j   = t >> 4;
    const int n   = t & 15;
    const float Af  = -__expf(Alog[(d0 + j)*NST + n]);
    const float Dpv = Dp[d0 + n];

    const int is_xc = (t >= 128);
    const int sl  = (t & 127) >> 2;
    const int sf  = (t & 3) << 2;
    const int bl  = t >> 3;
    const int bf4 = (t & 7) << 2;
    const int wl  = t >> 4;

    const float* dx_base = (is_xc ? xc : dt) + (size_t)b*LL*DII + d0 + sf;
    const float* bc_base = xdb + (size_t)b*LL*64 + 32 + bf4;
    const short* z_base  = zb  + (size_t)b*LL*DII + d0 + n;
    short*       ys_base = ys  + (size_t)b*LL*DII + d0 + n;

    const int NCH = LL / CH;
    float4 vdx, vbc; float rz0, rz1;
    vdx = *(const float4*)(dx_base + (size_t)(0*CH + sl)*DII);
    vbc = *(const float4*)(bc_base + (size_t)(0*CH + bl)*64);
    rz0 = bf2f(z_base[(size_t)(0*CH + wl)*DII]);
    rz1 = bf2f(z_base[(size_t)(0*CH + wl + 16)*DII]);
    if (is_xc) *(float4*)&s_xc[0][sl][sf] = vdx; else *(float4*)&s_dt[0][sl][sf] = vdx;
    *(float4*)&s_bc[0][bl][bf4] = vbc;
    __syncthreads();

    float hstate = 0.f;
    for (int c = 0; c < NCH; ++c) {
        const int p = c & 1;
        float4 nA, nB; float nz0 = 0.f, nz1 = 0.f;
        if (c + 1 < NCH) {
            nA  = *(const float4*)(dx_base + (size_t)((c+1)*CH + sl)*DII);
            nB  = *(const float4*)(bc_base + (size_t)((c+1)*CH + bl)*64);
            nz0 = bf2f(z_base[(size_t)((c+1)*CH + wl)*DII]);
            nz1 = bf2f(z_base[(size_t)((c+1)*CH + wl + 16)*DII]);
        }
        #pragma unroll 8
        for (int l = 0; l < CH; ++l) {
            float dtv = s_dt[p][l][j];
            float xcv = s_xc[p][l][j];
            float Bv  = s_bc[p][l][n];
            float Cv  = s_bc[p][l][16 + n];
            float dA  = __expf(dtv * Af);
            hstate = dA*hstate + (dtv*Bv)*xcv;
            float acc = hstate*Cv;
            acc += __shfl_xor(acc, 1);
            acc += __shfl_xor(acc, 2);
            acc += __shfl_xor(acc, 4);
            acc += __shfl_xor(acc, 8);
            if (n == 0) s_y[l][j] = acc;
        }
        __syncthreads();
        {
            float y0 = (s_y[wl][n]      + Dpv * s_xc[p][wl][n])      * siluf_(rz0);
            float y1 = (s_y[wl + 16][n] + Dpv * s_xc[p][wl + 16][n]) * siluf_(rz1);
            ys_base[(size_t)(c*CH + wl)*DII]      = f2bf(y0);
            ys_base[(size_t)(c*CH + wl + 16)*DII] = f2bf(y1);
        }
        if (c + 1 < NCH) {
            const int q = p ^ 1;
            if (is_xc) *(float4*)&s_xc[q][sl][sf] = nA; else *(float4*)&s_dt[q][sl][sf] = nA;
            *(float4*)&s_bc[q][bl][bf4] = nB;
            rz0 = nz0; rz1 = nz1;
        }
        __syncthreads();
    }
}

// ---------------------------------------------------------------------------
// GLU + transpose to [b, c, l] fp32.
// ---------------------------------------------------------------------------
__global__ void __launch_bounds__(256) glu_transpose_kernel(
    const float* __restrict__ pw1, float* __restrict__ out_t)
{
    __shared__ float sh[64][65];
    const int c0 = blockIdx.x << 6;
    const int l0 = blockIdx.y << 6;
    const int b  = blockIdx.z;
    const int t  = threadIdx.x;
    const int c4 = (t & 15) << 2;
    const int r  = t >> 4;
    #pragma unroll
    for (int i = 0; i < 4; i++) {
        int lrow = r + i*16;
        size_t row = (size_t)(b << 9) + l0 + lrow;
        float4 a = *(const float4*)(pw1 + row*1024 + c0 + c4);
        float4 g = *(const float4*)(pw1 + row*1024 + 512 + c0 + c4);
        sh[lrow][c4+0] = a.x * sigmoidf_(g.x);
        sh[lrow][c4+1] = a.y * sigmoidf_(g.y);
        sh[lrow][c4+2] = a.z * sigmoidf_(g.z);
        sh[lrow][c4+3] = a.w * sigmoidf_(g.w);
    }
    __syncthreads();
    #pragma unroll
    for (int i = 0; i < 4; i++) {
        int crow = r + i*16;
        float4 o;
        o.x = sh[c4+0][crow];
        o.y = sh[c4+1][crow];
        o.z = sh[c4+2][crow];
        o.w = sh[c4+3][crow];
        *(float4*)(out_t + ((size_t)(b << 9) + c0 + crow)*512 + l0 + c4) = o;
    }
}

// ---------------------------------------------------------------------------
// Channel-major fused 3x dwconv avg + BN + SiLU (SGPR weights).
// ---------------------------------------------------------------------------
__global__ void __launch_bounds__(256) multiconv_t_kernel(
    const float* __restrict__ gin_t,
    const float* __restrict__ w15, const float* __restrict__ w31,
    const float* __restrict__ w63,
    const float* __restrict__ bn_g, const float* __restrict__ bn_b,
    const float* __restrict__ bn_m, const float* __restrict__ bn_v,
    float* __restrict__ out_t)
{
    __shared__ float sh[574];
    const int c = blockIdx.x & (DD-1);
    const int b = blockIdx.x >> 9;
    const int t = threadIdx.x;
    const float* rowp = gin_t + ((size_t)(b << 9) + c)*512;
    sh[31 + t]       = rowp[t];
    sh[31 + t + 256] = rowp[t + 256];
    if (t < 31) { sh[t] = 0.f; sh[543 + t] = 0.f; }
    __syncthreads();

    const float bnscale = rsqrtf(bn_v[c] + 1e-5f) * bn_g[c];
    const float bnm = bn_m[c], bnb = bn_b[c];
    float* outp = out_t + ((size_t)(b << 9) + c)*512;
    #pragma unroll
    for (int half = 0; half < 2; half++) {
        int l = t + half*256;
        float s63 = 0.f, s31 = 0.f, s15 = 0.f;
        #pragma unroll
        for (int k = 0; k < 63; k++) s63 += w63[c*63 + k] * sh[l + k];
        #pragma unroll
        for (int k = 0; k < 31; k++) s31 += w31[c*31 + k] * sh[l + 16 + k];
        #pragma unroll
        for (int k = 0; k < 15; k++) s15 += w15[c*15 + k] * sh[l + 24 + k];
        float m = (s15 + s31 + s63) * (1.0f/3.0f);
        m = (m - bnm) * bnscale + bnb;
        outp[l] = siluf_(m);
    }
}

// ---------------------------------------------------------------------------
// Transpose [b, c, l] -> [b, l, c], bf16 out (feeds pw2 GEMM).
// ---------------------------------------------------------------------------
__global__ void __launch_bounds__(256) transpose_bcl_kernel(
    const float* __restrict__ in_t, short* __restrict__ out)
{
    __shared__ float sh[64][65];
    const int l0 = blockIdx.x << 6;
    const int c0 = blockIdx.y << 6;
    const int b  = blockIdx.z;
    const int t  = threadIdx.x;
    const int l4 = (t & 15) << 2;
    const int r  = t >> 4;
    #pragma unroll
    for (int i = 0; i < 4; i++) {
        int crow = r + i*16;
        float4 v = *(const float4*)(in_t + ((size_t)(b << 9) + c0 + crow)*512 + l0 + l4);
        sh[crow][l4+0] = v.x; sh[crow][l4+1] = v.y;
        sh[crow][l4+2] = v.z; sh[crow][l4+3] = v.w;
    }
    __syncthreads();
    #pragma unroll
    for (int i = 0; i < 4; i++) {
        int lrow = r + i*16;
        short4 o;
        o.x = f2bf(sh[l4+0][lrow]);
        o.y = f2bf(sh[l4+1][lrow]);
        o.z = f2bf(sh[l4+2][lrow]);
        o.w = f2bf(sh[l4+3][lrow]);
        *(short4*)(out + ((size_t)(b << 9) + l0 + lrow)*512 + c0 + l4) = o;
    }
}

// ---------------------------------------------------------------------------
extern "C" void kernel_launch(void* const* d_in, const int* in_sizes, int n_in,
                              void* d_out, int out_size, void* d_ws, size_t ws_size,
                              hipStream_t stream)
{
    const float* x        = (const float*)d_in[0];
    const float* ff1_ln_g = (const float*)d_in[1];
    const float* ff1_ln_b = (const float*)d_in[2];
    const float* ff1_w1   = (const float*)d_in[3];
    const float* ff1_b1   = (const float*)d_in[4];
    const float* ff1_w2   = (const float*)d_in[5];
    const float* ff1_b2   = (const float*)d_in[6];
    const float* ff2_ln_g = (const float*)d_in[7];
    const float* ff2_ln_b = (const float*)d_in[8];
    const float* ff2_w1   = (const float*)d_in[9];
    const float* ff2_b1   = (const float*)d_in[10];
    const float* ff2_w2   = (const float*)d_in[11];
    const float* ff2_b2   = (const float*)d_in[12];
    const float* m_win    = (const float*)d_in[13];
    const float* m_convw  = (const float*)d_in[14];
    const float* m_convb  = (const float*)d_in[15];
    const float* m_wx     = (const float*)d_in[16];
    const float* m_wdt    = (const float*)d_in[17];
    const float* m_bdt    = (const float*)d_in[18];
    const float* m_Alog   = (const float*)d_in[19];
    const float* m_Dp     = (const float*)d_in[20];
    const float* m_wout   = (const float*)d_in[21];
    const float* bi_wo    = (const float*)d_in[22];
    const float* bi_bo    = (const float*)d_in[23];
    const float* cv_ln_g  = (const float*)d_in[24];
    const float* cv_ln_b  = (const float*)d_in[25];
    const float* cv_pw1_w = (const float*)d_in[26];
    const float* cv_pw1_b = (const float*)d_in[27];
    const float* cv_dw15  = (const float*)d_in[28];
    const float* cv_dw31  = (const float*)d_in[29];
    const float* cv_dw63  = (const float*)d_in[30];
    const float* cv_bn_g  = (const float*)d_in[31];
    const float* cv_bn_b  = (const float*)d_in[32];
    const float* cv_bn_m  = (const float*)d_in[33];
    const float* cv_bn_v  = (const float*)d_in[34];
    const float* cv_pw2_w = (const float*)d_in[35];
    const float* cv_pw2_b = (const float*)d_in[36];
    const float* ln_g     = (const float*)d_in[37];
    const float* ln_b     = (const float*)d_in[38];

    // Workspace layout (byte offsets). Total 110.9 MB.
    char* wsb = (char*)d_ws;
    float* h      = (float*)(wsb + 0);          //  8 MB residual
    float* bigA   = (float*)(wsb + 8*MB_);      // 32 MB: xi / pw1out / partials
    float* xcb    = (float*)(wsb + 40*MB_);     // 16 MB: xc f32 (hid_bf overlay)
    float* dtb    = (float*)(wsb + 56*MB_);     // 16 MB: dt f32 (glu/mconv/wxpart overlay)
    float* xdbb   = (float*)(wsb + 72*MB_);     //  1 MB
    short* lnb_bf = (short*)(wsb + 73*MB_);     //  4 MB: LN bf16 (cvtb_bf reuse)
    short* xcbf   = (short*)(wsb + 77*MB_);     //  8 MB: xc bf16 (ys_bf overlay)
    short* h_bf   = (short*)(wsb + 85*MB_);     //  4 MB
    short* wbf    = (short*)(wsb + 89*MB_);     // 16.75 MB bf16 weights
    // overlays
    float* xi       = bigA;                              // [MM][1024] f32
    short* z_bf     = (short*)(wsb + 8*MB_ + 16*MB_);    // [MM][1024] bf16
    short* cat_bf   = (short*)(wsb + 8*MB_ + 24*MB_);    // [MM][1024] bf16
    float* part     = bigA;                              // split-K partials
    float* wxpart   = dtb;                               // 4 MB wx partials
    float* glu_t    = dtb;                               // 8 MB [b,c,l]
    float* mconv_o  = (float*)(wsb + 56*MB_ + 8*MB_);    // 8 MB [b,c,l]
    short* cvtb_bf  = lnb_bf;
    short* hid_bf   = (short*)xcb;                       // [MM][2048] bf16

    // bf16 weight sub-pointers
    short* w_ff1w1 = wbf;
    short* w_ff1w2 = wbf + 1048576;
    short* w_ff2w1 = wbf + 2097152;
    short* w_ff2w2 = wbf + 3145728;
    short* w_win   = wbf + 4194304;
    short* w_wx    = wbf + 6291456;
    short* w_wout  = wbf + 6422528;
    short* w_biwo  = wbf + 7471104;
    short* w_pw1   = wbf + 7995392;
    short* w_pw2   = wbf + 8519680;
    size_t need = 89ull*MB_ + 2ull*8781824;
    if (ws_size < need) return;

    // 0. convert weights to bf16 (one batched launch)
    WcvtArgs wa;
    wa.s[0]=ff1_w1;  wa.d[0]=w_ff1w1; wa.n[0]=1048576;
    wa.s[1]=ff1_w2;  wa.d[1]=w_ff1w2; wa.n[1]=1048576;
    wa.s[2]=ff2_w1;  wa.d[2]=w_ff2w1; wa.n[2]=1048576;
    wa.s[3]=ff2_w2;  wa.d[3]=w_ff2w2; wa.n[3]=1048576;
    wa.s[4]=m_win;   wa.d[4]=w_win;   wa.n[4]=2097152;
    wa.s[5]=m_wx;    wa.d[5]=w_wx;    wa.n[5]=131072;
    wa.s[6]=m_wout;  wa.d[6]=w_wout;  wa.n[6]=1048576;
    wa.s[7]=bi_wo;   wa.d[7]=w_biwo;  wa.n[7]=524288;
    wa.s[8]=cv_pw1_w;wa.d[8]=w_pw1;   wa.n[8]=524288;
    wa.s[9]=cv_pw2_w;wa.d[9]=w_pw2;   wa.n[9]=262144;
    wcvt_kernel<<<dim3(1024,10), 256, 0, stream>>>(wa);

    auto G3 = [&](const short* A, int lda, const short* W, int ldw,
                  const float* bias, float* oF, short* oB, int ldc,
                  const float* res, int ldr, float rs,
                  int N, int K, int splits, int act, int ri, float* prt) {
        dim3 g(N/128, 32, splits);
        gemm3_kernel<128><<<g, 256, 0, stream>>>(A, lda, W, ldw, bias, oF, oB, ldc,
            res, ldr, rs, K/splits, act, ri, prt, (size_t)MM*N, N);
    };
    auto RED = [&](const float* p, int S, int N, const float* bias, int act,
                   const float* res, int ldr, float rs,
                   float* oF, short* oB, int ldc, int colOff, int rev) {
        reduce_kernel<<<(MM*N/4)/256, 256, 0, stream>>>(p, S, (size_t)MM*N, N,
            bias, act, res, ldr, rs, oF, oB, ldc, colOff, rev);
    };

    // ---- FFN1: h = x + 0.5*(silu(LN@w1+b1)@w2+b2); also h_bf
    ln_kernel<<<MM, 128, 0, stream>>>(x, ff1_ln_g, ff1_ln_b, nullptr, lnb_bf);
    G3(lnb_bf, 512, w_ff1w1, 512, ff1_b1, nullptr, hid_bf, 2048,
       nullptr, 0, 0.f, 2048, 512, 1, 1, 0, nullptr);
    G3(hid_bf, 2048, w_ff1w2, 2048, nullptr, nullptr, nullptr, 0,
       nullptr, 0, 0.f, 512, 2048, 4, 0, 0, part);
    RED(part, 4, 512, ff1_b2, 0, x, 512, 0.5f, h, h_bf, 512, 0, 0);

    // ---- BiMamba
    for (int dir = 0; dir < 2; dir++) {
        const short* winb = w_win + (size_t)dir*2048*512;
        const float* convw = m_convw + (size_t)dir*DII*4;
        const float* convb = m_convb + (size_t)dir*DII;
        const short* wxb   = w_wx   + (size_t)dir*64*1024;
        const float* wdt   = m_wdt  + (size_t)dir*DII*32;
        const float* bdt   = m_bdt  + (size_t)dir*DII;
        const float* Alog  = m_Alog + (size_t)dir*DII*NST;
        const float* Dp    = m_Dp   + (size_t)dir*DII;
        const short* woutb = w_wout + (size_t)dir*512*1024;

        // xz split into xi (f32) and z (bf16)
        G3(h_bf, 512, winb, 512, nullptr, xi, nullptr, 1024,
           nullptr, 0, 0.f, 1024, 512, 1, 0, dir, nullptr);
        G3(h_bf, 512, winb + 1024*512, 512, nullptr, nullptr, z_bf, 1024,
           nullptr, 0, 0.f, 1024, 512, 1, 0, dir, nullptr);
        mamba_conv_kernel<<<MM*DII/256, 256, 0, stream>>>(xi, convw, convb, xcb, xcbf);
        // xdb = xc @ wx^T  (N=64, split-K 4)
        {
            dim3 g(1, 32, 4);
            gemm3_kernel<64><<<g, 256, 0, stream>>>(xcbf, 1024, wxb, 1024,
                nullptr, nullptr, nullptr, 0, nullptr, 0, 0.f,
                256, 0, 0, wxpart, (size_t)MM*64, 64);
        }
        RED(wxpart, 4, 64, nullptr, 0, nullptr, 0, 0.f, xdbb, nullptr, 64, 0, 0);
        // dt = softplus(xdb[:, :32] @ wdt^T + bdt)  (fp32, K=32)
        gemm_kernel<<<dim3(16, 64), 256, 0, stream>>>(xdbb, 64, wdt, 32, bdt, dtb, 1024, 32, 2);
        // scan (fused ycombine) -> ys bf16 (overlays xcbf)
        scan_kernel<<<BB*DII/16, 256, 0, stream>>>(dtb, xcb, xdbb, Alog, z_bf, Dp, xcbf);
        // out-proj -> cat half (rev in reduce)
        G3(xcbf, 1024, woutb, 1024, nullptr, nullptr, nullptr, 0,
           nullptr, 0, 0.f, 512, 1024, 2, 0, 0, part);
        RED(part, 2, 512, nullptr, 0, nullptr, 0, 0.f, nullptr, cat_bf, 1024, dir*512, dir);
    }
    // h += cat @ bi_wo^T + bi_bo
    G3(cat_bf, 1024, w_biwo, 1024, nullptr, nullptr, nullptr, 0,
       nullptr, 0, 0.f, 512, 1024, 2, 0, 0, part);
    RED(part, 2, 512, bi_bo, 0, h, 512, 1.0f, h, nullptr, 512, 0, 0);

    // ---- ConvMod
    ln_kernel<<<MM, 128, 0, stream>>>(h, cv_ln_g, cv_ln_b, nullptr, lnb_bf);
    G3(lnb_bf, 512, w_pw1, 512, cv_pw1_b, bigA, nullptr, 1024,
       nullptr, 0, 0.f, 1024, 512, 1, 0, 0, nullptr);
    glu_transpose_kernel<<<dim3(8,8,8), 256, 0, stream>>>(bigA, glu_t);
    multiconv_t_kernel<<<BB*DD, 256, 0, stream>>>(glu_t,
        cv_dw15, cv_dw31, cv_dw63, cv_bn_g, cv_bn_b, cv_bn_m, cv_bn_v, mconv_o);
    transpose_bcl_kernel<<<dim3(8,8,8), 256, 0, stream>>>(mconv_o, cvtb_bf);
    G3(cvtb_bf, 512, w_pw2, 512, nullptr, nullptr, nullptr, 0,
       nullptr, 0, 0.f, 512, 512, 2, 0, 0, part);
    RED(part, 2, 512, cv_pw2_b, 0, h, 512, 1.0f, h, nullptr, 512, 0, 0);

    // ---- FFN2
    ln_kernel<<<MM, 128, 0, stream>>>(h, ff2_ln_g, ff2_ln_b, nullptr, lnb_bf);
    G3(lnb_bf, 512, w_ff2w1, 512, ff2_b1, nullptr, hid_bf, 2048,
       nullptr, 0, 0.f, 2048, 512, 1, 1, 0, nullptr);
    G3(hid_bf, 2048, w_ff2w2, 2048, nullptr, nullptr, nullptr, 0,
       nullptr, 0, 0.f, 512, 2048, 4, 0, 0, part);
    RED(part, 4, 512, ff2_b2, 0, h, 512, 0.5f, h, nullptr, 512, 0, 0);

    // ---- Final LN -> d_out (fp32)
    ln_kernel<<<MM, 128, 0, stream>>>(h, ln_g, ln_b, (float*)d_out, nullptr);
}

// Round 5
// 711.697 us; speedup vs baseline: 3.4576x; 1.1035x over previous
//
#include <hip/hip_runtime.h>
#include <hip/hip_bf16.h>
#include <math.h>

#define LL   512
#define DD   512
#define DII  1024
#define NST  16
#define BB   8
#define MM   4096
#define CHL  32     // scan chunk length
#define NCH  16     // chunks (NCH*CHL == LL)
#define MB_  (1024*1024)

typedef __attribute__((ext_vector_type(8))) short bf16x8;
typedef __attribute__((ext_vector_type(4))) float f32x4;

__device__ __forceinline__ float sigmoidf_(float x){ return 1.0f/(1.0f+expf(-x)); }
__device__ __forceinline__ float siluf_(float x){ return x*sigmoidf_(x); }
__device__ __forceinline__ float softplusf_(float x){ return x > 20.0f ? x : log1pf(expf(x)); }

__device__ __forceinline__ short f2bf(float f) {
    union { float f; unsigned u; } v; v.f = f;
    unsigned r = v.u + 0x7fffu + ((v.u >> 16) & 1u);
    return (short)(r >> 16);
}
__device__ __forceinline__ float bf2f(short s) {
    union { unsigned u; float f; } v; v.u = ((unsigned)(unsigned short)s) << 16;
    return v.f;
}
__device__ __forceinline__ bf16x8 pack_bf8(float4 v0, float4 v1) {
    union { bf16x8 v; short e[8]; } pk;
    pk.e[0]=f2bf(v0.x); pk.e[1]=f2bf(v0.y); pk.e[2]=f2bf(v0.z); pk.e[3]=f2bf(v0.w);
    pk.e[4]=f2bf(v1.x); pk.e[5]=f2bf(v1.y); pk.e[6]=f2bf(v1.z); pk.e[7]=f2bf(v1.w);
    return pk.v;
}
__device__ __forceinline__ void gl_lds16(const short* g, short* l) {
    __builtin_amdgcn_global_load_lds(
        (const __attribute__((address_space(1))) void*)g,
        (__attribute__((address_space(3))) void*)l, 16, 0, 0);
}

// ---------------------------------------------------------------------------
// Batched fp32 -> bf16 weight conversion (11 segments).
// ---------------------------------------------------------------------------
struct WcvtArgs { const float* s[11]; short* d[11]; int n[11]; };
__global__ void __launch_bounds__(256) wcvt_kernel(WcvtArgs a) {
    const int seg = blockIdx.y;
    const int i = (blockIdx.x*256 + threadIdx.x) * 8;
    if (i >= a.n[seg]) return;
    const float* s = a.s[seg] + i;
    float4 v0 = *(const float4*)s;
    float4 v1 = *(const float4*)(s + 4);
    *(bf16x8*)(a.d[seg] + i) = pack_bf8(v0, v1);
}

// ---------------------------------------------------------------------------
// bf16 MFMA GEMM (m97 structure): C = A[M,K] @ W[N,K]^T, 128xBN tile, BK=32,
// 4 waves, global_load_lds(16B) staging, split-K via gridDim.z.
// ---------------------------------------------------------------------------
template<int BN>
__global__ void __launch_bounds__(256) gemm3_kernel(
    const short* __restrict__ A, int lda,
    const short* __restrict__ W, int ldw,
    const float* __restrict__ bias,
    float* __restrict__ outF, short* __restrict__ outB, int ldc,
    const float* __restrict__ resid, int ldr, float rscale,
    int kLen, int act, int rev_in,
    float* __restrict__ partial, size_t pstride, int N)
{
    constexpr int WN = BN / 64;
    constexpr int WM = 4 / WN;
    constexpr int TM = 128 / WM;
    constexpr int FM = TM / 16;
    constexpr int WRND = BN / 64;

    __shared__ short As[128*32];
    __shared__ short Ws[BN*32];

    const int tid = threadIdx.x, lane = tid & 63, wid = tid >> 6;
    const int rowBase = blockIdx.y << 7;
    const int colBase = blockIdx.x * BN;
    const int kBase = blockIdx.z * kLen;

    int arow[2], ac8[2];
    #pragma unroll
    for (int r = 0; r < 2; r++) {
        int u = (r*4 + wid)*64 + lane;
        int rr = rowBase + (u >> 2);
        if (rev_in) { int bb = rr >> 9, l = rr & 511; rr = (bb << 9) + (511 - l); }
        arow[r] = rr; ac8[r] = (u & 3) << 3;
    }
    int wrow[WRND], wc8[WRND];
    #pragma unroll
    for (int r = 0; r < WRND; r++) {
        int u = (r*4 + wid)*64 + lane;
        wrow[r] = colBase + (u >> 2); wc8[r] = (u & 3) << 3;
    }
    const int fr = lane & 15, fkb = (lane >> 4) << 3;
    const int wm = (wid / WN) * TM, wn = (wid % WN) * 64;

    f32x4 acc[FM][4] = {};

    for (int k0 = kBase; k0 < kBase + kLen; k0 += 32) {
        #pragma unroll
        for (int r = 0; r < 2; r++)
            gl_lds16(A + (size_t)arow[r]*lda + k0 + ac8[r], As + (r*4 + wid)*512);
        #pragma unroll
        for (int r = 0; r < WRND; r++)
            gl_lds16(W + (size_t)wrow[r]*ldw + k0 + wc8[r], Ws + (r*4 + wid)*512);
        __syncthreads();
        bf16x8 af[FM], bfr[4];
        #pragma unroll
        for (int mi = 0; mi < FM; mi++) af[mi]  = *(const bf16x8*)&As[(wm + mi*16 + fr)*32 + fkb];
        #pragma unroll
        for (int ni = 0; ni < 4;  ni++) bfr[ni] = *(const bf16x8*)&Ws[(wn + ni*16 + fr)*32 + fkb];
        #pragma unroll
        for (int mi = 0; mi < FM; mi++)
            #pragma unroll
            for (int ni = 0; ni < 4; ni++)
                acc[mi][ni] = __builtin_amdgcn_mfma_f32_16x16x32_bf16(af[mi], bfr[ni], acc[mi][ni], 0, 0, 0);
        __syncthreads();
    }

    if (partial) {
        float* pp = partial + (size_t)blockIdx.z * pstride;
        #pragma unroll
        for (int mi = 0; mi < FM; mi++)
            #pragma unroll
            for (int r = 0; r < 4; r++) {
                int orow = rowBase + wm + mi*16 + ((lane>>4)<<2) + r;
                #pragma unroll
                for (int ni = 0; ni < 4; ni++)
                    pp[(size_t)orow*N + colBase + wn + ni*16 + fr] = acc[mi][ni][r];
            }
    } else {
        #pragma unroll
        for (int mi = 0; mi < FM; mi++)
            #pragma unroll
            for (int r = 0; r < 4; r++) {
                int orow = rowBase + wm + mi*16 + ((lane>>4)<<2) + r;
                #pragma unroll
                for (int ni = 0; ni < 4; ni++) {
                    int gcol = colBase + wn + ni*16 + fr;
                    float v = acc[mi][ni][r];
                    if (bias) v += bias[gcol];
                    if (act == 1) v = siluf_(v);
                    else if (act == 2) v = softplusf_(v);
                    if (resid) v = resid[(size_t)orow*ldr + gcol] + rscale*v;
                    if (outF) outF[(size_t)orow*ldc + gcol] = v;
                    if (outB) outB[(size_t)orow*ldc + gcol] = f2bf(v);
                }
            }
    }
}

// ---------------------------------------------------------------------------
// Split-K reduce + epilogue.
// ---------------------------------------------------------------------------
__global__ void __launch_bounds__(256) reduce_kernel(
    const float* __restrict__ part, int S, size_t pstride, int N,
    const float* __restrict__ bias, int act,
    const float* __restrict__ resid, int ldr, float rscale,
    float* __restrict__ outF, short* __restrict__ outB, int ldc,
    int colOff, int rev_out)
{
    const int i4 = blockIdx.x*256 + threadIdx.x;
    const int row = i4 / (N >> 2);
    const int c4  = (i4 - row*(N >> 2)) << 2;
    float4 s = *(const float4*)(part + (size_t)row*N + c4);
    for (int z = 1; z < S; z++) {
        float4 t = *(const float4*)(part + (size_t)z*pstride + (size_t)row*N + c4);
        s.x += t.x; s.y += t.y; s.z += t.z; s.w += t.w;
    }
    if (bias) { float4 b = *(const float4*)(bias + c4); s.x+=b.x; s.y+=b.y; s.z+=b.z; s.w+=b.w; }
    if (act == 1) { s.x=siluf_(s.x); s.y=siluf_(s.y); s.z=siluf_(s.z); s.w=siluf_(s.w); }
    else if (act == 2) { s.x=softplusf_(s.x); s.y=softplusf_(s.y); s.z=softplusf_(s.z); s.w=softplusf_(s.w); }
    int orow = row;
    if (rev_out) { int b = row >> 9, l = row & 511; orow = (b << 9) + (511 - l); }
    if (resid) {
        float4 rr = *(const float4*)(resid + (size_t)orow*ldr + colOff + c4);
        s.x = rr.x + rscale*s.x; s.y = rr.y + rscale*s.y;
        s.z = rr.z + rscale*s.z; s.w = rr.w + rscale*s.w;
    }
    if (outF) *(float4*)(outF + (size_t)orow*ldc + colOff + c4) = s;
    if (outB) {
        short4 o; o.x=f2bf(s.x); o.y=f2bf(s.y); o.z=f2bf(s.z); o.w=f2bf(s.w);
        *(short4*)(outB + (size_t)orow*ldc + colOff + c4) = o;
    }
}

// ---------------------------------------------------------------------------
// LayerNorm over 512; fp32 and/or bf16 out.
// ---------------------------------------------------------------------------
__global__ void __launch_bounds__(128) ln_kernel(
    const float* __restrict__ x, const float* __restrict__ g,
    const float* __restrict__ bta, float* __restrict__ outF,
    short* __restrict__ outB)
{
    const int row = blockIdx.x;
    const int t = threadIdx.x;
    float4 v = ((const float4*)(x + (size_t)row*DD))[t];
    float s = v.x+v.y+v.z+v.w;
    float q = v.x*v.x+v.y*v.y+v.z*v.z+v.w*v.w;
    #pragma unroll
    for (int off = 32; off >= 1; off >>= 1) {
        s += __shfl_down(s, off);
        q += __shfl_down(q, off);
    }
    __shared__ float sh[4];
    if ((t & 63) == 0) { sh[(t>>6)*2] = s; sh[(t>>6)*2+1] = q; }
    __syncthreads();
    float mean = (sh[0]+sh[2]) * (1.0f/DD);
    float var  = (sh[1]+sh[3]) * (1.0f/DD) - mean*mean;
    float rstd = rsqrtf(var + 1e-5f);
    float4 gg = ((const float4*)g)[t];
    float4 bb = ((const float4*)bta)[t];
    float4 o;
    o.x = (v.x-mean)*rstd*gg.x + bb.x;
    o.y = (v.y-mean)*rstd*gg.y + bb.y;
    o.z = (v.z-mean)*rstd*gg.z + bb.z;
    o.w = (v.w-mean)*rstd*gg.w + bb.w;
    if (outF) ((float4*)(outF + (size_t)row*DD))[t] = o;
    if (outB) {
        short4 ob; ob.x=f2bf(o.x); ob.y=f2bf(o.y); ob.z=f2bf(o.z); ob.w=f2bf(o.w);
        *(short4*)(outB + (size_t)row*DD + t*4) = ob;
    }
}

// ---------------------------------------------------------------------------
// Mamba causal dwconv (K=4) + bias + SiLU; bf16 in [MM,1024], bf16 out.
// ---------------------------------------------------------------------------
__global__ void __launch_bounds__(256) mamba_conv_kernel(
    const short* __restrict__ xi, const float* __restrict__ cw,
    const float* __restrict__ cb, short* __restrict__ xcb16)
{
    const int idx = blockIdx.x*256 + threadIdx.x;
    const int c = idx & (DII-1);
    const int row = idx >> 10;
    const int l = row & (LL-1);
    float4 w = ((const float4*)cw)[c];
    const float* wf = (const float*)&w;
    float acc = cb[c];
    #pragma unroll
    for (int t = 0; t < 4; t++) {
        int ll = l - 3 + t;
        if (ll >= 0) acc += wf[t] * bf2f(xi[((size_t)(row - l + ll))*DII + c]);
    }
    xcb16[idx] = f2bf(siluf_(acc));
}

// ---------------------------------------------------------------------------
// Selective scan, 3-pass chunked associative form. One THREAD owns all 16
// states of a (b,d) chain for one L-chunk -> zero cross-lane ops, zero LDS.
// Pass A: per-chunk decay product P[16] and local end-state H[16] (from 0).
// Pass B: serial chunk combine -> h_in per chunk (hin aliases P).
// Pass C: rescan chunk from h_in, y = C.h, fused (y+Dp*xc)*silu(z) -> ys
//         (in place over xc).
// P/H layout: [b][chunk][n][DII] (coalesced across d).
// ---------------------------------------------------------------------------
__global__ void __launch_bounds__(256) scan_a_kernel(
    const short* __restrict__ dt_bf, const short* __restrict__ xc_bf,
    const float* __restrict__ xdb, const float* __restrict__ Alog,
    float* __restrict__ P, float* __restrict__ Hl)
{
    const int bid = blockIdx.x;
    const int dg = bid & 3;
    const int c  = (bid >> 2) & (NCH-1);
    const int b  = bid >> 6;
    const int d  = (dg << 8) + threadIdx.x;

    float Aexp[16];
    #pragma unroll
    for (int n = 0; n < 16; n++) Aexp[n] = -__expf(Alog[d*16 + n]);

    float h[16], Pp[16];
    #pragma unroll
    for (int n = 0; n < 16; n++) { h[n] = 0.f; Pp[n] = 1.f; }

    const size_t l0 = (size_t)b*LL + (size_t)c*CHL;
    const short* dtp = dt_bf + l0*DII + d;
    const short* xcp = xc_bf + l0*DII + d;
    const float* bp  = xdb + l0*64 + 32;

    #pragma unroll 2
    for (int l = 0; l < CHL; l++) {
        float dtv = bf2f(dtp[(size_t)l*DII]);
        float xcv = bf2f(xcp[(size_t)l*DII]);
        float co = dtv*xcv;
        float Bv[16];
        #pragma unroll
        for (int q4 = 0; q4 < 4; q4++) {
            float4 v = *(const float4*)(bp + (size_t)l*64 + q4*4);
            Bv[q4*4+0]=v.x; Bv[q4*4+1]=v.y; Bv[q4*4+2]=v.z; Bv[q4*4+3]=v.w;
        }
        #pragma unroll
        for (int n = 0; n < 16; n++) {
            float q = __expf(dtv*Aexp[n]);
            Pp[n] *= q;
            h[n] = fmaf(q, h[n], co*Bv[n]);
        }
    }
    size_t base = (((size_t)b*NCH + c)*16)*DII + d;
    #pragma unroll
    for (int n = 0; n < 16; n++) {
        P[base + (size_t)n*DII]  = Pp[n];
        Hl[base + (size_t)n*DII] = h[n];
    }
}

__global__ void __launch_bounds__(256) scan_b_kernel(
    const float* __restrict__ Hl, float* Phin /* P in, hin out (same buffer) */)
{
    const int g = blockIdx.x*256 + threadIdx.x;   // b*16*DII + n*DII + d
    const int d = g & (DII-1);
    const int n = (g >> 10) & 15;
    const int b = g >> 14;
    const size_t cs = (size_t)16*DII;
    const size_t base = ((size_t)b*NCH*16 + (size_t)n)*DII + d;
    float h = 0.f;
    for (int c = 0; c < NCH; c++) {
        size_t i = base + (size_t)c*cs;
        float pn = Phin[i];          // read P first
        float hn = pn*h + Hl[i];
        Phin[i] = h;                 // then overwrite with h_in
        h = hn;
    }
}

__global__ void __launch_bounds__(256) scan_c_kernel(
    const short* __restrict__ dt_bf, short* xc_ys,
    const float* __restrict__ xdb, const float* __restrict__ Alog,
    const float* __restrict__ hin, const short* __restrict__ z_bf,
    const float* __restrict__ Dp)
{
    const int bid = blockIdx.x;
    const int dg = bid & 3;
    const int c  = (bid >> 2) & (NCH-1);
    const int b  = bid >> 6;
    const int d  = (dg << 8) + threadIdx.x;

    float Aexp[16];
    #pragma unroll
    for (int n = 0; n < 16; n++) Aexp[n] = -__expf(Alog[d*16 + n]);
    const float Dpv = Dp[d];

    float h[16];
    const size_t hb = (((size_t)b*NCH + c)*16)*DII + d;
    #pragma unroll
    for (int n = 0; n < 16; n++) h[n] = hin[hb + (size_t)n*DII];

    const size_t l0 = (size_t)b*LL + (size_t)c*CHL;
    const short* dtp = dt_bf + l0*DII + d;
    short*       xcp = xc_ys + l0*DII + d;
    const short* zp  = z_bf + l0*DII + d;
    const float* bp  = xdb + l0*64 + 32;

    #pragma unroll 2
    for (int l = 0; l < CHL; l++) {
        float dtv = bf2f(dtp[(size_t)l*DII]);
        float xcv = bf2f(xcp[(size_t)l*DII]);
        float zv  = bf2f(zp[(size_t)l*DII]);
        float co = dtv*xcv;
        float Bv[16], Cv[16];
        #pragma unroll
        for (int q4 = 0; q4 < 4; q4++) {
            float4 v = *(const float4*)(bp + (size_t)l*64 + q4*4);
            Bv[q4*4+0]=v.x; Bv[q4*4+1]=v.y; Bv[q4*4+2]=v.z; Bv[q4*4+3]=v.w;
            float4 w = *(const float4*)(bp + (size_t)l*64 + 16 + q4*4);
            Cv[q4*4+0]=w.x; Cv[q4*4+1]=w.y; Cv[q4*4+2]=w.z; Cv[q4*4+3]=w.w;
        }
        float y = 0.f;
        #pragma unroll
        for (int n = 0; n < 16; n++) {
            float q = __expf(dtv*Aexp[n]);
            h[n] = fmaf(q, h[n], co*Bv[n]);
            y = fmaf(Cv[n], h[n], y);
        }
        float out = (y + Dpv*xcv) * siluf_(zv);
        xcp[(size_t)l*DII] = f2bf(out);
    }
}

// ---------------------------------------------------------------------------
// GLU + transpose to [b, c, l] fp32.
// ---------------------------------------------------------------------------
__global__ void __launch_bounds__(256) glu_transpose_kernel(
    const float* __restrict__ pw1, float* __restrict__ out_t)
{
    __shared__ float sh[64][65];
    const int c0 = blockIdx.x << 6;
    const int l0 = blockIdx.y << 6;
    const int b  = blockIdx.z;
    const int t  = threadIdx.x;
    const int c4 = (t & 15) << 2;
    const int r  = t >> 4;
    #pragma unroll
    for (int i = 0; i < 4; i++) {
        int lrow = r + i*16;
        size_t row = (size_t)(b << 9) + l0 + lrow;
        float4 a = *(const float4*)(pw1 + row*1024 + c0 + c4);
        float4 g = *(const float4*)(pw1 + row*1024 + 512 + c0 + c4);
        sh[lrow][c4+0] = a.x * sigmoidf_(g.x);
        sh[lrow][c4+1] = a.y * sigmoidf_(g.y);
        sh[lrow][c4+2] = a.z * sigmoidf_(g.z);
        sh[lrow][c4+3] = a.w * sigmoidf_(g.w);
    }
    __syncthreads();
    #pragma unroll
    for (int i = 0; i < 4; i++) {
        int crow = r + i*16;
        float4 o;
        o.x = sh[c4+0][crow];
        o.y = sh[c4+1][crow];
        o.z = sh[c4+2][crow];
        o.w = sh[c4+3][crow];
        *(float4*)(out_t + ((size_t)(b << 9) + c0 + crow)*512 + l0 + c4) = o;
    }
}

// ---------------------------------------------------------------------------
// Channel-major fused 3x dwconv avg + BN + SiLU (SGPR weights).
// ---------------------------------------------------------------------------
__global__ void __launch_bounds__(256) multiconv_t_kernel(
    const float* __restrict__ gin_t,
    const float* __restrict__ w15, const float* __restrict__ w31,
    const float* __restrict__ w63,
    const float* __restrict__ bn_g, const float* __restrict__ bn_b,
    const float* __restrict__ bn_m, const float* __restrict__ bn_v,
    float* __restrict__ out_t)
{
    __shared__ float sh[574];
    const int c = blockIdx.x & (DD-1);
    const int b = blockIdx.x >> 9;
    const int t = threadIdx.x;
    const float* rowp = gin_t + ((size_t)(b << 9) + c)*512;
    sh[31 + t]       = rowp[t];
    sh[31 + t + 256] = rowp[t + 256];
    if (t < 31) { sh[t] = 0.f; sh[543 + t] = 0.f; }
    __syncthreads();

    const float bnscale = rsqrtf(bn_v[c] + 1e-5f) * bn_g[c];
    const float bnm = bn_m[c], bnb = bn_b[c];
    float* outp = out_t + ((size_t)(b << 9) + c)*512;
    #pragma unroll
    for (int half = 0; half < 2; half++) {
        int l = t + half*256;
        float s63 = 0.f, s31 = 0.f, s15 = 0.f;
        #pragma unroll
        for (int k = 0; k < 63; k++) s63 += w63[c*63 + k] * sh[l + k];
        #pragma unroll
        for (int k = 0; k < 31; k++) s31 += w31[c*31 + k] * sh[l + 16 + k];
        #pragma unroll
        for (int k = 0; k < 15; k++) s15 += w15[c*15 + k] * sh[l + 24 + k];
        float m = (s15 + s31 + s63) * (1.0f/3.0f);
        m = (m - bnm) * bnscale + bnb;
        outp[l] = siluf_(m);
    }
}

// ---------------------------------------------------------------------------
// Transpose [b, c, l] -> [b, l, c], bf16 out.
// ---------------------------------------------------------------------------
__global__ void __launch_bounds__(256) transpose_bcl_kernel(
    const float* __restrict__ in_t, short* __restrict__ out)
{
    __shared__ float sh[64][65];
    const int l0 = blockIdx.x << 6;
    const int c0 = blockIdx.y << 6;
    const int b  = blockIdx.z;
    const int t  = threadIdx.x;
    const int l4 = (t & 15) << 2;
    const int r  = t >> 4;
    #pragma unroll
    for (int i = 0; i < 4; i++) {
        int crow = r + i*16;
        float4 v = *(const float4*)(in_t + ((size_t)(b << 9) + c0 + crow)*512 + l0 + l4);
        sh[crow][l4+0] = v.x; sh[crow][l4+1] = v.y;
        sh[crow][l4+2] = v.z; sh[crow][l4+3] = v.w;
    }
    __syncthreads();
    #pragma unroll
    for (int i = 0; i < 4; i++) {
        int lrow = r + i*16;
        short4 o;
        o.x = f2bf(sh[l4+0][lrow]);
        o.y = f2bf(sh[l4+1][lrow]);
        o.z = f2bf(sh[l4+2][lrow]);
        o.w = f2bf(sh[l4+3][lrow]);
        *(short4*)(out + ((size_t)(b << 9) + l0 + lrow)*512 + c0 + l4) = o;
    }
}

// ---------------------------------------------------------------------------
extern "C" void kernel_launch(void* const* d_in, const int* in_sizes, int n_in,
                              void* d_out, int out_size, void* d_ws, size_t ws_size,
                              hipStream_t stream)
{
    const float* x        = (const float*)d_in[0];
    const float* ff1_ln_g = (const float*)d_in[1];
    const float* ff1_ln_b = (const float*)d_in[2];
    const float* ff1_w1   = (const float*)d_in[3];
    const float* ff1_b1   = (const float*)d_in[4];
    const float* ff1_w2   = (const float*)d_in[5];
    const float* ff1_b2   = (const float*)d_in[6];
    const float* ff2_ln_g = (const float*)d_in[7];
    const float* ff2_ln_b = (const float*)d_in[8];
    const float* ff2_w1   = (const float*)d_in[9];
    const float* ff2_b1   = (const float*)d_in[10];
    const float* ff2_w2   = (const float*)d_in[11];
    const float* ff2_b2   = (const float*)d_in[12];
    const float* m_win    = (const float*)d_in[13];
    const float* m_convw  = (const float*)d_in[14];
    const float* m_convb  = (const float*)d_in[15];
    const float* m_wx     = (const float*)d_in[16];
    const float* m_wdt    = (const float*)d_in[17];
    const float* m_bdt    = (const float*)d_in[18];
    const float* m_Alog   = (const float*)d_in[19];
    const float* m_Dp     = (const float*)d_in[20];
    const float* m_wout   = (const float*)d_in[21];
    const float* bi_wo    = (const float*)d_in[22];
    const float* bi_bo    = (const float*)d_in[23];
    const float* cv_ln_g  = (const float*)d_in[24];
    const float* cv_ln_b  = (const float*)d_in[25];
    const float* cv_pw1_w = (const float*)d_in[26];
    const float* cv_pw1_b = (const float*)d_in[27];
    const float* cv_dw15  = (const float*)d_in[28];
    const float* cv_dw31  = (const float*)d_in[29];
    const float* cv_dw63  = (const float*)d_in[30];
    const float* cv_bn_g  = (const float*)d_in[31];
    const float* cv_bn_b  = (const float*)d_in[32];
    const float* cv_bn_m  = (const float*)d_in[33];
    const float* cv_bn_v  = (const float*)d_in[34];
    const float* cv_pw2_w = (const float*)d_in[35];
    const float* cv_pw2_b = (const float*)d_in[36];
    const float* ln_g     = (const float*)d_in[37];
    const float* ln_b     = (const float*)d_in[38];

    // ---- Workspace layout (MiB offsets), total exactly 113 MiB ----
    char* wsb = (char*)d_ws;
    float* h       = (float*)(wsb + 0);           // 0-8   residual f32
    short* h_bf    = (short*)(wsb + 8*MB_);       // 8-12
    short* lnb_bf  = (short*)(wsb + 12*MB_);      // 12-16 LN out / y_bf / cvtb_bf
    short* wbf     = (short*)(wsb + 16*MB_);      // 16-33 bf16 weights (16.875)
    short* hid_bf  = (short*)(wsb + 33*MB_);      // 33-49 FFN hidden [MM,2048]
    float* part    = (float*)(wsb + 49*MB_);      // 49-65 split-K partials / pw1out
    float* scanP   = (float*)(wsb + 65*MB_);      // 65-73 P (then h_in, aliased)
    float* scanH   = (float*)(wsb + 73*MB_);      // 73-81 Hlocal
    short* xi_bf   = (short*)(wsb + 89*MB_);      // 89-97 xi bf16 / glu_t f32
    float* glu_t   = (float*)(wsb + 89*MB_);
    short* z_bf    = (short*)(wsb + 97*MB_);      // 97-105 z bf16 / mconv_o f32
    float* mconv_o = (float*)(wsb + 97*MB_);
    short* xcbf    = (short*)(wsb + 105*MB_);     // 105-113 xc bf16 (ys in-place)
    // mamba-phase overlays inside hid_bf region (dead during mamba):
    short* dt_bf   = (short*)(wsb + 33*MB_);      // 33-41 dt bf16 [MM,1024]
    float* xdbb    = (float*)(wsb + 41*MB_);      // 41-42 xdb f32 [MM,64]
    short* xdb_bf  = (short*)(wsb + 42*MB_);      // 42-42.5 xdb bf16
    float* scanHin = scanP;                       // aliased (pass B in-place)

    // bf16 weight sub-pointers (element offsets)
    short* w_ff1w1 = wbf;
    short* w_ff1w2 = wbf + 1048576;
    short* w_ff2w1 = wbf + 2097152;
    short* w_ff2w2 = wbf + 3145728;
    short* w_win   = wbf + 4194304;
    short* w_wx    = wbf + 6291456;
    short* w_wout  = wbf + 6422528;
    short* w_biwo  = wbf + 7471104;
    short* w_pw1   = wbf + 7995392;
    short* w_pw2   = wbf + 8519680;
    short* w_wdt   = wbf + 8781824;   // 65536 els -> ends 8847360 (16.875 MiB)

    if (ws_size < (size_t)113*MB_) return;

    // 0. weights -> bf16
    WcvtArgs wa;
    wa.s[0]=ff1_w1;  wa.d[0]=w_ff1w1; wa.n[0]=1048576;
    wa.s[1]=ff1_w2;  wa.d[1]=w_ff1w2; wa.n[1]=1048576;
    wa.s[2]=ff2_w1;  wa.d[2]=w_ff2w1; wa.n[2]=1048576;
    wa.s[3]=ff2_w2;  wa.d[3]=w_ff2w2; wa.n[3]=1048576;
    wa.s[4]=m_win;   wa.d[4]=w_win;   wa.n[4]=2097152;
    wa.s[5]=m_wx;    wa.d[5]=w_wx;    wa.n[5]=131072;
    wa.s[6]=m_wout;  wa.d[6]=w_wout;  wa.n[6]=1048576;
    wa.s[7]=bi_wo;   wa.d[7]=w_biwo;  wa.n[7]=524288;
    wa.s[8]=cv_pw1_w;wa.d[8]=w_pw1;   wa.n[8]=524288;
    wa.s[9]=cv_pw2_w;wa.d[9]=w_pw2;   wa.n[9]=262144;
    wa.s[10]=m_wdt;  wa.d[10]=w_wdt;  wa.n[10]=65536;
    wcvt_kernel<<<dim3(1024,11), 256, 0, stream>>>(wa);

    auto G3 = [&](const short* A, int lda, const short* W, int ldw,
                  const float* bias, float* oF, short* oB, int ldc,
                  const float* res, int ldr, float rs,
                  int N, int K, int splits, int act, int ri, float* prt) {
        dim3 g(N/128, 32, splits);
        gemm3_kernel<128><<<g, 256, 0, stream>>>(A, lda, W, ldw, bias, oF, oB, ldc,
            res, ldr, rs, K/splits, act, ri, prt, (size_t)MM*N, N);
    };
    auto RED = [&](const float* p, int S, int N, const float* bias, int act,
                   const float* res, int ldr, float rs,
                   float* oF, short* oB, int ldc, int colOff, int rev) {
        reduce_kernel<<<(MM*N/4)/256, 256, 0, stream>>>(p, S, (size_t)MM*N, N,
            bias, act, res, ldr, rs, oF, oB, ldc, colOff, rev);
    };

    // ---- FFN1: h = x + 0.5*(silu(LN@w1+b1)@w2+b2), also h_bf
    ln_kernel<<<MM, 128, 0, stream>>>(x, ff1_ln_g, ff1_ln_b, nullptr, lnb_bf);
    G3(lnb_bf, 512, w_ff1w1, 512, ff1_b1, nullptr, hid_bf, 2048,
       nullptr, 0, 0.f, 2048, 512, 1, 1, 0, nullptr);
    G3(hid_bf, 2048, w_ff1w2, 2048, nullptr, nullptr, nullptr, 0,
       nullptr, 0, 0.f, 512, 2048, 2, 0, 0, part);
    RED(part, 2, 512, ff1_b2, 0, x, 512, 0.5f, h, h_bf, 512, 0, 0);

    // ---- BiMamba (per direction; bi_wo applied as two K=512 halves)
    for (int dir = 0; dir < 2; dir++) {
        const short* winb  = w_win  + (size_t)dir*2048*512;
        const float* convw = m_convw + (size_t)dir*DII*4;
        const float* convb = m_convb + (size_t)dir*DII;
        const short* wxb   = w_wx   + (size_t)dir*64*1024;
        const short* wdtb  = w_wdt  + (size_t)dir*1024*32;
        const float* bdt   = m_bdt  + (size_t)dir*DII;
        const float* Alog  = m_Alog + (size_t)dir*DII*NST;
        const float* Dp    = m_Dp   + (size_t)dir*DII;
        const short* woutb = w_wout + (size_t)dir*512*1024;

        // xz -> xi (bf16) and z (bf16), row-reversed read for dir=1
        G3(h_bf, 512, winb, 512, nullptr, nullptr, xi_bf, 1024,
           nullptr, 0, 0.f, 1024, 512, 1, 0, dir, nullptr);
        G3(h_bf, 512, winb + 1024*512, 512, nullptr, nullptr, z_bf, 1024,
           nullptr, 0, 0.f, 1024, 512, 1, 0, dir, nullptr);
        // causal dwconv + silu
        mamba_conv_kernel<<<MM*DII/256, 256, 0, stream>>>(xi_bf, convw, convb, xcbf);
        // xdb = xc @ wx^T (N=64, split-K 4)
        {
            dim3 g(1, 32, 4);
            gemm3_kernel<64><<<g, 256, 0, stream>>>(xcbf, 1024, wxb, 1024,
                nullptr, nullptr, nullptr, 0, nullptr, 0, 0.f,
                256, 0, 0, part, (size_t)MM*64, 64);
        }
        RED(part, 4, 64, nullptr, 0, nullptr, 0, 0.f, xdbb, xdb_bf, 64, 0, 0);
        // dt = softplus(xdb[:, :32] @ wdt^T + bdt) -> bf16
        G3(xdb_bf, 64, wdtb, 32, bdt, nullptr, dt_bf, 1024,
           nullptr, 0, 0.f, 1024, 32, 1, 2, 0, nullptr);
        // 3-pass scan + fused ycombine (ys overwrites xcbf)
        scan_a_kernel<<<BB*NCH*4, 256, 0, stream>>>(dt_bf, xcbf, xdbb, Alog, scanP, scanH);
        scan_b_kernel<<<BB*16*DII/256, 256, 0, stream>>>(scanH, scanP);
        scan_c_kernel<<<BB*NCH*4, 256, 0, stream>>>(dt_bf, xcbf, xdbb, Alog, scanHin, z_bf, Dp);
        // y_out = ys @ wout^T (rev rows back for dir=1) -> y_bf (lnb region)
        G3(xcbf, 1024, woutb, 1024, nullptr, nullptr, nullptr, 0,
           nullptr, 0, 0.f, 512, 1024, 2, 0, 0, part);
        RED(part, 2, 512, nullptr, 0, nullptr, 0, 0.f, nullptr, lnb_bf, 512, 0, dir);
        // h += y_out @ bi_wo[:, dir*512 : dir*512+512]^T (+ bi_bo on dir=1)
        G3(lnb_bf, 512, w_biwo + dir*512, 1024, nullptr, nullptr, nullptr, 0,
           nullptr, 0, 0.f, 512, 512, 2, 0, 0, part);
        RED(part, 2, 512, dir ? bi_bo : nullptr, 0, h, 512, 1.0f, h, nullptr, 512, 0, 0);
    }

    // ---- ConvMod
    ln_kernel<<<MM, 128, 0, stream>>>(h, cv_ln_g, cv_ln_b, nullptr, lnb_bf);
    G3(lnb_bf, 512, w_pw1, 512, cv_pw1_b, part, nullptr, 1024,
       nullptr, 0, 0.f, 1024, 512, 1, 0, 0, nullptr);           // pw1out f32 in part region
    glu_transpose_kernel<<<dim3(8,8,8), 256, 0, stream>>>(part, glu_t);
    multiconv_t_kernel<<<BB*DD, 256, 0, stream>>>(glu_t,
        cv_dw15, cv_dw31, cv_dw63, cv_bn_g, cv_bn_b, cv_bn_m, cv_bn_v, mconv_o);
    transpose_bcl_kernel<<<dim3(8,8,8), 256, 0, stream>>>(mconv_o, lnb_bf);
    G3(lnb_bf, 512, w_pw2, 512, nullptr, nullptr, nullptr, 0,
       nullptr, 0, 0.f, 512, 512, 2, 0, 0, part);
    RED(part, 2, 512, cv_pw2_b, 0, h, 512, 1.0f, h, nullptr, 512, 0, 0);

    // ---- FFN2
    ln_kernel<<<MM, 128, 0, stream>>>(h, ff2_ln_g, ff2_ln_b, nullptr, lnb_bf);
    G3(lnb_bf, 512, w_ff2w1, 512, ff2_b1, nullptr, hid_bf, 2048,
       nullptr, 0, 0.f, 2048, 512, 1, 1, 0, nullptr);
    G3(hid_bf, 2048, w_ff2w2, 2048, nullptr, nullptr, nullptr, 0,
       nullptr, 0, 0.f, 512, 2048, 2, 0, 0, part);
    RED(part, 2, 512, ff2_b2, 0, h, 512, 0.5f, h, nullptr, 512, 0, 0);

    // ---- Final LN -> d_out (fp32)
    ln_kernel<<<MM, 128, 0, stream>>>(h, ln_g, ln_b, (float*)d_out, nullptr);
}

// Round 6
// 633.226 us; speedup vs baseline: 3.8861x; 1.1239x over previous
//
#include <hip/hip_runtime.h>
#include <hip/hip_bf16.h>
#include <math.h>

#define LL   512
#define DD   512
#define DII  1024
#define NST  16
#define BB   8
#define MM   4096
#define CHL  32     // scan chunk length
#define NCH  16     // chunks (NCH*CHL == LL)
#define MB_  (1024*1024)

typedef __attribute__((ext_vector_type(8))) short bf16x8;
typedef __attribute__((ext_vector_type(4))) float f32x4;

__device__ __forceinline__ float sigmoidf_(float x){ return 1.0f/(1.0f+expf(-x)); }
__device__ __forceinline__ float siluf_(float x){ return x*sigmoidf_(x); }
__device__ __forceinline__ float softplusf_(float x){ return x > 20.0f ? x : log1pf(expf(x)); }

__device__ __forceinline__ short f2bf(float f) {
    union { float f; unsigned u; } v; v.f = f;
    unsigned r = v.u + 0x7fffu + ((v.u >> 16) & 1u);
    return (short)(r >> 16);
}
__device__ __forceinline__ float bf2f(short s) {
    union { unsigned u; float f; } v; v.u = ((unsigned)(unsigned short)s) << 16;
    return v.f;
}
__device__ __forceinline__ bf16x8 pack_bf8(float4 v0, float4 v1) {
    union { bf16x8 v; short e[8]; } pk;
    pk.e[0]=f2bf(v0.x); pk.e[1]=f2bf(v0.y); pk.e[2]=f2bf(v0.z); pk.e[3]=f2bf(v0.w);
    pk.e[4]=f2bf(v1.x); pk.e[5]=f2bf(v1.y); pk.e[6]=f2bf(v1.z); pk.e[7]=f2bf(v1.w);
    return pk.v;
}
__device__ __forceinline__ void gl_lds16(const short* g, short* l) {
    __builtin_amdgcn_global_load_lds(
        (const __attribute__((address_space(1))) void*)g,
        (__attribute__((address_space(3))) void*)l, 16, 0, 0);
}

// ---------------------------------------------------------------------------
// Batched fp32 -> bf16 weight conversion. Segment 10 (wdt) is written into a
// zero-padded [1024,64] layout (cols 32-63 pre-zeroed via hipMemsetAsync).
// ---------------------------------------------------------------------------
struct WcvtArgs { const float* s[11]; short* d[11]; int n[11]; };
__global__ void __launch_bounds__(256) wcvt_kernel(WcvtArgs a) {
    const int seg = blockIdx.y;
    const int i = (blockIdx.x*256 + threadIdx.x) * 8;
    if (i >= a.n[seg]) return;
    const float* s = a.s[seg] + i;
    float4 v0 = *(const float4*)s;
    float4 v1 = *(const float4*)(s + 4);
    int di = i;
    if (seg == 10) di = ((i >> 5) << 6) | (i & 31);   // pad K 32 -> 64
    *(bf16x8*)(a.d[seg] + di) = pack_bf8(v0, v1);
}

// ---------------------------------------------------------------------------
// bf16 MFMA GEMM v4: 2-phase double-buffered, BK=64, 4 waves, 128xBN tile.
// STAGE(next) issued BEFORE compute(cur); ONE barrier per k-tile (T3 minimum
// 2-phase recipe). global_load_lds(16B) into linear LDS. XCD-aware block
// swizzle for per-XCD L2 A-panel reuse. Split-K via gridDim.z.
// ---------------------------------------------------------------------------
template<int BN>
__global__ void __launch_bounds__(256) gemm3_kernel(
    const short* __restrict__ A, int lda,
    const short* __restrict__ W, int ldw,
    const float* __restrict__ bias,
    float* __restrict__ outF, short* __restrict__ outB, int ldc,
    const float* __restrict__ resid, int ldr, float rscale,
    int kLen, int act, int rev_in,
    float* __restrict__ partial, size_t pstride, int N)
{
    constexpr int WN = BN / 64;          // 2 (BN=128) or 1 (BN=64)
    constexpr int WM = 4 / WN;
    constexpr int TM = 128 / WM;         // 64 or 32
    constexpr int FM = TM / 16;          // 4 or 2
    constexpr int WR = BN / 32;          // W staging rounds (4 or 2)

    __shared__ short As[2][128*64];
    __shared__ short Ws[2][BN*64];

    const int tid = threadIdx.x, lane = tid & 63, wid = tid >> 6;

    // XCD-aware swizzle (bijective when nwg % 8 == 0, true for all our grids)
    int nwg = gridDim.x * gridDim.y;
    int flat = blockIdx.y * gridDim.x + blockIdx.x;
    if (!(nwg & 7)) { int cpx = nwg >> 3; flat = (flat & 7)*cpx + (flat >> 3); }
    const int bx = flat % gridDim.x, by = flat / gridDim.x;

    const int rowBase = by << 7;
    const int colBase = bx * BN;
    const int kBase = blockIdx.z * kLen;

    // staging coordinates: unit u = r*256+tid covers 8 shorts
    const int acol = (tid & 7) << 3;
    int arow[4];
    #pragma unroll
    for (int r = 0; r < 4; r++) {
        int rr = rowBase + r*32 + (tid >> 3);
        if (rev_in) { int bb = rr >> 9, l = rr & 511; rr = (bb << 9) + (511 - l); }
        arow[r] = rr;
    }
    int wrow[WR];
    #pragma unroll
    for (int r = 0; r < WR; r++) wrow[r] = colBase + r*32 + (tid >> 3);

    const int fr = lane & 15, fkb = (lane >> 4) << 3;
    const int wm = (wid / WN) * TM, wn = (wid % WN) * 64;

    f32x4 acc[FM][4] = {};

    auto STAGE = [&](int buf, int k0) {
        #pragma unroll
        for (int r = 0; r < 4; r++)
            gl_lds16(A + (size_t)arow[r]*lda + k0 + acol, &As[buf][(r*256 + tid)*8]);
        #pragma unroll
        for (int r = 0; r < WR; r++)
            gl_lds16(W + (size_t)wrow[r]*ldw + k0 + acol, &Ws[buf][(r*256 + tid)*8]);
    };

    const int nT = kLen >> 6;
    STAGE(0, kBase);
    __syncthreads();
    int cur = 0;
    for (int t = 0; t < nT; ++t) {
        if (t + 1 < nT) STAGE(cur ^ 1, kBase + (t+1)*64);
        #pragma unroll
        for (int ks = 0; ks < 2; ks++) {
            bf16x8 af[FM], bfr[4];
            #pragma unroll
            for (int mi = 0; mi < FM; mi++)
                af[mi] = *(const bf16x8*)&As[cur][(wm + mi*16 + fr)*64 + ks*32 + fkb];
            #pragma unroll
            for (int ni = 0; ni < 4; ni++)
                bfr[ni] = *(const bf16x8*)&Ws[cur][(wn + ni*16 + fr)*64 + ks*32 + fkb];
            #pragma unroll
            for (int mi = 0; mi < FM; mi++)
                #pragma unroll
                for (int ni = 0; ni < 4; ni++)
                    acc[mi][ni] = __builtin_amdgcn_mfma_f32_16x16x32_bf16(af[mi], bfr[ni], acc[mi][ni], 0, 0, 0);
        }
        __syncthreads();   // drains just-issued STAGE (vmcnt) + readers of cur
        cur ^= 1;
    }

    if (partial) {
        float* pp = partial + (size_t)blockIdx.z * pstride;
        #pragma unroll
        for (int mi = 0; mi < FM; mi++)
            #pragma unroll
            for (int r = 0; r < 4; r++) {
                int orow = rowBase + wm + mi*16 + ((lane>>4)<<2) + r;
                #pragma unroll
                for (int ni = 0; ni < 4; ni++)
                    pp[(size_t)orow*N + colBase + wn + ni*16 + fr] = acc[mi][ni][r];
            }
    } else {
        #pragma unroll
        for (int mi = 0; mi < FM; mi++)
            #pragma unroll
            for (int r = 0; r < 4; r++) {
                int orow = rowBase + wm + mi*16 + ((lane>>4)<<2) + r;
                #pragma unroll
                for (int ni = 0; ni < 4; ni++) {
                    int gcol = colBase + wn + ni*16 + fr;
                    float v = acc[mi][ni][r];
                    if (bias) v += bias[gcol];
                    if (act == 1) v = siluf_(v);
                    else if (act == 2) v = softplusf_(v);
                    if (resid) v = resid[(size_t)orow*ldr + gcol] + rscale*v;
                    if (outF) outF[(size_t)orow*ldc + gcol] = v;
                    if (outB) outB[(size_t)orow*ldc + gcol] = f2bf(v);
                }
            }
    }
}

// ---------------------------------------------------------------------------
// Split-K reduce + epilogue.
// ---------------------------------------------------------------------------
__global__ void __launch_bounds__(256) reduce_kernel(
    const float* __restrict__ part, int S, size_t pstride, int N,
    const float* __restrict__ bias, int act,
    const float* __restrict__ resid, int ldr, float rscale,
    float* __restrict__ outF, short* __restrict__ outB, int ldc,
    int colOff, int rev_out)
{
    const int i4 = blockIdx.x*256 + threadIdx.x;
    const int row = i4 / (N >> 2);
    const int c4  = (i4 - row*(N >> 2)) << 2;
    float4 s = *(const float4*)(part + (size_t)row*N + c4);
    for (int z = 1; z < S; z++) {
        float4 t = *(const float4*)(part + (size_t)z*pstride + (size_t)row*N + c4);
        s.x += t.x; s.y += t.y; s.z += t.z; s.w += t.w;
    }
    if (bias) { float4 b = *(const float4*)(bias + c4); s.x+=b.x; s.y+=b.y; s.z+=b.z; s.w+=b.w; }
    if (act == 1) { s.x=siluf_(s.x); s.y=siluf_(s.y); s.z=siluf_(s.z); s.w=siluf_(s.w); }
    else if (act == 2) { s.x=softplusf_(s.x); s.y=softplusf_(s.y); s.z=softplusf_(s.z); s.w=softplusf_(s.w); }
    int orow = row;
    if (rev_out) { int b = row >> 9, l = row & 511; orow = (b << 9) + (511 - l); }
    if (resid) {
        float4 rr = *(const float4*)(resid + (size_t)orow*ldr + colOff + c4);
        s.x = rr.x + rscale*s.x; s.y = rr.y + rscale*s.y;
        s.z = rr.z + rscale*s.z; s.w = rr.w + rscale*s.w;
    }
    if (outF) *(float4*)(outF + (size_t)orow*ldc + colOff + c4) = s;
    if (outB) {
        short4 o; o.x=f2bf(s.x); o.y=f2bf(s.y); o.z=f2bf(s.z); o.w=f2bf(s.w);
        *(short4*)(outB + (size_t)orow*ldc + colOff + c4) = o;
    }
}

// ---------------------------------------------------------------------------
// LayerNorm over 512; fp32 and/or bf16 out.
// ---------------------------------------------------------------------------
__global__ void __launch_bounds__(128) ln_kernel(
    const float* __restrict__ x, const float* __restrict__ g,
    const float* __restrict__ bta, float* __restrict__ outF,
    short* __restrict__ outB)
{
    const int row = blockIdx.x;
    const int t = threadIdx.x;
    float4 v = ((const float4*)(x + (size_t)row*DD))[t];
    float s = v.x+v.y+v.z+v.w;
    float q = v.x*v.x+v.y*v.y+v.z*v.z+v.w*v.w;
    #pragma unroll
    for (int off = 32; off >= 1; off >>= 1) {
        s += __shfl_down(s, off);
        q += __shfl_down(q, off);
    }
    __shared__ float sh[4];
    if ((t & 63) == 0) { sh[(t>>6)*2] = s; sh[(t>>6)*2+1] = q; }
    __syncthreads();
    float mean = (sh[0]+sh[2]) * (1.0f/DD);
    float var  = (sh[1]+sh[3]) * (1.0f/DD) - mean*mean;
    float rstd = rsqrtf(var + 1e-5f);
    float4 gg = ((const float4*)g)[t];
    float4 bb = ((const float4*)bta)[t];
    float4 o;
    o.x = (v.x-mean)*rstd*gg.x + bb.x;
    o.y = (v.y-mean)*rstd*gg.y + bb.y;
    o.z = (v.z-mean)*rstd*gg.z + bb.z;
    o.w = (v.w-mean)*rstd*gg.w + bb.w;
    if (outF) ((float4*)(outF + (size_t)row*DD))[t] = o;
    if (outB) {
        short4 ob; ob.x=f2bf(o.x); ob.y=f2bf(o.y); ob.z=f2bf(o.z); ob.w=f2bf(o.w);
        *(short4*)(outB + (size_t)row*DD + t*4) = ob;
    }
}

// ---------------------------------------------------------------------------
// Mamba causal dwconv (K=4) + bias + SiLU; xi = cols 0-1023 of xz [MM,2048].
// ---------------------------------------------------------------------------
__global__ void __launch_bounds__(256) mamba_conv_kernel(
    const short* __restrict__ xz, const float* __restrict__ cw,
    const float* __restrict__ cb, short* __restrict__ xcb16)
{
    const int idx = blockIdx.x*256 + threadIdx.x;
    const int c = idx & (DII-1);
    const int row = idx >> 10;
    const int l = row & (LL-1);
    float4 w = ((const float4*)cw)[c];
    const float* wf = (const float*)&w;
    float acc = cb[c];
    #pragma unroll
    for (int t = 0; t < 4; t++) {
        int ll = l - 3 + t;
        if (ll >= 0) acc += wf[t] * bf2f(xz[((size_t)(row - l + ll))*2048 + c]);
    }
    xcb16[idx] = f2bf(siluf_(acc));
}

// ---------------------------------------------------------------------------
// Selective scan, 3-pass chunked associative (one thread owns 16 states).
// ---------------------------------------------------------------------------
__global__ void __launch_bounds__(256) scan_a_kernel(
    const short* __restrict__ dt_bf, const short* __restrict__ xc_bf,
    const float* __restrict__ xdb, const float* __restrict__ Alog,
    float* __restrict__ P, float* __restrict__ Hl)
{
    const int bid = blockIdx.x;
    const int dg = bid & 3;
    const int c  = (bid >> 2) & (NCH-1);
    const int b  = bid >> 6;
    const int d  = (dg << 8) + threadIdx.x;

    float Aexp[16];
    #pragma unroll
    for (int n = 0; n < 16; n++) Aexp[n] = -__expf(Alog[d*16 + n]);

    float h[16], Pp[16];
    #pragma unroll
    for (int n = 0; n < 16; n++) { h[n] = 0.f; Pp[n] = 1.f; }

    const size_t l0 = (size_t)b*LL + (size_t)c*CHL;
    const short* dtp = dt_bf + l0*DII + d;
    const short* xcp = xc_bf + l0*DII + d;
    const float* bp  = xdb + l0*64 + 32;

    #pragma unroll 2
    for (int l = 0; l < CHL; l++) {
        float dtv = bf2f(dtp[(size_t)l*DII]);
        float xcv = bf2f(xcp[(size_t)l*DII]);
        float co = dtv*xcv;
        float Bv[16];
        #pragma unroll
        for (int q4 = 0; q4 < 4; q4++) {
            float4 v = *(const float4*)(bp + (size_t)l*64 + q4*4);
            Bv[q4*4+0]=v.x; Bv[q4*4+1]=v.y; Bv[q4*4+2]=v.z; Bv[q4*4+3]=v.w;
        }
        #pragma unroll
        for (int n = 0; n < 16; n++) {
            float q = __expf(dtv*Aexp[n]);
            Pp[n] *= q;
            h[n] = fmaf(q, h[n], co*Bv[n]);
        }
    }
    size_t base = (((size_t)b*NCH + c)*16)*DII + d;
    #pragma unroll
    for (int n = 0; n < 16; n++) {
        P[base + (size_t)n*DII]  = Pp[n];
        Hl[base + (size_t)n*DII] = h[n];
    }
}

__global__ void __launch_bounds__(256) scan_b_kernel(
    const float* __restrict__ Hl, float* Phin)
{
    const int g = blockIdx.x*256 + threadIdx.x;
    const int d = g & (DII-1);
    const int n = (g >> 10) & 15;
    const int b = g >> 14;
    const size_t cs = (size_t)16*DII;
    const size_t base = ((size_t)b*NCH*16 + (size_t)n)*DII + d;
    float h = 0.f;
    for (int c = 0; c < NCH; c++) {
        size_t i = base + (size_t)c*cs;
        float pn = Phin[i];
        float hn = pn*h + Hl[i];
        Phin[i] = h;
        h = hn;
    }
}

__global__ void __launch_bounds__(256) scan_c_kernel(
    const short* __restrict__ dt_bf, short* xc_ys,
    const float* __restrict__ xdb, const float* __restrict__ Alog,
    const float* __restrict__ hin, const short* __restrict__ zb, /* stride 2048 */
    const float* __restrict__ Dp)
{
    const int bid = blockIdx.x;
    const int dg = bid & 3;
    const int c  = (bid >> 2) & (NCH-1);
    const int b  = bid >> 6;
    const int d  = (dg << 8) + threadIdx.x;

    float Aexp[16];
    #pragma unroll
    for (int n = 0; n < 16; n++) Aexp[n] = -__expf(Alog[d*16 + n]);
    const float Dpv = Dp[d];

    float h[16];
    const size_t hb = (((size_t)b*NCH + c)*16)*DII + d;
    #pragma unroll
    for (int n = 0; n < 16; n++) h[n] = hin[hb + (size_t)n*DII];

    const size_t l0 = (size_t)b*LL + (size_t)c*CHL;
    const short* dtp = dt_bf + l0*DII + d;
    short*       xcp = xc_ys + l0*DII + d;
    const short* zp  = zb + l0*2048 + d;
    const float* bp  = xdb + l0*64 + 32;

    #pragma unroll 2
    for (int l = 0; l < CHL; l++) {
        float dtv = bf2f(dtp[(size_t)l*DII]);
        float xcv = bf2f(xcp[(size_t)l*DII]);
        float zv  = bf2f(zp[(size_t)l*2048]);
        float co = dtv*xcv;
        float Bv[16], Cv[16];
        #pragma unroll
        for (int q4 = 0; q4 < 4; q4++) {
            float4 v = *(const float4*)(bp + (size_t)l*64 + q4*4);
            Bv[q4*4+0]=v.x; Bv[q4*4+1]=v.y; Bv[q4*4+2]=v.z; Bv[q4*4+3]=v.w;
            float4 w = *(const float4*)(bp + (size_t)l*64 + 16 + q4*4);
            Cv[q4*4+0]=w.x; Cv[q4*4+1]=w.y; Cv[q4*4+2]=w.z; Cv[q4*4+3]=w.w;
        }
        float y = 0.f;
        #pragma unroll
        for (int n = 0; n < 16; n++) {
            float q = __expf(dtv*Aexp[n]);
            h[n] = fmaf(q, h[n], co*Bv[n]);
            y = fmaf(Cv[n], h[n], y);
        }
        float out = (y + Dpv*xcv) * siluf_(zv);
        xcp[(size_t)l*DII] = f2bf(out);
    }
}

// ---------------------------------------------------------------------------
// GLU + transpose to [b, c, l] fp32.
// ---------------------------------------------------------------------------
__global__ void __launch_bounds__(256) glu_transpose_kernel(
    const float* __restrict__ pw1, float* __restrict__ out_t)
{
    __shared__ float sh[64][65];
    const int c0 = blockIdx.x << 6;
    const int l0 = blockIdx.y << 6;
    const int b  = blockIdx.z;
    const int t  = threadIdx.x;
    const int c4 = (t & 15) << 2;
    const int r  = t >> 4;
    #pragma unroll
    for (int i = 0; i < 4; i++) {
        int lrow = r + i*16;
        size_t row = (size_t)(b << 9) + l0 + lrow;
        float4 a = *(const float4*)(pw1 + row*1024 + c0 + c4);
        float4 g = *(const float4*)(pw1 + row*1024 + 512 + c0 + c4);
        sh[lrow][c4+0] = a.x * sigmoidf_(g.x);
        sh[lrow][c4+1] = a.y * sigmoidf_(g.y);
        sh[lrow][c4+2] = a.z * sigmoidf_(g.z);
        sh[lrow][c4+3] = a.w * sigmoidf_(g.w);
    }
    __syncthreads();
    #pragma unroll
    for (int i = 0; i < 4; i++) {
        int crow = r + i*16;
        float4 o;
        o.x = sh[c4+0][crow];
        o.y = sh[c4+1][crow];
        o.z = sh[c4+2][crow];
        o.w = sh[c4+3][crow];
        *(float4*)(out_t + ((size_t)(b << 9) + c0 + crow)*512 + l0 + c4) = o;
    }
}

// ---------------------------------------------------------------------------
// Channel-major fused 3x dwconv avg + BN + SiLU (SGPR weights).
// ---------------------------------------------------------------------------
__global__ void __launch_bounds__(256) multiconv_t_kernel(
    const float* __restrict__ gin_t,
    const float* __restrict__ w15, const float* __restrict__ w31,
    const float* __restrict__ w63,
    const float* __restrict__ bn_g, const float* __restrict__ bn_b,
    const float* __restrict__ bn_m, const float* __restrict__ bn_v,
    float* __restrict__ out_t)
{
    __shared__ float sh[574];
    const int c = blockIdx.x & (DD-1);
    const int b = blockIdx.x >> 9;
    const int t = threadIdx.x;
    const float* rowp = gin_t + ((size_t)(b << 9) + c)*512;
    sh[31 + t]       = rowp[t];
    sh[31 + t + 256] = rowp[t + 256];
    if (t < 31) { sh[t] = 0.f; sh[543 + t] = 0.f; }
    __syncthreads();

    const float bnscale = rsqrtf(bn_v[c] + 1e-5f) * bn_g[c];
    const float bnm = bn_m[c], bnb = bn_b[c];
    float* outp = out_t + ((size_t)(b << 9) + c)*512;
    #pragma unroll
    for (int half = 0; half < 2; half++) {
        int l = t + half*256;
        float s63 = 0.f, s31 = 0.f, s15 = 0.f;
        #pragma unroll
        for (int k = 0; k < 63; k++) s63 += w63[c*63 + k] * sh[l + k];
        #pragma unroll
        for (int k = 0; k < 31; k++) s31 += w31[c*31 + k] * sh[l + 16 + k];
        #pragma unroll
        for (int k = 0; k < 15; k++) s15 += w15[c*15 + k] * sh[l + 24 + k];
        float m = (s15 + s31 + s63) * (1.0f/3.0f);
        m = (m - bnm) * bnscale + bnb;
        outp[l] = siluf_(m);
    }
}

// ---------------------------------------------------------------------------
// Transpose [b, c, l] -> [b, l, c], bf16 out.
// ---------------------------------------------------------------------------
__global__ void __launch_bounds__(256) transpose_bcl_kernel(
    const float* __restrict__ in_t, short* __restrict__ out)
{
    __shared__ float sh[64][65];
    const int l0 = blockIdx.x << 6;
    const int c0 = blockIdx.y << 6;
    const int b  = blockIdx.z;
    const int t  = threadIdx.x;
    const int l4 = (t & 15) << 2;
    const int r  = t >> 4;
    #pragma unroll
    for (int i = 0; i < 4; i++) {
        int crow = r + i*16;
        float4 v = *(const float4*)(in_t + ((size_t)(b << 9) + c0 + crow)*512 + l0 + l4);
        sh[crow][l4+0] = v.x; sh[crow][l4+1] = v.y;
        sh[crow][l4+2] = v.z; sh[crow][l4+3] = v.w;
    }
    __syncthreads();
    #pragma unroll
    for (int i = 0; i < 4; i++) {
        int lrow = r + i*16;
        short4 o;
        o.x = f2bf(sh[l4+0][lrow]);
        o.y = f2bf(sh[l4+1][lrow]);
        o.z = f2bf(sh[l4+2][lrow]);
        o.w = f2bf(sh[l4+3][lrow]);
        *(short4*)(out + ((size_t)(b << 9) + l0 + lrow)*512 + c0 + l4) = o;
    }
}

// ---------------------------------------------------------------------------
extern "C" void kernel_launch(void* const* d_in, const int* in_sizes, int n_in,
                              void* d_out, int out_size, void* d_ws, size_t ws_size,
                              hipStream_t stream)
{
    const float* x        = (const float*)d_in[0];
    const float* ff1_ln_g = (const float*)d_in[1];
    const float* ff1_ln_b = (const float*)d_in[2];
    const float* ff1_w1   = (const float*)d_in[3];
    const float* ff1_b1   = (const float*)d_in[4];
    const float* ff1_w2   = (const float*)d_in[5];
    const float* ff1_b2   = (const float*)d_in[6];
    const float* ff2_ln_g = (const float*)d_in[7];
    const float* ff2_ln_b = (const float*)d_in[8];
    const float* ff2_w1   = (const float*)d_in[9];
    const float* ff2_b1   = (const float*)d_in[10];
    const float* ff2_w2   = (const float*)d_in[11];
    const float* ff2_b2   = (const float*)d_in[12];
    const float* m_win    = (const float*)d_in[13];
    const float* m_convw  = (const float*)d_in[14];
    const float* m_convb  = (const float*)d_in[15];
    const float* m_wx     = (const float*)d_in[16];
    const float* m_wdt    = (const float*)d_in[17];
    const float* m_bdt    = (const float*)d_in[18];
    const float* m_Alog   = (const float*)d_in[19];
    const float* m_Dp     = (const float*)d_in[20];
    const float* m_wout   = (const float*)d_in[21];
    const float* bi_wo    = (const float*)d_in[22];
    const float* bi_bo    = (const float*)d_in[23];
    const float* cv_ln_g  = (const float*)d_in[24];
    const float* cv_ln_b  = (const float*)d_in[25];
    const float* cv_pw1_w = (const float*)d_in[26];
    const float* cv_pw1_b = (const float*)d_in[27];
    const float* cv_dw15  = (const float*)d_in[28];
    const float* cv_dw31  = (const float*)d_in[29];
    const float* cv_dw63  = (const float*)d_in[30];
    const float* cv_bn_g  = (const float*)d_in[31];
    const float* cv_bn_b  = (const float*)d_in[32];
    const float* cv_bn_m  = (const float*)d_in[33];
    const float* cv_bn_v  = (const float*)d_in[34];
    const float* cv_pw2_w = (const float*)d_in[35];
    const float* cv_pw2_b = (const float*)d_in[36];
    const float* ln_g     = (const float*)d_in[37];
    const float* ln_b     = (const float*)d_in[38];

    // ---- Workspace layout (MiB offsets), total 113 MiB ----
    char* wsb = (char*)d_ws;
    float* h       = (float*)(wsb + 0);           // 0-8   residual f32
    short* h_bf    = (short*)(wsb + 8*MB_);       // 8-12
    short* lnb_bf  = (short*)(wsb + 12*MB_);      // 12-16 LN out / y_bf
    short* wbf     = (short*)(wsb + 16*MB_);      // 16-33 bf16 weights (17 MiB)
    short* hid_bf  = (short*)(wsb + 33*MB_);      // 33-49 FFN hidden [MM,2048]
    float* part    = (float*)(wsb + 49*MB_);      // 49-65 split-K partials / pw1out
    float* scanP   = (float*)(wsb + 65*MB_);      // 65-73 P (then h_in, aliased)
    float* scanH   = (float*)(wsb + 73*MB_);      // 73-81 Hlocal
    short* xz_bf   = (short*)(wsb + 89*MB_);      // 89-105 xz bf16 [MM,2048]
    float* glu_t   = (float*)(wsb + 89*MB_);      //   (ConvMod overlay)
    float* mconv_o = (float*)(wsb + 97*MB_);      //   (ConvMod overlay)
    short* xcbf    = (short*)(wsb + 105*MB_);     // 105-113 xc bf16 (ys in-place)
    // mamba-phase overlays inside hid_bf region:
    short* dt_bf   = (short*)(wsb + 33*MB_);      // 33-41 dt bf16 [MM,1024]
    float* xdbb    = (float*)(wsb + 41*MB_);      // 41-42 xdb f32 [MM,64]
    short* xdb_bf  = (short*)(wsb + 42*MB_);      // 42-42.5 xdb bf16
    float* scanHin = scanP;

    // bf16 weight sub-pointers (element offsets)
    short* w_ff1w1 = wbf;
    short* w_ff1w2 = wbf + 1048576;
    short* w_ff2w1 = wbf + 2097152;
    short* w_ff2w2 = wbf + 3145728;
    short* w_win   = wbf + 4194304;
    short* w_wx    = wbf + 6291456;
    short* w_wout  = wbf + 6422528;
    short* w_biwo  = wbf + 7471104;
    short* w_pw1   = wbf + 7995392;
    short* w_pw2   = wbf + 8519680;
    short* w_wdt   = wbf + 8781824;   // padded [2*1024, 64] -> 131072 els

    if (ws_size < (size_t)113*MB_) return;

    // 0. weights -> bf16 (wdt region pre-zeroed for K-padding)
    hipMemsetAsync(w_wdt, 0, 131072*sizeof(short), stream);
    WcvtArgs wa;
    wa.s[0]=ff1_w1;  wa.d[0]=w_ff1w1; wa.n[0]=1048576;
    wa.s[1]=ff1_w2;  wa.d[1]=w_ff1w2; wa.n[1]=1048576;
    wa.s[2]=ff2_w1;  wa.d[2]=w_ff2w1; wa.n[2]=1048576;
    wa.s[3]=ff2_w2;  wa.d[3]=w_ff2w2; wa.n[3]=1048576;
    wa.s[4]=m_win;   wa.d[4]=w_win;   wa.n[4]=2097152;
    wa.s[5]=m_wx;    wa.d[5]=w_wx;    wa.n[5]=131072;
    wa.s[6]=m_wout;  wa.d[6]=w_wout;  wa.n[6]=1048576;
    wa.s[7]=bi_wo;   wa.d[7]=w_biwo;  wa.n[7]=524288;
    wa.s[8]=cv_pw1_w;wa.d[8]=w_pw1;   wa.n[8]=524288;
    wa.s[9]=cv_pw2_w;wa.d[9]=w_pw2;   wa.n[9]=262144;
    wa.s[10]=m_wdt;  wa.d[10]=w_wdt;  wa.n[10]=131072;
    wcvt_kernel<<<dim3(1024,11), 256, 0, stream>>>(wa);

    auto G3 = [&](const short* A, int lda, const short* W, int ldw,
                  const float* bias, float* oF, short* oB, int ldc,
                  const float* res, int ldr, float rs,
                  int N, int K, int splits, int act, int ri, float* prt) {
        dim3 g(N/128, 32, splits);
        gemm3_kernel<128><<<g, 256, 0, stream>>>(A, lda, W, ldw, bias, oF, oB, ldc,
            res, ldr, rs, K/splits, act, ri, prt, (size_t)MM*N, N);
    };
    auto RED = [&](const float* p, int S, int N, const float* bias, int act,
                   const float* res, int ldr, float rs,
                   float* oF, short* oB, int ldc, int colOff, int rev) {
        reduce_kernel<<<(MM*N/4)/256, 256, 0, stream>>>(p, S, (size_t)MM*N, N,
            bias, act, res, ldr, rs, oF, oB, ldc, colOff, rev);
    };

    // ---- FFN1: h = x + 0.5*(silu(LN@w1+b1)@w2+b2), also h_bf
    ln_kernel<<<MM, 128, 0, stream>>>(x, ff1_ln_g, ff1_ln_b, nullptr, lnb_bf);
    G3(lnb_bf, 512, w_ff1w1, 512, ff1_b1, nullptr, hid_bf, 2048,
       nullptr, 0, 0.f, 2048, 512, 1, 1, 0, nullptr);
    G3(hid_bf, 2048, w_ff1w2, 2048, nullptr, nullptr, nullptr, 0,
       nullptr, 0, 0.f, 512, 2048, 2, 0, 0, part);
    RED(part, 2, 512, ff1_b2, 0, x, 512, 0.5f, h, h_bf, 512, 0, 0);

    // ---- BiMamba
    for (int dir = 0; dir < 2; dir++) {
        const short* winb  = w_win  + (size_t)dir*2048*512;
        const float* convw = m_convw + (size_t)dir*DII*4;
        const float* convb = m_convb + (size_t)dir*DII;
        const short* wxb   = w_wx   + (size_t)dir*64*1024;
        const short* wdtb  = w_wdt  + (size_t)dir*1024*64;
        const float* bdt   = m_bdt  + (size_t)dir*DII;
        const float* Alog  = m_Alog + (size_t)dir*DII*NST;
        const float* Dp    = m_Dp   + (size_t)dir*DII;
        const short* woutb = w_wout + (size_t)dir*512*1024;

        // xz = h(rev for dir=1) @ win^T -> [MM,2048] bf16, one GEMM
        G3(h_bf, 512, winb, 512, nullptr, nullptr, xz_bf, 2048,
           nullptr, 0, 0.f, 2048, 512, 1, 0, dir, nullptr);
        // causal dwconv + silu (xi = xz cols 0-1023)
        mamba_conv_kernel<<<MM*DII/256, 256, 0, stream>>>(xz_bf, convw, convb, xcbf);
        // xdb = xc @ wx^T (N=64, split-K 4)
        {
            dim3 g(1, 32, 4);
            gemm3_kernel<64><<<g, 256, 0, stream>>>(xcbf, 1024, wxb, 1024,
                nullptr, nullptr, nullptr, 0, nullptr, 0, 0.f,
                256, 0, 0, part, (size_t)MM*64, 64);
        }
        RED(part, 4, 64, nullptr, 0, nullptr, 0, 0.f, xdbb, xdb_bf, 64, 0, 0);
        // dt = softplus(xdb @ wdt_pad^T + bdt) -> bf16 (K padded to 64)
        G3(xdb_bf, 64, wdtb, 64, bdt, nullptr, dt_bf, 1024,
           nullptr, 0, 0.f, 1024, 64, 1, 2, 0, nullptr);
        // 3-pass scan + fused ycombine (ys overwrites xcbf)
        scan_a_kernel<<<BB*NCH*4, 256, 0, stream>>>(dt_bf, xcbf, xdbb, Alog, scanP, scanH);
        scan_b_kernel<<<BB*16*DII/256, 256, 0, stream>>>(scanH, scanP);
        scan_c_kernel<<<BB*NCH*4, 256, 0, stream>>>(dt_bf, xcbf, xdbb, Alog, scanHin,
                                                    xz_bf + DII, Dp);
        // y_out = ys @ wout^T (rev rows back for dir=1) -> y_bf
        G3(xcbf, 1024, woutb, 1024, nullptr, nullptr, nullptr, 0,
           nullptr, 0, 0.f, 512, 1024, 2, 0, 0, part);
        RED(part, 2, 512, nullptr, 0, nullptr, 0, 0.f, nullptr, lnb_bf, 512, 0, dir);
        // h += y_out @ bi_wo[:, dir*512:]^T (+ bi_bo on dir=1)
        G3(lnb_bf, 512, w_biwo + dir*512, 1024, nullptr, nullptr, nullptr, 0,
           nullptr, 0, 0.f, 512, 512, 2, 0, 0, part);
        RED(part, 2, 512, dir ? bi_bo : nullptr, 0, h, 512, 1.0f, h, nullptr, 512, 0, 0);
    }

    // ---- ConvMod
    ln_kernel<<<MM, 128, 0, stream>>>(h, cv_ln_g, cv_ln_b, nullptr, lnb_bf);
    G3(lnb_bf, 512, w_pw1, 512, cv_pw1_b, part, nullptr, 1024,
       nullptr, 0, 0.f, 1024, 512, 1, 0, 0, nullptr);
    glu_transpose_kernel<<<dim3(8,8,8), 256, 0, stream>>>(part, glu_t);
    multiconv_t_kernel<<<BB*DD, 256, 0, stream>>>(glu_t,
        cv_dw15, cv_dw31, cv_dw63, cv_bn_g, cv_bn_b, cv_bn_m, cv_bn_v, mconv_o);
    transpose_bcl_kernel<<<dim3(8,8,8), 256, 0, stream>>>(mconv_o, lnb_bf);
    G3(lnb_bf, 512, w_pw2, 512, nullptr, nullptr, nullptr, 0,
       nullptr, 0, 0.f, 512, 512, 2, 0, 0, part);
    RED(part, 2, 512, cv_pw2_b, 0, h, 512, 1.0f, h, nullptr, 512, 0, 0);

    // ---- FFN2
    ln_kernel<<<MM, 128, 0, stream>>>(h, ff2_ln_g, ff2_ln_b, nullptr, lnb_bf);
    G3(lnb_bf, 512, w_ff2w1, 512, ff2_b1, nullptr, hid_bf, 2048,
       nullptr, 0, 0.f, 2048, 512, 1, 1, 0, nullptr);
    G3(hid_bf, 2048, w_ff2w2, 2048, nullptr, nullptr, nullptr, 0,
       nullptr, 0, 0.f, 512, 2048, 2, 0, 0, part);
    RED(part, 2, 512, ff2_b2, 0, h, 512, 0.5f, h, nullptr, 512, 0, 0);

    // ---- Final LN -> d_out (fp32)
    ln_kernel<<<MM, 128, 0, stream>>>(h, ln_g, ln_b, (float*)d_out, nullptr);
}

// Round 7
// 602.931 us; speedup vs baseline: 4.0814x; 1.0502x over previous
//
#include <hip/hip_runtime.h>
#include <hip/hip_bf16.h>
#include <math.h>

#define LL   512
#define DD   512
#define DII  1024
#define NST  16
#define BB   8
#define MM   4096
#define CHL  32     // scan chunk length
#define NCH  16     // chunks (NCH*CHL == LL)
#define MB_  (1024*1024)

typedef __attribute__((ext_vector_type(8))) short bf16x8;
typedef __attribute__((ext_vector_type(4))) float f32x4;

__device__ __forceinline__ float sigmoidf_(float x){ return 1.0f/(1.0f+expf(-x)); }
__device__ __forceinline__ float siluf_(float x){ return x*sigmoidf_(x); }
__device__ __forceinline__ float softplusf_(float x){ return x > 20.0f ? x : log1pf(expf(x)); }

__device__ __forceinline__ short f2bf(float f) {
    union { float f; unsigned u; } v; v.f = f;
    unsigned r = v.u + 0x7fffu + ((v.u >> 16) & 1u);
    return (short)(r >> 16);
}
__device__ __forceinline__ float bf2f(short s) {
    union { unsigned u; float f; } v; v.u = ((unsigned)(unsigned short)s) << 16;
    return v.f;
}
__device__ __forceinline__ bf16x8 pack_bf8(float4 v0, float4 v1) {
    union { bf16x8 v; short e[8]; } pk;
    pk.e[0]=f2bf(v0.x); pk.e[1]=f2bf(v0.y); pk.e[2]=f2bf(v0.z); pk.e[3]=f2bf(v0.w);
    pk.e[4]=f2bf(v1.x); pk.e[5]=f2bf(v1.y); pk.e[6]=f2bf(v1.z); pk.e[7]=f2bf(v1.w);
    return pk.v;
}
__device__ __forceinline__ void gl_lds16(const short* g, short* l) {
    __builtin_amdgcn_global_load_lds(
        (const __attribute__((address_space(1))) void*)g,
        (__attribute__((address_space(3))) void*)l, 16, 0, 0);
}

// ---------------------------------------------------------------------------
// Batched fp32 -> bf16 weight conversion. Segment 10 (wdt) is written into a
// zero-padded [1024,64] layout (cols 32-63 pre-zeroed via hipMemsetAsync).
// ---------------------------------------------------------------------------
struct WcvtArgs { const float* s[11]; short* d[11]; int n[11]; };
__global__ void __launch_bounds__(256) wcvt_kernel(WcvtArgs a) {
    const int seg = blockIdx.y;
    const int i = (blockIdx.x*256 + threadIdx.x) * 8;
    if (i >= a.n[seg]) return;
    const float* s = a.s[seg] + i;
    float4 v0 = *(const float4*)s;
    float4 v1 = *(const float4*)(s + 4);
    int di = i;
    if (seg == 10) di = ((i >> 5) << 6) | (i & 31);   // pad K 32 -> 64
    *(bf16x8*)(a.d[seg] + di) = pack_bf8(v0, v1);
}

// ---------------------------------------------------------------------------
// bf16 MFMA GEMM v5: 2-deep pipeline with COUNTED vmcnt (T4) + T2 source-
// pre-swizzle. 128xBN tile, BK=64, 4 waves.
//  - STAGE(t+1) issued, then s_waitcnt vmcnt(8) waits only for tile t's loads
//    (issued one full iteration earlier) -> no full drain in the main loop.
//  - Raw s_barrier (no implicit vmcnt(0)); sched_barrier(0) fences (rule 18).
//  - T2: LDS dest stays linear (gload_lds requirement); global source col-unit
//    XORed with (row&7); ds_read applies the same XOR -> conflict-free
//    (2 lanes/bank). Read offsets reduce to 2 per-lane constants since
//    row&7 == lane&7 for all fragment rows.
// ---------------------------------------------------------------------------
template<int BN>
__global__ void __launch_bounds__(256) gemm3_kernel(
    const short* __restrict__ A, int lda,
    const short* __restrict__ W, int ldw,
    const float* __restrict__ bias,
    float* __restrict__ outF, short* __restrict__ outB, int ldc,
    const float* __restrict__ resid, int ldr, float rscale,
    int kLen, int act, int rev_in,
    float* __restrict__ partial, size_t pstride, int N)
{
    constexpr int WN = BN / 64;          // 2 (BN=128) or 1 (BN=64)
    constexpr int WM = 4 / WN;
    constexpr int TM = 128 / WM;         // 64 or 32
    constexpr int FM = TM / 16;          // 4 or 2
    constexpr int WR = BN / 32;          // W staging rounds (4 or 2)

    __shared__ short As[2][128*64];
    __shared__ short Ws[2][BN*64];

    const int tid = threadIdx.x, lane = tid & 63, wid = tid >> 6;

    // XCD-aware swizzle (bijective when nwg % 8 == 0 — true for all our grids)
    int nwg = gridDim.x * gridDim.y;
    int flat = blockIdx.y * gridDim.x + blockIdx.x;
    if (!(nwg & 7)) { int cpx = nwg >> 3; flat = (flat & 7)*cpx + (flat >> 3); }
    const int bx = flat % gridDim.x, by = flat / gridDim.x;

    const int rowBase = by << 7;
    const int colBase = bx * BN;
    const int kBase = blockIdx.z * kLen;

    // staging: thread covers row r*32+(tid>>3), LDS 16B-unit (tid&7);
    // T2 pre-swizzle: global col-unit = (tid&7) ^ (row&7)
    const int srcu = (((tid & 7) ^ ((tid >> 3) & 7)) << 3);   // shorts
    int arow[4];
    #pragma unroll
    for (int r = 0; r < 4; r++) {
        int rr = rowBase + r*32 + (tid >> 3);
        if (rev_in) { int bb = rr >> 9, l = rr & 511; rr = (bb << 9) + (511 - l); }
        arow[r] = rr;
    }
    int wrow[WR];
    #pragma unroll
    for (int r = 0; r < WR; r++) wrow[r] = colBase + r*32 + (tid >> 3);

    const int fr = lane & 15;
    // swizzled read offsets (shorts), ks=0/1: ((ks*4 + lane>>4) ^ (lane&7)) * 8
    const int swz0 = ((((lane >> 4)    ) ^ (lane & 7)) << 3);
    const int swz1 = ((((lane >> 4) | 4) ^ (lane & 7)) << 3);
    const int wm = (wid / WN) * TM, wn = (wid % WN) * 64;

    f32x4 acc[FM][4] = {};

    auto STAGE = [&](int buf, int k0) {
        #pragma unroll
        for (int r = 0; r < 4; r++)
            gl_lds16(A + (size_t)arow[r]*lda + k0 + srcu, &As[buf][(r*256 + tid)*8]);
        #pragma unroll
        for (int r = 0; r < WR; r++)
            gl_lds16(W + (size_t)wrow[r]*ldw + k0 + srcu, &Ws[buf][(r*256 + tid)*8]);
    };

    const int nT = kLen >> 6;
    STAGE(0, kBase);
    int cur = 0;
    for (int t = 0; t < nT; ++t) {
        if (t + 1 < nT) {
            STAGE(cur ^ 1, kBase + (t+1)*64);
            if (BN == 128) { asm volatile("s_waitcnt vmcnt(8)" ::: "memory"); }
            else           { asm volatile("s_waitcnt vmcnt(6)" ::: "memory"); }
        } else {
            asm volatile("s_waitcnt vmcnt(0)" ::: "memory");
        }
        __builtin_amdgcn_sched_barrier(0);
        __builtin_amdgcn_s_barrier();        // all waves' tile-t loads landed
        __builtin_amdgcn_sched_barrier(0);
        #pragma unroll
        for (int ks = 0; ks < 2; ks++) {
            const int so = ks ? swz1 : swz0;
            bf16x8 af[FM], bfr[4];
            #pragma unroll
            for (int mi = 0; mi < FM; mi++)
                af[mi] = *(const bf16x8*)&As[cur][(wm + mi*16 + fr)*64 + so];
            #pragma unroll
            for (int ni = 0; ni < 4; ni++)
                bfr[ni] = *(const bf16x8*)&Ws[cur][(wn + ni*16 + fr)*64 + so];
            #pragma unroll
            for (int mi = 0; mi < FM; mi++)
                #pragma unroll
                for (int ni = 0; ni < 4; ni++)
                    acc[mi][ni] = __builtin_amdgcn_mfma_f32_16x16x32_bf16(af[mi], bfr[ni], acc[mi][ni], 0, 0, 0);
        }
        __builtin_amdgcn_sched_barrier(0);
        __builtin_amdgcn_s_barrier();        // readers of buf[cur] done
        __builtin_amdgcn_sched_barrier(0);
        cur ^= 1;
    }

    if (partial) {
        float* pp = partial + (size_t)blockIdx.z * pstride;
        #pragma unroll
        for (int mi = 0; mi < FM; mi++)
            #pragma unroll
            for (int r = 0; r < 4; r++) {
                int orow = rowBase + wm + mi*16 + ((lane>>4)<<2) + r;
                #pragma unroll
                for (int ni = 0; ni < 4; ni++)
                    pp[(size_t)orow*N + colBase + wn + ni*16 + fr] = acc[mi][ni][r];
            }
    } else {
        #pragma unroll
        for (int mi = 0; mi < FM; mi++)
            #pragma unroll
            for (int r = 0; r < 4; r++) {
                int orow = rowBase + wm + mi*16 + ((lane>>4)<<2) + r;
                #pragma unroll
                for (int ni = 0; ni < 4; ni++) {
                    int gcol = colBase + wn + ni*16 + fr;
                    float v = acc[mi][ni][r];
                    if (bias) v += bias[gcol];
                    if (act == 1) v = siluf_(v);
                    else if (act == 2) v = softplusf_(v);
                    if (resid) v = resid[(size_t)orow*ldr + gcol] + rscale*v;
                    if (outF) outF[(size_t)orow*ldc + gcol] = v;
                    if (outB) outB[(size_t)orow*ldc + gcol] = f2bf(v);
                }
            }
    }
}

// ---------------------------------------------------------------------------
// Split-K reduce + epilogue.
// ---------------------------------------------------------------------------
__global__ void __launch_bounds__(256) reduce_kernel(
    const float* __restrict__ part, int S, size_t pstride, int N,
    const float* __restrict__ bias, int act,
    const float* __restrict__ resid, int ldr, float rscale,
    float* __restrict__ outF, short* __restrict__ outB, int ldc,
    int colOff, int rev_out)
{
    const int i4 = blockIdx.x*256 + threadIdx.x;
    const int row = i4 / (N >> 2);
    const int c4  = (i4 - row*(N >> 2)) << 2;
    float4 s = *(const float4*)(part + (size_t)row*N + c4);
    for (int z = 1; z < S; z++) {
        float4 t = *(const float4*)(part + (size_t)z*pstride + (size_t)row*N + c4);
        s.x += t.x; s.y += t.y; s.z += t.z; s.w += t.w;
    }
    if (bias) { float4 b = *(const float4*)(bias + c4); s.x+=b.x; s.y+=b.y; s.z+=b.z; s.w+=b.w; }
    if (act == 1) { s.x=siluf_(s.x); s.y=siluf_(s.y); s.z=siluf_(s.z); s.w=siluf_(s.w); }
    else if (act == 2) { s.x=softplusf_(s.x); s.y=softplusf_(s.y); s.z=softplusf_(s.z); s.w=softplusf_(s.w); }
    int orow = row;
    if (rev_out) { int b = row >> 9, l = row & 511; orow = (b << 9) + (511 - l); }
    if (resid) {
        float4 rr = *(const float4*)(resid + (size_t)orow*ldr + colOff + c4);
        s.x = rr.x + rscale*s.x; s.y = rr.y + rscale*s.y;
        s.z = rr.z + rscale*s.z; s.w = rr.w + rscale*s.w;
    }
    if (outF) *(float4*)(outF + (size_t)orow*ldc + colOff + c4) = s;
    if (outB) {
        short4 o; o.x=f2bf(s.x); o.y=f2bf(s.y); o.z=f2bf(s.z); o.w=f2bf(s.w);
        *(short4*)(outB + (size_t)orow*ldc + colOff + c4) = o;
    }
}

// ---------------------------------------------------------------------------
// LayerNorm over 512; fp32 and/or bf16 out.
// ---------------------------------------------------------------------------
__global__ void __launch_bounds__(128) ln_kernel(
    const float* __restrict__ x, const float* __restrict__ g,
    const float* __restrict__ bta, float* __restrict__ outF,
    short* __restrict__ outB)
{
    const int row = blockIdx.x;
    const int t = threadIdx.x;
    float4 v = ((const float4*)(x + (size_t)row*DD))[t];
    float s = v.x+v.y+v.z+v.w;
    float q = v.x*v.x+v.y*v.y+v.z*v.z+v.w*v.w;
    #pragma unroll
    for (int off = 32; off >= 1; off >>= 1) {
        s += __shfl_down(s, off);
        q += __shfl_down(q, off);
    }
    __shared__ float sh[4];
    if ((t & 63) == 0) { sh[(t>>6)*2] = s; sh[(t>>6)*2+1] = q; }
    __syncthreads();
    float mean = (sh[0]+sh[2]) * (1.0f/DD);
    float var  = (sh[1]+sh[3]) * (1.0f/DD) - mean*mean;
    float rstd = rsqrtf(var + 1e-5f);
    float4 gg = ((const float4*)g)[t];
    float4 bb = ((const float4*)bta)[t];
    float4 o;
    o.x = (v.x-mean)*rstd*gg.x + bb.x;
    o.y = (v.y-mean)*rstd*gg.y + bb.y;
    o.z = (v.z-mean)*rstd*gg.z + bb.z;
    o.w = (v.w-mean)*rstd*gg.w + bb.w;
    if (outF) ((float4*)(outF + (size_t)row*DD))[t] = o;
    if (outB) {
        short4 ob; ob.x=f2bf(o.x); ob.y=f2bf(o.y); ob.z=f2bf(o.z); ob.w=f2bf(o.w);
        *(short4*)(outB + (size_t)row*DD + t*4) = ob;
    }
}

// ---------------------------------------------------------------------------
// Mamba causal dwconv (K=4) + bias + SiLU; xi = cols 0-1023 of xz [MM,2048].
// ---------------------------------------------------------------------------
__global__ void __launch_bounds__(256) mamba_conv_kernel(
    const short* __restrict__ xz, const float* __restrict__ cw,
    const float* __restrict__ cb, short* __restrict__ xcb16)
{
    const int idx = blockIdx.x*256 + threadIdx.x;
    const int c = idx & (DII-1);
    const int row = idx >> 10;
    const int l = row & (LL-1);
    float4 w = ((const float4*)cw)[c];
    const float* wf = (const float*)&w;
    float acc = cb[c];
    #pragma unroll
    for (int t = 0; t < 4; t++) {
        int ll = l - 3 + t;
        if (ll >= 0) acc += wf[t] * bf2f(xz[((size_t)(row - l + ll))*2048 + c]);
    }
    xcb16[idx] = f2bf(siluf_(acc));
}

// ---------------------------------------------------------------------------
// Selective scan, 3-pass chunked associative (one thread owns 16 states).
// ---------------------------------------------------------------------------
__global__ void __launch_bounds__(256) scan_a_kernel(
    const short* __restrict__ dt_bf, const short* __restrict__ xc_bf,
    const float* __restrict__ xdb, const float* __restrict__ Alog,
    float* __restrict__ P, float* __restrict__ Hl)
{
    const int bid = blockIdx.x;
    const int dg = bid & 3;
    const int c  = (bid >> 2) & (NCH-1);
    const int b  = bid >> 6;
    const int d  = (dg << 8) + threadIdx.x;

    float Aexp[16];
    #pragma unroll
    for (int n = 0; n < 16; n++) Aexp[n] = -__expf(Alog[d*16 + n]);

    float h[16], Pp[16];
    #pragma unroll
    for (int n = 0; n < 16; n++) { h[n] = 0.f; Pp[n] = 1.f; }

    const size_t l0 = (size_t)b*LL + (size_t)c*CHL;
    const short* dtp = dt_bf + l0*DII + d;
    const short* xcp = xc_bf + l0*DII + d;
    const float* bp  = xdb + l0*64 + 32;

    #pragma unroll 2
    for (int l = 0; l < CHL; l++) {
        float dtv = bf2f(dtp[(size_t)l*DII]);
        float xcv = bf2f(xcp[(size_t)l*DII]);
        float co = dtv*xcv;
        float Bv[16];
        #pragma unroll
        for (int q4 = 0; q4 < 4; q4++) {
            float4 v = *(const float4*)(bp + (size_t)l*64 + q4*4);
            Bv[q4*4+0]=v.x; Bv[q4*4+1]=v.y; Bv[q4*4+2]=v.z; Bv[q4*4+3]=v.w;
        }
        #pragma unroll
        for (int n = 0; n < 16; n++) {
            float q = __expf(dtv*Aexp[n]);
            Pp[n] *= q;
            h[n] = fmaf(q, h[n], co*Bv[n]);
        }
    }
    size_t base = (((size_t)b*NCH + c)*16)*DII + d;
    #pragma unroll
    for (int n = 0; n < 16; n++) {
        P[base + (size_t)n*DII]  = Pp[n];
        Hl[base + (size_t)n*DII] = h[n];
    }
}

__global__ void __launch_bounds__(256) scan_b_kernel(
    const float* __restrict__ Hl, float* Phin)
{
    const int g = blockIdx.x*256 + threadIdx.x;
    const int d = g & (DII-1);
    const int n = (g >> 10) & 15;
    const int b = g >> 14;
    const size_t cs = (size_t)16*DII;
    const size_t base = ((size_t)b*NCH*16 + (size_t)n)*DII + d;
    float h = 0.f;
    for (int c = 0; c < NCH; c++) {
        size_t i = base + (size_t)c*cs;
        float pn = Phin[i];
        float hn = pn*h + Hl[i];
        Phin[i] = h;
        h = hn;
    }
}

__global__ void __launch_bounds__(256) scan_c_kernel(
    const short* __restrict__ dt_bf, short* xc_ys,
    const float* __restrict__ xdb, const float* __restrict__ Alog,
    const float* __restrict__ hin, const short* __restrict__ zb, /* stride 2048 */
    const float* __restrict__ Dp)
{
    const int bid = blockIdx.x;
    const int dg = bid & 3;
    const int c  = (bid >> 2) & (NCH-1);
    const int b  = bid >> 6;
    const int d  = (dg << 8) + threadIdx.x;

    float Aexp[16];
    #pragma unroll
    for (int n = 0; n < 16; n++) Aexp[n] = -__expf(Alog[d*16 + n]);
    const float Dpv = Dp[d];

    float h[16];
    const size_t hb = (((size_t)b*NCH + c)*16)*DII + d;
    #pragma unroll
    for (int n = 0; n < 16; n++) h[n] = hin[hb + (size_t)n*DII];

    const size_t l0 = (size_t)b*LL + (size_t)c*CHL;
    const short* dtp = dt_bf + l0*DII + d;
    short*       xcp = xc_ys + l0*DII + d;
    const short* zp  = zb + l0*2048 + d;
    const float* bp  = xdb + l0*64 + 32;

    #pragma unroll 2
    for (int l = 0; l < CHL; l++) {
        float dtv = bf2f(dtp[(size_t)l*DII]);
        float xcv = bf2f(xcp[(size_t)l*DII]);
        float zv  = bf2f(zp[(size_t)l*2048]);
        float co = dtv*xcv;
        float Bv[16], Cv[16];
        #pragma unroll
        for (int q4 = 0; q4 < 4; q4++) {
            float4 v = *(const float4*)(bp + (size_t)l*64 + q4*4);
            Bv[q4*4+0]=v.x; Bv[q4*4+1]=v.y; Bv[q4*4+2]=v.z; Bv[q4*4+3]=v.w;
            float4 w = *(const float4*)(bp + (size_t)l*64 + 16 + q4*4);
            Cv[q4*4+0]=w.x; Cv[q4*4+1]=w.y; Cv[q4*4+2]=w.z; Cv[q4*4+3]=w.w;
        }
        float y = 0.f;
        #pragma unroll
        for (int n = 0; n < 16; n++) {
            float q = __expf(dtv*Aexp[n]);
            h[n] = fmaf(q, h[n], co*Bv[n]);
            y = fmaf(Cv[n], h[n], y);
        }
        float out = (y + Dpv*xcv) * siluf_(zv);
        xcp[(size_t)l*DII] = f2bf(out);
    }
}

// ---------------------------------------------------------------------------
// GLU + transpose to [b, c, l] fp32.
// ---------------------------------------------------------------------------
__global__ void __launch_bounds__(256) glu_transpose_kernel(
    const float* __restrict__ pw1, float* __restrict__ out_t)
{
    __shared__ float sh[64][65];
    const int c0 = blockIdx.x << 6;
    const int l0 = blockIdx.y << 6;
    const int b  = blockIdx.z;
    const int t  = threadIdx.x;
    const int c4 = (t & 15) << 2;
    const int r  = t >> 4;
    #pragma unroll
    for (int i = 0; i < 4; i++) {
        int lrow = r + i*16;
        size_t row = (size_t)(b << 9) + l0 + lrow;
        float4 a = *(const float4*)(pw1 + row*1024 + c0 + c4);
        float4 g = *(const float4*)(pw1 + row*1024 + 512 + c0 + c4);
        sh[lrow][c4+0] = a.x * sigmoidf_(g.x);
        sh[lrow][c4+1] = a.y * sigmoidf_(g.y);
        sh[lrow][c4+2] = a.z * sigmoidf_(g.z);
        sh[lrow][c4+3] = a.w * sigmoidf_(g.w);
    }
    __syncthreads();
    #pragma unroll
    for (int i = 0; i < 4; i++) {
        int crow = r + i*16;
        float4 o;
        o.x = sh[c4+0][crow];
        o.y = sh[c4+1][crow];
        o.z = sh[c4+2][crow];
        o.w = sh[c4+3][crow];
        *(float4*)(out_t + ((size_t)(b << 9) + c0 + crow)*512 + l0 + c4) = o;
    }
}

// ---------------------------------------------------------------------------
// Channel-major fused 3x dwconv avg + BN + SiLU (SGPR weights).
// ---------------------------------------------------------------------------
__global__ void __launch_bounds__(256) multiconv_t_kernel(
    const float* __restrict__ gin_t,
    const float* __restrict__ w15, const float* __restrict__ w31,
    const float* __restrict__ w63,
    const float* __restrict__ bn_g, const float* __restrict__ bn_b,
    const float* __restrict__ bn_m, const float* __restrict__ bn_v,
    float* __restrict__ out_t)
{
    __shared__ float sh[574];
    const int c = blockIdx.x & (DD-1);
    const int b = blockIdx.x >> 9;
    const int t = threadIdx.x;
    const float* rowp = gin_t + ((size_t)(b << 9) + c)*512;
    sh[31 + t]       = rowp[t];
    sh[31 + t + 256] = rowp[t + 256];
    if (t < 31) { sh[t] = 0.f; sh[543 + t] = 0.f; }
    __syncthreads();

    const float bnscale = rsqrtf(bn_v[c] + 1e-5f) * bn_g[c];
    const float bnm = bn_m[c], bnb = bn_b[c];
    float* outp = out_t + ((size_t)(b << 9) + c)*512;
    #pragma unroll
    for (int half = 0; half < 2; half++) {
        int l = t + half*256;
        float s63 = 0.f, s31 = 0.f, s15 = 0.f;
        #pragma unroll
        for (int k = 0; k < 63; k++) s63 += w63[c*63 + k] * sh[l + k];
        #pragma unroll
        for (int k = 0; k < 31; k++) s31 += w31[c*31 + k] * sh[l + 16 + k];
        #pragma unroll
        for (int k = 0; k < 15; k++) s15 += w15[c*15 + k] * sh[l + 24 + k];
        float m = (s15 + s31 + s63) * (1.0f/3.0f);
        m = (m - bnm) * bnscale + bnb;
        outp[l] = siluf_(m);
    }
}

// ---------------------------------------------------------------------------
// Transpose [b, c, l] -> [b, l, c], bf16 out.
// ---------------------------------------------------------------------------
__global__ void __launch_bounds__(256) transpose_bcl_kernel(
    const float* __restrict__ in_t, short* __restrict__ out)
{
    __shared__ float sh[64][65];
    const int l0 = blockIdx.x << 6;
    const int c0 = blockIdx.y << 6;
    const int b  = blockIdx.z;
    const int t  = threadIdx.x;
    const int l4 = (t & 15) << 2;
    const int r  = t >> 4;
    #pragma unroll
    for (int i = 0; i < 4; i++) {
        int crow = r + i*16;
        float4 v = *(const float4*)(in_t + ((size_t)(b << 9) + c0 + crow)*512 + l0 + l4);
        sh[crow][l4+0] = v.x; sh[crow][l4+1] = v.y;
        sh[crow][l4+2] = v.z; sh[crow][l4+3] = v.w;
    }
    __syncthreads();
    #pragma unroll
    for (int i = 0; i < 4; i++) {
        int lrow = r + i*16;
        short4 o;
        o.x = f2bf(sh[l4+0][lrow]);
        o.y = f2bf(sh[l4+1][lrow]);
        o.z = f2bf(sh[l4+2][lrow]);
        o.w = f2bf(sh[l4+3][lrow]);
        *(short4*)(out + ((size_t)(b << 9) + l0 + lrow)*512 + c0 + l4) = o;
    }
}

// ---------------------------------------------------------------------------
extern "C" void kernel_launch(void* const* d_in, const int* in_sizes, int n_in,
                              void* d_out, int out_size, void* d_ws, size_t ws_size,
                              hipStream_t stream)
{
    const float* x        = (const float*)d_in[0];
    const float* ff1_ln_g = (const float*)d_in[1];
    const float* ff1_ln_b = (const float*)d_in[2];
    const float* ff1_w1   = (const float*)d_in[3];
    const float* ff1_b1   = (const float*)d_in[4];
    const float* ff1_w2   = (const float*)d_in[5];
    const float* ff1_b2   = (const float*)d_in[6];
    const float* ff2_ln_g = (const float*)d_in[7];
    const float* ff2_ln_b = (const float*)d_in[8];
    const float* ff2_w1   = (const float*)d_in[9];
    const float* ff2_b1   = (const float*)d_in[10];
    const float* ff2_w2   = (const float*)d_in[11];
    const float* ff2_b2   = (const float*)d_in[12];
    const float* m_win    = (const float*)d_in[13];
    const float* m_convw  = (const float*)d_in[14];
    const float* m_convb  = (const float*)d_in[15];
    const float* m_wx     = (const float*)d_in[16];
    const float* m_wdt    = (const float*)d_in[17];
    const float* m_bdt    = (const float*)d_in[18];
    const float* m_Alog   = (const float*)d_in[19];
    const float* m_Dp     = (const float*)d_in[20];
    const float* m_wout   = (const float*)d_in[21];
    const float* bi_wo    = (const float*)d_in[22];
    const float* bi_bo    = (const float*)d_in[23];
    const float* cv_ln_g  = (const float*)d_in[24];
    const float* cv_ln_b  = (const float*)d_in[25];
    const float* cv_pw1_w = (const float*)d_in[26];
    const float* cv_pw1_b = (const float*)d_in[27];
    const float* cv_dw15  = (const float*)d_in[28];
    const float* cv_dw31  = (const float*)d_in[29];
    const float* cv_dw63  = (const float*)d_in[30];
    const float* cv_bn_g  = (const float*)d_in[31];
    const float* cv_bn_b  = (const float*)d_in[32];
    const float* cv_bn_m  = (const float*)d_in[33];
    const float* cv_bn_v  = (const float*)d_in[34];
    const float* cv_pw2_w = (const float*)d_in[35];
    const float* cv_pw2_b = (const float*)d_in[36];
    const float* ln_g     = (const float*)d_in[37];
    const float* ln_b     = (const float*)d_in[38];

    // ---- Workspace layout (MiB offsets), total 113 MiB ----
    char* wsb = (char*)d_ws;
    float* h       = (float*)(wsb + 0);           // 0-8   residual f32
    short* h_bf    = (short*)(wsb + 8*MB_);       // 8-12
    short* lnb_bf  = (short*)(wsb + 12*MB_);      // 12-16 LN out / y_bf
    short* wbf     = (short*)(wsb + 16*MB_);      // 16-33 bf16 weights (17 MiB)
    short* hid_bf  = (short*)(wsb + 33*MB_);      // 33-49 FFN hidden [MM,2048]
    float* part    = (float*)(wsb + 49*MB_);      // 49-65 split-K partials / pw1out
    float* scanP   = (float*)(wsb + 65*MB_);      // 65-73 P (then h_in, aliased)
    float* scanH   = (float*)(wsb + 73*MB_);      // 73-81 Hlocal
    short* xz_bf   = (short*)(wsb + 89*MB_);      // 89-105 xz bf16 [MM,2048]
    float* glu_t   = (float*)(wsb + 89*MB_);      //   (ConvMod overlay)
    float* mconv_o = (float*)(wsb + 97*MB_);      //   (ConvMod overlay)
    short* xcbf    = (short*)(wsb + 105*MB_);     // 105-113 xc bf16 (ys in-place)
    // mamba-phase overlays inside hid_bf region:
    short* dt_bf   = (short*)(wsb + 33*MB_);      // 33-41 dt bf16 [MM,1024]
    float* xdbb    = (float*)(wsb + 41*MB_);      // 41-42 xdb f32 [MM,64]
    short* xdb_bf  = (short*)(wsb + 42*MB_);      // 42-42.5 xdb bf16
    float* scanHin = scanP;

    // bf16 weight sub-pointers (element offsets)
    short* w_ff1w1 = wbf;
    short* w_ff1w2 = wbf + 1048576;
    short* w_ff2w1 = wbf + 2097152;
    short* w_ff2w2 = wbf + 3145728;
    short* w_win   = wbf + 4194304;
    short* w_wx    = wbf + 6291456;
    short* w_wout  = wbf + 6422528;
    short* w_biwo  = wbf + 7471104;
    short* w_pw1   = wbf + 7995392;
    short* w_pw2   = wbf + 8519680;
    short* w_wdt   = wbf + 8781824;   // padded [2*1024, 64] -> 131072 els

    if (ws_size < (size_t)113*MB_) return;

    // 0. weights -> bf16 (wdt region pre-zeroed for K-padding)
    hipMemsetAsync(w_wdt, 0, 131072*sizeof(short), stream);
    WcvtArgs wa;
    wa.s[0]=ff1_w1;  wa.d[0]=w_ff1w1; wa.n[0]=1048576;
    wa.s[1]=ff1_w2;  wa.d[1]=w_ff1w2; wa.n[1]=1048576;
    wa.s[2]=ff2_w1;  wa.d[2]=w_ff2w1; wa.n[2]=1048576;
    wa.s[3]=ff2_w2;  wa.d[3]=w_ff2w2; wa.n[3]=1048576;
    wa.s[4]=m_win;   wa.d[4]=w_win;   wa.n[4]=2097152;
    wa.s[5]=m_wx;    wa.d[5]=w_wx;    wa.n[5]=131072;
    wa.s[6]=m_wout;  wa.d[6]=w_wout;  wa.n[6]=1048576;
    wa.s[7]=bi_wo;   wa.d[7]=w_biwo;  wa.n[7]=524288;
    wa.s[8]=cv_pw1_w;wa.d[8]=w_pw1;   wa.n[8]=524288;
    wa.s[9]=cv_pw2_w;wa.d[9]=w_pw2;   wa.n[9]=262144;
    wa.s[10]=m_wdt;  wa.d[10]=w_wdt;  wa.n[10]=131072;
    wcvt_kernel<<<dim3(1024,11), 256, 0, stream>>>(wa);

    auto G3 = [&](const short* A, int lda, const short* W, int ldw,
                  const float* bias, float* oF, short* oB, int ldc,
                  const float* res, int ldr, float rs,
                  int N, int K, int splits, int act, int ri, float* prt) {
        dim3 g(N/128, 32, splits);
        gemm3_kernel<128><<<g, 256, 0, stream>>>(A, lda, W, ldw, bias, oF, oB, ldc,
            res, ldr, rs, K/splits, act, ri, prt, (size_t)MM*N, N);
    };
    auto RED = [&](const float* p, int S, int N, const float* bias, int act,
                   const float* res, int ldr, float rs,
                   float* oF, short* oB, int ldc, int colOff, int rev) {
        reduce_kernel<<<(MM*N/4)/256, 256, 0, stream>>>(p, S, (size_t)MM*N, N,
            bias, act, res, ldr, rs, oF, oB, ldc, colOff, rev);
    };

    // ---- FFN1: h = x + 0.5*(silu(LN@w1+b1)@w2+b2), also h_bf
    ln_kernel<<<MM, 128, 0, stream>>>(x, ff1_ln_g, ff1_ln_b, nullptr, lnb_bf);
    G3(lnb_bf, 512, w_ff1w1, 512, ff1_b1, nullptr, hid_bf, 2048,
       nullptr, 0, 0.f, 2048, 512, 1, 1, 0, nullptr);
    G3(hid_bf, 2048, w_ff1w2, 2048, nullptr, nullptr, nullptr, 0,
       nullptr, 0, 0.f, 512, 2048, 2, 0, 0, part);
    RED(part, 2, 512, ff1_b2, 0, x, 512, 0.5f, h, h_bf, 512, 0, 0);

    // ---- BiMamba
    for (int dir = 0; dir < 2; dir++) {
        const short* winb  = w_win  + (size_t)dir*2048*512;
        const float* convw = m_convw + (size_t)dir*DII*4;
        const float* convb = m_convb + (size_t)dir*DII;
        const short* wxb   = w_wx   + (size_t)dir*64*1024;
        const short* wdtb  = w_wdt  + (size_t)dir*1024*64;
        const float* bdt   = m_bdt  + (size_t)dir*DII;
        const float* Alog  = m_Alog + (size_t)dir*DII*NST;
        const float* Dp    = m_Dp   + (size_t)dir*DII;
        const short* woutb = w_wout + (size_t)dir*512*1024;

        // xz = h(rev for dir=1) @ win^T -> [MM,2048] bf16, one GEMM
        G3(h_bf, 512, winb, 512, nullptr, nullptr, xz_bf, 2048,
           nullptr, 0, 0.f, 2048, 512, 1, 0, dir, nullptr);
        // causal dwconv + silu (xi = xz cols 0-1023)
        mamba_conv_kernel<<<MM*DII/256, 256, 0, stream>>>(xz_bf, convw, convb, xcbf);
        // xdb = xc @ wx^T (N=64, split-K 4)
        {
            dim3 g(1, 32, 4);
            gemm3_kernel<64><<<g, 256, 0, stream>>>(xcbf, 1024, wxb, 1024,
                nullptr, nullptr, nullptr, 0, nullptr, 0, 0.f,
                256, 0, 0, part, (size_t)MM*64, 64);
        }
        RED(part, 4, 64, nullptr, 0, nullptr, 0, 0.f, xdbb, xdb_bf, 64, 0, 0);
        // dt = softplus(xdb @ wdt_pad^T + bdt) -> bf16 (K padded to 64)
        G3(xdb_bf, 64, wdtb, 64, bdt, nullptr, dt_bf, 1024,
           nullptr, 0, 0.f, 1024, 64, 1, 2, 0, nullptr);
        // 3-pass scan + fused ycombine (ys overwrites xcbf)
        scan_a_kernel<<<BB*NCH*4, 256, 0, stream>>>(dt_bf, xcbf, xdbb, Alog, scanP, scanH);
        scan_b_kernel<<<BB*16*DII/256, 256, 0, stream>>>(scanH, scanP);
        scan_c_kernel<<<BB*NCH*4, 256, 0, stream>>>(dt_bf, xcbf, xdbb, Alog, scanHin,
                                                    xz_bf + DII, Dp);
        // y_out = ys @ wout^T (rev rows back for dir=1) -> y_bf
        G3(xcbf, 1024, woutb, 1024, nullptr, nullptr, nullptr, 0,
           nullptr, 0, 0.f, 512, 1024, 2, 0, 0, part);
        RED(part, 2, 512, nullptr, 0, nullptr, 0, 0.f, nullptr, lnb_bf, 512, 0, dir);
        // h += y_out @ bi_wo[:, dir*512:]^T (+ bi_bo on dir=1)
        G3(lnb_bf, 512, w_biwo + dir*512, 1024, nullptr, nullptr, nullptr, 0,
           nullptr, 0, 0.f, 512, 512, 2, 0, 0, part);
        RED(part, 2, 512, dir ? bi_bo : nullptr, 0, h, 512, 1.0f, h, nullptr, 512, 0, 0);
    }

    // ---- ConvMod
    ln_kernel<<<MM, 128, 0, stream>>>(h, cv_ln_g, cv_ln_b, nullptr, lnb_bf);
    G3(lnb_bf, 512, w_pw1, 512, cv_pw1_b, part, nullptr, 1024,
       nullptr, 0, 0.f, 1024, 512, 1, 0, 0, nullptr);
    glu_transpose_kernel<<<dim3(8,8,8), 256, 0, stream>>>(part, glu_t);
    multiconv_t_kernel<<<BB*DD, 256, 0, stream>>>(glu_t,
        cv_dw15, cv_dw31, cv_dw63, cv_bn_g, cv_bn_b, cv_bn_m, cv_bn_v, mconv_o);
    transpose_bcl_kernel<<<dim3(8,8,8), 256, 0, stream>>>(mconv_o, lnb_bf);
    G3(lnb_bf, 512, w_pw2, 512, nullptr, nullptr, nullptr, 0,
       nullptr, 0, 0.f, 512, 512, 2, 0, 0, part);
    RED(part, 2, 512, cv_pw2_b, 0, h, 512, 1.0f, h, nullptr, 512, 0, 0);

    // ---- FFN2
    ln_kernel<<<MM, 128, 0, stream>>>(h, ff2_ln_g, ff2_ln_b, nullptr, lnb_bf);
    G3(lnb_bf, 512, w_ff2w1, 512, ff2_b1, nullptr, hid_bf, 2048,
       nullptr, 0, 0.f, 2048, 512, 1, 1, 0, nullptr);
    G3(hid_bf, 2048, w_ff2w2, 2048, nullptr, nullptr, nullptr, 0,
       nullptr, 0, 0.f, 512, 2048, 2, 0, 0, part);
    RED(part, 2, 512, ff2_b2, 0, h, 512, 0.5f, h, nullptr, 512, 0, 0);

    // ---- Final LN -> d_out (fp32)
    ln_kernel<<<MM, 128, 0, stream>>>(h, ln_g, ln_b, (float*)d_out, nullptr);
}

// Round 8
// 498.352 us; speedup vs baseline: 4.9378x; 1.2098x over previous
//
#include <hip/hip_runtime.h>
#include <hip/hip_bf16.h>
#include <math.h>

#define LL   512
#define DD   512
#define DII  1024
#define NST  16
#define BB   8
#define MM   4096
#define CHL  32
#define NCH  16
#define MB_  (1024*1024)

typedef __attribute__((ext_vector_type(8))) short bf16x8;
typedef __attribute__((ext_vector_type(4))) float f32x4;

__device__ __forceinline__ float sigmoidf_(float x){ return 1.0f/(1.0f+expf(-x)); }
__device__ __forceinline__ float siluf_(float x){ return x*sigmoidf_(x); }
__device__ __forceinline__ float softplusf_(float x){ return x > 20.0f ? x : log1pf(expf(x)); }

__device__ __forceinline__ short f2bf(float f) {
    union { float f; unsigned u; } v; v.f = f;
    unsigned r = v.u + 0x7fffu + ((v.u >> 16) & 1u);
    return (short)(r >> 16);
}
__device__ __forceinline__ float bf2f(short s) {
    union { unsigned u; float f; } v; v.u = ((unsigned)(unsigned short)s) << 16;
    return v.f;
}
__device__ __forceinline__ bf16x8 pack_bf8(float4 v0, float4 v1) {
    union { bf16x8 v; short e[8]; } pk;
    pk.e[0]=f2bf(v0.x); pk.e[1]=f2bf(v0.y); pk.e[2]=f2bf(v0.z); pk.e[3]=f2bf(v0.w);
    pk.e[4]=f2bf(v1.x); pk.e[5]=f2bf(v1.y); pk.e[6]=f2bf(v1.z); pk.e[7]=f2bf(v1.w);
    return pk.v;
}
__device__ __forceinline__ void gl_lds16(const short* g, short* l) {
    __builtin_amdgcn_global_load_lds(
        (const __attribute__((address_space(1))) void*)g,
        (__attribute__((address_space(3))) void*)l, 16, 0, 0);
}

// ---------------------------------------------------------------------------
// Batched fp32 -> bf16 weight conversion (10 segments).
// Seg 9 (wdt, 65536 src elems) is written into zero-padded [1024,64] layout.
// ---------------------------------------------------------------------------
struct WcvtArgs { const float* s[10]; short* d[10]; int n[10]; };
__global__ void __launch_bounds__(256) wcvt_kernel(WcvtArgs a) {
    const int seg = blockIdx.y;
    const int i = (blockIdx.x*256 + threadIdx.x) * 8;
    if (i >= a.n[seg]) return;
    const float* s = a.s[seg] + i;
    float4 v0 = *(const float4*)s;
    float4 v1 = *(const float4*)(s + 4);
    int di = i;
    if (seg == 9) di = ((i >> 5) << 6) | (i & 31);   // pad K 32 -> 64
    *(bf16x8*)(a.d[seg] + di) = pack_bf8(v0, v1);
}

// ---------------------------------------------------------------------------
// wout [2][512][1024] fp32 -> woutT [2][1024][512] bf16 (tiled transpose).
// ---------------------------------------------------------------------------
__global__ void __launch_bounds__(256) woutT_kernel(
    const float* __restrict__ wout, short* __restrict__ outT)
{
    __shared__ float sh[64][65];
    const int o0 = blockIdx.x << 6;     // 8 tiles over 512
    const int j0 = blockIdx.y << 6;     // 16 tiles over 1024
    const int d  = blockIdx.z;
    const float* in = wout + (size_t)d*512*1024;
    short* out = outT + (size_t)d*1024*512;
    const int t = threadIdx.x;
    const int c4 = (t & 15) << 2;
    const int r  = t >> 4;
    #pragma unroll
    for (int i = 0; i < 4; i++) {
        int orow = r + i*16;
        float4 v = *(const float4*)(in + (size_t)(o0 + orow)*1024 + j0 + c4);
        sh[orow][c4+0]=v.x; sh[orow][c4+1]=v.y; sh[orow][c4+2]=v.z; sh[orow][c4+3]=v.w;
    }
    __syncthreads();
    #pragma unroll
    for (int i = 0; i < 4; i++) {
        int jr = r + i*16;
        short4 o;
        o.x = f2bf(sh[c4+0][jr]); o.y = f2bf(sh[c4+1][jr]);
        o.z = f2bf(sh[c4+2][jr]); o.w = f2bf(sh[c4+3][jr]);
        *(short4*)(out + (size_t)(j0 + jr)*512 + o0 + c4) = o;
    }
}

// ---------------------------------------------------------------------------
// bf16 MFMA GEMM v6: BM=64 x BN tile, BK=64, 4 waves, 2-deep counted-vmcnt
// pipeline + T2 source-pre-swizzle (conflict-free), XCD block swizzle.
// LDS 2*(64+BN)*64*2B = 48 KB (BN=128) -> 3 blocks/CU (was 2 at 128x128).
// ---------------------------------------------------------------------------
template<int BN>
__global__ void __launch_bounds__(256) gemm3_kernel(
    const short* __restrict__ A, int lda,
    const short* __restrict__ W, int ldw,
    const float* __restrict__ bias,
    float* __restrict__ outF, short* __restrict__ outB, int ldc,
    const float* __restrict__ resid, int ldr, float rscale,
    int kLen, int act,
    float* __restrict__ partial, size_t pstride, int N)
{
    constexpr int WN = BN / 64;          // 2 (BN=128) or 1 (BN=64)
    constexpr int WM = 4 / WN;           // 2 or 4
    constexpr int TM = 64 / WM;          // 32 or 16
    constexpr int FM = TM / 16;          // 2 or 1
    constexpr int WRW = BN / 32;         // W staging rounds (4 or 2)

    __shared__ short As[2][64*64];
    __shared__ short Ws[2][BN*64];

    const int tid = threadIdx.x, lane = tid & 63, wid = tid >> 6;

    // XCD-aware swizzle (all grids have nwg % 8 == 0)
    int nwg = gridDim.x * gridDim.y;
    int flat = blockIdx.y * gridDim.x + blockIdx.x;
    if (!(nwg & 7)) { int cpx = nwg >> 3; flat = (flat & 7)*cpx + (flat >> 3); }
    const int bx = flat % gridDim.x, by = flat / gridDim.x;

    const int rowBase = by << 6;
    const int colBase = bx * BN;
    const int kBase = blockIdx.z * kLen;

    // staging: unit id = rd*256+tid; row = id>>3, unit u = id&7;
    // T2 pre-swizzle: source col-unit = u ^ (row&7); LDS stays linear.
    size_t asrc[2];
    #pragma unroll
    for (int rd = 0; rd < 2; rd++) {
        int id = rd*256 + tid, row = id >> 3, u = id & 7;
        asrc[rd] = (size_t)(rowBase + row)*lda + ((u ^ (row & 7)) << 3);
    }
    size_t wsrc[WRW];
    #pragma unroll
    for (int rd = 0; rd < WRW; rd++) {
        int id = rd*256 + tid, row = id >> 3, u = id & 7;
        wsrc[rd] = (size_t)(colBase + row)*ldw + ((u ^ (row & 7)) << 3);
    }

    const int fr = lane & 15;
    const int swz0 = ((((lane >> 4)    ) ^ (lane & 7)) << 3);
    const int swz1 = ((((lane >> 4) | 4) ^ (lane & 7)) << 3);
    const int wm = (wid / WN) * TM, wn = (wid % WN) * 64;

    f32x4 acc[FM][4] = {};

    auto STAGE = [&](int buf, int k0) {
        #pragma unroll
        for (int rd = 0; rd < 2; rd++)
            gl_lds16(A + asrc[rd] + k0, &As[buf][(rd*256 + tid)*8]);
        #pragma unroll
        for (int rd = 0; rd < WRW; rd++)
            gl_lds16(W + wsrc[rd] + k0, &Ws[buf][(rd*256 + tid)*8]);
    };

    const int nT = kLen >> 6;
    STAGE(0, kBase);
    int cur = 0;
    for (int t = 0; t < nT; ++t) {
        if (t + 1 < nT) {
            STAGE(cur ^ 1, kBase + (t+1)*64);
            if (BN == 128) { asm volatile("s_waitcnt vmcnt(6)" ::: "memory"); }
            else           { asm volatile("s_waitcnt vmcnt(4)" ::: "memory"); }
        } else {
            asm volatile("s_waitcnt vmcnt(0)" ::: "memory");
        }
        __builtin_amdgcn_sched_barrier(0);
        __builtin_amdgcn_s_barrier();
        __builtin_amdgcn_sched_barrier(0);
        #pragma unroll
        for (int ks = 0; ks < 2; ks++) {
            const int so = ks ? swz1 : swz0;
            bf16x8 af[FM], bfr[4];
            #pragma unroll
            for (int mi = 0; mi < FM; mi++)
                af[mi] = *(const bf16x8*)&As[cur][(wm + mi*16 + fr)*64 + so];
            #pragma unroll
            for (int ni = 0; ni < 4; ni++)
                bfr[ni] = *(const bf16x8*)&Ws[cur][(wn + ni*16 + fr)*64 + so];
            #pragma unroll
            for (int mi = 0; mi < FM; mi++)
                #pragma unroll
                for (int ni = 0; ni < 4; ni++)
                    acc[mi][ni] = __builtin_amdgcn_mfma_f32_16x16x32_bf16(af[mi], bfr[ni], acc[mi][ni], 0, 0, 0);
        }
        __builtin_amdgcn_sched_barrier(0);
        __builtin_amdgcn_s_barrier();
        __builtin_amdgcn_sched_barrier(0);
        cur ^= 1;
    }

    if (partial) {
        float* pp = partial + (size_t)blockIdx.z * pstride;
        #pragma unroll
        for (int mi = 0; mi < FM; mi++)
            #pragma unroll
            for (int r = 0; r < 4; r++) {
                int orow = rowBase + wm + mi*16 + ((lane>>4)<<2) + r;
                #pragma unroll
                for (int ni = 0; ni < 4; ni++)
                    pp[(size_t)orow*N + colBase + wn + ni*16 + fr] = acc[mi][ni][r];
            }
    } else {
        #pragma unroll
        for (int mi = 0; mi < FM; mi++)
            #pragma unroll
            for (int r = 0; r < 4; r++) {
                int orow = rowBase + wm + mi*16 + ((lane>>4)<<2) + r;
                #pragma unroll
                for (int ni = 0; ni < 4; ni++) {
                    int gcol = colBase + wn + ni*16 + fr;
                    float v = acc[mi][ni][r];
                    if (bias) v += bias[gcol];
                    if (act == 1) v = siluf_(v);
                    else if (act == 2) v = softplusf_(v);
                    if (resid) v = resid[(size_t)orow*ldr + gcol] + rscale*v;
                    if (outF) outF[(size_t)orow*ldc + gcol] = v;
                    if (outB) outB[(size_t)orow*ldc + gcol] = f2bf(v);
                }
            }
    }
}

// ---------------------------------------------------------------------------
// Split-K reduce + epilogue.
// ---------------------------------------------------------------------------
__global__ void __launch_bounds__(256) reduce_kernel(
    const float* __restrict__ part, int S, size_t pstride, int N,
    const float* __restrict__ bias, int act,
    const float* __restrict__ resid, int ldr, float rscale,
    float* __restrict__ outF, short* __restrict__ outB, int ldc)
{
    const int i4 = blockIdx.x*256 + threadIdx.x;
    const int row = i4 / (N >> 2);
    const int c4  = (i4 - row*(N >> 2)) << 2;
    float4 s = *(const float4*)(part + (size_t)row*N + c4);
    for (int z = 1; z < S; z++) {
        float4 t = *(const float4*)(part + (size_t)z*pstride + (size_t)row*N + c4);
        s.x += t.x; s.y += t.y; s.z += t.z; s.w += t.w;
    }
    if (bias) { float4 b = *(const float4*)(bias + c4); s.x+=b.x; s.y+=b.y; s.z+=b.z; s.w+=b.w; }
    if (act == 1) { s.x=siluf_(s.x); s.y=siluf_(s.y); s.z=siluf_(s.z); s.w=siluf_(s.w); }
    else if (act == 2) { s.x=softplusf_(s.x); s.y=softplusf_(s.y); s.z=softplusf_(s.z); s.w=softplusf_(s.w); }
    if (resid) {
        float4 rr = *(const float4*)(resid + (size_t)row*ldr + c4);
        s.x = rr.x + rscale*s.x; s.y = rr.y + rscale*s.y;
        s.z = rr.z + rscale*s.z; s.w = rr.w + rscale*s.w;
    }
    if (outF) *(float4*)(outF + (size_t)row*ldc + c4) = s;
    if (outB) {
        short4 o; o.x=f2bf(s.x); o.y=f2bf(s.y); o.z=f2bf(s.z); o.w=f2bf(s.w);
        *(short4*)(outB + (size_t)row*ldc + c4) = o;
    }
}

// ---------------------------------------------------------------------------
// LayerNorm over 512; fp32 and/or bf16 out.
// ---------------------------------------------------------------------------
__global__ void __launch_bounds__(128) ln_kernel(
    const float* __restrict__ x, const float* __restrict__ g,
    const float* __restrict__ bta, float* __restrict__ outF,
    short* __restrict__ outB)
{
    const int row = blockIdx.x;
    const int t = threadIdx.x;
    float4 v = ((const float4*)(x + (size_t)row*DD))[t];
    float s = v.x+v.y+v.z+v.w;
    float q = v.x*v.x+v.y*v.y+v.z*v.z+v.w*v.w;
    #pragma unroll
    for (int off = 32; off >= 1; off >>= 1) {
        s += __shfl_down(s, off);
        q += __shfl_down(q, off);
    }
    __shared__ float sh[4];
    if ((t & 63) == 0) { sh[(t>>6)*2] = s; sh[(t>>6)*2+1] = q; }
    __syncthreads();
    float mean = (sh[0]+sh[2]) * (1.0f/DD);
    float var  = (sh[1]+sh[3]) * (1.0f/DD) - mean*mean;
    float rstd = rsqrtf(var + 1e-5f);
    float4 gg = ((const float4*)g)[t];
    float4 bb = ((const float4*)bta)[t];
    float4 o;
    o.x = (v.x-mean)*rstd*gg.x + bb.x;
    o.y = (v.y-mean)*rstd*gg.y + bb.y;
    o.z = (v.z-mean)*rstd*gg.z + bb.z;
    o.w = (v.w-mean)*rstd*gg.w + bb.w;
    if (outF) ((float4*)(outF + (size_t)row*DD))[t] = o;
    if (outB) {
        short4 ob; ob.x=f2bf(o.x); ob.y=f2bf(o.y); ob.z=f2bf(o.z); ob.w=f2bf(o.w);
        *(short4*)(outB + (size_t)row*DD + t*4) = ob;
    }
}

// ---------------------------------------------------------------------------
// Mamba dwconv (K=4) + bias + SiLU on xz_all [MM,4096].
// dir=0: causal taps l-3+t, w[t]. dir=1: anti-causal taps l+3-t, w[t]
// (equivalent to causal conv on the reversed sequence, output in orig order).
// ---------------------------------------------------------------------------
__global__ void __launch_bounds__(256) mamba_conv_kernel(
    const short* __restrict__ xz_all, const float* __restrict__ cw,
    const float* __restrict__ cb, short* __restrict__ xcb16, int dir)
{
    const int idx = blockIdx.x*256 + threadIdx.x;
    const int c = idx & (DII-1);
    const int row = idx >> 10;
    const int l = row & (LL-1);
    float4 w = ((const float4*)cw)[c];
    const float* wf = (const float*)&w;
    const short* xi = xz_all + (size_t)(row - l)*4096 + dir*2048 + c;
    float acc = cb[c];
    #pragma unroll
    for (int t = 0; t < 4; t++) {
        int lt = dir ? (l + 3 - t) : (l - 3 + t);
        if (lt >= 0 && lt < LL) acc += wf[t] * bf2f(xi[(size_t)lt*4096]);
    }
    xcb16[idx] = f2bf(siluf_(acc));
}

// ---------------------------------------------------------------------------
// Selective scan, 3-pass chunked associative; dir via index order.
// ---------------------------------------------------------------------------
__global__ void __launch_bounds__(256) scan_a_kernel(
    const short* __restrict__ dt_bf, const short* __restrict__ xc_bf,
    const float* __restrict__ xdb, const float* __restrict__ Alog,
    float* __restrict__ P, float* __restrict__ Hl, int dir)
{
    const int bid = blockIdx.x;
    const int dg = bid & 3;
    const int c  = (bid >> 2) & (NCH-1);
    const int b  = bid >> 6;
    const int d  = (dg << 8) + threadIdx.x;

    float Aexp[16];
    #pragma unroll
    for (int n = 0; n < 16; n++) Aexp[n] = -__expf(Alog[d*16 + n]);

    float h[16], Pp[16];
    #pragma unroll
    for (int n = 0; n < 16; n++) { h[n] = 0.f; Pp[n] = 1.f; }

    const size_t l0 = (size_t)b*LL + (size_t)c*CHL;
    const short* dtp = dt_bf + l0*DII + d;
    const short* xcp = xc_bf + l0*DII + d;
    const float* bp  = xdb + l0*64 + 32;

    for (int i = 0; i < CHL; i++) {
        int lp = dir ? (CHL-1-i) : i;
        float dtv = bf2f(dtp[(size_t)lp*DII]);
        float xcv = bf2f(xcp[(size_t)lp*DII]);
        float co = dtv*xcv;
        float Bv[16];
        #pragma unroll
        for (int q4 = 0; q4 < 4; q4++) {
            float4 v = *(const float4*)(bp + (size_t)lp*64 + q4*4);
            Bv[q4*4+0]=v.x; Bv[q4*4+1]=v.y; Bv[q4*4+2]=v.z; Bv[q4*4+3]=v.w;
        }
        #pragma unroll
        for (int n = 0; n < 16; n++) {
            float q = __expf(dtv*Aexp[n]);
            Pp[n] *= q;
            h[n] = fmaf(q, h[n], co*Bv[n]);
        }
    }
    size_t base = (((size_t)b*NCH + c)*16)*DII + d;
    #pragma unroll
    for (int n = 0; n < 16; n++) {
        P[base + (size_t)n*DII]  = Pp[n];
        Hl[base + (size_t)n*DII] = h[n];
    }
}

__global__ void __launch_bounds__(256) scan_b_kernel(
    const float* __restrict__ Hl, float* Phin, int dir)
{
    const int g = blockIdx.x*256 + threadIdx.x;
    const int d = g & (DII-1);
    const int n = (g >> 10) & 15;
    const int b = g >> 14;
    const size_t cs = (size_t)16*DII;
    const size_t base = ((size_t)b*NCH*16 + (size_t)n)*DII + d;
    float h = 0.f;
    for (int ci = 0; ci < NCH; ci++) {
        int c = dir ? (NCH-1-ci) : ci;
        size_t i = base + (size_t)c*cs;
        float pn = Phin[i];
        float hn = pn*h + Hl[i];
        Phin[i] = h;
        h = hn;
    }
}

__global__ void __launch_bounds__(256) scan_c_kernel(
    const short* __restrict__ dt_bf, short* xc_ys,
    const float* __restrict__ xdb, const float* __restrict__ Alog,
    const float* __restrict__ hin, const short* __restrict__ xz_all,
    const float* __restrict__ Dp, int dir)
{
    const int bid = blockIdx.x;
    const int dg = bid & 3;
    const int c  = (bid >> 2) & (NCH-1);
    const int b  = bid >> 6;
    const int d  = (dg << 8) + threadIdx.x;

    float Aexp[16];
    #pragma unroll
    for (int n = 0; n < 16; n++) Aexp[n] = -__expf(Alog[d*16 + n]);
    const float Dpv = Dp[d];

    float h[16];
    const size_t hb = (((size_t)b*NCH + c)*16)*DII + d;
    #pragma unroll
    for (int n = 0; n < 16; n++) h[n] = hin[hb + (size_t)n*DII];

    const size_t l0 = (size_t)b*LL + (size_t)c*CHL;
    const short* dtp = dt_bf + l0*DII + d;
    short*       xcp = xc_ys + l0*DII + d;
    const short* zp  = xz_all + l0*4096 + dir*2048 + 1024 + d;
    const float* bp  = xdb + l0*64 + 32;

    for (int i = 0; i < CHL; i++) {
        int lp = dir ? (CHL-1-i) : i;
        float dtv = bf2f(dtp[(size_t)lp*DII]);
        float xcv = bf2f(xcp[(size_t)lp*DII]);
        float zv  = bf2f(zp[(size_t)lp*4096]);
        float co = dtv*xcv;
        float Bv[16], Cv[16];
        #pragma unroll
        for (int q4 = 0; q4 < 4; q4++) {
            float4 v = *(const float4*)(bp + (size_t)lp*64 + q4*4);
            Bv[q4*4+0]=v.x; Bv[q4*4+1]=v.y; Bv[q4*4+2]=v.z; Bv[q4*4+3]=v.w;
            float4 w = *(const float4*)(bp + (size_t)lp*64 + 16 + q4*4);
            Cv[q4*4+0]=w.x; Cv[q4*4+1]=w.y; Cv[q4*4+2]=w.z; Cv[q4*4+3]=w.w;
        }
        float y = 0.f;
        #pragma unroll
        for (int n = 0; n < 16; n++) {
            float q = __expf(dtv*Aexp[n]);
            h[n] = fmaf(q, h[n], co*Bv[n]);
            y = fmaf(Cv[n], h[n], y);
        }
        float out = (y + Dpv*xcv) * siluf_(zv);
        xcp[(size_t)lp*DII] = f2bf(out);
    }
}

// ---------------------------------------------------------------------------
// GLU + transpose to [b, c, l] fp32.
// ---------------------------------------------------------------------------
__global__ void __launch_bounds__(256) glu_transpose_kernel(
    const float* __restrict__ pw1, float* __restrict__ out_t)
{
    __shared__ float sh[64][65];
    const int c0 = blockIdx.x << 6;
    const int l0 = blockIdx.y << 6;
    const int b  = blockIdx.z;
    const int t  = threadIdx.x;
    const int c4 = (t & 15) << 2;
    const int r  = t >> 4;
    #pragma unroll
    for (int i = 0; i < 4; i++) {
        int lrow = r + i*16;
        size_t row = (size_t)(b << 9) + l0 + lrow;
        float4 a = *(const float4*)(pw1 + row*1024 + c0 + c4);
        float4 g = *(const float4*)(pw1 + row*1024 + 512 + c0 + c4);
        sh[lrow][c4+0] = a.x * sigmoidf_(g.x);
        sh[lrow][c4+1] = a.y * sigmoidf_(g.y);
        sh[lrow][c4+2] = a.z * sigmoidf_(g.z);
        sh[lrow][c4+3] = a.w * sigmoidf_(g.w);
    }
    __syncthreads();
    #pragma unroll
    for (int i = 0; i < 4; i++) {
        int crow = r + i*16;
        float4 o;
        o.x = sh[c4+0][crow];
        o.y = sh[c4+1][crow];
        o.z = sh[c4+2][crow];
        o.w = sh[c4+3][crow];
        *(float4*)(out_t + ((size_t)(b << 9) + c0 + crow)*512 + l0 + c4) = o;
    }
}

// ---------------------------------------------------------------------------
// Channel-major fused 3x dwconv avg + BN + SiLU (SGPR weights).
// ---------------------------------------------------------------------------
__global__ void __launch_bounds__(256) multiconv_t_kernel(
    const float* __restrict__ gin_t,
    const float* __restrict__ w15, const float* __restrict__ w31,
    const float* __restrict__ w63,
    const float* __restrict__ bn_g, const float* __restrict__ bn_b,
    const float* __restrict__ bn_m, const float* __restrict__ bn_v,
    float* __restrict__ out_t)
{
    __shared__ float sh[574];
    const int c = blockIdx.x & (DD-1);
    const int b = blockIdx.x >> 9;
    const int t = threadIdx.x;
    const float* rowp = gin_t + ((size_t)(b << 9) + c)*512;
    sh[31 + t]       = rowp[t];
    sh[31 + t + 256] = rowp[t + 256];
    if (t < 31) { sh[t] = 0.f; sh[543 + t] = 0.f; }
    __syncthreads();

    const float bnscale = rsqrtf(bn_v[c] + 1e-5f) * bn_g[c];
    const float bnm = bn_m[c], bnb = bn_b[c];
    float* outp = out_t + ((size_t)(b << 9) + c)*512;
    #pragma unroll
    for (int half = 0; half < 2; half++) {
        int l = t + half*256;
        float s63 = 0.f, s31 = 0.f, s15 = 0.f;
        #pragma unroll
        for (int k = 0; k < 63; k++) s63 += w63[c*63 + k] * sh[l + k];
        #pragma unroll
        for (int k = 0; k < 31; k++) s31 += w31[c*31 + k] * sh[l + 16 + k];
        #pragma unroll
        for (int k = 0; k < 15; k++) s15 += w15[c*15 + k] * sh[l + 24 + k];
        float m = (s15 + s31 + s63) * (1.0f/3.0f);
        m = (m - bnm) * bnscale + bnb;
        outp[l] = siluf_(m);
    }
}

// ---------------------------------------------------------------------------
// Transpose [b, c, l] -> [b, l, c], bf16 out.
// ---------------------------------------------------------------------------
__global__ void __launch_bounds__(256) transpose_bcl_kernel(
    const float* __restrict__ in_t, short* __restrict__ out)
{
    __shared__ float sh[64][65];
    const int l0 = blockIdx.x << 6;
    const int c0 = blockIdx.y << 6;
    const int b  = blockIdx.z;
    const int t  = threadIdx.x;
    const int l4 = (t & 15) << 2;
    const int r  = t >> 4;
    #pragma unroll
    for (int i = 0; i < 4; i++) {
        int crow = r + i*16;
        float4 v = *(const float4*)(in_t + ((size_t)(b << 9) + c0 + crow)*512 + l0 + l4);
        sh[crow][l4+0] = v.x; sh[crow][l4+1] = v.y;
        sh[crow][l4+2] = v.z; sh[crow][l4+3] = v.w;
    }
    __syncthreads();
    #pragma unroll
    for (int i = 0; i < 4; i++) {
        int lrow = r + i*16;
        short4 o;
        o.x = f2bf(sh[l4+0][lrow]);
        o.y = f2bf(sh[l4+1][lrow]);
        o.z = f2bf(sh[l4+2][lrow]);
        o.w = f2bf(sh[l4+3][lrow]);
        *(short4*)(out + ((size_t)(b << 9) + l0 + lrow)*512 + c0 + l4) = o;
    }
}

// ---------------------------------------------------------------------------
extern "C" void kernel_launch(void* const* d_in, const int* in_sizes, int n_in,
                              void* d_out, int out_size, void* d_ws, size_t ws_size,
                              hipStream_t stream)
{
    const float* x        = (const float*)d_in[0];
    const float* ff1_ln_g = (const float*)d_in[1];
    const float* ff1_ln_b = (const float*)d_in[2];
    const float* ff1_w1   = (const float*)d_in[3];
    const float* ff1_b1   = (const float*)d_in[4];
    const float* ff1_w2   = (const float*)d_in[5];
    const float* ff1_b2   = (const float*)d_in[6];
    const float* ff2_ln_g = (const float*)d_in[7];
    const float* ff2_ln_b = (const float*)d_in[8];
    const float* ff2_w1   = (const float*)d_in[9];
    const float* ff2_b1   = (const float*)d_in[10];
    const float* ff2_w2   = (const float*)d_in[11];
    const float* ff2_b2   = (const float*)d_in[12];
    const float* m_win    = (const float*)d_in[13];
    const float* m_convw  = (const float*)d_in[14];
    const float* m_convb  = (const float*)d_in[15];
    const float* m_wx     = (const float*)d_in[16];
    const float* m_wdt    = (const float*)d_in[17];
    const float* m_bdt    = (const float*)d_in[18];
    const float* m_Alog   = (const float*)d_in[19];
    const float* m_Dp     = (const float*)d_in[20];
    const float* m_wout   = (const float*)d_in[21];
    const float* bi_wo    = (const float*)d_in[22];
    const float* bi_bo    = (const float*)d_in[23];
    const float* cv_ln_g  = (const float*)d_in[24];
    const float* cv_ln_b  = (const float*)d_in[25];
    const float* cv_pw1_w = (const float*)d_in[26];
    const float* cv_pw1_b = (const float*)d_in[27];
    const float* cv_dw15  = (const float*)d_in[28];
    const float* cv_dw31  = (const float*)d_in[29];
    const float* cv_dw63  = (const float*)d_in[30];
    const float* cv_bn_g  = (const float*)d_in[31];
    const float* cv_bn_b  = (const float*)d_in[32];
    const float* cv_bn_m  = (const float*)d_in[33];
    const float* cv_bn_v  = (const float*)d_in[34];
    const float* cv_pw2_w = (const float*)d_in[35];
    const float* cv_pw2_b = (const float*)d_in[36];
    const float* ln_g     = (const float*)d_in[37];
    const float* ln_b     = (const float*)d_in[38];

    // ---- Workspace layout (MiB offsets), total 100 MiB ----
    char* wsb = (char*)d_ws;
    float* h       = (float*)(wsb + 0);           // 0-8
    short* h_bf    = (short*)(wsb + 8*MB_);       // 8-12
    short* lnb_bf  = (short*)(wsb + 12*MB_);      // 12-16 (FFN/Conv phases)
    float* xdbb    = (float*)(wsb + 12*MB_);      //   mamba overlay [MM,64] f32
    short* xdb_bf  = (short*)(wsb + 13*MB_);      //   mamba overlay
    short* wbf     = (short*)(wsb + 16*MB_);      // 16-36 weights (~19 MiB)
    float* part    = (float*)(wsb + 36*MB_);      // 36-52 partials / pw1out
    float* scanP   = (float*)(wsb + 36*MB_);      //   scan overlay (P -> h_in)
    float* scanH   = (float*)(wsb + 44*MB_);      //   scan overlay
    short* xz_all  = (short*)(wsb + 52*MB_);      // 52-84 [MM,4096] both dirs
    short* hid_bf  = (short*)(wsb + 52*MB_);      //   FFN overlay [MM,2048]
    short* xcbf    = (short*)(wsb + 84*MB_);      // 84-92 xc/ys bf16
    float* glu_t   = (float*)(wsb + 84*MB_);      //   ConvMod overlay
    short* dt_bf   = (short*)(wsb + 92*MB_);      // 92-100 dt bf16
    float* mconv_o = (float*)(wsb + 92*MB_);      //   ConvMod overlay

    // bf16 weight sub-pointers (element offsets)
    short* w_ff1w1 = wbf;
    short* w_ff1w2 = wbf + 1048576;
    short* w_ff2w1 = wbf + 2097152;
    short* w_ff2w2 = wbf + 3145728;
    short* w_win   = wbf + 4194304;   // [4096, 512] both dirs stacked
    short* w_wx    = wbf + 6291456;
    short* w_biwo  = wbf + 6422528;   // [512, 1024]
    short* w_pw1   = wbf + 6946816;
    short* w_pw2   = wbf + 7471104;
    short* w_wdt   = wbf + 7733248;   // padded [2*1024, 64]
    short* w_woutT = wbf + 7864320;   // [2][1024][512]
    short* w_Wc    = wbf + 8912896;   // [2][512][1024] composed biwo_h @ wout

    if (ws_size < (size_t)100*MB_) return;

    // ---- Weight prep: cvt, wout^T, Wc = biwo_half @ wout ----
    hipMemsetAsync(w_wdt, 0, 131072*sizeof(short), stream);
    WcvtArgs wa;
    wa.s[0]=ff1_w1;  wa.d[0]=w_ff1w1; wa.n[0]=1048576;
    wa.s[1]=ff1_w2;  wa.d[1]=w_ff1w2; wa.n[1]=1048576;
    wa.s[2]=ff2_w1;  wa.d[2]=w_ff2w1; wa.n[2]=1048576;
    wa.s[3]=ff2_w2;  wa.d[3]=w_ff2w2; wa.n[3]=1048576;
    wa.s[4]=m_win;   wa.d[4]=w_win;   wa.n[4]=2097152;
    wa.s[5]=m_wx;    wa.d[5]=w_wx;    wa.n[5]=131072;
    wa.s[6]=bi_wo;   wa.d[6]=w_biwo;  wa.n[6]=524288;
    wa.s[7]=cv_pw1_w;wa.d[7]=w_pw1;   wa.n[7]=524288;
    wa.s[8]=cv_pw2_w;wa.d[8]=w_pw2;   wa.n[8]=262144;
    wa.s[9]=m_wdt;   wa.d[9]=w_wdt;   wa.n[9]=65536;
    wcvt_kernel<<<dim3(1024,10), 256, 0, stream>>>(wa);
    woutT_kernel<<<dim3(8,16,2), 256, 0, stream>>>(m_wout, w_woutT);

    auto G3 = [&](const short* A, int lda, const short* W, int ldw,
                  const float* bias, float* oF, short* oB, int ldc,
                  const float* res, int ldr, float rs,
                  int M, int N, int K, int splits, int act, float* prt) {
        dim3 g(N/128, M/64, splits);
        gemm3_kernel<128><<<g, 256, 0, stream>>>(A, lda, W, ldw, bias, oF, oB, ldc,
            res, ldr, rs, K/splits, act, prt, (size_t)MM*N, N);
    };
    auto RED = [&](const float* p, int S, int N, const float* bias, int act,
                   const float* res, int ldr, float rs,
                   float* oF, short* oB, int ldc) {
        reduce_kernel<<<(MM*N/4)/256, 256, 0, stream>>>(p, S, (size_t)MM*N, N,
            bias, act, res, ldr, rs, oF, oB, ldc);
    };

    // Wc_d = biwo[:, d*512:] @ wout_d  -> bf16 [512, 1024]
    for (int d = 0; d < 2; d++)
        G3(w_biwo + d*512, 1024, w_woutT + (size_t)d*524288, 512,
           nullptr, nullptr, w_Wc + (size_t)d*524288, 1024,
           nullptr, 0, 0.f, 512, 1024, 512, 1, 0, nullptr);

    // ---- FFN1: h = x + 0.5*(silu(LN@w1+b1)@w2+b2), also h_bf
    ln_kernel<<<MM, 128, 0, stream>>>(x, ff1_ln_g, ff1_ln_b, nullptr, lnb_bf);
    G3(lnb_bf, 512, w_ff1w1, 512, ff1_b1, nullptr, hid_bf, 2048,
       nullptr, 0, 0.f, MM, 2048, 512, 1, 1, nullptr);
    G3(hid_bf, 2048, w_ff1w2, 2048, nullptr, nullptr, nullptr, 0,
       nullptr, 0, 0.f, MM, 512, 2048, 2, 0, part);
    RED(part, 2, 512, ff1_b2, 0, x, 512, 0.5f, h, h_bf, 512);

    // ---- BiMamba: one merged xz GEMM (N=4096), dirs via conv/scan order
    G3(h_bf, 512, w_win, 512, nullptr, nullptr, xz_all, 4096,
       nullptr, 0, 0.f, MM, 4096, 512, 1, 0, nullptr);
    for (int dir = 0; dir < 2; dir++) {
        const float* convw = m_convw + (size_t)dir*DII*4;
        const float* convb = m_convb + (size_t)dir*DII;
        const short* wxb   = w_wx   + (size_t)dir*64*1024;
        const short* wdtb  = w_wdt  + (size_t)dir*1024*64;
        const float* bdt   = m_bdt  + (size_t)dir*DII;
        const float* Alog  = m_Alog + (size_t)dir*DII*NST;
        const float* Dp    = m_Dp   + (size_t)dir*DII;

        mamba_conv_kernel<<<MM*DII/256, 256, 0, stream>>>(xz_all, convw, convb, xcbf, dir);
        // xdb = xc @ wx^T (N=64, split-K 4)
        {
            dim3 g(1, 64, 4);
            gemm3_kernel<64><<<g, 256, 0, stream>>>(xcbf, 1024, wxb, 1024,
                nullptr, nullptr, nullptr, 0, nullptr, 0, 0.f,
                256, 0, part, (size_t)MM*64, 64);
        }
        RED(part, 4, 64, nullptr, 0, nullptr, 0, 0.f, xdbb, xdb_bf, 64);
        // dt = softplus(xdb @ wdt_pad^T + bdt) -> bf16
        G3(xdb_bf, 64, wdtb, 64, bdt, nullptr, dt_bf, 1024,
           nullptr, 0, 0.f, MM, 1024, 64, 1, 2, nullptr);
        // 3-pass scan + fused ycombine (ys overwrites xcbf)
        scan_a_kernel<<<BB*NCH*4, 256, 0, stream>>>(dt_bf, xcbf, xdbb, Alog, scanP, scanH, dir);
        scan_b_kernel<<<BB*16*DII/256, 256, 0, stream>>>(scanH, scanP, dir);
        scan_c_kernel<<<BB*NCH*4, 256, 0, stream>>>(dt_bf, xcbf, xdbb, Alog, scanP,
                                                    xz_all, Dp, dir);
        // h += ys @ Wc_d^T (+ bi_bo on dir=1)
        G3(xcbf, 1024, w_Wc + (size_t)dir*524288, 1024, nullptr, nullptr, nullptr, 0,
           nullptr, 0, 0.f, MM, 512, 1024, 2, 0, part);
        RED(part, 2, 512, dir ? bi_bo : nullptr, 0, h, 512, 1.0f, h, nullptr, 512);
    }

    // ---- ConvMod
    ln_kernel<<<MM, 128, 0, stream>>>(h, cv_ln_g, cv_ln_b, nullptr, lnb_bf);
    G3(lnb_bf, 512, w_pw1, 512, cv_pw1_b, part, nullptr, 1024,
       nullptr, 0, 0.f, MM, 1024, 512, 1, 0, nullptr);
    glu_transpose_kernel<<<dim3(8,8,8), 256, 0, stream>>>(part, glu_t);
    multiconv_t_kernel<<<BB*DD, 256, 0, stream>>>(glu_t,
        cv_dw15, cv_dw31, cv_dw63, cv_bn_g, cv_bn_b, cv_bn_m, cv_bn_v, mconv_o);
    transpose_bcl_kernel<<<dim3(8,8,8), 256, 0, stream>>>(mconv_o, lnb_bf);
    G3(lnb_bf, 512, w_pw2, 512, nullptr, nullptr, nullptr, 0,
       nullptr, 0, 0.f, MM, 512, 512, 2, 0, part);
    RED(part, 2, 512, cv_pw2_b, 0, h, 512, 1.0f, h, nullptr, 512);

    // ---- FFN2
    ln_kernel<<<MM, 128, 0, stream>>>(h, ff2_ln_g, ff2_ln_b, nullptr, lnb_bf);
    G3(lnb_bf, 512, w_ff2w1, 512, ff2_b1, nullptr, hid_bf, 2048,
       nullptr, 0, 0.f, MM, 2048, 512, 1, 1, nullptr);
    G3(hid_bf, 2048, w_ff2w2, 2048, nullptr, nullptr, nullptr, 0,
       nullptr, 0, 0.f, MM, 512, 2048, 2, 0, part);
    RED(part, 2, 512, ff2_b2, 0, h, 512, 0.5f, h, nullptr, 512);

    // ---- Final LN -> d_out (fp32)
    ln_kernel<<<MM, 128, 0, stream>>>(h, ln_g, ln_b, (float*)d_out, nullptr);
}

// Round 9
// 484.646 us; speedup vs baseline: 5.0775x; 1.0283x over previous
//
#include <hip/hip_runtime.h>
#include <hip/hip_bf16.h>
#include <math.h>

#define LL   512
#define DD   512
#define DII  1024
#define NST  16
#define BB   8
#define MM   4096
#define CHL  64
#define NCH  8
#define MB_  (1024*1024)
#define Q_(n) ((size_t)(n)*262144)   // quarter-MiB units

typedef __attribute__((ext_vector_type(8))) short bf16x8;
typedef __attribute__((ext_vector_type(4))) float f32x4;

__device__ __forceinline__ float sigmoidf_(float x){ return 1.0f/(1.0f+expf(-x)); }
__device__ __forceinline__ float siluf_(float x){ return x*sigmoidf_(x); }
__device__ __forceinline__ float softplusf_(float x){ return x > 20.0f ? x : log1pf(expf(x)); }

__device__ __forceinline__ short f2bf(float f) {
    union { float f; unsigned u; } v; v.f = f;
    unsigned r = v.u + 0x7fffu + ((v.u >> 16) & 1u);
    return (short)(r >> 16);
}
__device__ __forceinline__ float bf2f(short s) {
    union { unsigned u; float f; } v; v.u = ((unsigned)(unsigned short)s) << 16;
    return v.f;
}
__device__ __forceinline__ bf16x8 pack_bf8(float4 v0, float4 v1) {
    union { bf16x8 v; short e[8]; } pk;
    pk.e[0]=f2bf(v0.x); pk.e[1]=f2bf(v0.y); pk.e[2]=f2bf(v0.z); pk.e[3]=f2bf(v0.w);
    pk.e[4]=f2bf(v1.x); pk.e[5]=f2bf(v1.y); pk.e[6]=f2bf(v1.z); pk.e[7]=f2bf(v1.w);
    return pk.v;
}
__device__ __forceinline__ void gl_lds16(const short* g, short* l) {
    __builtin_amdgcn_global_load_lds(
        (const __attribute__((address_space(1))) void*)g,
        (__attribute__((address_space(3))) void*)l, 16, 0, 0);
}

// ---------------------------------------------------------------------------
// Batched fp32 -> bf16 weight conversion (11 segments).
// Seg 8 (wdt) -> zero-padded [1024,64] K-layout.
// ---------------------------------------------------------------------------
struct WcvtArgs { const float* s[11]; short* d[11]; int n[11]; };
__global__ void __launch_bounds__(256) wcvt_kernel(WcvtArgs a) {
    const int seg = blockIdx.y;
    const int i = (blockIdx.x*256 + threadIdx.x) * 8;
    if (i >= a.n[seg]) return;
    const float* s = a.s[seg] + i;
    float4 v0 = *(const float4*)s;
    float4 v1 = *(const float4*)(s + 4);
    int di = i;
    if (seg == 8) di = ((i >> 5) << 6) | (i & 31);   // pad K 32 -> 64
    *(bf16x8*)(a.d[seg] + di) = pack_bf8(v0, v1);
}

// wout [2][512][1024] f32 -> [2][1024][512] bf16
__global__ void __launch_bounds__(256) woutT_kernel(
    const float* __restrict__ wout, short* __restrict__ outT)
{
    __shared__ float sh[64][65];
    const int o0 = blockIdx.x << 6;
    const int j0 = blockIdx.y << 6;
    const int d  = blockIdx.z;
    const float* in = wout + (size_t)d*512*1024;
    short* out = outT + (size_t)d*1024*512;
    const int t = threadIdx.x;
    const int c4 = (t & 15) << 2;
    const int r  = t >> 4;
    #pragma unroll
    for (int i = 0; i < 4; i++) {
        int orow = r + i*16;
        float4 v = *(const float4*)(in + (size_t)(o0 + orow)*1024 + j0 + c4);
        sh[orow][c4+0]=v.x; sh[orow][c4+1]=v.y; sh[orow][c4+2]=v.z; sh[orow][c4+3]=v.w;
    }
    __syncthreads();
    #pragma unroll
    for (int i = 0; i < 4; i++) {
        int jr = r + i*16;
        short4 o;
        o.x = f2bf(sh[c4+0][jr]); o.y = f2bf(sh[c4+1][jr]);
        o.z = f2bf(sh[c4+2][jr]); o.w = f2bf(sh[c4+3][jr]);
        *(short4*)(out + (size_t)(j0 + jr)*512 + o0 + c4) = o;
    }
}

// wx first-32-rows transpose: wxT[dir][j][r] = wx[dir][r][j] (r<32), bf16
__global__ void __launch_bounds__(256) wxT_kernel(
    const float* __restrict__ wx, short* __restrict__ outT)
{
    const int g = blockIdx.x*256 + threadIdx.x;   // 2*1024*32
    if (g >= 65536) return;
    const int r = g & 31;
    const int j = (g >> 5) & 1023;
    const int dir = g >> 15;
    outT[(size_t)dir*65536 + j*64 + r] = f2bf(wx[(size_t)dir*65536 + r*1024 + j]);
}

// bias1152[dir][c] = c<1024 ? bdt[dir][c] : 0
__global__ void __launch_bounds__(256) bias_build_kernel(
    const float* __restrict__ bdt, float* __restrict__ out)
{
    const int i = blockIdx.x*256 + threadIdx.x;
    if (i >= 2304) return;
    const int dir = i / 1152, c = i % 1152;
    out[i] = (c < 1024) ? bdt[dir*1024 + c] : 0.f;
}

// ---------------------------------------------------------------------------
// bf16 MFMA GEMM v7: 64x128 tile, BK=64, 4 waves, counted-vmcnt 2-deep
// pipeline, T2 source-pre-swizzle, XCD swizzle. Generalized z:
//   A += z*zA, W += z*zW, bias += z*zB, out += z*zO, kBase = z*kOff.
//   (split-K: kOff=kLen, zA..zO=0, partial[z]; batched: kOff=0, offsets set)
// act applied only to cols < actLim.
// ---------------------------------------------------------------------------
template<int BN>
__global__ void __launch_bounds__(256) gemm3_kernel(
    const short* __restrict__ A, int lda,
    const short* __restrict__ W, int ldw,
    const float* __restrict__ bias,
    float* __restrict__ outF, short* __restrict__ outB, int ldc,
    int kLen, int kOff, int act, int actLim,
    size_t zA, size_t zW, int zB, size_t zO,
    float* __restrict__ partial, size_t pstride, int N)
{
    constexpr int WN = BN / 64;
    constexpr int WM = 4 / WN;
    constexpr int TM = 64 / WM;
    constexpr int FM = TM / 16;
    constexpr int WRW = BN / 32;

    __shared__ short As[2][64*64];
    __shared__ short Ws[2][BN*64];

    const int tid = threadIdx.x, lane = tid & 63, wid = tid >> 6;
    const int z = blockIdx.z;
    A += (size_t)z * zA; W += (size_t)z * zW;
    if (bias) bias += (size_t)z * (size_t)zB;
    if (outF) outF += (size_t)z * zO;
    if (outB) outB += (size_t)z * zO;

    int nwg = gridDim.x * gridDim.y;
    int flat = blockIdx.y * gridDim.x + blockIdx.x;
    if (!(nwg & 7)) { int cpx = nwg >> 3; flat = (flat & 7)*cpx + (flat >> 3); }
    const int bx = flat % gridDim.x, by = flat / gridDim.x;

    const int rowBase = by << 6;
    const int colBase = bx * BN;
    const int kBase = z * kOff;

    size_t asrc[2];
    #pragma unroll
    for (int rd = 0; rd < 2; rd++) {
        int id = rd*256 + tid, row = id >> 3, u = id & 7;
        asrc[rd] = (size_t)(rowBase + row)*lda + ((u ^ (row & 7)) << 3);
    }
    size_t wsrc[WRW];
    #pragma unroll
    for (int rd = 0; rd < WRW; rd++) {
        int id = rd*256 + tid, row = id >> 3, u = id & 7;
        wsrc[rd] = (size_t)(colBase + row)*ldw + ((u ^ (row & 7)) << 3);
    }

    const int fr = lane & 15;
    const int swz0 = ((((lane >> 4)    ) ^ (lane & 7)) << 3);
    const int swz1 = ((((lane >> 4) | 4) ^ (lane & 7)) << 3);
    const int wm = (wid / WN) * TM, wn = (wid % WN) * 64;

    f32x4 acc[FM][4] = {};

    auto STAGE = [&](int buf, int k0) {
        #pragma unroll
        for (int rd = 0; rd < 2; rd++)
            gl_lds16(A + asrc[rd] + k0, &As[buf][(rd*256 + tid)*8]);
        #pragma unroll
        for (int rd = 0; rd < WRW; rd++)
            gl_lds16(W + wsrc[rd] + k0, &Ws[buf][(rd*256 + tid)*8]);
    };

    const int nT = kLen >> 6;
    STAGE(0, kBase);
    int cur = 0;
    for (int t = 0; t < nT; ++t) {
        if (t + 1 < nT) {
            STAGE(cur ^ 1, kBase + (t+1)*64);
            asm volatile("s_waitcnt vmcnt(6)" ::: "memory");
        } else {
            asm volatile("s_waitcnt vmcnt(0)" ::: "memory");
        }
        __builtin_amdgcn_sched_barrier(0);
        __builtin_amdgcn_s_barrier();
        __builtin_amdgcn_sched_barrier(0);
        #pragma unroll
        for (int ks = 0; ks < 2; ks++) {
            const int so = ks ? swz1 : swz0;
            bf16x8 af[FM], bfr[4];
            #pragma unroll
            for (int mi = 0; mi < FM; mi++)
                af[mi] = *(const bf16x8*)&As[cur][(wm + mi*16 + fr)*64 + so];
            #pragma unroll
            for (int ni = 0; ni < 4; ni++)
                bfr[ni] = *(const bf16x8*)&Ws[cur][(wn + ni*16 + fr)*64 + so];
            #pragma unroll
            for (int mi = 0; mi < FM; mi++)
                #pragma unroll
                for (int ni = 0; ni < 4; ni++)
                    acc[mi][ni] = __builtin_amdgcn_mfma_f32_16x16x32_bf16(af[mi], bfr[ni], acc[mi][ni], 0, 0, 0);
        }
        __builtin_amdgcn_sched_barrier(0);
        __builtin_amdgcn_s_barrier();
        __builtin_amdgcn_sched_barrier(0);
        cur ^= 1;
    }

    if (partial) {
        float* pp = partial + (size_t)z * pstride;
        #pragma unroll
        for (int mi = 0; mi < FM; mi++)
            #pragma unroll
            for (int r = 0; r < 4; r++) {
                int orow = rowBase + wm + mi*16 + ((lane>>4)<<2) + r;
                #pragma unroll
                for (int ni = 0; ni < 4; ni++)
                    pp[(size_t)orow*N + colBase + wn + ni*16 + fr] = acc[mi][ni][r];
            }
    } else {
        #pragma unroll
        for (int mi = 0; mi < FM; mi++)
            #pragma unroll
            for (int r = 0; r < 4; r++) {
                int orow = rowBase + wm + mi*16 + ((lane>>4)<<2) + r;
                #pragma unroll
                for (int ni = 0; ni < 4; ni++) {
                    int gcol = colBase + wn + ni*16 + fr;
                    float v = acc[mi][ni][r];
                    if (bias) v += bias[gcol];
                    if (gcol < actLim) {
                        if (act == 1) v = siluf_(v);
                        else if (act == 2) v = softplusf_(v);
                    }
                    if (outF) outF[(size_t)orow*ldc + gcol] = v;
                    if (outB) outB[(size_t)orow*ldc + gcol] = f2bf(v);
                }
            }
    }
}

// ---------------------------------------------------------------------------
// REDLN: sum S partials (N=512) + bias + act + resid*rscale -> h; optional
// fused LayerNorm -> bf16/f32. One 128-thread block per row.
// ---------------------------------------------------------------------------
__global__ void __launch_bounds__(128) redln_kernel(
    const float* __restrict__ part, int S,
    const float* __restrict__ bias, int act,
    const float* __restrict__ resid, float rscale,
    float* __restrict__ houtF, short* __restrict__ houtB,
    const float* __restrict__ lng, const float* __restrict__ lnb2,
    float* __restrict__ lnoutF, short* __restrict__ lnoutB)
{
    const int row = blockIdx.x;
    const int t = threadIdx.x;
    const size_t pstride = (size_t)MM*512;
    float4 s = ((const float4*)(part + (size_t)row*512))[t];
    for (int z = 1; z < S; z++) {
        float4 v = ((const float4*)(part + z*pstride + (size_t)row*512))[t];
        s.x += v.x; s.y += v.y; s.z += v.z; s.w += v.w;
    }
    if (bias) { float4 b = ((const float4*)bias)[t]; s.x+=b.x; s.y+=b.y; s.z+=b.z; s.w+=b.w; }
    if (act == 1) { s.x=siluf_(s.x); s.y=siluf_(s.y); s.z=siluf_(s.z); s.w=siluf_(s.w); }
    if (resid) {
        float4 r = ((const float4*)(resid + (size_t)row*512))[t];
        s.x = r.x + rscale*s.x; s.y = r.y + rscale*s.y;
        s.z = r.z + rscale*s.z; s.w = r.w + rscale*s.w;
    }
    if (houtF) ((float4*)(houtF + (size_t)row*512))[t] = s;
    if (houtB) {
        short4 o; o.x=f2bf(s.x); o.y=f2bf(s.y); o.z=f2bf(s.z); o.w=f2bf(s.w);
        *(short4*)(houtB + (size_t)row*512 + t*4) = o;
    }
    if (!lng) return;
    float sum = s.x+s.y+s.z+s.w;
    float sq  = s.x*s.x+s.y*s.y+s.z*s.z+s.w*s.w;
    #pragma unroll
    for (int off = 32; off >= 1; off >>= 1) {
        sum += __shfl_down(sum, off);
        sq  += __shfl_down(sq, off);
    }
    __shared__ float sh[4];
    if ((t & 63) == 0) { sh[(t>>6)*2] = sum; sh[(t>>6)*2+1] = sq; }
    __syncthreads();
    float mean = (sh[0]+sh[2]) * (1.0f/512.f);
    float var  = (sh[1]+sh[3]) * (1.0f/512.f) - mean*mean;
    float rstd = rsqrtf(var + 1e-5f);
    float4 gg = ((const float4*)lng)[t];
    float4 bb = ((const float4*)lnb2)[t];
    float4 o;
    o.x = (s.x-mean)*rstd*gg.x + bb.x;
    o.y = (s.y-mean)*rstd*gg.y + bb.y;
    o.z = (s.z-mean)*rstd*gg.z + bb.z;
    o.w = (s.w-mean)*rstd*gg.w + bb.w;
    if (lnoutF) ((float4*)(lnoutF + (size_t)row*512))[t] = o;
    if (lnoutB) {
        short4 ob; ob.x=f2bf(o.x); ob.y=f2bf(o.y); ob.z=f2bf(o.z); ob.w=f2bf(o.w);
        *(short4*)(lnoutB + (size_t)row*512 + t*4) = ob;
    }
}

// ---------------------------------------------------------------------------
// LayerNorm over 512 (pre-FFN1 only).
// ---------------------------------------------------------------------------
__global__ void __launch_bounds__(128) ln_kernel(
    const float* __restrict__ x, const float* __restrict__ g,
    const float* __restrict__ bta, short* __restrict__ outB)
{
    const int row = blockIdx.x;
    const int t = threadIdx.x;
    float4 v = ((const float4*)(x + (size_t)row*DD))[t];
    float s = v.x+v.y+v.z+v.w;
    float q = v.x*v.x+v.y*v.y+v.z*v.z+v.w*v.w;
    #pragma unroll
    for (int off = 32; off >= 1; off >>= 1) {
        s += __shfl_down(s, off);
        q += __shfl_down(q, off);
    }
    __shared__ float sh[4];
    if ((t & 63) == 0) { sh[(t>>6)*2] = s; sh[(t>>6)*2+1] = q; }
    __syncthreads();
    float mean = (sh[0]+sh[2]) * (1.0f/DD);
    float var  = (sh[1]+sh[3]) * (1.0f/DD) - mean*mean;
    float rstd = rsqrtf(var + 1e-5f);
    float4 gg = ((const float4*)g)[t];
    float4 bb = ((const float4*)bta)[t];
    short4 ob;
    ob.x = f2bf((v.x-mean)*rstd*gg.x + bb.x);
    ob.y = f2bf((v.y-mean)*rstd*gg.y + bb.y);
    ob.z = f2bf((v.z-mean)*rstd*gg.z + bb.z);
    ob.w = f2bf((v.w-mean)*rstd*gg.w + bb.w);
    *(short4*)(outB + (size_t)row*DD + t*4) = ob;
}

// ---------------------------------------------------------------------------
// Both-dir dwconv (K=4) + bias + SiLU, 8 channels/thread (short8 loads).
// dir=0 causal, dir=1 anti-causal (R8-proven index mapping).
// ---------------------------------------------------------------------------
__global__ void __launch_bounds__(256) conv_both_kernel(
    const short* __restrict__ xz_all, const float* __restrict__ cw,
    const float* __restrict__ cb, short* __restrict__ xc_both)
{
    const int gid = blockIdx.x*256 + threadIdx.x;    // 2*MM*128
    const int c8  = (gid & 127) << 3;
    const int row = (gid >> 7) & (MM-1);
    const int dir = gid >> 19;
    const int l   = row & (LL-1);
    const short* base = xz_all + (size_t)(row - l)*4096 + dir*2048 + c8;
    float acc[8];
    #pragma unroll
    for (int j = 0; j < 8; j++) acc[j] = cb[dir*1024 + c8 + j];
    float wt[8][4];
    #pragma unroll
    for (int j = 0; j < 8; j++) {
        float4 w = *(const float4*)(cw + (size_t)dir*4096 + (c8 + j)*4);
        wt[j][0]=w.x; wt[j][1]=w.y; wt[j][2]=w.z; wt[j][3]=w.w;
    }
    #pragma unroll
    for (int t = 0; t < 4; t++) {
        int lt = dir ? (l + 3 - t) : (l - 3 + t);
        if (lt >= 0 && lt < LL) {
            union { bf16x8 v; short e[8]; } u;
            u.v = *(const bf16x8*)(base + (size_t)lt*4096);
            #pragma unroll
            for (int j = 0; j < 8; j++) acc[j] += wt[j][t]*bf2f(u.e[j]);
        }
    }
    union { bf16x8 v; short e[8]; } o;
    #pragma unroll
    for (int j = 0; j < 8; j++) o.e[j] = f2bf(siluf_(acc[j]));
    *(bf16x8*)(xc_both + (size_t)dir*MM*1024 + (size_t)row*1024 + c8) = o.v;
}

// ---------------------------------------------------------------------------
// 3-pass scan, both dirs batched. dt/B/C from dtbc [2][MM,1152] bf16,
// xc from xc_both. Pass A: S_dt (sum dt) + local H. Pass B: chunk combine
// in-place (H -> h_in). Pass C: rescan + fused (y+Dp*xc)*silu(z), ys over xc.
// ---------------------------------------------------------------------------
__global__ void __launch_bounds__(256) scan_a_kernel(
    const short* __restrict__ dtbc, const short* __restrict__ xc_both,
    const float* __restrict__ Alog,
    float* __restrict__ S_dt, float* __restrict__ H)
{
    const int bid = blockIdx.x;                // 512
    const int dg  = bid & 3;
    const int c   = (bid >> 2) & (NCH-1);
    const int b   = (bid >> 5) & 7;
    const int dir = bid >> 8;
    const int d   = (dg << 8) + threadIdx.x;

    float Aexp[16];
    #pragma unroll
    for (int n = 0; n < 16; n++) Aexp[n] = -__expf(Alog[dir*16384 + d*16 + n]);

    float h[16];
    #pragma unroll
    for (int n = 0; n < 16; n++) h[n] = 0.f;
    float S = 0.f;

    const size_t rbase = (size_t)b*LL + (size_t)c*CHL;
    const short* dtp = dtbc + ((size_t)dir*MM + rbase)*1152 + d;
    const short* bcp = dtbc + ((size_t)dir*MM + rbase)*1152 + 1024;
    const short* xcp = xc_both + ((size_t)dir*MM + rbase)*1024 + d;

    for (int i = 0; i < CHL; i++) {
        int lp = dir ? (CHL-1-i) : i;
        float dtv = bf2f(dtp[(size_t)lp*1152]);
        float xcv = bf2f(xcp[(size_t)lp*1024]);
        S += dtv;
        float co = dtv*xcv;
        union { bf16x8 v; short e[8]; } b0, b1;
        b0.v = *(const bf16x8*)(bcp + (size_t)lp*1152);
        b1.v = *(const bf16x8*)(bcp + (size_t)lp*1152 + 8);
        #pragma unroll
        for (int n = 0; n < 16; n++) {
            float q = __expf(dtv*Aexp[n]);
            float Bv = bf2f(n < 8 ? b0.e[n] : b1.e[n & 7]);
            h[n] = fmaf(q, h[n], co*Bv);
        }
    }
    S_dt[(((size_t)dir*BB + b)*NCH + c)*1024 + d] = S;
    const size_t hb = ((((size_t)dir*BB + b)*NCH + c)*16)*1024 + d;
    #pragma unroll
    for (int n = 0; n < 16; n++) H[hb + (size_t)n*1024] = h[n];
}

__global__ void __launch_bounds__(256) scan_b_kernel(
    const float* __restrict__ S_dt, float* H, const float* __restrict__ Alog)
{
    const int g = blockIdx.x*256 + threadIdx.x;  // 2*8*16*1024
    const int d = g & 1023;
    const int n = (g >> 10) & 15;
    const int b = (g >> 14) & 7;
    const int dir = g >> 17;
    const float Aexp = -__expf(Alog[dir*16384 + d*16 + n]);
    float h = 0.f;
    for (int ci = 0; ci < NCH; ci++) {
        int c = dir ? (NCH-1-ci) : ci;
        float S = S_dt[(((size_t)dir*BB + b)*NCH + c)*1024 + d];
        size_t i = ((((size_t)dir*BB + b)*NCH + c)*16 + n)*1024 + d;
        float q = __expf(Aexp*S);
        float hn = q*h + H[i];
        H[i] = h;          // in-place: now holds h_in for this chunk
        h = hn;
    }
}

__global__ void __launch_bounds__(256) scan_c_kernel(
    const short* __restrict__ dtbc, short* xc_ys,
    const float* __restrict__ Alog, const float* __restrict__ H,
    const short* __restrict__ xz_all, const float* __restrict__ Dp)
{
    const int bid = blockIdx.x;
    const int dg  = bid & 3;
    const int c   = (bid >> 2) & (NCH-1);
    const int b   = (bid >> 5) & 7;
    const int dir = bid >> 8;
    const int d   = (dg << 8) + threadIdx.x;

    float Aexp[16];
    #pragma unroll
    for (int n = 0; n < 16; n++) Aexp[n] = -__expf(Alog[dir*16384 + d*16 + n]);
    const float Dpv = Dp[dir*1024 + d];

    float h[16];
    const size_t hb = ((((size_t)dir*BB + b)*NCH + c)*16)*1024 + d;
    #pragma unroll
    for (int n = 0; n < 16; n++) h[n] = H[hb + (size_t)n*1024];

    const size_t rbase = (size_t)b*LL + (size_t)c*CHL;
    const short* dtp = dtbc + ((size_t)dir*MM + rbase)*1152 + d;
    const short* bcp = dtbc + ((size_t)dir*MM + rbase)*1152 + 1024;
    short*       xcp = xc_ys + ((size_t)dir*MM + rbase)*1024 + d;
    const short* zp  = xz_all + rbase*4096 + dir*2048 + 1024 + d;

    for (int i = 0; i < CHL; i++) {
        int lp = dir ? (CHL-1-i) : i;
        float dtv = bf2f(dtp[(size_t)lp*1152]);
        float xcv = bf2f(xcp[(size_t)lp*1024]);
        float zv  = bf2f(zp[(size_t)lp*4096]);
        float co = dtv*xcv;
        union { bf16x8 v; short e[8]; } b0, b1, c0, c1;
        b0.v = *(const bf16x8*)(bcp + (size_t)lp*1152);
        b1.v = *(const bf16x8*)(bcp + (size_t)lp*1152 + 8);
        c0.v = *(const bf16x8*)(bcp + (size_t)lp*1152 + 16);
        c1.v = *(const bf16x8*)(bcp + (size_t)lp*1152 + 24);
        float y = 0.f;
        #pragma unroll
        for (int n = 0; n < 16; n++) {
            float q = __expf(dtv*Aexp[n]);
            float Bv = bf2f(n < 8 ? b0.e[n] : b1.e[n & 7]);
            float Cv = bf2f(n < 8 ? c0.e[n] : c1.e[n & 7]);
            h[n] = fmaf(q, h[n], co*Bv);
            y = fmaf(Cv, h[n], y);
        }
        float out = (y + Dpv*xcv) * siluf_(zv);
        xcp[(size_t)lp*1024] = f2bf(out);
    }
}

// ---------------------------------------------------------------------------
// GLU + transpose to [b, c, l] f32.
// ---------------------------------------------------------------------------
__global__ void __launch_bounds__(256) glu_transpose_kernel(
    const float* __restrict__ pw1, float* __restrict__ out_t)
{
    __shared__ float sh[64][65];
    const int c0 = blockIdx.x << 6;
    const int l0 = blockIdx.y << 6;
    const int b  = blockIdx.z;
    const int t  = threadIdx.x;
    const int c4 = (t & 15) << 2;
    const int r  = t >> 4;
    #pragma unroll
    for (int i = 0; i < 4; i++) {
        int lrow = r + i*16;
        size_t row = (size_t)(b << 9) + l0 + lrow;
        float4 a = *(const float4*)(pw1 + row*1024 + c0 + c4);
        float4 g = *(const float4*)(pw1 + row*1024 + 512 + c0 + c4);
        sh[lrow][c4+0] = a.x * sigmoidf_(g.x);
        sh[lrow][c4+1] = a.y * sigmoidf_(g.y);
        sh[lrow][c4+2] = a.z * sigmoidf_(g.z);
        sh[lrow][c4+3] = a.w * sigmoidf_(g.w);
    }
    __syncthreads();
    #pragma unroll
    for (int i = 0; i < 4; i++) {
        int crow = r + i*16;
        float4 o;
        o.x = sh[c4+0][crow];
        o.y = sh[c4+1][crow];
        o.z = sh[c4+2][crow];
        o.w = sh[c4+3][crow];
        *(float4*)(out_t + ((size_t)(b << 9) + c0 + crow)*512 + l0 + c4) = o;
    }
}

// ---------------------------------------------------------------------------
// Channel-major fused 3x dwconv avg + BN + SiLU.
// ---------------------------------------------------------------------------
__global__ void __launch_bounds__(256) multiconv_t_kernel(
    const float* __restrict__ gin_t,
    const float* __restrict__ w15, const float* __restrict__ w31,
    const float* __restrict__ w63,
    const float* __restrict__ bn_g, const float* __restrict__ bn_b,
    const float* __restrict__ bn_m, const float* __restrict__ bn_v,
    float* __restrict__ out_t)
{
    __shared__ float sh[574];
    const int c = blockIdx.x & (DD-1);
    const int b = blockIdx.x >> 9;
    const int t = threadIdx.x;
    const float* rowp = gin_t + ((size_t)(b << 9) + c)*512;
    sh[31 + t]       = rowp[t];
    sh[31 + t + 256] = rowp[t + 256];
    if (t < 31) { sh[t] = 0.f; sh[543 + t] = 0.f; }
    __syncthreads();

    const float bnscale = rsqrtf(bn_v[c] + 1e-5f) * bn_g[c];
    const float bnm = bn_m[c], bnb = bn_b[c];
    float* outp = out_t + ((size_t)(b << 9) + c)*512;
    #pragma unroll
    for (int half = 0; half < 2; half++) {
        int l = t + half*256;
        float s63 = 0.f, s31 = 0.f, s15 = 0.f;
        #pragma unroll
        for (int k = 0; k < 63; k++) s63 += w63[c*63 + k] * sh[l + k];
        #pragma unroll
        for (int k = 0; k < 31; k++) s31 += w31[c*31 + k] * sh[l + 16 + k];
        #pragma unroll
        for (int k = 0; k < 15; k++) s15 += w15[c*15 + k] * sh[l + 24 + k];
        float m = (s15 + s31 + s63) * (1.0f/3.0f);
        m = (m - bnm) * bnscale + bnb;
        outp[l] = siluf_(m);
    }
}

// ---------------------------------------------------------------------------
// Transpose [b, c, l] -> [b, l, c], bf16 out.
// ---------------------------------------------------------------------------
__global__ void __launch_bounds__(256) transpose_bcl_kernel(
    const float* __restrict__ in_t, short* __restrict__ out)
{
    __shared__ float sh[64][65];
    const int l0 = blockIdx.x << 6;
    const int c0 = blockIdx.y << 6;
    const int b  = blockIdx.z;
    const int t  = threadIdx.x;
    const int l4 = (t & 15) << 2;
    const int r  = t >> 4;
    #pragma unroll
    for (int i = 0; i < 4; i++) {
        int crow = r + i*16;
        float4 v = *(const float4*)(in_t + ((size_t)(b << 9) + c0 + crow)*512 + l0 + l4);
        sh[crow][l4+0] = v.x; sh[crow][l4+1] = v.y;
        sh[crow][l4+2] = v.z; sh[crow][l4+3] = v.w;
    }
    __syncthreads();
    #pragma unroll
    for (int i = 0; i < 4; i++) {
        int lrow = r + i*16;
        short4 o;
        o.x = f2bf(sh[l4+0][lrow]);
        o.y = f2bf(sh[l4+1][lrow]);
        o.z = f2bf(sh[l4+2][lrow]);
        o.w = f2bf(sh[l4+3][lrow]);
        *(short4*)(out + ((size_t)(b << 9) + l0 + lrow)*512 + c0 + l4) = o;
    }
}

// ---------------------------------------------------------------------------
extern "C" void kernel_launch(void* const* d_in, const int* in_sizes, int n_in,
                              void* d_out, int out_size, void* d_ws, size_t ws_size,
                              hipStream_t stream)
{
    const float* x        = (const float*)d_in[0];
    const float* ff1_ln_g = (const float*)d_in[1];
    const float* ff1_ln_b = (const float*)d_in[2];
    const float* ff1_w1   = (const float*)d_in[3];
    const float* ff1_b1   = (const float*)d_in[4];
    const float* ff1_w2   = (const float*)d_in[5];
    const float* ff1_b2   = (const float*)d_in[6];
    const float* ff2_ln_g = (const float*)d_in[7];
    const float* ff2_ln_b = (const float*)d_in[8];
    const float* ff2_w1   = (const float*)d_in[9];
    const float* ff2_b1   = (const float*)d_in[10];
    const float* ff2_w2   = (const float*)d_in[11];
    const float* ff2_b2   = (const float*)d_in[12];
    const float* m_win    = (const float*)d_in[13];
    const float* m_convw  = (const float*)d_in[14];
    const float* m_convb  = (const float*)d_in[15];
    const float* m_wx     = (const float*)d_in[16];
    const float* m_wdt    = (const float*)d_in[17];
    const float* m_bdt    = (const float*)d_in[18];
    const float* m_Alog   = (const float*)d_in[19];
    const float* m_Dp     = (const float*)d_in[20];
    const float* m_wout   = (const float*)d_in[21];
    const float* bi_wo    = (const float*)d_in[22];
    const float* bi_bo    = (const float*)d_in[23];
    const float* cv_ln_g  = (const float*)d_in[24];
    const float* cv_ln_b  = (const float*)d_in[25];
    const float* cv_pw1_w = (const float*)d_in[26];
    const float* cv_pw1_b = (const float*)d_in[27];
    const float* cv_dw15  = (const float*)d_in[28];
    const float* cv_dw31  = (const float*)d_in[29];
    const float* cv_dw63  = (const float*)d_in[30];
    const float* cv_bn_g  = (const float*)d_in[31];
    const float* cv_bn_b  = (const float*)d_in[32];
    const float* cv_bn_m  = (const float*)d_in[33];
    const float* cv_bn_v  = (const float*)d_in[34];
    const float* cv_pw2_w = (const float*)d_in[35];
    const float* cv_pw2_b = (const float*)d_in[36];
    const float* ln_g     = (const float*)d_in[37];
    const float* ln_b     = (const float*)d_in[38];

    // ---- Workspace (quarter-MiB offsets), total 103.5 MiB ----
    char* wsb = (char*)d_ws;
    float* h        = (float*)(wsb + Q_(0));     // 8 MB
    short* h_bf     = (short*)(wsb + Q_(32));    // 4 MB
    short* lnb_bf   = (short*)(wsb + Q_(48));    // 4 MB
    short* w_ff1w1  = (short*)(wsb + Q_(64));
    short* w_ff1w2  = (short*)(wsb + Q_(72));
    short* w_ff2w1  = (short*)(wsb + Q_(80));
    short* w_ff2w2  = (short*)(wsb + Q_(88));
    short* w_win    = (short*)(wsb + Q_(96));    // [4096,512] 4 MB
    short* w_pw1    = (short*)(wsb + Q_(112));
    short* w_pw2    = (short*)(wsb + Q_(116));
    short* w_Wc     = (short*)(wsb + Q_(118));   // [2][512][1024] 2 MB
    short* w_Wbig   = (short*)(wsb + Q_(126));   // [2][1152][1024] 4.5 MB
    short* w_wxT    = (short*)(wsb + Q_(144));   // [2][1024][64] 0.25 MB
    short* w_wdtp   = (short*)(wsb + Q_(145));   // [2][1024][64] 0.25 MB
    float* bias1152 = (float*)(wsb + Q_(146));   // [2][1152]
    float* part     = (float*)(wsb + Q_(148));   // 16 MB (2x [MM,512] f32 / pw1out)
    float* Hbuf     = (float*)(wsb + Q_(148));   // 8 MB overlay (scan H / h_in)
    float* S_dt     = (float*)(wsb + Q_(212));   // 0.5 MB
    short* xz_all   = (short*)(wsb + Q_(214));   // [MM,4096] 16 MB
    short* woutT_ov = (short*)(wsb + Q_(214));   // prep overlay 2 MB
    short* biwo_ov  = (short*)(wsb + Q_(222));   // prep overlay 1 MB
    float* glu_t    = (float*)(wsb + Q_(214));   // ConvMod overlay 8 MB
    float* mconv_o  = (float*)(wsb + Q_(246));   // ConvMod overlay 8 MB
    short* xc_both  = (short*)(wsb + Q_(278));   // [2][MM,1024] 16 MB
    short* hid_bf   = (short*)(wsb + Q_(278));   // FFN overlay [MM,2048] 8 MB
    short* dtbc     = (short*)(wsb + Q_(342));   // [2][MM,1152] 18 MB -> ends 414

    if (ws_size < Q_(414)) return;

    // ---- Prep ----
    hipMemsetAsync(w_Wbig, 0, (size_t)2*1152*1024*2, stream);
    hipMemsetAsync(w_wxT, 0, (size_t)2*1024*64*2, stream);
    hipMemsetAsync(w_wdtp, 0, (size_t)2*1024*64*2, stream);
    WcvtArgs wa;
    wa.s[0]=ff1_w1;   wa.d[0]=w_ff1w1;            wa.n[0]=1048576;
    wa.s[1]=ff1_w2;   wa.d[1]=w_ff1w2;            wa.n[1]=1048576;
    wa.s[2]=ff2_w1;   wa.d[2]=w_ff2w1;            wa.n[2]=1048576;
    wa.s[3]=ff2_w2;   wa.d[3]=w_ff2w2;            wa.n[3]=1048576;
    wa.s[4]=m_win;    wa.d[4]=w_win;              wa.n[4]=2097152;
    wa.s[5]=bi_wo;    wa.d[5]=biwo_ov;            wa.n[5]=524288;
    wa.s[6]=cv_pw1_w; wa.d[6]=w_pw1;              wa.n[6]=524288;
    wa.s[7]=cv_pw2_w; wa.d[7]=w_pw2;              wa.n[7]=262144;
    wa.s[8]=m_wdt;    wa.d[8]=w_wdtp;             wa.n[8]=65536;   // pad map
    wa.s[9]=m_wx+32768;  wa.d[9]=w_Wbig+1048576;            wa.n[9]=32768;  // dir0 B/C
    wa.s[10]=m_wx+98304; wa.d[10]=w_Wbig+1152*1024+1048576; wa.n[10]=32768; // dir1 B/C
    wcvt_kernel<<<dim3(1024,11), 256, 0, stream>>>(wa);
    woutT_kernel<<<dim3(8,16,2), 256, 0, stream>>>(m_wout, woutT_ov);
    wxT_kernel<<<dim3(256), 256, 0, stream>>>(m_wx, w_wxT);
    bias_build_kernel<<<dim3(9), 256, 0, stream>>>(m_bdt, bias1152);

    auto G = [&](const short* A, int lda, const short* W, int ldw,
                 const float* bias, float* oF, short* oB, int ldc,
                 int M, int N, int nz, int kLen, int kOff,
                 size_t zA, size_t zW, int zB, size_t zO,
                 int act, int actLim, float* prt) {
        dim3 g(N/128, M/64, nz);
        gemm3_kernel<128><<<g, 256, 0, stream>>>(A, lda, W, ldw, bias, oF, oB, ldc,
            kLen, kOff, act, actLim, zA, zW, zB, zO, prt, (size_t)M*N, N);
    };

    // prep GEMMs (batched z=dir):
    // Wdtc = wdt @ wx_dt^T -> Wbig rows 0..1023
    G(w_wdtp, 64, w_wxT, 64, nullptr, nullptr, w_Wbig, 1024,
      1024, 1024, 2, 64, 0, 65536, 65536, 0, (size_t)1152*1024, 0, 0, nullptr);
    // Wc = biwo_half @ woutT -> [2][512][1024]
    G(biwo_ov, 1024, woutT_ov, 512, nullptr, nullptr, w_Wc, 1024,
      512, 1024, 2, 512, 0, 512, 524288, 0, 524288, 0, 0, nullptr);

    // ---- FFN1 ----
    ln_kernel<<<MM, 128, 0, stream>>>(x, ff1_ln_g, ff1_ln_b, lnb_bf);
    G(lnb_bf, 512, w_ff1w1, 512, ff1_b1, nullptr, hid_bf, 2048,
      MM, 2048, 1, 512, 0, 0, 0, 0, 0, 1, 2048, nullptr);
    G(hid_bf, 2048, w_ff1w2, 2048, nullptr, nullptr, nullptr, 0,
      MM, 512, 2, 1024, 1024, 0, 0, 0, 0, 0, 0, part);
    redln_kernel<<<MM, 128, 0, stream>>>(part, 2, ff1_b2, 0, x, 0.5f,
        h, h_bf, nullptr, nullptr, nullptr, nullptr);

    // ---- BiMamba ----
    G(h_bf, 512, w_win, 512, nullptr, nullptr, xz_all, 4096,
      MM, 4096, 1, 512, 0, 0, 0, 0, 0, 0, 0, nullptr);
    conv_both_kernel<<<4096, 256, 0, stream>>>(xz_all, m_convw, m_convb, xc_both);
    // dt|B|C = xc @ Wbig^T (z=dir), softplus on cols<1024
    G(xc_both, 1024, w_Wbig, 1024, bias1152, nullptr, dtbc, 1152,
      MM, 1152, 2, 1024, 0, (size_t)MM*1024, (size_t)1152*1024, 1152, (size_t)MM*1152,
      2, 1024, nullptr);
    scan_a_kernel<<<512, 256, 0, stream>>>(dtbc, xc_both, m_Alog, S_dt, Hbuf);
    scan_b_kernel<<<1024, 256, 0, stream>>>(S_dt, Hbuf, m_Alog);
    scan_c_kernel<<<512, 256, 0, stream>>>(dtbc, xc_both, m_Alog, Hbuf, xz_all, m_Dp);
    // h += ys0@Wc0 + ys1@Wc1 + bi_bo ; fused cv-LN
    G(xc_both, 1024, w_Wc, 1024, nullptr, nullptr, nullptr, 0,
      MM, 512, 2, 1024, 0, (size_t)MM*1024, 524288, 0, 0, 0, 0, part);
    redln_kernel<<<MM, 128, 0, stream>>>(part, 2, bi_bo, 0, h, 1.0f,
        h, nullptr, cv_ln_g, cv_ln_b, nullptr, lnb_bf);

    // ---- ConvMod ----
    G(lnb_bf, 512, w_pw1, 512, cv_pw1_b, part, nullptr, 1024,
      MM, 1024, 1, 512, 0, 0, 0, 0, 0, 0, 0, nullptr);
    glu_transpose_kernel<<<dim3(8,8,8), 256, 0, stream>>>(part, glu_t);
    multiconv_t_kernel<<<BB*DD, 256, 0, stream>>>(glu_t,
        cv_dw15, cv_dw31, cv_dw63, cv_bn_g, cv_bn_b, cv_bn_m, cv_bn_v, mconv_o);
    transpose_bcl_kernel<<<dim3(8,8,8), 256, 0, stream>>>(mconv_o, lnb_bf);
    G(lnb_bf, 512, w_pw2, 512, nullptr, nullptr, nullptr, 0,
      MM, 512, 2, 256, 256, 0, 0, 0, 0, 0, 0, part);
    redln_kernel<<<MM, 128, 0, stream>>>(part, 2, cv_pw2_b, 0, h, 1.0f,
        h, nullptr, ff2_ln_g, ff2_ln_b, nullptr, lnb_bf);

    // ---- FFN2 ----
    G(lnb_bf, 512, w_ff2w1, 512, ff2_b1, nullptr, hid_bf, 2048,
      MM, 2048, 1, 512, 0, 0, 0, 0, 0, 1, 2048, nullptr);
    G(hid_bf, 2048, w_ff2w2, 2048, nullptr, nullptr, nullptr, 0,
      MM, 512, 2, 1024, 1024, 0, 0, 0, 0, 0, 0, part);
    // final: h = h + 0.5*v, then LN -> d_out (f32)
    redln_kernel<<<MM, 128, 0, stream>>>(part, 2, ff2_b2, 0, h, 0.5f,
        nullptr, nullptr, ln_g, ln_b, (float*)d_out, nullptr);
}

// Round 10
// 449.997 us; speedup vs baseline: 5.4684x; 1.0770x over previous
//
#include <hip/hip_runtime.h>
#include <hip/hip_bf16.h>
#include <math.h>

#define LL   512
#define DD   512
#define DII  1024
#define NST  16
#define BB   8
#define MM   4096
#define CHL  64
#define NCH  8
#define MB_  (1024*1024)
#define Q_(n) ((size_t)(n)*262144)   // quarter-MiB units

typedef __attribute__((ext_vector_type(8))) short bf16x8;
typedef __attribute__((ext_vector_type(4))) float f32x4;

__device__ __forceinline__ float sigmoidf_(float x){ return 1.0f/(1.0f+expf(-x)); }
__device__ __forceinline__ float siluf_(float x){ return x*sigmoidf_(x); }
__device__ __forceinline__ float softplusf_(float x){ return x > 20.0f ? x : log1pf(expf(x)); }

__device__ __forceinline__ short f2bf(float f) {
    union { float f; unsigned u; } v; v.f = f;
    unsigned r = v.u + 0x7fffu + ((v.u >> 16) & 1u);
    return (short)(r >> 16);
}
__device__ __forceinline__ float bf2f(short s) {
    union { unsigned u; float f; } v; v.u = ((unsigned)(unsigned short)s) << 16;
    return v.f;
}
__device__ __forceinline__ bf16x8 pack_bf8(float4 v0, float4 v1) {
    union { bf16x8 v; short e[8]; } pk;
    pk.e[0]=f2bf(v0.x); pk.e[1]=f2bf(v0.y); pk.e[2]=f2bf(v0.z); pk.e[3]=f2bf(v0.w);
    pk.e[4]=f2bf(v1.x); pk.e[5]=f2bf(v1.y); pk.e[6]=f2bf(v1.z); pk.e[7]=f2bf(v1.w);
    return pk.v;
}
__device__ __forceinline__ void gl_lds16(const short* g, short* l) {
    __builtin_amdgcn_global_load_lds(
        (const __attribute__((address_space(1))) void*)g,
        (__attribute__((address_space(3))) void*)l, 16, 0, 0);
}

// ---------------------------------------------------------------------------
// Batched fp32 -> bf16 weight conversion (10 segments).
// Seg 8 (wdt, 65536 elems) -> zero-padded [2048,64] K-layout.
// ---------------------------------------------------------------------------
struct WcvtArgs { const float* s[10]; short* d[10]; int n[10]; };
__global__ void __launch_bounds__(256) wcvt_kernel(WcvtArgs a) {
    const int seg = blockIdx.y;
    const int i = (blockIdx.x*256 + threadIdx.x) * 8;
    if (i >= a.n[seg]) return;
    const float* s = a.s[seg] + i;
    float4 v0 = *(const float4*)s;
    float4 v1 = *(const float4*)(s + 4);
    int di = i;
    if (seg == 8) di = ((i >> 5) << 6) | (i & 31);   // pad K 32 -> 64
    *(bf16x8*)(a.d[seg] + di) = pack_bf8(v0, v1);
}

// wout [2][512][1024] f32 -> [2][1024][512] bf16
__global__ void __launch_bounds__(256) woutT_kernel(
    const float* __restrict__ wout, short* __restrict__ outT)
{
    __shared__ float sh[64][65];
    const int o0 = blockIdx.x << 6;
    const int j0 = blockIdx.y << 6;
    const int d  = blockIdx.z;
    const float* in = wout + (size_t)d*512*1024;
    short* out = outT + (size_t)d*1024*512;
    const int t = threadIdx.x;
    const int c4 = (t & 15) << 2;
    const int r  = t >> 4;
    #pragma unroll
    for (int i = 0; i < 4; i++) {
        int orow = r + i*16;
        float4 v = *(const float4*)(in + (size_t)(o0 + orow)*1024 + j0 + c4);
        sh[orow][c4+0]=v.x; sh[orow][c4+1]=v.y; sh[orow][c4+2]=v.z; sh[orow][c4+3]=v.w;
    }
    __syncthreads();
    #pragma unroll
    for (int i = 0; i < 4; i++) {
        int jr = r + i*16;
        short4 o;
        o.x = f2bf(sh[c4+0][jr]); o.y = f2bf(sh[c4+1][jr]);
        o.z = f2bf(sh[c4+2][jr]); o.w = f2bf(sh[c4+3][jr]);
        *(short4*)(out + (size_t)(j0 + jr)*512 + o0 + c4) = o;
    }
}

// ---------------------------------------------------------------------------
// bf16 MFMA GEMM v8: 64xBN tile, BK=64, 4 waves, counted-vmcnt 2-deep
// pipeline, T2 source-pre-swizzle, XCD swizzle. Generalized batching:
//   A += z*zA, out += z*zO, kBase = z*kOff (split-K partials via z).
//   W/bias select: dsel = rowsPerW ? rowBase/rowsPerW : z;
//   W += dsel*zW, bias += dsel*zB.  act applied only to cols < actLim.
// ---------------------------------------------------------------------------
template<int BN>
__global__ void __launch_bounds__(256) gemm3_kernel(
    const short* __restrict__ A, int lda,
    const short* __restrict__ W, int ldw,
    const float* __restrict__ bias,
    float* __restrict__ outF, short* __restrict__ outB, int ldc,
    int kLen, int kOff, int act, int actLim,
    size_t zA, size_t zW, int zB, size_t zO, int rowsPerW,
    float* __restrict__ partial, size_t pstride, int N)
{
    constexpr int WN = BN / 64;
    constexpr int WM = 4 / WN;
    constexpr int TM = 64 / WM;
    constexpr int FM = TM / 16;
    constexpr int WRW = BN / 32;

    __shared__ short As[2][64*64];
    __shared__ short Ws[2][BN*64];

    const int tid = threadIdx.x, lane = tid & 63, wid = tid >> 6;
    const int z = blockIdx.z;
    A += (size_t)z * zA;
    if (outF) outF += (size_t)z * zO;
    if (outB) outB += (size_t)z * zO;

    int nwg = gridDim.x * gridDim.y;
    int flat = blockIdx.y * gridDim.x + blockIdx.x;
    if (!(nwg & 7)) { int cpx = nwg >> 3; flat = (flat & 7)*cpx + (flat >> 3); }
    const int bx = flat % gridDim.x, by = flat / gridDim.x;

    const int rowBase = by << 6;
    const int colBase = bx * BN;
    const int kBase = z * kOff;

    const int dsel = rowsPerW ? (rowBase / rowsPerW) : z;
    W += (size_t)dsel * zW;
    if (bias) bias += (size_t)dsel * (size_t)zB;

    size_t asrc[2];
    #pragma unroll
    for (int rd = 0; rd < 2; rd++) {
        int id = rd*256 + tid, row = id >> 3, u = id & 7;
        asrc[rd] = (size_t)(rowBase + row)*lda + ((u ^ (row & 7)) << 3);
    }
    size_t wsrc[WRW];
    #pragma unroll
    for (int rd = 0; rd < WRW; rd++) {
        int id = rd*256 + tid, row = id >> 3, u = id & 7;
        wsrc[rd] = (size_t)(colBase + row)*ldw + ((u ^ (row & 7)) << 3);
    }

    const int fr = lane & 15;
    const int swz0 = ((((lane >> 4)    ) ^ (lane & 7)) << 3);
    const int swz1 = ((((lane >> 4) | 4) ^ (lane & 7)) << 3);
    const int wm = (wid / WN) * TM, wn = (wid % WN) * 64;

    f32x4 acc[FM][4] = {};

    auto STAGE = [&](int buf, int k0) {
        #pragma unroll
        for (int rd = 0; rd < 2; rd++)
            gl_lds16(A + asrc[rd] + k0, &As[buf][(rd*256 + tid)*8]);
        #pragma unroll
        for (int rd = 0; rd < WRW; rd++)
            gl_lds16(W + wsrc[rd] + k0, &Ws[buf][(rd*256 + tid)*8]);
    };

    const int nT = kLen >> 6;
    STAGE(0, kBase);
    int cur = 0;
    for (int t = 0; t < nT; ++t) {
        if (t + 1 < nT) {
            STAGE(cur ^ 1, kBase + (t+1)*64);
            asm volatile("s_waitcnt vmcnt(6)" ::: "memory");
        } else {
            asm volatile("s_waitcnt vmcnt(0)" ::: "memory");
        }
        __builtin_amdgcn_sched_barrier(0);
        __builtin_amdgcn_s_barrier();
        __builtin_amdgcn_sched_barrier(0);
        #pragma unroll
        for (int ks = 0; ks < 2; ks++) {
            const int so = ks ? swz1 : swz0;
            bf16x8 af[FM], bfr[4];
            #pragma unroll
            for (int mi = 0; mi < FM; mi++)
                af[mi] = *(const bf16x8*)&As[cur][(wm + mi*16 + fr)*64 + so];
            #pragma unroll
            for (int ni = 0; ni < 4; ni++)
                bfr[ni] = *(const bf16x8*)&Ws[cur][(wn + ni*16 + fr)*64 + so];
            #pragma unroll
            for (int mi = 0; mi < FM; mi++)
                #pragma unroll
                for (int ni = 0; ni < 4; ni++)
                    acc[mi][ni] = __builtin_amdgcn_mfma_f32_16x16x32_bf16(af[mi], bfr[ni], acc[mi][ni], 0, 0, 0);
        }
        __builtin_amdgcn_sched_barrier(0);
        __builtin_amdgcn_s_barrier();
        __builtin_amdgcn_sched_barrier(0);
        cur ^= 1;
    }

    if (partial) {
        float* pp = partial + (size_t)z * pstride;
        #pragma unroll
        for (int mi = 0; mi < FM; mi++)
            #pragma unroll
            for (int r = 0; r < 4; r++) {
                int orow = rowBase + wm + mi*16 + ((lane>>4)<<2) + r;
                #pragma unroll
                for (int ni = 0; ni < 4; ni++)
                    pp[(size_t)orow*N + colBase + wn + ni*16 + fr] = acc[mi][ni][r];
            }
    } else {
        #pragma unroll
        for (int mi = 0; mi < FM; mi++)
            #pragma unroll
            for (int r = 0; r < 4; r++) {
                int orow = rowBase + wm + mi*16 + ((lane>>4)<<2) + r;
                #pragma unroll
                for (int ni = 0; ni < 4; ni++) {
                    int gcol = colBase + wn + ni*16 + fr;
                    float v = acc[mi][ni][r];
                    if (bias) v += bias[gcol];
                    if (gcol < actLim) {
                        if (act == 1) v = siluf_(v);
                        else if (act == 2) v = softplusf_(v);
                    }
                    if (outF) outF[(size_t)orow*ldc + gcol] = v;
                    if (outB) outB[(size_t)orow*ldc + gcol] = f2bf(v);
                }
            }
    }
}

// ---------------------------------------------------------------------------
// Generic split-K reduce -> bf16 (used only for the xdb projection).
// ---------------------------------------------------------------------------
__global__ void __launch_bounds__(256) reduce_kernel(
    const float* __restrict__ part, int S, size_t pstride, int N,
    short* __restrict__ outB, int ldc)
{
    const int i4 = blockIdx.x*256 + threadIdx.x;
    const int row = i4 / (N >> 2);
    const int c4  = (i4 - row*(N >> 2)) << 2;
    float4 s = *(const float4*)(part + (size_t)row*N + c4);
    for (int z = 1; z < S; z++) {
        float4 t = *(const float4*)(part + (size_t)z*pstride + (size_t)row*N + c4);
        s.x += t.x; s.y += t.y; s.z += t.z; s.w += t.w;
    }
    short4 o; o.x=f2bf(s.x); o.y=f2bf(s.y); o.z=f2bf(s.z); o.w=f2bf(s.w);
    *(short4*)(outB + (size_t)row*ldc + c4) = o;
}

// ---------------------------------------------------------------------------
// REDLN: sum S partials (N=512) + bias + resid*rscale -> h; optional fused
// LayerNorm -> bf16/f32. One 128-thread block per row.
// ---------------------------------------------------------------------------
__global__ void __launch_bounds__(128) redln_kernel(
    const float* __restrict__ part, int S,
    const float* __restrict__ bias,
    const float* __restrict__ resid, float rscale,
    float* __restrict__ houtF, short* __restrict__ houtB,
    const float* __restrict__ lng, const float* __restrict__ lnb2,
    float* __restrict__ lnoutF, short* __restrict__ lnoutB)
{
    const int row = blockIdx.x;
    const int t = threadIdx.x;
    const size_t pstride = (size_t)MM*512;
    float4 s = ((const float4*)(part + (size_t)row*512))[t];
    for (int z = 1; z < S; z++) {
        float4 v = ((const float4*)(part + z*pstride + (size_t)row*512))[t];
        s.x += v.x; s.y += v.y; s.z += v.z; s.w += v.w;
    }
    if (bias) { float4 b = ((const float4*)bias)[t]; s.x+=b.x; s.y+=b.y; s.z+=b.z; s.w+=b.w; }
    if (resid) {
        float4 r = ((const float4*)(resid + (size_t)row*512))[t];
        s.x = r.x + rscale*s.x; s.y = r.y + rscale*s.y;
        s.z = r.z + rscale*s.z; s.w = r.w + rscale*s.w;
    }
    if (houtF) ((float4*)(houtF + (size_t)row*512))[t] = s;
    if (houtB) {
        short4 o; o.x=f2bf(s.x); o.y=f2bf(s.y); o.z=f2bf(s.z); o.w=f2bf(s.w);
        *(short4*)(houtB + (size_t)row*512 + t*4) = o;
    }
    if (!lng) return;
    float sum = s.x+s.y+s.z+s.w;
    float sq  = s.x*s.x+s.y*s.y+s.z*s.z+s.w*s.w;
    #pragma unroll
    for (int off = 32; off >= 1; off >>= 1) {
        sum += __shfl_down(sum, off);
        sq  += __shfl_down(sq, off);
    }
    __shared__ float sh[4];
    if ((t & 63) == 0) { sh[(t>>6)*2] = sum; sh[(t>>6)*2+1] = sq; }
    __syncthreads();
    float mean = (sh[0]+sh[2]) * (1.0f/512.f);
    float var  = (sh[1]+sh[3]) * (1.0f/512.f) - mean*mean;
    float rstd = rsqrtf(var + 1e-5f);
    float4 gg = ((const float4*)lng)[t];
    float4 bb = ((const float4*)lnb2)[t];
    float4 o;
    o.x = (s.x-mean)*rstd*gg.x + bb.x;
    o.y = (s.y-mean)*rstd*gg.y + bb.y;
    o.z = (s.z-mean)*rstd*gg.z + bb.z;
    o.w = (s.w-mean)*rstd*gg.w + bb.w;
    if (lnoutF) ((float4*)(lnoutF + (size_t)row*512))[t] = o;
    if (lnoutB) {
        short4 ob; ob.x=f2bf(o.x); ob.y=f2bf(o.y); ob.z=f2bf(o.z); ob.w=f2bf(o.w);
        *(short4*)(lnoutB + (size_t)row*512 + t*4) = ob;
    }
}

// ---------------------------------------------------------------------------
// LayerNorm over 512 (pre-FFN1 only).
// ---------------------------------------------------------------------------
__global__ void __launch_bounds__(128) ln_kernel(
    const float* __restrict__ x, const float* __restrict__ g,
    const float* __restrict__ bta, short* __restrict__ outB)
{
    const int row = blockIdx.x;
    const int t = threadIdx.x;
    float4 v = ((const float4*)(x + (size_t)row*DD))[t];
    float s = v.x+v.y+v.z+v.w;
    float q = v.x*v.x+v.y*v.y+v.z*v.z+v.w*v.w;
    #pragma unroll
    for (int off = 32; off >= 1; off >>= 1) {
        s += __shfl_down(s, off);
        q += __shfl_down(q, off);
    }
    __shared__ float sh[4];
    if ((t & 63) == 0) { sh[(t>>6)*2] = s; sh[(t>>6)*2+1] = q; }
    __syncthreads();
    float mean = (sh[0]+sh[2]) * (1.0f/DD);
    float var  = (sh[1]+sh[3]) * (1.0f/DD) - mean*mean;
    float rstd = rsqrtf(var + 1e-5f);
    float4 gg = ((const float4*)g)[t];
    float4 bb = ((const float4*)bta)[t];
    short4 ob;
    ob.x = f2bf((v.x-mean)*rstd*gg.x + bb.x);
    ob.y = f2bf((v.y-mean)*rstd*gg.y + bb.y);
    ob.z = f2bf((v.z-mean)*rstd*gg.z + bb.z);
    ob.w = f2bf((v.w-mean)*rstd*gg.w + bb.w);
    *(short4*)(outB + (size_t)row*DD + t*4) = ob;
}

// ---------------------------------------------------------------------------
// Both-dir dwconv (K=4) + bias + SiLU, 4 channels/thread (short4 loads).
// dir=0 causal, dir=1 anti-causal.
// ---------------------------------------------------------------------------
__global__ void __launch_bounds__(256) conv_both_kernel(
    const short* __restrict__ xz_all, const float* __restrict__ cw,
    const float* __restrict__ cb, short* __restrict__ xc_both)
{
    const int gid = blockIdx.x*256 + threadIdx.x;    // 2*MM*256 = 2^21
    const int c4  = (gid & 255) << 2;
    const int row = (gid >> 8) & (MM-1);
    const int dir = gid >> 20;
    const int l   = row & (LL-1);
    const short* base = xz_all + (size_t)(row - l)*4096 + dir*2048 + c4;
    float acc[4];
    #pragma unroll
    for (int j = 0; j < 4; j++) acc[j] = cb[dir*1024 + c4 + j];
    float wt[4][4];
    #pragma unroll
    for (int j = 0; j < 4; j++) {
        float4 w = *(const float4*)(cw + (size_t)dir*4096 + (c4 + j)*4);
        wt[j][0]=w.x; wt[j][1]=w.y; wt[j][2]=w.z; wt[j][3]=w.w;
    }
    #pragma unroll
    for (int t = 0; t < 4; t++) {
        int lt = dir ? (l + 3 - t) : (l - 3 + t);
        if (lt >= 0 && lt < LL) {
            short4 u = *(const short4*)(base + (size_t)lt*4096);
            acc[0] += wt[0][t]*bf2f(u.x);
            acc[1] += wt[1][t]*bf2f(u.y);
            acc[2] += wt[2][t]*bf2f(u.z);
            acc[3] += wt[3][t]*bf2f(u.w);
        }
    }
    short4 o;
    o.x = f2bf(siluf_(acc[0])); o.y = f2bf(siluf_(acc[1]));
    o.z = f2bf(siluf_(acc[2])); o.w = f2bf(siluf_(acc[3]));
    *(short4*)(xc_both + (size_t)dir*MM*1024 + (size_t)row*1024 + c4) = o;
}

// ---------------------------------------------------------------------------
// 3-pass scan, both dirs batched. dt from dt_bf [2][MM,1024]; B/C from
// xdb_bf [2][MM,64] (cols 32-47 B, 48-63 C); xc from xc_both.
// Pass A: S_dt (sum dt) + local H. Pass B: chunk combine in-place.
// Pass C: rescan + fused (y+Dp*xc)*silu(z), ys over xc.
// ---------------------------------------------------------------------------
__global__ void __launch_bounds__(256) scan_a_kernel(
    const short* __restrict__ dt_bf, const short* __restrict__ xc_both,
    const short* __restrict__ xdb_bf, const float* __restrict__ Alog,
    float* __restrict__ S_dt, float* __restrict__ H)
{
    const int bid = blockIdx.x;                // 512
    const int dg  = bid & 3;
    const int c   = (bid >> 2) & (NCH-1);
    const int b   = (bid >> 5) & 7;
    const int dir = bid >> 8;
    const int d   = (dg << 8) + threadIdx.x;

    float Aexp[16];
    #pragma unroll
    for (int n = 0; n < 16; n++) Aexp[n] = -__expf(Alog[dir*16384 + d*16 + n]);

    float h[16];
    #pragma unroll
    for (int n = 0; n < 16; n++) h[n] = 0.f;
    float S = 0.f;

    const size_t rbase = (size_t)b*LL + (size_t)c*CHL;
    const short* dtp = dt_bf + ((size_t)dir*MM + rbase)*1024 + d;
    const short* bcp = xdb_bf + ((size_t)dir*MM + rbase)*64 + 32;
    const short* xcp = xc_both + ((size_t)dir*MM + rbase)*1024 + d;

    for (int i = 0; i < CHL; i++) {
        int lp = dir ? (CHL-1-i) : i;
        float dtv = bf2f(dtp[(size_t)lp*1024]);
        float xcv = bf2f(xcp[(size_t)lp*1024]);
        S += dtv;
        float co = dtv*xcv;
        union { bf16x8 v; short e[8]; } b0, b1;
        b0.v = *(const bf16x8*)(bcp + (size_t)lp*64);
        b1.v = *(const bf16x8*)(bcp + (size_t)lp*64 + 8);
        #pragma unroll
        for (int n = 0; n < 16; n++) {
            float q = __expf(dtv*Aexp[n]);
            float Bv = bf2f(n < 8 ? b0.e[n] : b1.e[n & 7]);
            h[n] = fmaf(q, h[n], co*Bv);
        }
    }
    S_dt[(((size_t)dir*BB + b)*NCH + c)*1024 + d] = S;
    const size_t hb = ((((size_t)dir*BB + b)*NCH + c)*16)*1024 + d;
    #pragma unroll
    for (int n = 0; n < 16; n++) H[hb + (size_t)n*1024] = h[n];
}

__global__ void __launch_bounds__(256) scan_b_kernel(
    const float* __restrict__ S_dt, float* H, const float* __restrict__ Alog)
{
    const int g = blockIdx.x*256 + threadIdx.x;  // 2*8*16*1024
    const int d = g & 1023;
    const int n = (g >> 10) & 15;
    const int b = (g >> 14) & 7;
    const int dir = g >> 17;
    const float Aexp = -__expf(Alog[dir*16384 + d*16 + n]);
    float h = 0.f;
    for (int ci = 0; ci < NCH; ci++) {
        int c = dir ? (NCH-1-ci) : ci;
        float S = S_dt[(((size_t)dir*BB + b)*NCH + c)*1024 + d];
        size_t i = ((((size_t)dir*BB + b)*NCH + c)*16 + n)*1024 + d;
        float q = __expf(Aexp*S);
        float hn = q*h + H[i];
        H[i] = h;
        h = hn;
    }
}

__global__ void __launch_bounds__(256) scan_c_kernel(
    const short* __restrict__ dt_bf, short* xc_ys,
    const short* __restrict__ xdb_bf, const float* __restrict__ Alog,
    const float* __restrict__ H, const short* __restrict__ xz_all,
    const float* __restrict__ Dp)
{
    const int bid = blockIdx.x;
    const int dg  = bid & 3;
    const int c   = (bid >> 2) & (NCH-1);
    const int b   = (bid >> 5) & 7;
    const int dir = bid >> 8;
    const int d   = (dg << 8) + threadIdx.x;

    float Aexp[16];
    #pragma unroll
    for (int n = 0; n < 16; n++) Aexp[n] = -__expf(Alog[dir*16384 + d*16 + n]);
    const float Dpv = Dp[dir*1024 + d];

    float h[16];
    const size_t hb = ((((size_t)dir*BB + b)*NCH + c)*16)*1024 + d;
    #pragma unroll
    for (int n = 0; n < 16; n++) h[n] = H[hb + (size_t)n*1024];

    const size_t rbase = (size_t)b*LL + (size_t)c*CHL;
    const short* dtp = dt_bf + ((size_t)dir*MM + rbase)*1024 + d;
    const short* bcp = xdb_bf + ((size_t)dir*MM + rbase)*64 + 32;
    short*       xcp = xc_ys + ((size_t)dir*MM + rbase)*1024 + d;
    const short* zp  = xz_all + rbase*4096 + dir*2048 + 1024 + d;

    for (int i = 0; i < CHL; i++) {
        int lp = dir ? (CHL-1-i) : i;
        float dtv = bf2f(dtp[(size_t)lp*1024]);
        float xcv = bf2f(xcp[(size_t)lp*1024]);
        float zv  = bf2f(zp[(size_t)lp*4096]);
        float co = dtv*xcv;
        union { bf16x8 v; short e[8]; } b0, b1, c0, c1;
        b0.v = *(const bf16x8*)(bcp + (size_t)lp*64);
        b1.v = *(const bf16x8*)(bcp + (size_t)lp*64 + 8);
        c0.v = *(const bf16x8*)(bcp + (size_t)lp*64 + 16);
        c1.v = *(const bf16x8*)(bcp + (size_t)lp*64 + 24);
        float y = 0.f;
        #pragma unroll
        for (int n = 0; n < 16; n++) {
            float q = __expf(dtv*Aexp[n]);
            float Bv = bf2f(n < 8 ? b0.e[n] : b1.e[n & 7]);
            float Cv = bf2f(n < 8 ? c0.e[n] : c1.e[n & 7]);
            h[n] = fmaf(q, h[n], co*Bv);
            y = fmaf(Cv, h[n], y);
        }
        float out = (y + Dpv*xcv) * siluf_(zv);
        xcp[(size_t)lp*1024] = f2bf(out);
    }
}

// ---------------------------------------------------------------------------
// GLU + transpose to [b, c, l] f32.
// ---------------------------------------------------------------------------
__global__ void __launch_bounds__(256) glu_transpose_kernel(
    const float* __restrict__ pw1, float* __restrict__ out_t)
{
    __shared__ float sh[64][65];
    const int c0 = blockIdx.x << 6;
    const int l0 = blockIdx.y << 6;
    const int b  = blockIdx.z;
    const int t  = threadIdx.x;
    const int c4 = (t & 15) << 2;
    const int r  = t >> 4;
    #pragma unroll
    for (int i = 0; i < 4; i++) {
        int lrow = r + i*16;
        size_t row = (size_t)(b << 9) + l0 + lrow;
        float4 a = *(const float4*)(pw1 + row*1024 + c0 + c4);
        float4 g = *(const float4*)(pw1 + row*1024 + 512 + c0 + c4);
        sh[lrow][c4+0] = a.x * sigmoidf_(g.x);
        sh[lrow][c4+1] = a.y * sigmoidf_(g.y);
        sh[lrow][c4+2] = a.z * sigmoidf_(g.z);
        sh[lrow][c4+3] = a.w * sigmoidf_(g.w);
    }
    __syncthreads();
    #pragma unroll
    for (int i = 0; i < 4; i++) {
        int crow = r + i*16;
        float4 o;
        o.x = sh[c4+0][crow];
        o.y = sh[c4+1][crow];
        o.z = sh[c4+2][crow];
        o.w = sh[c4+3][crow];
        *(float4*)(out_t + ((size_t)(b << 9) + c0 + crow)*512 + l0 + c4) = o;
    }
}

// ---------------------------------------------------------------------------
// Channel-major fused 3x dwconv avg + BN + SiLU.
// ---------------------------------------------------------------------------
__global__ void __launch_bounds__(256) multiconv_t_kernel(
    const float* __restrict__ gin_t,
    const float* __restrict__ w15, const float* __restrict__ w31,
    const float* __restrict__ w63,
    const float* __restrict__ bn_g, const float* __restrict__ bn_b,
    const float* __restrict__ bn_m, const float* __restrict__ bn_v,
    float* __restrict__ out_t)
{
    __shared__ float sh[574];
    const int c = blockIdx.x & (DD-1);
    const int b = blockIdx.x >> 9;
    const int t = threadIdx.x;
    const float* rowp = gin_t + ((size_t)(b << 9) + c)*512;
    sh[31 + t]       = rowp[t];
    sh[31 + t + 256] = rowp[t + 256];
    if (t < 31) { sh[t] = 0.f; sh[543 + t] = 0.f; }
    __syncthreads();

    const float bnscale = rsqrtf(bn_v[c] + 1e-5f) * bn_g[c];
    const float bnm = bn_m[c], bnb = bn_b[c];
    float* outp = out_t + ((size_t)(b << 9) + c)*512;
    #pragma unroll
    for (int half = 0; half < 2; half++) {
        int l = t + half*256;
        float s63 = 0.f, s31 = 0.f, s15 = 0.f;
        #pragma unroll
        for (int k = 0; k < 63; k++) s63 += w63[c*63 + k] * sh[l + k];
        #pragma unroll
        for (int k = 0; k < 31; k++) s31 += w31[c*31 + k] * sh[l + 16 + k];
        #pragma unroll
        for (int k = 0; k < 15; k++) s15 += w15[c*15 + k] * sh[l + 24 + k];
        float m = (s15 + s31 + s63) * (1.0f/3.0f);
        m = (m - bnm) * bnscale + bnb;
        outp[l] = siluf_(m);
    }
}

// ---------------------------------------------------------------------------
// Transpose [b, c, l] -> [b, l, c], bf16 out.
// ---------------------------------------------------------------------------
__global__ void __launch_bounds__(256) transpose_bcl_kernel(
    const float* __restrict__ in_t, short* __restrict__ out)
{
    __shared__ float sh[64][65];
    const int l0 = blockIdx.x << 6;
    const int c0 = blockIdx.y << 6;
    const int b  = blockIdx.z;
    const int t  = threadIdx.x;
    const int l4 = (t & 15) << 2;
    const int r  = t >> 4;
    #pragma unroll
    for (int i = 0; i < 4; i++) {
        int crow = r + i*16;
        float4 v = *(const float4*)(in_t + ((size_t)(b << 9) + c0 + crow)*512 + l0 + l4);
        sh[crow][l4+0] = v.x; sh[crow][l4+1] = v.y;
        sh[crow][l4+2] = v.z; sh[crow][l4+3] = v.w;
    }
    __syncthreads();
    #pragma unroll
    for (int i = 0; i < 4; i++) {
        int lrow = r + i*16;
        short4 o;
        o.x = f2bf(sh[l4+0][lrow]);
        o.y = f2bf(sh[l4+1][lrow]);
        o.z = f2bf(sh[l4+2][lrow]);
        o.w = f2bf(sh[l4+3][lrow]);
        *(short4*)(out + ((size_t)(b << 9) + l0 + lrow)*512 + c0 + l4) = o;
    }
}

// ---------------------------------------------------------------------------
extern "C" void kernel_launch(void* const* d_in, const int* in_sizes, int n_in,
                              void* d_out, int out_size, void* d_ws, size_t ws_size,
                              hipStream_t stream)
{
    const float* x        = (const float*)d_in[0];
    const float* ff1_ln_g = (const float*)d_in[1];
    const float* ff1_ln_b = (const float*)d_in[2];
    const float* ff1_w1   = (const float*)d_in[3];
    const float* ff1_b1   = (const float*)d_in[4];
    const float* ff1_w2   = (const float*)d_in[5];
    const float* ff1_b2   = (const float*)d_in[6];
    const float* ff2_ln_g = (const float*)d_in[7];
    const float* ff2_ln_b = (const float*)d_in[8];
    const float* ff2_w1   = (const float*)d_in[9];
    const float* ff2_b1   = (const float*)d_in[10];
    const float* ff2_w2   = (const float*)d_in[11];
    const float* ff2_b2   = (const float*)d_in[12];
    const float* m_win    = (const float*)d_in[13];
    const float* m_convw  = (const float*)d_in[14];
    const float* m_convb  = (const float*)d_in[15];
    const float* m_wx     = (const float*)d_in[16];
    const float* m_wdt    = (const float*)d_in[17];
    const float* m_bdt    = (const float*)d_in[18];
    const float* m_Alog   = (const float*)d_in[19];
    const float* m_Dp     = (const float*)d_in[20];
    const float* m_wout   = (const float*)d_in[21];
    const float* bi_wo    = (const float*)d_in[22];
    const float* bi_bo    = (const float*)d_in[23];
    const float* cv_ln_g  = (const float*)d_in[24];
    const float* cv_ln_b  = (const float*)d_in[25];
    const float* cv_pw1_w = (const float*)d_in[26];
    const float* cv_pw1_b = (const float*)d_in[27];
    const float* cv_dw15  = (const float*)d_in[28];
    const float* cv_dw31  = (const float*)d_in[29];
    const float* cv_dw63  = (const float*)d_in[30];
    const float* cv_bn_g  = (const float*)d_in[31];
    const float* cv_bn_b  = (const float*)d_in[32];
    const float* cv_bn_m  = (const float*)d_in[33];
    const float* cv_bn_v  = (const float*)d_in[34];
    const float* cv_pw2_w = (const float*)d_in[35];
    const float* cv_pw2_b = (const float*)d_in[36];
    const float* ln_g     = (const float*)d_in[37];
    const float* ln_b     = (const float*)d_in[38];

    // ---- Workspace (quarter-MiB offsets), total 105.5 MiB ----
    char* wsb = (char*)d_ws;
    float* h        = (float*)(wsb + Q_(0));     // 8 MB
    short* h_bf     = (short*)(wsb + Q_(32));    // 4 MB
    short* lnb_bf   = (short*)(wsb + Q_(48));    // 4 MB
    short* w_ff1w1  = (short*)(wsb + Q_(64));
    short* w_ff1w2  = (short*)(wsb + Q_(72));
    short* w_ff2w1  = (short*)(wsb + Q_(80));
    short* w_ff2w2  = (short*)(wsb + Q_(88));
    short* w_win    = (short*)(wsb + Q_(96));    // [4096,512] 4 MB
    short* w_pw1    = (short*)(wsb + Q_(112));
    short* w_pw2    = (short*)(wsb + Q_(116));
    short* w_Wc     = (short*)(wsb + Q_(118));   // [2][512][1024] 2 MB
    short* w_wdtp   = (short*)(wsb + Q_(126));   // [2][1024][64] 0.25 MB
    short* w_wx     = (short*)(wsb + Q_(127));   // [2][64][1024] 0.25 MB
    float* part     = (float*)(wsb + Q_(128));   // 16 MB: partials / pw1out
    float* Hbuf     = (float*)(wsb + Q_(192));   // 8 MB scan H / h_in
    float* S_dt     = (float*)(wsb + Q_(224));   // 0.5 MB
    short* xz_all   = (short*)(wsb + Q_(226));   // [MM,4096] 16 MB
    short* woutT_ov = (short*)(wsb + Q_(226));   // prep overlay 2 MB
    short* biwo_ov  = (short*)(wsb + Q_(234));   // prep overlay 1 MB
    float* glu_t    = (float*)(wsb + Q_(226));   // ConvMod overlay 8 MB
    short* xc_both  = (short*)(wsb + Q_(290));   // [2][MM,1024] 16 MB
    short* hid_bf   = (short*)(wsb + Q_(290));   // FFN overlay [MM,2048] 8 MB
    short* dt_bf    = (short*)(wsb + Q_(354));   // [2][MM,1024] 16 MB
    float* mconv_o  = (float*)(wsb + Q_(354));   // ConvMod overlay 8 MB
    short* xdb_bf   = (short*)(wsb + Q_(418));   // [2][MM,64] 1 MB -> ends 422

    if (ws_size < Q_(422)) return;

    // ---- Prep ----
    hipMemsetAsync(w_wdtp, 0, (size_t)2*1024*64*2, stream);
    WcvtArgs wa;
    wa.s[0]=ff1_w1;   wa.d[0]=w_ff1w1; wa.n[0]=1048576;
    wa.s[1]=ff1_w2;   wa.d[1]=w_ff1w2; wa.n[1]=1048576;
    wa.s[2]=ff2_w1;   wa.d[2]=w_ff2w1; wa.n[2]=1048576;
    wa.s[3]=ff2_w2;   wa.d[3]=w_ff2w2; wa.n[3]=1048576;
    wa.s[4]=m_win;    wa.d[4]=w_win;   wa.n[4]=2097152;
    wa.s[5]=bi_wo;    wa.d[5]=biwo_ov; wa.n[5]=524288;
    wa.s[6]=cv_pw1_w; wa.d[6]=w_pw1;   wa.n[6]=524288;
    wa.s[7]=cv_pw2_w; wa.d[7]=w_pw2;   wa.n[7]=262144;
    wa.s[8]=m_wdt;    wa.d[8]=w_wdtp;  wa.n[8]=65536;   // pad K 32->64
    wa.s[9]=m_wx;     wa.d[9]=w_wx;    wa.n[9]=131072;
    wcvt_kernel<<<dim3(1024,10), 256, 0, stream>>>(wa);
    woutT_kernel<<<dim3(8,16,2), 256, 0, stream>>>(m_wout, woutT_ov);

    auto G = [&](const short* A, int lda, const short* W, int ldw,
                 const float* bias, float* oF, short* oB, int ldc,
                 int M, int N, int nz, int kLen, int kOff,
                 size_t zA, size_t zW, int zB, size_t zO, int rowsPerW,
                 int act, int actLim, float* prt) {
        dim3 g(N/128, M/64, nz);
        gemm3_kernel<128><<<g, 256, 0, stream>>>(A, lda, W, ldw, bias, oF, oB, ldc,
            kLen, kOff, act, actLim, zA, zW, zB, zO, rowsPerW,
            prt, (size_t)M*N, N);
    };

    // Wc = biwo_half @ woutT -> [2][512][1024] bf16 (batched z=dir)
    G(biwo_ov, 1024, woutT_ov, 512, nullptr, nullptr, w_Wc, 1024,
      512, 1024, 2, 512, 0, 512, 524288, 0, 524288, 0, 0, 0, nullptr);

    // ---- FFN1 ----
    ln_kernel<<<MM, 128, 0, stream>>>(x, ff1_ln_g, ff1_ln_b, lnb_bf);
    G(lnb_bf, 512, w_ff1w1, 512, ff1_b1, nullptr, hid_bf, 2048,
      MM, 2048, 1, 512, 0, 0, 0, 0, 0, 0, 1, 2048, nullptr);
    G(hid_bf, 2048, w_ff1w2, 2048, nullptr, nullptr, nullptr, 0,
      MM, 512, 2, 1024, 1024, 0, 0, 0, 0, 0, 0, 0, part);
    redln_kernel<<<MM, 128, 0, stream>>>(part, 2, ff1_b2, x, 0.5f,
        h, h_bf, nullptr, nullptr, nullptr, nullptr);

    // ---- BiMamba ----
    G(h_bf, 512, w_win, 512, nullptr, nullptr, xz_all, 4096,
      MM, 4096, 1, 512, 0, 0, 0, 0, 0, 0, 0, 0, nullptr);
    conv_both_kernel<<<8192, 256, 0, stream>>>(xz_all, m_convw, m_convb, xc_both);
    // xdb = xc @ wx^T : M=8192 (both dirs), N=64, split-K 4, W by row-dir
    {
        dim3 g(1, 128, 4);
        gemm3_kernel<64><<<g, 256, 0, stream>>>(xc_both, 1024, w_wx, 1024,
            nullptr, nullptr, nullptr, 0, 256, 256, 0, 0,
            0, 65536, 0, 0, 4096, part, (size_t)8192*64, 64);
    }
    reduce_kernel<<<512, 256, 0, stream>>>(part, 4, (size_t)8192*64, 64, xdb_bf, 64);
    // dt = softplus(xdb @ wdt_pad^T + bdt) : M=8192, N=1024, K=64
    G(xdb_bf, 64, w_wdtp, 64, m_bdt, nullptr, dt_bf, 1024,
      8192, 1024, 1, 64, 0, 0, 65536, 1024, 0, 4096, 2, 1024, nullptr);
    // 3-pass scan (both dirs) + fused ycombine (ys overwrites xc_both)
    scan_a_kernel<<<512, 256, 0, stream>>>(dt_bf, xc_both, xdb_bf, m_Alog, S_dt, Hbuf);
    scan_b_kernel<<<1024, 256, 0, stream>>>(S_dt, Hbuf, m_Alog);
    scan_c_kernel<<<512, 256, 0, stream>>>(dt_bf, xc_both, xdb_bf, m_Alog, Hbuf,
                                           xz_all, m_Dp);
    // h += ys0@Wc0 + ys1@Wc1 + bi_bo ; fused cv-LN
    G(xc_both, 1024, w_Wc, 1024, nullptr, nullptr, nullptr, 0,
      MM, 512, 2, 1024, 0, (size_t)MM*1024, 524288, 0, 0, 0, 0, 0, part);
    redln_kernel<<<MM, 128, 0, stream>>>(part, 2, bi_bo, h, 1.0f,
        h, nullptr, cv_ln_g, cv_ln_b, nullptr, lnb_bf);

    // ---- ConvMod ----
    G(lnb_bf, 512, w_pw1, 512, cv_pw1_b, part, nullptr, 1024,
      MM, 1024, 1, 512, 0, 0, 0, 0, 0, 0, 0, 0, nullptr);
    glu_transpose_kernel<<<dim3(8,8,8), 256, 0, stream>>>(part, glu_t);
    multiconv_t_kernel<<<BB*DD, 256, 0, stream>>>(glu_t,
        cv_dw15, cv_dw31, cv_dw63, cv_bn_g, cv_bn_b, cv_bn_m, cv_bn_v, mconv_o);
    transpose_bcl_kernel<<<dim3(8,8,8), 256, 0, stream>>>(mconv_o, lnb_bf);
    G(lnb_bf, 512, w_pw2, 512, nullptr, nullptr, nullptr, 0,
      MM, 512, 2, 256, 256, 0, 0, 0, 0, 0, 0, 0, part);
    redln_kernel<<<MM, 128, 0, stream>>>(part, 2, cv_pw2_b, h, 1.0f,
        h, nullptr, ff2_ln_g, ff2_ln_b, nullptr, lnb_bf);

    // ---- FFN2 ----
    G(lnb_bf, 512, w_ff2w1, 512, ff2_b1, nullptr, hid_bf, 2048,
      MM, 2048, 1, 512, 0, 0, 0, 0, 0, 0, 1, 2048, nullptr);
    G(hid_bf, 2048, w_ff2w2, 2048, nullptr, nullptr, nullptr, 0,
      MM, 512, 2, 1024, 1024, 0, 0, 0, 0, 0, 0, 0, part);
    // final: h = h + 0.5*v, then LN -> d_out (f32)
    redln_kernel<<<MM, 128, 0, stream>>>(part, 2, ff2_b2, h, 0.5f,
        nullptr, nullptr, ln_g, ln_b, (float*)d_out, nullptr);
}

// Round 11
// 424.357 us; speedup vs baseline: 5.7988x; 1.0604x over previous
//
#include <hip/hip_runtime.h>
#include <hip/hip_bf16.h>
#include <math.h>

#define LL   512
#define DD   512
#define DII  1024
#define NST  16
#define BB   8
#define MM   4096
#define CHL  32
#define NCH  16
#define MB_  (1024*1024)
#define Q_(n) ((size_t)(n)*262144)   // quarter-MiB units

typedef __attribute__((ext_vector_type(8))) short bf16x8;
typedef __attribute__((ext_vector_type(4))) float f32x4;

__device__ __forceinline__ float sigmoidf_(float x){ return 1.0f/(1.0f+expf(-x)); }
__device__ __forceinline__ float siluf_(float x){ return x*sigmoidf_(x); }
__device__ __forceinline__ float softplusf_(float x){ return x > 20.0f ? x : log1pf(expf(x)); }

__device__ __forceinline__ short f2bf(float f) {
    union { float f; unsigned u; } v; v.f = f;
    unsigned r = v.u + 0x7fffu + ((v.u >> 16) & 1u);
    return (short)(r >> 16);
}
__device__ __forceinline__ float bf2f(short s) {
    union { unsigned u; float f; } v; v.u = ((unsigned)(unsigned short)s) << 16;
    return v.f;
}
__device__ __forceinline__ bf16x8 pack_bf8(float4 v0, float4 v1) {
    union { bf16x8 v; short e[8]; } pk;
    pk.e[0]=f2bf(v0.x); pk.e[1]=f2bf(v0.y); pk.e[2]=f2bf(v0.z); pk.e[3]=f2bf(v0.w);
    pk.e[4]=f2bf(v1.x); pk.e[5]=f2bf(v1.y); pk.e[6]=f2bf(v1.z); pk.e[7]=f2bf(v1.w);
    return pk.v;
}
__device__ __forceinline__ void gl_lds16(const short* g, short* l) {
    __builtin_amdgcn_global_load_lds(
        (const __attribute__((address_space(1))) void*)g,
        (__attribute__((address_space(3))) void*)l, 16, 0, 0);
}

// ---------------------------------------------------------------------------
// Batched fp32 -> bf16 weight conversion (10 segments).
// Seg 8 (wdt) -> zero-padded [2048,64] K-layout.
// ---------------------------------------------------------------------------
struct WcvtArgs { const float* s[10]; short* d[10]; int n[10]; };
__global__ void __launch_bounds__(256) wcvt_kernel(WcvtArgs a) {
    const int seg = blockIdx.y;
    const int i = (blockIdx.x*256 + threadIdx.x) * 8;
    if (i >= a.n[seg]) return;
    const float* s = a.s[seg] + i;
    float4 v0 = *(const float4*)s;
    float4 v1 = *(const float4*)(s + 4);
    int di = i;
    if (seg == 8) di = ((i >> 5) << 6) | (i & 31);   // pad K 32 -> 64
    *(bf16x8*)(a.d[seg] + di) = pack_bf8(v0, v1);
}

// wout [2][512][1024] f32 -> [2][1024][512] bf16
__global__ void __launch_bounds__(256) woutT_kernel(
    const float* __restrict__ wout, short* __restrict__ outT)
{
    __shared__ float sh[64][65];
    const int o0 = blockIdx.x << 6;
    const int j0 = blockIdx.y << 6;
    const int d  = blockIdx.z;
    const float* in = wout + (size_t)d*512*1024;
    short* out = outT + (size_t)d*1024*512;
    const int t = threadIdx.x;
    const int c4 = (t & 15) << 2;
    const int r  = t >> 4;
    #pragma unroll
    for (int i = 0; i < 4; i++) {
        int orow = r + i*16;
        float4 v = *(const float4*)(in + (size_t)(o0 + orow)*1024 + j0 + c4);
        sh[orow][c4+0]=v.x; sh[orow][c4+1]=v.y; sh[orow][c4+2]=v.z; sh[orow][c4+3]=v.w;
    }
    __syncthreads();
    #pragma unroll
    for (int i = 0; i < 4; i++) {
        int jr = r + i*16;
        short4 o;
        o.x = f2bf(sh[c4+0][jr]); o.y = f2bf(sh[c4+1][jr]);
        o.z = f2bf(sh[c4+2][jr]); o.w = f2bf(sh[c4+3][jr]);
        *(short4*)(out + (size_t)(j0 + jr)*512 + o0 + c4) = o;
    }
}

// ---------------------------------------------------------------------------
// bf16 MFMA GEMM v8: 64xBN tile, BK=64, 4 waves, counted-vmcnt 2-deep
// pipeline, T2 source-pre-swizzle, XCD swizzle. Generalized batching:
//   A += z*zA, out += z*zO, kBase = z*kOff (split-K partials via z).
//   W/bias select: dsel = rowsPerW ? rowBase/rowsPerW : z.
// act applied only to cols < actLim.
// ---------------------------------------------------------------------------
template<int BN>
__global__ void __launch_bounds__(256) gemm3_kernel(
    const short* __restrict__ A, int lda,
    const short* __restrict__ W, int ldw,
    const float* __restrict__ bias,
    float* __restrict__ outF, short* __restrict__ outB, int ldc,
    int kLen, int kOff, int act, int actLim,
    size_t zA, size_t zW, int zB, size_t zO, int rowsPerW,
    float* __restrict__ partial, size_t pstride, int N)
{
    constexpr int WN = BN / 64;
    constexpr int WM = 4 / WN;
    constexpr int TM = 64 / WM;
    constexpr int FM = TM / 16;
    constexpr int WRW = BN / 32;

    __shared__ short As[2][64*64];
    __shared__ short Ws[2][BN*64];

    const int tid = threadIdx.x, lane = tid & 63, wid = tid >> 6;
    const int z = blockIdx.z;
    A += (size_t)z * zA;
    if (outF) outF += (size_t)z * zO;
    if (outB) outB += (size_t)z * zO;

    int nwg = gridDim.x * gridDim.y;
    int flat = blockIdx.y * gridDim.x + blockIdx.x;
    if (!(nwg & 7)) { int cpx = nwg >> 3; flat = (flat & 7)*cpx + (flat >> 3); }
    const int bx = flat % gridDim.x, by = flat / gridDim.x;

    const int rowBase = by << 6;
    const int colBase = bx * BN;
    const int kBase = z * kOff;

    const int dsel = rowsPerW ? (rowBase / rowsPerW) : z;
    W += (size_t)dsel * zW;
    if (bias) bias += (size_t)dsel * (size_t)zB;

    size_t asrc[2];
    #pragma unroll
    for (int rd = 0; rd < 2; rd++) {
        int id = rd*256 + tid, row = id >> 3, u = id & 7;
        asrc[rd] = (size_t)(rowBase + row)*lda + ((u ^ (row & 7)) << 3);
    }
    size_t wsrc[WRW];
    #pragma unroll
    for (int rd = 0; rd < WRW; rd++) {
        int id = rd*256 + tid, row = id >> 3, u = id & 7;
        wsrc[rd] = (size_t)(colBase + row)*ldw + ((u ^ (row & 7)) << 3);
    }

    const int fr = lane & 15;
    const int swz0 = ((((lane >> 4)    ) ^ (lane & 7)) << 3);
    const int swz1 = ((((lane >> 4) | 4) ^ (lane & 7)) << 3);
    const int wm = (wid / WN) * TM, wn = (wid % WN) * 64;

    f32x4 acc[FM][4] = {};

    auto STAGE = [&](int buf, int k0) {
        #pragma unroll
        for (int rd = 0; rd < 2; rd++)
            gl_lds16(A + asrc[rd] + k0, &As[buf][(rd*256 + tid)*8]);
        #pragma unroll
        for (int rd = 0; rd < WRW; rd++)
            gl_lds16(W + wsrc[rd] + k0, &Ws[buf][(rd*256 + tid)*8]);
    };

    const int nT = kLen >> 6;
    STAGE(0, kBase);
    int cur = 0;
    for (int t = 0; t < nT; ++t) {
        if (t + 1 < nT) {
            STAGE(cur ^ 1, kBase + (t+1)*64);
            asm volatile("s_waitcnt vmcnt(6)" ::: "memory");
        } else {
            asm volatile("s_waitcnt vmcnt(0)" ::: "memory");
        }
        __builtin_amdgcn_sched_barrier(0);
        __builtin_amdgcn_s_barrier();
        __builtin_amdgcn_sched_barrier(0);
        #pragma unroll
        for (int ks = 0; ks < 2; ks++) {
            const int so = ks ? swz1 : swz0;
            bf16x8 af[FM], bfr[4];
            #pragma unroll
            for (int mi = 0; mi < FM; mi++)
                af[mi] = *(const bf16x8*)&As[cur][(wm + mi*16 + fr)*64 + so];
            #pragma unroll
            for (int ni = 0; ni < 4; ni++)
                bfr[ni] = *(const bf16x8*)&Ws[cur][(wn + ni*16 + fr)*64 + so];
            #pragma unroll
            for (int mi = 0; mi < FM; mi++)
                #pragma unroll
                for (int ni = 0; ni < 4; ni++)
                    acc[mi][ni] = __builtin_amdgcn_mfma_f32_16x16x32_bf16(af[mi], bfr[ni], acc[mi][ni], 0, 0, 0);
        }
        __builtin_amdgcn_sched_barrier(0);
        __builtin_amdgcn_s_barrier();
        __builtin_amdgcn_sched_barrier(0);
        cur ^= 1;
    }

    if (partial) {
        float* pp = partial + (size_t)z * pstride;
        #pragma unroll
        for (int mi = 0; mi < FM; mi++)
            #pragma unroll
            for (int r = 0; r < 4; r++) {
                int orow = rowBase + wm + mi*16 + ((lane>>4)<<2) + r;
                #pragma unroll
                for (int ni = 0; ni < 4; ni++)
                    pp[(size_t)orow*N + colBase + wn + ni*16 + fr] = acc[mi][ni][r];
            }
    } else {
        #pragma unroll
        for (int mi = 0; mi < FM; mi++)
            #pragma unroll
            for (int r = 0; r < 4; r++) {
                int orow = rowBase + wm + mi*16 + ((lane>>4)<<2) + r;
                #pragma unroll
                for (int ni = 0; ni < 4; ni++) {
                    int gcol = colBase + wn + ni*16 + fr;
                    float v = acc[mi][ni][r];
                    if (bias) v += bias[gcol];
                    if (gcol < actLim) {
                        if (act == 1) v = siluf_(v);
                        else if (act == 2) v = softplusf_(v);
                    }
                    if (outF) outF[(size_t)orow*ldc + gcol] = v;
                    if (outB) outB[(size_t)orow*ldc + gcol] = f2bf(v);
                }
            }
    }
}

// ---------------------------------------------------------------------------
// Generic split-K reduce -> bf16 (xdb projection only).
// ---------------------------------------------------------------------------
__global__ void __launch_bounds__(256) reduce_kernel(
    const float* __restrict__ part, int S, size_t pstride, int N,
    short* __restrict__ outB, int ldc)
{
    const int i4 = blockIdx.x*256 + threadIdx.x;
    const int row = i4 / (N >> 2);
    const int c4  = (i4 - row*(N >> 2)) << 2;
    float4 s = *(const float4*)(part + (size_t)row*N + c4);
    for (int z = 1; z < S; z++) {
        float4 t = *(const float4*)(part + (size_t)z*pstride + (size_t)row*N + c4);
        s.x += t.x; s.y += t.y; s.z += t.z; s.w += t.w;
    }
    short4 o; o.x=f2bf(s.x); o.y=f2bf(s.y); o.z=f2bf(s.z); o.w=f2bf(s.w);
    *(short4*)(outB + (size_t)row*ldc + c4) = o;
}

// ---------------------------------------------------------------------------
// REDLN: sum S partials (N=512) + bias + resid*rscale -> h; optional fused
// LayerNorm -> bf16/f32.
// ---------------------------------------------------------------------------
__global__ void __launch_bounds__(128) redln_kernel(
    const float* __restrict__ part, int S,
    const float* __restrict__ bias,
    const float* __restrict__ resid, float rscale,
    float* __restrict__ houtF, short* __restrict__ houtB,
    const float* __restrict__ lng, const float* __restrict__ lnb2,
    float* __restrict__ lnoutF, short* __restrict__ lnoutB)
{
    const int row = blockIdx.x;
    const int t = threadIdx.x;
    const size_t pstride = (size_t)MM*512;
    float4 s = ((const float4*)(part + (size_t)row*512))[t];
    for (int z = 1; z < S; z++) {
        float4 v = ((const float4*)(part + z*pstride + (size_t)row*512))[t];
        s.x += v.x; s.y += v.y; s.z += v.z; s.w += v.w;
    }
    if (bias) { float4 b = ((const float4*)bias)[t]; s.x+=b.x; s.y+=b.y; s.z+=b.z; s.w+=b.w; }
    if (resid) {
        float4 r = ((const float4*)(resid + (size_t)row*512))[t];
        s.x = r.x + rscale*s.x; s.y = r.y + rscale*s.y;
        s.z = r.z + rscale*s.z; s.w = r.w + rscale*s.w;
    }
    if (houtF) ((float4*)(houtF + (size_t)row*512))[t] = s;
    if (houtB) {
        short4 o; o.x=f2bf(s.x); o.y=f2bf(s.y); o.z=f2bf(s.z); o.w=f2bf(s.w);
        *(short4*)(houtB + (size_t)row*512 + t*4) = o;
    }
    if (!lng) return;
    float sum = s.x+s.y+s.z+s.w;
    float sq  = s.x*s.x+s.y*s.y+s.z*s.z+s.w*s.w;
    #pragma unroll
    for (int off = 32; off >= 1; off >>= 1) {
        sum += __shfl_down(sum, off);
        sq  += __shfl_down(sq, off);
    }
    __shared__ float sh[4];
    if ((t & 63) == 0) { sh[(t>>6)*2] = sum; sh[(t>>6)*2+1] = sq; }
    __syncthreads();
    float mean = (sh[0]+sh[2]) * (1.0f/512.f);
    float var  = (sh[1]+sh[3]) * (1.0f/512.f) - mean*mean;
    float rstd = rsqrtf(var + 1e-5f);
    float4 gg = ((const float4*)lng)[t];
    float4 bb = ((const float4*)lnb2)[t];
    float4 o;
    o.x = (s.x-mean)*rstd*gg.x + bb.x;
    o.y = (s.y-mean)*rstd*gg.y + bb.y;
    o.z = (s.z-mean)*rstd*gg.z + bb.z;
    o.w = (s.w-mean)*rstd*gg.w + bb.w;
    if (lnoutF) ((float4*)(lnoutF + (size_t)row*512))[t] = o;
    if (lnoutB) {
        short4 ob; ob.x=f2bf(o.x); ob.y=f2bf(o.y); ob.z=f2bf(o.z); ob.w=f2bf(o.w);
        *(short4*)(lnoutB + (size_t)row*512 + t*4) = ob;
    }
}

// ---------------------------------------------------------------------------
// LayerNorm over 512 (pre-FFN1 only).
// ---------------------------------------------------------------------------
__global__ void __launch_bounds__(128) ln_kernel(
    const float* __restrict__ x, const float* __restrict__ g,
    const float* __restrict__ bta, short* __restrict__ outB)
{
    const int row = blockIdx.x;
    const int t = threadIdx.x;
    float4 v = ((const float4*)(x + (size_t)row*DD))[t];
    float s = v.x+v.y+v.z+v.w;
    float q = v.x*v.x+v.y*v.y+v.z*v.z+v.w*v.w;
    #pragma unroll
    for (int off = 32; off >= 1; off >>= 1) {
        s += __shfl_down(s, off);
        q += __shfl_down(q, off);
    }
    __shared__ float sh[4];
    if ((t & 63) == 0) { sh[(t>>6)*2] = s; sh[(t>>6)*2+1] = q; }
    __syncthreads();
    float mean = (sh[0]+sh[2]) * (1.0f/DD);
    float var  = (sh[1]+sh[3]) * (1.0f/DD) - mean*mean;
    float rstd = rsqrtf(var + 1e-5f);
    float4 gg = ((const float4*)g)[t];
    float4 bb = ((const float4*)bta)[t];
    short4 ob;
    ob.x = f2bf((v.x-mean)*rstd*gg.x + bb.x);
    ob.y = f2bf((v.y-mean)*rstd*gg.y + bb.y);
    ob.z = f2bf((v.z-mean)*rstd*gg.z + bb.z);
    ob.w = f2bf((v.w-mean)*rstd*gg.w + bb.w);
    *(short4*)(outB + (size_t)row*DD + t*4) = ob;
}

// ---------------------------------------------------------------------------
// Both-dir dwconv (K=4) + bias + SiLU, 4 channels/thread.
// ---------------------------------------------------------------------------
__global__ void __launch_bounds__(256) conv_both_kernel(
    const short* __restrict__ xz_all, const float* __restrict__ cw,
    const float* __restrict__ cb, short* __restrict__ xc_both)
{
    const int gid = blockIdx.x*256 + threadIdx.x;    // 2*MM*256 = 2^21
    const int c4  = (gid & 255) << 2;
    const int row = (gid >> 8) & (MM-1);
    const int dir = gid >> 20;
    const int l   = row & (LL-1);
    const short* base = xz_all + (size_t)(row - l)*4096 + dir*2048 + c4;
    float acc[4];
    #pragma unroll
    for (int j = 0; j < 4; j++) acc[j] = cb[dir*1024 + c4 + j];
    float wt[4][4];
    #pragma unroll
    for (int j = 0; j < 4; j++) {
        float4 w = *(const float4*)(cw + (size_t)dir*4096 + (c4 + j)*4);
        wt[j][0]=w.x; wt[j][1]=w.y; wt[j][2]=w.z; wt[j][3]=w.w;
    }
    #pragma unroll
    for (int t = 0; t < 4; t++) {
        int lt = dir ? (l + 3 - t) : (l - 3 + t);
        if (lt >= 0 && lt < LL) {
            short4 u = *(const short4*)(base + (size_t)lt*4096);
            acc[0] += wt[0][t]*bf2f(u.x);
            acc[1] += wt[1][t]*bf2f(u.y);
            acc[2] += wt[2][t]*bf2f(u.z);
            acc[3] += wt[3][t]*bf2f(u.w);
        }
    }
    short4 o;
    o.x = f2bf(siluf_(acc[0])); o.y = f2bf(siluf_(acc[1]));
    o.z = f2bf(siluf_(acc[2])); o.w = f2bf(siluf_(acc[3]));
    *(short4*)(xc_both + (size_t)dir*MM*1024 + (size_t)row*1024 + c4) = o;
}

// ---------------------------------------------------------------------------
// 3-pass scan, both dirs batched, CHL=32/NCH=16.
// FAST PATH: when A_n == (n+1)*A_0 (true for Alog = log(1..16)), compute
// q_n = p^(n+1) from ONE exp p=exp(dt*A0) + 15 muls instead of 16 exps.
// Guarded per-thread with relative-tolerance check; exact fallback kept.
// ---------------------------------------------------------------------------
__global__ void __launch_bounds__(256) scan_a_kernel(
    const short* __restrict__ dt_bf, const short* __restrict__ xc_both,
    const short* __restrict__ xdb_bf, const float* __restrict__ Alog,
    float* __restrict__ S_dt, float* __restrict__ H)
{
    const int bid = blockIdx.x;                // 1024
    const int dg  = bid & 3;
    const int c   = (bid >> 2) & (NCH-1);
    const int b   = (bid >> 6) & 7;
    const int dir = bid >> 9;
    const int d   = (dg << 8) + threadIdx.x;

    float Aexp[16];
    #pragma unroll
    for (int n = 0; n < 16; n++) Aexp[n] = -__expf(Alog[dir*16384 + d*16 + n]);
    const float A0 = Aexp[0];
    int fast = 1;
    #pragma unroll
    for (int n = 1; n < 16; n++)
        fast &= (fabsf(Aexp[n] - (float)(n+1)*A0) <= 1e-4f*fabsf(Aexp[n]) + 1e-6f);

    float h[16];
    #pragma unroll
    for (int n = 0; n < 16; n++) h[n] = 0.f;
    float S = 0.f;

    const size_t rbase = (size_t)b*LL + (size_t)c*CHL;
    const short* dtp = dt_bf + ((size_t)dir*MM + rbase)*1024 + d;
    const short* bcp = xdb_bf + ((size_t)dir*MM + rbase)*64 + 32;
    const short* xcp = xc_both + ((size_t)dir*MM + rbase)*1024 + d;

#define SCAN_A_BODY(FASTQ) \
    for (int i = 0; i < CHL; i++) { \
        int lp = dir ? (CHL-1-i) : i; \
        float dtv = bf2f(dtp[(size_t)lp*1024]); \
        float xcv = bf2f(xcp[(size_t)lp*1024]); \
        S += dtv; \
        float co = dtv*xcv; \
        union { bf16x8 v; short e[8]; } b0, b1; \
        b0.v = *(const bf16x8*)(bcp + (size_t)lp*64); \
        b1.v = *(const bf16x8*)(bcp + (size_t)lp*64 + 8); \
        float q[16]; \
        if (FASTQ) { \
            float p = __expf(dtv*A0); float qq = p; \
            _Pragma("unroll") for (int n = 0; n < 16; n++) { q[n] = qq; qq *= p; } \
        } else { \
            _Pragma("unroll") for (int n = 0; n < 16; n++) q[n] = __expf(dtv*Aexp[n]); \
        } \
        _Pragma("unroll") for (int n = 0; n < 16; n++) { \
            float Bv = bf2f(n < 8 ? b0.e[n] : b1.e[n & 7]); \
            h[n] = fmaf(q[n], h[n], co*Bv); \
        } \
    }
    if (fast) { SCAN_A_BODY(1) } else { SCAN_A_BODY(0) }
#undef SCAN_A_BODY

    S_dt[(((size_t)dir*BB + b)*NCH + c)*1024 + d] = S;
    const size_t hb = ((((size_t)dir*BB + b)*NCH + c)*16)*1024 + d;
    #pragma unroll
    for (int n = 0; n < 16; n++) H[hb + (size_t)n*1024] = h[n];
}

__global__ void __launch_bounds__(256) scan_b_kernel(
    const float* __restrict__ S_dt, float* H, const float* __restrict__ Alog)
{
    const int g = blockIdx.x*256 + threadIdx.x;  // 2*8*16*1024
    const int d = g & 1023;
    const int n = (g >> 10) & 15;
    const int b = (g >> 14) & 7;
    const int dir = g >> 17;
    const float Aexp = -__expf(Alog[dir*16384 + d*16 + n]);
    float h = 0.f;
    for (int ci = 0; ci < NCH; ci++) {
        int c = dir ? (NCH-1-ci) : ci;
        float S = S_dt[(((size_t)dir*BB + b)*NCH + c)*1024 + d];
        size_t i = ((((size_t)dir*BB + b)*NCH + c)*16 + n)*1024 + d;
        float q = __expf(Aexp*S);
        float hn = q*h + H[i];
        H[i] = h;
        h = hn;
    }
}

__global__ void __launch_bounds__(256) scan_c_kernel(
    const short* __restrict__ dt_bf, short* xc_ys,
    const short* __restrict__ xdb_bf, const float* __restrict__ Alog,
    const float* __restrict__ H, const short* __restrict__ xz_all,
    const float* __restrict__ Dp)
{
    const int bid = blockIdx.x;                // 1024
    const int dg  = bid & 3;
    const int c   = (bid >> 2) & (NCH-1);
    const int b   = (bid >> 6) & 7;
    const int dir = bid >> 9;
    const int d   = (dg << 8) + threadIdx.x;

    float Aexp[16];
    #pragma unroll
    for (int n = 0; n < 16; n++) Aexp[n] = -__expf(Alog[dir*16384 + d*16 + n]);
    const float A0 = Aexp[0];
    int fast = 1;
    #pragma unroll
    for (int n = 1; n < 16; n++)
        fast &= (fabsf(Aexp[n] - (float)(n+1)*A0) <= 1e-4f*fabsf(Aexp[n]) + 1e-6f);
    const float Dpv = Dp[dir*1024 + d];

    float h[16];
    const size_t hb = ((((size_t)dir*BB + b)*NCH + c)*16)*1024 + d;
    #pragma unroll
    for (int n = 0; n < 16; n++) h[n] = H[hb + (size_t)n*1024];

    const size_t rbase = (size_t)b*LL + (size_t)c*CHL;
    const short* dtp = dt_bf + ((size_t)dir*MM + rbase)*1024 + d;
    const short* bcp = xdb_bf + ((size_t)dir*MM + rbase)*64 + 32;
    short*       xcp = xc_ys + ((size_t)dir*MM + rbase)*1024 + d;
    const short* zp  = xz_all + rbase*4096 + dir*2048 + 1024 + d;

#define SCAN_C_BODY(FASTQ) \
    for (int i = 0; i < CHL; i++) { \
        int lp = dir ? (CHL-1-i) : i; \
        float dtv = bf2f(dtp[(size_t)lp*1024]); \
        float xcv = bf2f(xcp[(size_t)lp*1024]); \
        float zv  = bf2f(zp[(size_t)lp*4096]); \
        float co = dtv*xcv; \
        union { bf16x8 v; short e[8]; } b0, b1, c0, c1; \
        b0.v = *(const bf16x8*)(bcp + (size_t)lp*64); \
        b1.v = *(const bf16x8*)(bcp + (size_t)lp*64 + 8); \
        c0.v = *(const bf16x8*)(bcp + (size_t)lp*64 + 16); \
        c1.v = *(const bf16x8*)(bcp + (size_t)lp*64 + 24); \
        float q[16]; \
        if (FASTQ) { \
            float p = __expf(dtv*A0); float qq = p; \
            _Pragma("unroll") for (int n = 0; n < 16; n++) { q[n] = qq; qq *= p; } \
        } else { \
            _Pragma("unroll") for (int n = 0; n < 16; n++) q[n] = __expf(dtv*Aexp[n]); \
        } \
        float y = 0.f; \
        _Pragma("unroll") for (int n = 0; n < 16; n++) { \
            float Bv = bf2f(n < 8 ? b0.e[n] : b1.e[n & 7]); \
            float Cv = bf2f(n < 8 ? c0.e[n] : c1.e[n & 7]); \
            h[n] = fmaf(q[n], h[n], co*Bv); \
            y = fmaf(Cv, h[n], y); \
        } \
        float out = (y + Dpv*xcv) * siluf_(zv); \
        xcp[(size_t)lp*1024] = f2bf(out); \
    }
    if (fast) { SCAN_C_BODY(1) } else { SCAN_C_BODY(0) }
#undef SCAN_C_BODY
}

// ---------------------------------------------------------------------------
// GLU + transpose to [b, c, l] f32.
// ---------------------------------------------------------------------------
__global__ void __launch_bounds__(256) glu_transpose_kernel(
    const float* __restrict__ pw1, float* __restrict__ out_t)
{
    __shared__ float sh[64][65];
    const int c0 = blockIdx.x << 6;
    const int l0 = blockIdx.y << 6;
    const int b  = blockIdx.z;
    const int t  = threadIdx.x;
    const int c4 = (t & 15) << 2;
    const int r  = t >> 4;
    #pragma unroll
    for (int i = 0; i < 4; i++) {
        int lrow = r + i*16;
        size_t row = (size_t)(b << 9) + l0 + lrow;
        float4 a = *(const float4*)(pw1 + row*1024 + c0 + c4);
        float4 g = *(const float4*)(pw1 + row*1024 + 512 + c0 + c4);
        sh[lrow][c4+0] = a.x * sigmoidf_(g.x);
        sh[lrow][c4+1] = a.y * sigmoidf_(g.y);
        sh[lrow][c4+2] = a.z * sigmoidf_(g.z);
        sh[lrow][c4+3] = a.w * sigmoidf_(g.w);
    }
    __syncthreads();
    #pragma unroll
    for (int i = 0; i < 4; i++) {
        int crow = r + i*16;
        float4 o;
        o.x = sh[c4+0][crow];
        o.y = sh[c4+1][crow];
        o.z = sh[c4+2][crow];
        o.w = sh[c4+3][crow];
        *(float4*)(out_t + ((size_t)(b << 9) + c0 + crow)*512 + l0 + c4) = o;
    }
}

// ---------------------------------------------------------------------------
// Channel-major fused 3x dwconv avg + BN + SiLU.
// ---------------------------------------------------------------------------
__global__ void __launch_bounds__(256) multiconv_t_kernel(
    const float* __restrict__ gin_t,
    const float* __restrict__ w15, const float* __restrict__ w31,
    const float* __restrict__ w63,
    const float* __restrict__ bn_g, const float* __restrict__ bn_b,
    const float* __restrict__ bn_m, const float* __restrict__ bn_v,
    float* __restrict__ out_t)
{
    __shared__ float sh[574];
    const int c = blockIdx.x & (DD-1);
    const int b = blockIdx.x >> 9;
    const int t = threadIdx.x;
    const float* rowp = gin_t + ((size_t)(b << 9) + c)*512;
    sh[31 + t]       = rowp[t];
    sh[31 + t + 256] = rowp[t + 256];
    if (t < 31) { sh[t] = 0.f; sh[543 + t] = 0.f; }
    __syncthreads();

    const float bnscale = rsqrtf(bn_v[c] + 1e-5f) * bn_g[c];
    const float bnm = bn_m[c], bnb = bn_b[c];
    float* outp = out_t + ((size_t)(b << 9) + c)*512;
    #pragma unroll
    for (int half = 0; half < 2; half++) {
        int l = t + half*256;
        float s63 = 0.f, s31 = 0.f, s15 = 0.f;
        #pragma unroll
        for (int k = 0; k < 63; k++) s63 += w63[c*63 + k] * sh[l + k];
        #pragma unroll
        for (int k = 0; k < 31; k++) s31 += w31[c*31 + k] * sh[l + 16 + k];
        #pragma unroll
        for (int k = 0; k < 15; k++) s15 += w15[c*15 + k] * sh[l + 24 + k];
        float m = (s15 + s31 + s63) * (1.0f/3.0f);
        m = (m - bnm) * bnscale + bnb;
        outp[l] = siluf_(m);
    }
}

// ---------------------------------------------------------------------------
// Transpose [b, c, l] -> [b, l, c], bf16 out.
// ---------------------------------------------------------------------------
__global__ void __launch_bounds__(256) transpose_bcl_kernel(
    const float* __restrict__ in_t, short* __restrict__ out)
{
    __shared__ float sh[64][65];
    const int l0 = blockIdx.x << 6;
    const int c0 = blockIdx.y << 6;
    const int b  = blockIdx.z;
    const int t  = threadIdx.x;
    const int l4 = (t & 15) << 2;
    const int r  = t >> 4;
    #pragma unroll
    for (int i = 0; i < 4; i++) {
        int crow = r + i*16;
        float4 v = *(const float4*)(in_t + ((size_t)(b << 9) + c0 + crow)*512 + l0 + l4);
        sh[crow][l4+0] = v.x; sh[crow][l4+1] = v.y;
        sh[crow][l4+2] = v.z; sh[crow][l4+3] = v.w;
    }
    __syncthreads();
    #pragma unroll
    for (int i = 0; i < 4; i++) {
        int lrow = r + i*16;
        short4 o;
        o.x = f2bf(sh[l4+0][lrow]);
        o.y = f2bf(sh[l4+1][lrow]);
        o.z = f2bf(sh[l4+2][lrow]);
        o.w = f2bf(sh[l4+3][lrow]);
        *(short4*)(out + ((size_t)(b << 9) + l0 + lrow)*512 + c0 + l4) = o;
    }
}

// ---------------------------------------------------------------------------
extern "C" void kernel_launch(void* const* d_in, const int* in_sizes, int n_in,
                              void* d_out, int out_size, void* d_ws, size_t ws_size,
                              hipStream_t stream)
{
    const float* x        = (const float*)d_in[0];
    const float* ff1_ln_g = (const float*)d_in[1];
    const float* ff1_ln_b = (const float*)d_in[2];
    const float* ff1_w1   = (const float*)d_in[3];
    const float* ff1_b1   = (const float*)d_in[4];
    const float* ff1_w2   = (const float*)d_in[5];
    const float* ff1_b2   = (const float*)d_in[6];
    const float* ff2_ln_g = (const float*)d_in[7];
    const float* ff2_ln_b = (const float*)d_in[8];
    const float* ff2_w1   = (const float*)d_in[9];
    const float* ff2_b1   = (const float*)d_in[10];
    const float* ff2_w2   = (const float*)d_in[11];
    const float* ff2_b2   = (const float*)d_in[12];
    const float* m_win    = (const float*)d_in[13];
    const float* m_convw  = (const float*)d_in[14];
    const float* m_convb  = (const float*)d_in[15];
    const float* m_wx     = (const float*)d_in[16];
    const float* m_wdt    = (const float*)d_in[17];
    const float* m_bdt    = (const float*)d_in[18];
    const float* m_Alog   = (const float*)d_in[19];
    const float* m_Dp     = (const float*)d_in[20];
    const float* m_wout   = (const float*)d_in[21];
    const float* bi_wo    = (const float*)d_in[22];
    const float* bi_bo    = (const float*)d_in[23];
    const float* cv_ln_g  = (const float*)d_in[24];
    const float* cv_ln_b  = (const float*)d_in[25];
    const float* cv_pw1_w = (const float*)d_in[26];
    const float* cv_pw1_b = (const float*)d_in[27];
    const float* cv_dw15  = (const float*)d_in[28];
    const float* cv_dw31  = (const float*)d_in[29];
    const float* cv_dw63  = (const float*)d_in[30];
    const float* cv_bn_g  = (const float*)d_in[31];
    const float* cv_bn_b  = (const float*)d_in[32];
    const float* cv_bn_m  = (const float*)d_in[33];
    const float* cv_bn_v  = (const float*)d_in[34];
    const float* cv_pw2_w = (const float*)d_in[35];
    const float* cv_pw2_b = (const float*)d_in[36];
    const float* ln_g     = (const float*)d_in[37];
    const float* ln_b     = (const float*)d_in[38];

    // ---- Workspace (quarter-MiB offsets), total 105.5 MiB ----
    char* wsb = (char*)d_ws;
    float* h        = (float*)(wsb + Q_(0));     // 8 MB
    short* h_bf     = (short*)(wsb + Q_(32));    // 4 MB
    short* lnb_bf   = (short*)(wsb + Q_(48));    // 4 MB
    short* w_ff1w1  = (short*)(wsb + Q_(64));
    short* w_ff1w2  = (short*)(wsb + Q_(72));
    short* w_ff2w1  = (short*)(wsb + Q_(80));
    short* w_ff2w2  = (short*)(wsb + Q_(88));
    short* w_win    = (short*)(wsb + Q_(96));    // [4096,512] 4 MB
    short* w_pw1    = (short*)(wsb + Q_(112));
    short* w_pw2    = (short*)(wsb + Q_(116));
    short* w_Wc     = (short*)(wsb + Q_(118));   // [2][512][1024] 2 MB
    short* w_wdtp   = (short*)(wsb + Q_(126));   // [2][1024][64] 0.25 MB
    short* w_wx     = (short*)(wsb + Q_(127));   // [2][64][1024] 0.25 MB
    float* part     = (float*)(wsb + Q_(128));   // 16 MB partials / pw1out
    float* Hbuf     = (float*)(wsb + Q_(128));   // 16 MB scan H overlay (NCH=16)
    float* S_dt     = (float*)(wsb + Q_(192));   // 1 MB (dead zone Q_192..224)
    short* xz_all   = (short*)(wsb + Q_(226));   // [MM,4096] 16 MB
    short* woutT_ov = (short*)(wsb + Q_(226));   // prep overlay 2 MB
    short* biwo_ov  = (short*)(wsb + Q_(234));   // prep overlay 1 MB
    float* glu_t    = (float*)(wsb + Q_(226));   // ConvMod overlay 8 MB
    short* xc_both  = (short*)(wsb + Q_(290));   // [2][MM,1024] 16 MB
    short* hid_bf   = (short*)(wsb + Q_(290));   // FFN overlay [MM,2048] 8 MB
    short* dt_bf    = (short*)(wsb + Q_(354));   // [2][MM,1024] 16 MB
    float* mconv_o  = (float*)(wsb + Q_(354));   // ConvMod overlay 8 MB
    short* xdb_bf   = (short*)(wsb + Q_(418));   // [2][MM,64] 1 MB -> ends 422

    if (ws_size < Q_(422)) return;

    // ---- Prep ----
    hipMemsetAsync(w_wdtp, 0, (size_t)2*1024*64*2, stream);
    WcvtArgs wa;
    wa.s[0]=ff1_w1;   wa.d[0]=w_ff1w1; wa.n[0]=1048576;
    wa.s[1]=ff1_w2;   wa.d[1]=w_ff1w2; wa.n[1]=1048576;
    wa.s[2]=ff2_w1;   wa.d[2]=w_ff2w1; wa.n[2]=1048576;
    wa.s[3]=ff2_w2;   wa.d[3]=w_ff2w2; wa.n[3]=1048576;
    wa.s[4]=m_win;    wa.d[4]=w_win;   wa.n[4]=2097152;
    wa.s[5]=bi_wo;    wa.d[5]=biwo_ov; wa.n[5]=524288;
    wa.s[6]=cv_pw1_w; wa.d[6]=w_pw1;   wa.n[6]=524288;
    wa.s[7]=cv_pw2_w; wa.d[7]=w_pw2;   wa.n[7]=262144;
    wa.s[8]=m_wdt;    wa.d[8]=w_wdtp;  wa.n[8]=65536;   // pad K 32->64
    wa.s[9]=m_wx;     wa.d[9]=w_wx;    wa.n[9]=131072;
    wcvt_kernel<<<dim3(1024,10), 256, 0, stream>>>(wa);
    woutT_kernel<<<dim3(8,16,2), 256, 0, stream>>>(m_wout, woutT_ov);

    auto G = [&](const short* A, int lda, const short* W, int ldw,
                 const float* bias, float* oF, short* oB, int ldc,
                 int M, int N, int nz, int kLen, int kOff,
                 size_t zA, size_t zW, int zB, size_t zO, int rowsPerW,
                 int act, int actLim, float* prt) {
        dim3 g(N/128, M/64, nz);
        gemm3_kernel<128><<<g, 256, 0, stream>>>(A, lda, W, ldw, bias, oF, oB, ldc,
            kLen, kOff, act, actLim, zA, zW, zB, zO, rowsPerW,
            prt, (size_t)M*N, N);
    };

    // Wc = biwo_half @ woutT -> [2][512][1024] bf16 (batched z=dir)
    G(biwo_ov, 1024, woutT_ov, 512, nullptr, nullptr, w_Wc, 1024,
      512, 1024, 2, 512, 0, 512, 524288, 0, 524288, 0, 0, 0, nullptr);

    // ---- FFN1 ----
    ln_kernel<<<MM, 128, 0, stream>>>(x, ff1_ln_g, ff1_ln_b, lnb_bf);
    G(lnb_bf, 512, w_ff1w1, 512, ff1_b1, nullptr, hid_bf, 2048,
      MM, 2048, 1, 512, 0, 0, 0, 0, 0, 0, 1, 2048, nullptr);
    G(hid_bf, 2048, w_ff1w2, 2048, nullptr, nullptr, nullptr, 0,
      MM, 512, 2, 1024, 1024, 0, 0, 0, 0, 0, 0, 0, part);
    redln_kernel<<<MM, 128, 0, stream>>>(part, 2, ff1_b2, x, 0.5f,
        h, h_bf, nullptr, nullptr, nullptr, nullptr);

    // ---- BiMamba ----
    G(h_bf, 512, w_win, 512, nullptr, nullptr, xz_all, 4096,
      MM, 4096, 1, 512, 0, 0, 0, 0, 0, 0, 0, 0, nullptr);
    conv_both_kernel<<<8192, 256, 0, stream>>>(xz_all, m_convw, m_convb, xc_both);
    // xdb = xc @ wx^T : M=8192 (both dirs), N=64, split-K 4, W by row-dir
    {
        dim3 g(1, 128, 4);
        gemm3_kernel<64><<<g, 256, 0, stream>>>(xc_both, 1024, w_wx, 1024,
            nullptr, nullptr, nullptr, 0, 256, 256, 0, 0,
            0, 65536, 0, 0, 4096, part, (size_t)8192*64, 64);
    }
    reduce_kernel<<<512, 256, 0, stream>>>(part, 4, (size_t)8192*64, 64, xdb_bf, 64);
    // dt = softplus(xdb @ wdt_pad^T + bdt) : M=8192, N=1024, K=64
    G(xdb_bf, 64, w_wdtp, 64, m_bdt, nullptr, dt_bf, 1024,
      8192, 1024, 1, 64, 0, 0, 65536, 1024, 0, 4096, 2, 1024, nullptr);
    // 3-pass scan (both dirs) + fused ycombine (ys overwrites xc_both)
    scan_a_kernel<<<1024, 256, 0, stream>>>(dt_bf, xc_both, xdb_bf, m_Alog, S_dt, Hbuf);
    scan_b_kernel<<<1024, 256, 0, stream>>>(S_dt, Hbuf, m_Alog);
    scan_c_kernel<<<1024, 256, 0, stream>>>(dt_bf, xc_both, xdb_bf, m_Alog, Hbuf,
                                            xz_all, m_Dp);
    // h += ys0@Wc0 + ys1@Wc1 + bi_bo ; fused cv-LN
    G(xc_both, 1024, w_Wc, 1024, nullptr, nullptr, nullptr, 0,
      MM, 512, 2, 1024, 0, (size_t)MM*1024, 524288, 0, 0, 0, 0, 0, part);
    redln_kernel<<<MM, 128, 0, stream>>>(part, 2, bi_bo, h, 1.0f,
        h, nullptr, cv_ln_g, cv_ln_b, nullptr, lnb_bf);

    // ---- ConvMod ----
    G(lnb_bf, 512, w_pw1, 512, cv_pw1_b, part, nullptr, 1024,
      MM, 1024, 1, 512, 0, 0, 0, 0, 0, 0, 0, 0, nullptr);
    glu_transpose_kernel<<<dim3(8,8,8), 256, 0, stream>>>(part, glu_t);
    multiconv_t_kernel<<<BB*DD, 256, 0, stream>>>(glu_t,
        cv_dw15, cv_dw31, cv_dw63, cv_bn_g, cv_bn_b, cv_bn_m, cv_bn_v, mconv_o);
    transpose_bcl_kernel<<<dim3(8,8,8), 256, 0, stream>>>(mconv_o, lnb_bf);
    G(lnb_bf, 512, w_pw2, 512, nullptr, nullptr, nullptr, 0,
      MM, 512, 2, 256, 256, 0, 0, 0, 0, 0, 0, 0, part);
    redln_kernel<<<MM, 128, 0, stream>>>(part, 2, cv_pw2_b, h, 1.0f,
        h, nullptr, ff2_ln_g, ff2_ln_b, nullptr, lnb_bf);

    // ---- FFN2 ----
    G(lnb_bf, 512, w_ff2w1, 512, ff2_b1, nullptr, hid_bf, 2048,
      MM, 2048, 1, 512, 0, 0, 0, 0, 0, 0, 1, 2048, nullptr);
    G(hid_bf, 2048, w_ff2w2, 2048, nullptr, nullptr, nullptr, 0,
      MM, 512, 2, 1024, 1024, 0, 0, 0, 0, 0, 0, 0, part);
    // final: h = h + 0.5*v, then LN -> d_out (f32)
    redln_kernel<<<MM, 128, 0, stream>>>(part, 2, ff2_b2, h, 0.5f,
        nullptr, nullptr, ln_g, ln_b, (float*)d_out, nullptr);
}

// Round 12
// 392.829 us; speedup vs baseline: 6.2643x; 1.0803x over previous
//
#include <hip/hip_runtime.h>
#include <hip/hip_bf16.h>
#include <math.h>

#define LL   512
#define DD   512
#define DII  1024
#define NST  16
#define BB   8
#define MM   4096
#define CHL  32
#define NCH  16
#define MB_  (1024*1024)
#define Q_(n) ((size_t)(n)*262144)   // quarter-MiB units

typedef __attribute__((ext_vector_type(8))) short bf16x8;
typedef __attribute__((ext_vector_type(4))) float f32x4;

// Fast HW-native activations (v_exp/v_log/v_rcp): rel err ~1e-6, far below
// the bf16 noise floor already in the pipeline (absmax budget 0.1, now 0.03).
__device__ __forceinline__ float fast_rcp(float x){ return __builtin_amdgcn_rcpf(x); }
__device__ __forceinline__ float sigmoidf_(float x){ return fast_rcp(1.0f + __expf(-x)); }
__device__ __forceinline__ float siluf_(float x){ return x * sigmoidf_(x); }
// softplus(x) = log1p(exp(x)) == max(x,0) + log(1 + exp(-|x|))  (exact identity)
__device__ __forceinline__ float softplusf_(float x){
    return fmaxf(x, 0.0f) + __logf(1.0f + __expf(-fabsf(x)));
}

__device__ __forceinline__ short f2bf(float f) {
    union { float f; unsigned u; } v; v.f = f;
    unsigned r = v.u + 0x7fffu + ((v.u >> 16) & 1u);
    return (short)(r >> 16);
}
__device__ __forceinline__ float bf2f(short s) {
    union { unsigned u; float f; } v; v.u = ((unsigned)(unsigned short)s) << 16;
    return v.f;
}
__device__ __forceinline__ bf16x8 pack_bf8(float4 v0, float4 v1) {
    union { bf16x8 v; short e[8]; } pk;
    pk.e[0]=f2bf(v0.x); pk.e[1]=f2bf(v0.y); pk.e[2]=f2bf(v0.z); pk.e[3]=f2bf(v0.w);
    pk.e[4]=f2bf(v1.x); pk.e[5]=f2bf(v1.y); pk.e[6]=f2bf(v1.z); pk.e[7]=f2bf(v1.w);
    return pk.v;
}
__device__ __forceinline__ void gl_lds16(const short* g, short* l) {
    __builtin_amdgcn_global_load_lds(
        (const __attribute__((address_space(1))) void*)g,
        (__attribute__((address_space(3))) void*)l, 16, 0, 0);
}

// ---------------------------------------------------------------------------
// Batched fp32 -> bf16 weight conversion (10 segments).
// Seg 8 (wdt) -> zero-padded [2048,64] K-layout.
// ---------------------------------------------------------------------------
struct WcvtArgs { const float* s[10]; short* d[10]; int n[10]; };
__global__ void __launch_bounds__(256) wcvt_kernel(WcvtArgs a) {
    const int seg = blockIdx.y;
    const int i = (blockIdx.x*256 + threadIdx.x) * 8;
    if (i >= a.n[seg]) return;
    const float* s = a.s[seg] + i;
    float4 v0 = *(const float4*)s;
    float4 v1 = *(const float4*)(s + 4);
    int di = i;
    if (seg == 8) di = ((i >> 5) << 6) | (i & 31);   // pad K 32 -> 64
    *(bf16x8*)(a.d[seg] + di) = pack_bf8(v0, v1);
}

// wout [2][512][1024] f32 -> [2][1024][512] bf16
__global__ void __launch_bounds__(256) woutT_kernel(
    const float* __restrict__ wout, short* __restrict__ outT)
{
    __shared__ float sh[64][65];
    const int o0 = blockIdx.x << 6;
    const int j0 = blockIdx.y << 6;
    const int d  = blockIdx.z;
    const float* in = wout + (size_t)d*512*1024;
    short* out = outT + (size_t)d*1024*512;
    const int t = threadIdx.x;
    const int c4 = (t & 15) << 2;
    const int r  = t >> 4;
    #pragma unroll
    for (int i = 0; i < 4; i++) {
        int orow = r + i*16;
        float4 v = *(const float4*)(in + (size_t)(o0 + orow)*1024 + j0 + c4);
        sh[orow][c4+0]=v.x; sh[orow][c4+1]=v.y; sh[orow][c4+2]=v.z; sh[orow][c4+3]=v.w;
    }
    __syncthreads();
    #pragma unroll
    for (int i = 0; i < 4; i++) {
        int jr = r + i*16;
        short4 o;
        o.x = f2bf(sh[c4+0][jr]); o.y = f2bf(sh[c4+1][jr]);
        o.z = f2bf(sh[c4+2][jr]); o.w = f2bf(sh[c4+3][jr]);
        *(short4*)(out + (size_t)(j0 + jr)*512 + o0 + c4) = o;
    }
}

// ---------------------------------------------------------------------------
// bf16 MFMA GEMM v8: 64xBN tile, BK=64, 4 waves, counted-vmcnt 2-deep
// pipeline, T2 source-pre-swizzle, XCD swizzle. Generalized batching:
//   A += z*zA, out += z*zO, kBase = z*kOff (split-K partials via z).
//   W/bias select: dsel = rowsPerW ? rowBase/rowsPerW : z.
// act applied only to cols < actLim.
// ---------------------------------------------------------------------------
template<int BN>
__global__ void __launch_bounds__(256) gemm3_kernel(
    const short* __restrict__ A, int lda,
    const short* __restrict__ W, int ldw,
    const float* __restrict__ bias,
    float* __restrict__ outF, short* __restrict__ outB, int ldc,
    int kLen, int kOff, int act, int actLim,
    size_t zA, size_t zW, int zB, size_t zO, int rowsPerW,
    float* __restrict__ partial, size_t pstride, int N)
{
    constexpr int WN = BN / 64;
    constexpr int WM = 4 / WN;
    constexpr int TM = 64 / WM;
    constexpr int FM = TM / 16;
    constexpr int WRW = BN / 32;

    __shared__ short As[2][64*64];
    __shared__ short Ws[2][BN*64];

    const int tid = threadIdx.x, lane = tid & 63, wid = tid >> 6;
    const int z = blockIdx.z;
    A += (size_t)z * zA;
    if (outF) outF += (size_t)z * zO;
    if (outB) outB += (size_t)z * zO;

    int nwg = gridDim.x * gridDim.y;
    int flat = blockIdx.y * gridDim.x + blockIdx.x;
    if (!(nwg & 7)) { int cpx = nwg >> 3; flat = (flat & 7)*cpx + (flat >> 3); }
    const int bx = flat % gridDim.x, by = flat / gridDim.x;

    const int rowBase = by << 6;
    const int colBase = bx * BN;
    const int kBase = z * kOff;

    const int dsel = rowsPerW ? (rowBase / rowsPerW) : z;
    W += (size_t)dsel * zW;
    if (bias) bias += (size_t)dsel * (size_t)zB;

    size_t asrc[2];
    #pragma unroll
    for (int rd = 0; rd < 2; rd++) {
        int id = rd*256 + tid, row = id >> 3, u = id & 7;
        asrc[rd] = (size_t)(rowBase + row)*lda + ((u ^ (row & 7)) << 3);
    }
    size_t wsrc[WRW];
    #pragma unroll
    for (int rd = 0; rd < WRW; rd++) {
        int id = rd*256 + tid, row = id >> 3, u = id & 7;
        wsrc[rd] = (size_t)(colBase + row)*ldw + ((u ^ (row & 7)) << 3);
    }

    const int fr = lane & 15;
    const int swz0 = ((((lane >> 4)    ) ^ (lane & 7)) << 3);
    const int swz1 = ((((lane >> 4) | 4) ^ (lane & 7)) << 3);
    const int wm = (wid / WN) * TM, wn = (wid % WN) * 64;

    f32x4 acc[FM][4] = {};

    auto STAGE = [&](int buf, int k0) {
        #pragma unroll
        for (int rd = 0; rd < 2; rd++)
            gl_lds16(A + asrc[rd] + k0, &As[buf][(rd*256 + tid)*8]);
        #pragma unroll
        for (int rd = 0; rd < WRW; rd++)
            gl_lds16(W + wsrc[rd] + k0, &Ws[buf][(rd*256 + tid)*8]);
    };

    const int nT = kLen >> 6;
    STAGE(0, kBase);
    int cur = 0;
    for (int t = 0; t < nT; ++t) {
        if (t + 1 < nT) {
            STAGE(cur ^ 1, kBase + (t+1)*64);
            asm volatile("s_waitcnt vmcnt(6)" ::: "memory");
        } else {
            asm volatile("s_waitcnt vmcnt(0)" ::: "memory");
        }
        __builtin_amdgcn_sched_barrier(0);
        __builtin_amdgcn_s_barrier();
        __builtin_amdgcn_sched_barrier(0);
        #pragma unroll
        for (int ks = 0; ks < 2; ks++) {
            const int so = ks ? swz1 : swz0;
            bf16x8 af[FM], bfr[4];
            #pragma unroll
            for (int mi = 0; mi < FM; mi++)
                af[mi] = *(const bf16x8*)&As[cur][(wm + mi*16 + fr)*64 + so];
            #pragma unroll
            for (int ni = 0; ni < 4; ni++)
                bfr[ni] = *(const bf16x8*)&Ws[cur][(wn + ni*16 + fr)*64 + so];
            #pragma unroll
            for (int mi = 0; mi < FM; mi++)
                #pragma unroll
                for (int ni = 0; ni < 4; ni++)
                    acc[mi][ni] = __builtin_amdgcn_mfma_f32_16x16x32_bf16(af[mi], bfr[ni], acc[mi][ni], 0, 0, 0);
        }
        __builtin_amdgcn_sched_barrier(0);
        __builtin_amdgcn_s_barrier();
        __builtin_amdgcn_sched_barrier(0);
        cur ^= 1;
    }

    if (partial) {
        float* pp = partial + (size_t)z * pstride;
        #pragma unroll
        for (int mi = 0; mi < FM; mi++)
            #pragma unroll
            for (int r = 0; r < 4; r++) {
                int orow = rowBase + wm + mi*16 + ((lane>>4)<<2) + r;
                #pragma unroll
                for (int ni = 0; ni < 4; ni++)
                    pp[(size_t)orow*N + colBase + wn + ni*16 + fr] = acc[mi][ni][r];
            }
    } else {
        #pragma unroll
        for (int mi = 0; mi < FM; mi++)
            #pragma unroll
            for (int r = 0; r < 4; r++) {
                int orow = rowBase + wm + mi*16 + ((lane>>4)<<2) + r;
                #pragma unroll
                for (int ni = 0; ni < 4; ni++) {
                    int gcol = colBase + wn + ni*16 + fr;
                    float v = acc[mi][ni][r];
                    if (bias) v += bias[gcol];
                    if (gcol < actLim) {
                        if (act == 1) v = siluf_(v);
                        else if (act == 2) v = softplusf_(v);
                    }
                    if (outF) outF[(size_t)orow*ldc + gcol] = v;
                    if (outB) outB[(size_t)orow*ldc + gcol] = f2bf(v);
                }
            }
    }
}

// ---------------------------------------------------------------------------
// Generic split-K reduce -> bf16 (xdb projection only).
// ---------------------------------------------------------------------------
__global__ void __launch_bounds__(256) reduce_kernel(
    const float* __restrict__ part, int S, size_t pstride, int N,
    short* __restrict__ outB, int ldc)
{
    const int i4 = blockIdx.x*256 + threadIdx.x;
    const int row = i4 / (N >> 2);
    const int c4  = (i4 - row*(N >> 2)) << 2;
    float4 s = *(const float4*)(part + (size_t)row*N + c4);
    for (int z = 1; z < S; z++) {
        float4 t = *(const float4*)(part + (size_t)z*pstride + (size_t)row*N + c4);
        s.x += t.x; s.y += t.y; s.z += t.z; s.w += t.w;
    }
    short4 o; o.x=f2bf(s.x); o.y=f2bf(s.y); o.z=f2bf(s.z); o.w=f2bf(s.w);
    *(short4*)(outB + (size_t)row*ldc + c4) = o;
}

// ---------------------------------------------------------------------------
// REDLN: sum S partials (N=512) + bias + resid*rscale -> h; optional fused
// LayerNorm -> bf16/f32.
// ---------------------------------------------------------------------------
__global__ void __launch_bounds__(128) redln_kernel(
    const float* __restrict__ part, int S,
    const float* __restrict__ bias,
    const float* __restrict__ resid, float rscale,
    float* __restrict__ houtF, short* __restrict__ houtB,
    const float* __restrict__ lng, const float* __restrict__ lnb2,
    float* __restrict__ lnoutF, short* __restrict__ lnoutB)
{
    const int row = blockIdx.x;
    const int t = threadIdx.x;
    const size_t pstride = (size_t)MM*512;
    float4 s = ((const float4*)(part + (size_t)row*512))[t];
    for (int z = 1; z < S; z++) {
        float4 v = ((const float4*)(part + z*pstride + (size_t)row*512))[t];
        s.x += v.x; s.y += v.y; s.z += v.z; s.w += v.w;
    }
    if (bias) { float4 b = ((const float4*)bias)[t]; s.x+=b.x; s.y+=b.y; s.z+=b.z; s.w+=b.w; }
    if (resid) {
        float4 r = ((const float4*)(resid + (size_t)row*512))[t];
        s.x = r.x + rscale*s.x; s.y = r.y + rscale*s.y;
        s.z = r.z + rscale*s.z; s.w = r.w + rscale*s.w;
    }
    if (houtF) ((float4*)(houtF + (size_t)row*512))[t] = s;
    if (houtB) {
        short4 o; o.x=f2bf(s.x); o.y=f2bf(s.y); o.z=f2bf(s.z); o.w=f2bf(s.w);
        *(short4*)(houtB + (size_t)row*512 + t*4) = o;
    }
    if (!lng) return;
    float sum = s.x+s.y+s.z+s.w;
    float sq  = s.x*s.x+s.y*s.y+s.z*s.z+s.w*s.w;
    #pragma unroll
    for (int off = 32; off >= 1; off >>= 1) {
        sum += __shfl_down(sum, off);
        sq  += __shfl_down(sq, off);
    }
    __shared__ float sh[4];
    if ((t & 63) == 0) { sh[(t>>6)*2] = sum; sh[(t>>6)*2+1] = sq; }
    __syncthreads();
    float mean = (sh[0]+sh[2]) * (1.0f/512.f);
    float var  = (sh[1]+sh[3]) * (1.0f/512.f) - mean*mean;
    float rstd = rsqrtf(var + 1e-5f);
    float4 gg = ((const float4*)lng)[t];
    float4 bb = ((const float4*)lnb2)[t];
    float4 o;
    o.x = (s.x-mean)*rstd*gg.x + bb.x;
    o.y = (s.y-mean)*rstd*gg.y + bb.y;
    o.z = (s.z-mean)*rstd*gg.z + bb.z;
    o.w = (s.w-mean)*rstd*gg.w + bb.w;
    if (lnoutF) ((float4*)(lnoutF + (size_t)row*512))[t] = o;
    if (lnoutB) {
        short4 ob; ob.x=f2bf(o.x); ob.y=f2bf(o.y); ob.z=f2bf(o.z); ob.w=f2bf(o.w);
        *(short4*)(lnoutB + (size_t)row*512 + t*4) = ob;
    }
}

// ---------------------------------------------------------------------------
// LayerNorm over 512 (pre-FFN1 only).
// ---------------------------------------------------------------------------
__global__ void __launch_bounds__(128) ln_kernel(
    const float* __restrict__ x, const float* __restrict__ g,
    const float* __restrict__ bta, short* __restrict__ outB)
{
    const int row = blockIdx.x;
    const int t = threadIdx.x;
    float4 v = ((const float4*)(x + (size_t)row*DD))[t];
    float s = v.x+v.y+v.z+v.w;
    float q = v.x*v.x+v.y*v.y+v.z*v.z+v.w*v.w;
    #pragma unroll
    for (int off = 32; off >= 1; off >>= 1) {
        s += __shfl_down(s, off);
        q += __shfl_down(q, off);
    }
    __shared__ float sh[4];
    if ((t & 63) == 0) { sh[(t>>6)*2] = s; sh[(t>>6)*2+1] = q; }
    __syncthreads();
    float mean = (sh[0]+sh[2]) * (1.0f/DD);
    float var  = (sh[1]+sh[3]) * (1.0f/DD) - mean*mean;
    float rstd = rsqrtf(var + 1e-5f);
    float4 gg = ((const float4*)g)[t];
    float4 bb = ((const float4*)bta)[t];
    short4 ob;
    ob.x = f2bf((v.x-mean)*rstd*gg.x + bb.x);
    ob.y = f2bf((v.y-mean)*rstd*gg.y + bb.y);
    ob.z = f2bf((v.z-mean)*rstd*gg.z + bb.z);
    ob.w = f2bf((v.w-mean)*rstd*gg.w + bb.w);
    *(short4*)(outB + (size_t)row*DD + t*4) = ob;
}

// ---------------------------------------------------------------------------
// Both-dir dwconv (K=4) + bias + SiLU, 4 channels/thread.
// ---------------------------------------------------------------------------
__global__ void __launch_bounds__(256) conv_both_kernel(
    const short* __restrict__ xz_all, const float* __restrict__ cw,
    const float* __restrict__ cb, short* __restrict__ xc_both)
{
    const int gid = blockIdx.x*256 + threadIdx.x;    // 2*MM*256 = 2^21
    const int c4  = (gid & 255) << 2;
    const int row = (gid >> 8) & (MM-1);
    const int dir = gid >> 20;
    const int l   = row & (LL-1);
    const short* base = xz_all + (size_t)(row - l)*4096 + dir*2048 + c4;
    float acc[4];
    #pragma unroll
    for (int j = 0; j < 4; j++) acc[j] = cb[dir*1024 + c4 + j];
    float wt[4][4];
    #pragma unroll
    for (int j = 0; j < 4; j++) {
        float4 w = *(const float4*)(cw + (size_t)dir*4096 + (c4 + j)*4);
        wt[j][0]=w.x; wt[j][1]=w.y; wt[j][2]=w.z; wt[j][3]=w.w;
    }
    #pragma unroll
    for (int t = 0; t < 4; t++) {
        int lt = dir ? (l + 3 - t) : (l - 3 + t);
        if (lt >= 0 && lt < LL) {
            short4 u = *(const short4*)(base + (size_t)lt*4096);
            acc[0] += wt[0][t]*bf2f(u.x);
            acc[1] += wt[1][t]*bf2f(u.y);
            acc[2] += wt[2][t]*bf2f(u.z);
            acc[3] += wt[3][t]*bf2f(u.w);
        }
    }
    short4 o;
    o.x = f2bf(siluf_(acc[0])); o.y = f2bf(siluf_(acc[1]));
    o.z = f2bf(siluf_(acc[2])); o.w = f2bf(siluf_(acc[3]));
    *(short4*)(xc_both + (size_t)dir*MM*1024 + (size_t)row*1024 + c4) = o;
}

// ---------------------------------------------------------------------------
// 3-pass scan, both dirs batched, CHL=32/NCH=16.
// FAST PATH: when A_n == (n+1)*A_0 (true for Alog = log(1..16)), compute
// q_n = p^(n+1) from ONE exp p=exp(dt*A0) + 15 muls instead of 16 exps.
// Guarded per-thread; exact fallback kept.
// ---------------------------------------------------------------------------
__global__ void __launch_bounds__(256) scan_a_kernel(
    const short* __restrict__ dt_bf, const short* __restrict__ xc_both,
    const short* __restrict__ xdb_bf, const float* __restrict__ Alog,
    float* __restrict__ S_dt, float* __restrict__ H)
{
    const int bid = blockIdx.x;                // 1024
    const int dg  = bid & 3;
    const int c   = (bid >> 2) & (NCH-1);
    const int b   = (bid >> 6) & 7;
    const int dir = bid >> 9;
    const int d   = (dg << 8) + threadIdx.x;

    float Aexp[16];
    #pragma unroll
    for (int n = 0; n < 16; n++) Aexp[n] = -__expf(Alog[dir*16384 + d*16 + n]);
    const float A0 = Aexp[0];
    int fast = 1;
    #pragma unroll
    for (int n = 1; n < 16; n++)
        fast &= (fabsf(Aexp[n] - (float)(n+1)*A0) <= 1e-4f*fabsf(Aexp[n]) + 1e-6f);

    float h[16];
    #pragma unroll
    for (int n = 0; n < 16; n++) h[n] = 0.f;
    float S = 0.f;

    const size_t rbase = (size_t)b*LL + (size_t)c*CHL;
    const short* dtp = dt_bf + ((size_t)dir*MM + rbase)*1024 + d;
    const short* bcp = xdb_bf + ((size_t)dir*MM + rbase)*64 + 32;
    const short* xcp = xc_both + ((size_t)dir*MM + rbase)*1024 + d;

#define SCAN_A_BODY(FASTQ) \
    for (int i = 0; i < CHL; i++) { \
        int lp = dir ? (CHL-1-i) : i; \
        float dtv = bf2f(dtp[(size_t)lp*1024]); \
        float xcv = bf2f(xcp[(size_t)lp*1024]); \
        S += dtv; \
        float co = dtv*xcv; \
        union { bf16x8 v; short e[8]; } b0, b1; \
        b0.v = *(const bf16x8*)(bcp + (size_t)lp*64); \
        b1.v = *(const bf16x8*)(bcp + (size_t)lp*64 + 8); \
        float q[16]; \
        if (FASTQ) { \
            float p = __expf(dtv*A0); float qq = p; \
            _Pragma("unroll") for (int n = 0; n < 16; n++) { q[n] = qq; qq *= p; } \
        } else { \
            _Pragma("unroll") for (int n = 0; n < 16; n++) q[n] = __expf(dtv*Aexp[n]); \
        } \
        _Pragma("unroll") for (int n = 0; n < 16; n++) { \
            float Bv = bf2f(n < 8 ? b0.e[n] : b1.e[n & 7]); \
            h[n] = fmaf(q[n], h[n], co*Bv); \
        } \
    }
    if (fast) { SCAN_A_BODY(1) } else { SCAN_A_BODY(0) }
#undef SCAN_A_BODY

    S_dt[(((size_t)dir*BB + b)*NCH + c)*1024 + d] = S;
    const size_t hb = ((((size_t)dir*BB + b)*NCH + c)*16)*1024 + d;
    #pragma unroll
    for (int n = 0; n < 16; n++) H[hb + (size_t)n*1024] = h[n];
}

__global__ void __launch_bounds__(256) scan_b_kernel(
    const float* __restrict__ S_dt, float* H, const float* __restrict__ Alog)
{
    const int g = blockIdx.x*256 + threadIdx.x;  // 2*8*16*1024
    const int d = g & 1023;
    const int n = (g >> 10) & 15;
    const int b = (g >> 14) & 7;
    const int dir = g >> 17;
    const float Aexp = -__expf(Alog[dir*16384 + d*16 + n]);
    float h = 0.f;
    for (int ci = 0; ci < NCH; ci++) {
        int c = dir ? (NCH-1-ci) : ci;
        float S = S_dt[(((size_t)dir*BB + b)*NCH + c)*1024 + d];
        size_t i = ((((size_t)dir*BB + b)*NCH + c)*16 + n)*1024 + d;
        float q = __expf(Aexp*S);
        float hn = q*h + H[i];
        H[i] = h;
        h = hn;
    }
}

__global__ void __launch_bounds__(256) scan_c_kernel(
    const short* __restrict__ dt_bf, short* xc_ys,
    const short* __restrict__ xdb_bf, const float* __restrict__ Alog,
    const float* __restrict__ H, const short* __restrict__ xz_all,
    const float* __restrict__ Dp)
{
    const int bid = blockIdx.x;                // 1024
    const int dg  = bid & 3;
    const int c   = (bid >> 2) & (NCH-1);
    const int b   = (bid >> 6) & 7;
    const int dir = bid >> 9;
    const int d   = (dg << 8) + threadIdx.x;

    float Aexp[16];
    #pragma unroll
    for (int n = 0; n < 16; n++) Aexp[n] = -__expf(Alog[dir*16384 + d*16 + n]);
    const float A0 = Aexp[0];
    int fast = 1;
    #pragma unroll
    for (int n = 1; n < 16; n++)
        fast &= (fabsf(Aexp[n] - (float)(n+1)*A0) <= 1e-4f*fabsf(Aexp[n]) + 1e-6f);
    const float Dpv = Dp[dir*1024 + d];

    float h[16];
    const size_t hb = ((((size_t)dir*BB + b)*NCH + c)*16)*1024 + d;
    #pragma unroll
    for (int n = 0; n < 16; n++) h[n] = H[hb + (size_t)n*1024];

    const size_t rbase = (size_t)b*LL + (size_t)c*CHL;
    const short* dtp = dt_bf + ((size_t)dir*MM + rbase)*1024 + d;
    const short* bcp = xdb_bf + ((size_t)dir*MM + rbase)*64 + 32;
    short*       xcp = xc_ys + ((size_t)dir*MM + rbase)*1024 + d;
    const short* zp  = xz_all + rbase*4096 + dir*2048 + 1024 + d;

#define SCAN_C_BODY(FASTQ) \
    for (int i = 0; i < CHL; i++) { \
        int lp = dir ? (CHL-1-i) : i; \
        float dtv = bf2f(dtp[(size_t)lp*1024]); \
        float xcv = bf2f(xcp[(size_t)lp*1024]); \
        float zv  = bf2f(zp[(size_t)lp*4096]); \
        float co = dtv*xcv; \
        union { bf16x8 v; short e[8]; } b0, b1, c0, c1; \
        b0.v = *(const bf16x8*)(bcp + (size_t)lp*64); \
        b1.v = *(const bf16x8*)(bcp + (size_t)lp*64 + 8); \
        c0.v = *(const bf16x8*)(bcp + (size_t)lp*64 + 16); \
        c1.v = *(const bf16x8*)(bcp + (size_t)lp*64 + 24); \
        float q[16]; \
        if (FASTQ) { \
            float p = __expf(dtv*A0); float qq = p; \
            _Pragma("unroll") for (int n = 0; n < 16; n++) { q[n] = qq; qq *= p; } \
        } else { \
            _Pragma("unroll") for (int n = 0; n < 16; n++) q[n] = __expf(dtv*Aexp[n]); \
        } \
        float y = 0.f; \
        _Pragma("unroll") for (int n = 0; n < 16; n++) { \
            float Bv = bf2f(n < 8 ? b0.e[n] : b1.e[n & 7]); \
            float Cv = bf2f(n < 8 ? c0.e[n] : c1.e[n & 7]); \
            h[n] = fmaf(q[n], h[n], co*Bv); \
            y = fmaf(Cv, h[n], y); \
        } \
        float out = (y + Dpv*xcv) * siluf_(zv); \
        xcp[(size_t)lp*1024] = f2bf(out); \
    }
    if (fast) { SCAN_C_BODY(1) } else { SCAN_C_BODY(0) }
#undef SCAN_C_BODY
}

// ---------------------------------------------------------------------------
// GLU + transpose to [b, c, l] f32.
// ---------------------------------------------------------------------------
__global__ void __launch_bounds__(256) glu_transpose_kernel(
    const float* __restrict__ pw1, float* __restrict__ out_t)
{
    __shared__ float sh[64][65];
    const int c0 = blockIdx.x << 6;
    const int l0 = blockIdx.y << 6;
    const int b  = blockIdx.z;
    const int t  = threadIdx.x;
    const int c4 = (t & 15) << 2;
    const int r  = t >> 4;
    #pragma unroll
    for (int i = 0; i < 4; i++) {
        int lrow = r + i*16;
        size_t row = (size_t)(b << 9) + l0 + lrow;
        float4 a = *(const float4*)(pw1 + row*1024 + c0 + c4);
        float4 g = *(const float4*)(pw1 + row*1024 + 512 + c0 + c4);
        sh[lrow][c4+0] = a.x * sigmoidf_(g.x);
        sh[lrow][c4+1] = a.y * sigmoidf_(g.y);
        sh[lrow][c4+2] = a.z * sigmoidf_(g.z);
        sh[lrow][c4+3] = a.w * sigmoidf_(g.w);
    }
    __syncthreads();
    #pragma unroll
    for (int i = 0; i < 4; i++) {
        int crow = r + i*16;
        float4 o;
        o.x = sh[c4+0][crow];
        o.y = sh[c4+1][crow];
        o.z = sh[c4+2][crow];
        o.w = sh[c4+3][crow];
        *(float4*)(out_t + ((size_t)(b << 9) + c0 + crow)*512 + l0 + c4) = o;
    }
}

// ---------------------------------------------------------------------------
// Channel-major fused 3x dwconv avg + BN + SiLU.
// ---------------------------------------------------------------------------
__global__ void __launch_bounds__(256) multiconv_t_kernel(
    const float* __restrict__ gin_t,
    const float* __restrict__ w15, const float* __restrict__ w31,
    const float* __restrict__ w63,
    const float* __restrict__ bn_g, const float* __restrict__ bn_b,
    const float* __restrict__ bn_m, const float* __restrict__ bn_v,
    float* __restrict__ out_t)
{
    __shared__ float sh[574];
    const int c = blockIdx.x & (DD-1);
    const int b = blockIdx.x >> 9;
    const int t = threadIdx.x;
    const float* rowp = gin_t + ((size_t)(b << 9) + c)*512;
    sh[31 + t]       = rowp[t];
    sh[31 + t + 256] = rowp[t + 256];
    if (t < 31) { sh[t] = 0.f; sh[543 + t] = 0.f; }
    __syncthreads();

    const float bnscale = rsqrtf(bn_v[c] + 1e-5f) * bn_g[c];
    const float bnm = bn_m[c], bnb = bn_b[c];
    float* outp = out_t + ((size_t)(b << 9) + c)*512;
    #pragma unroll
    for (int half = 0; half < 2; half++) {
        int l = t + half*256;
        float s63 = 0.f, s31 = 0.f, s15 = 0.f;
        #pragma unroll
        for (int k = 0; k < 63; k++) s63 += w63[c*63 + k] * sh[l + k];
        #pragma unroll
        for (int k = 0; k < 31; k++) s31 += w31[c*31 + k] * sh[l + 16 + k];
        #pragma unroll
        for (int k = 0; k < 15; k++) s15 += w15[c*15 + k] * sh[l + 24 + k];
        float m = (s15 + s31 + s63) * (1.0f/3.0f);
        m = (m - bnm) * bnscale + bnb;
        outp[l] = siluf_(m);
    }
}

// ---------------------------------------------------------------------------
// Transpose [b, c, l] -> [b, l, c], bf16 out.
// ---------------------------------------------------------------------------
__global__ void __launch_bounds__(256) transpose_bcl_kernel(
    const float* __restrict__ in_t, short* __restrict__ out)
{
    __shared__ float sh[64][65];
    const int l0 = blockIdx.x << 6;
    const int c0 = blockIdx.y << 6;
    const int b  = blockIdx.z;
    const int t  = threadIdx.x;
    const int l4 = (t & 15) << 2;
    const int r  = t >> 4;
    #pragma unroll
    for (int i = 0; i < 4; i++) {
        int crow = r + i*16;
        float4 v = *(const float4*)(in_t + ((size_t)(b << 9) + c0 + crow)*512 + l0 + l4);
        sh[crow][l4+0] = v.x; sh[crow][l4+1] = v.y;
        sh[crow][l4+2] = v.z; sh[crow][l4+3] = v.w;
    }
    __syncthreads();
    #pragma unroll
    for (int i = 0; i < 4; i++) {
        int lrow = r + i*16;
        short4 o;
        o.x = f2bf(sh[l4+0][lrow]);
        o.y = f2bf(sh[l4+1][lrow]);
        o.z = f2bf(sh[l4+2][lrow]);
        o.w = f2bf(sh[l4+3][lrow]);
        *(short4*)(out + ((size_t)(b << 9) + l0 + lrow)*512 + c0 + l4) = o;
    }
}

// ---------------------------------------------------------------------------
extern "C" void kernel_launch(void* const* d_in, const int* in_sizes, int n_in,
                              void* d_out, int out_size, void* d_ws, size_t ws_size,
                              hipStream_t stream)
{
    const float* x        = (const float*)d_in[0];
    const float* ff1_ln_g = (const float*)d_in[1];
    const float* ff1_ln_b = (const float*)d_in[2];
    const float* ff1_w1   = (const float*)d_in[3];
    const float* ff1_b1   = (const float*)d_in[4];
    const float* ff1_w2   = (const float*)d_in[5];
    const float* ff1_b2   = (const float*)d_in[6];
    const float* ff2_ln_g = (const float*)d_in[7];
    const float* ff2_ln_b = (const float*)d_in[8];
    const float* ff2_w1   = (const float*)d_in[9];
    const float* ff2_b1   = (const float*)d_in[10];
    const float* ff2_w2   = (const float*)d_in[11];
    const float* ff2_b2   = (const float*)d_in[12];
    const float* m_win    = (const float*)d_in[13];
    const float* m_convw  = (const float*)d_in[14];
    const float* m_convb  = (const float*)d_in[15];
    const float* m_wx     = (const float*)d_in[16];
    const float* m_wdt    = (const float*)d_in[17];
    const float* m_bdt    = (const float*)d_in[18];
    const float* m_Alog   = (const float*)d_in[19];
    const float* m_Dp     = (const float*)d_in[20];
    const float* m_wout   = (const float*)d_in[21];
    const float* bi_wo    = (const float*)d_in[22];
    const float* bi_bo    = (const float*)d_in[23];
    const float* cv_ln_g  = (const float*)d_in[24];
    const float* cv_ln_b  = (const float*)d_in[25];
    const float* cv_pw1_w = (const float*)d_in[26];
    const float* cv_pw1_b = (const float*)d_in[27];
    const float* cv_dw15  = (const float*)d_in[28];
    const float* cv_dw31  = (const float*)d_in[29];
    const float* cv_dw63  = (const float*)d_in[30];
    const float* cv_bn_g  = (const float*)d_in[31];
    const float* cv_bn_b  = (const float*)d_in[32];
    const float* cv_bn_m  = (const float*)d_in[33];
    const float* cv_bn_v  = (const float*)d_in[34];
    const float* cv_pw2_w = (const float*)d_in[35];
    const float* cv_pw2_b = (const float*)d_in[36];
    const float* ln_g     = (const float*)d_in[37];
    const float* ln_b     = (const float*)d_in[38];

    // ---- Workspace (quarter-MiB offsets), total 105.5 MiB ----
    char* wsb = (char*)d_ws;
    float* h        = (float*)(wsb + Q_(0));     // 8 MB
    short* h_bf     = (short*)(wsb + Q_(32));    // 4 MB
    short* lnb_bf   = (short*)(wsb + Q_(48));    // 4 MB
    short* w_ff1w1  = (short*)(wsb + Q_(64));
    short* w_ff1w2  = (short*)(wsb + Q_(72));
    short* w_ff2w1  = (short*)(wsb + Q_(80));
    short* w_ff2w2  = (short*)(wsb + Q_(88));
    short* w_win    = (short*)(wsb + Q_(96));    // [4096,512] 4 MB
    short* w_pw1    = (short*)(wsb + Q_(112));
    short* w_pw2    = (short*)(wsb + Q_(116));
    short* w_Wc     = (short*)(wsb + Q_(118));   // [2][512][1024] 2 MB
    short* w_wdtp   = (short*)(wsb + Q_(126));   // [2][1024][64] 0.25 MB
    short* w_wx     = (short*)(wsb + Q_(127));   // [2][64][1024] 0.25 MB
    float* part     = (float*)(wsb + Q_(128));   // 16 MB partials / pw1out
    float* Hbuf     = (float*)(wsb + Q_(128));   // 16 MB scan H overlay (NCH=16)
    float* S_dt     = (float*)(wsb + Q_(192));   // 1 MB
    short* xz_all   = (short*)(wsb + Q_(226));   // [MM,4096] 16 MB
    short* woutT_ov = (short*)(wsb + Q_(226));   // prep overlay 2 MB
    short* biwo_ov  = (short*)(wsb + Q_(234));   // prep overlay 1 MB
    float* glu_t    = (float*)(wsb + Q_(226));   // ConvMod overlay 8 MB
    short* xc_both  = (short*)(wsb + Q_(290));   // [2][MM,1024] 16 MB
    short* hid_bf   = (short*)(wsb + Q_(290));   // FFN overlay [MM,2048] 8 MB
    short* dt_bf    = (short*)(wsb + Q_(354));   // [2][MM,1024] 16 MB
    float* mconv_o  = (float*)(wsb + Q_(354));   // ConvMod overlay 8 MB
    short* xdb_bf   = (short*)(wsb + Q_(418));   // [2][MM,64] 1 MB -> ends 422

    if (ws_size < Q_(422)) return;

    // ---- Prep ----
    hipMemsetAsync(w_wdtp, 0, (size_t)2*1024*64*2, stream);
    WcvtArgs wa;
    wa.s[0]=ff1_w1;   wa.d[0]=w_ff1w1; wa.n[0]=1048576;
    wa.s[1]=ff1_w2;   wa.d[1]=w_ff1w2; wa.n[1]=1048576;
    wa.s[2]=ff2_w1;   wa.d[2]=w_ff2w1; wa.n[2]=1048576;
    wa.s[3]=ff2_w2;   wa.d[3]=w_ff2w2; wa.n[3]=1048576;
    wa.s[4]=m_win;    wa.d[4]=w_win;   wa.n[4]=2097152;
    wa.s[5]=bi_wo;    wa.d[5]=biwo_ov; wa.n[5]=524288;
    wa.s[6]=cv_pw1_w; wa.d[6]=w_pw1;   wa.n[6]=524288;
    wa.s[7]=cv_pw2_w; wa.d[7]=w_pw2;   wa.n[7]=262144;
    wa.s[8]=m_wdt;    wa.d[8]=w_wdtp;  wa.n[8]=65536;   // pad K 32->64
    wa.s[9]=m_wx;     wa.d[9]=w_wx;    wa.n[9]=131072;
    wcvt_kernel<<<dim3(1024,10), 256, 0, stream>>>(wa);
    woutT_kernel<<<dim3(8,16,2), 256, 0, stream>>>(m_wout, woutT_ov);

    auto G = [&](const short* A, int lda, const short* W, int ldw,
                 const float* bias, float* oF, short* oB, int ldc,
                 int M, int N, int nz, int kLen, int kOff,
                 size_t zA, size_t zW, int zB, size_t zO, int rowsPerW,
                 int act, int actLim, float* prt) {
        dim3 g(N/128, M/64, nz);
        gemm3_kernel<128><<<g, 256, 0, stream>>>(A, lda, W, ldw, bias, oF, oB, ldc,
            kLen, kOff, act, actLim, zA, zW, zB, zO, rowsPerW,
            prt, (size_t)M*N, N);
    };

    // Wc = biwo_half @ woutT -> [2][512][1024] bf16 (batched z=dir)
    G(biwo_ov, 1024, woutT_ov, 512, nullptr, nullptr, w_Wc, 1024,
      512, 1024, 2, 512, 0, 512, 524288, 0, 524288, 0, 0, 0, nullptr);

    // ---- FFN1 ----
    ln_kernel<<<MM, 128, 0, stream>>>(x, ff1_ln_g, ff1_ln_b, lnb_bf);
    G(lnb_bf, 512, w_ff1w1, 512, ff1_b1, nullptr, hid_bf, 2048,
      MM, 2048, 1, 512, 0, 0, 0, 0, 0, 0, 1, 2048, nullptr);
    G(hid_bf, 2048, w_ff1w2, 2048, nullptr, nullptr, nullptr, 0,
      MM, 512, 2, 1024, 1024, 0, 0, 0, 0, 0, 0, 0, part);
    redln_kernel<<<MM, 128, 0, stream>>>(part, 2, ff1_b2, x, 0.5f,
        h, h_bf, nullptr, nullptr, nullptr, nullptr);

    // ---- BiMamba ----
    G(h_bf, 512, w_win, 512, nullptr, nullptr, xz_all, 4096,
      MM, 4096, 1, 512, 0, 0, 0, 0, 0, 0, 0, 0, nullptr);
    conv_both_kernel<<<8192, 256, 0, stream>>>(xz_all, m_convw, m_convb, xc_both);
    // xdb = xc @ wx^T : M=8192 (both dirs), N=64, split-K 4, W by row-dir
    {
        dim3 g(1, 128, 4);
        gemm3_kernel<64><<<g, 256, 0, stream>>>(xc_both, 1024, w_wx, 1024,
            nullptr, nullptr, nullptr, 0, 256, 256, 0, 0,
            0, 65536, 0, 0, 4096, part, (size_t)8192*64, 64);
    }
    reduce_kernel<<<512, 256, 0, stream>>>(part, 4, (size_t)8192*64, 64, xdb_bf, 64);
    // dt = softplus(xdb @ wdt_pad^T + bdt) : M=8192, N=1024, K=64
    G(xdb_bf, 64, w_wdtp, 64, m_bdt, nullptr, dt_bf, 1024,
      8192, 1024, 1, 64, 0, 0, 65536, 1024, 0, 4096, 2, 1024, nullptr);
    // 3-pass scan (both dirs) + fused ycombine (ys overwrites xc_both)
    scan_a_kernel<<<1024, 256, 0, stream>>>(dt_bf, xc_both, xdb_bf, m_Alog, S_dt, Hbuf);
    scan_b_kernel<<<1024, 256, 0, stream>>>(S_dt, Hbuf, m_Alog);
    scan_c_kernel<<<1024, 256, 0, stream>>>(dt_bf, xc_both, xdb_bf, m_Alog, Hbuf,
                                            xz_all, m_Dp);
    // h += ys0@Wc0 + ys1@Wc1 + bi_bo ; fused cv-LN
    G(xc_both, 1024, w_Wc, 1024, nullptr, nullptr, nullptr, 0,
      MM, 512, 2, 1024, 0, (size_t)MM*1024, 524288, 0, 0, 0, 0, 0, part);
    redln_kernel<<<MM, 128, 0, stream>>>(part, 2, bi_bo, h, 1.0f,
        h, nullptr, cv_ln_g, cv_ln_b, nullptr, lnb_bf);

    // ---- ConvMod ----
    G(lnb_bf, 512, w_pw1, 512, cv_pw1_b, part, nullptr, 1024,
      MM, 1024, 1, 512, 0, 0, 0, 0, 0, 0, 0, 0, nullptr);
    glu_transpose_kernel<<<dim3(8,8,8), 256, 0, stream>>>(part, glu_t);
    multiconv_t_kernel<<<BB*DD, 256, 0, stream>>>(glu_t,
        cv_dw15, cv_dw31, cv_dw63, cv_bn_g, cv_bn_b, cv_bn_m, cv_bn_v, mconv_o);
    transpose_bcl_kernel<<<dim3(8,8,8), 256, 0, stream>>>(mconv_o, lnb_bf);
    G(lnb_bf, 512, w_pw2, 512, nullptr, nullptr, nullptr, 0,
      MM, 512, 2, 256, 256, 0, 0, 0, 0, 0, 0, 0, part);
    redln_kernel<<<MM, 128, 0, stream>>>(part, 2, cv_pw2_b, h, 1.0f,
        h, nullptr, ff2_ln_g, ff2_ln_b, nullptr, lnb_bf);

    // ---- FFN2 ----
    G(lnb_bf, 512, w_ff2w1, 512, ff2_b1, nullptr, hid_bf, 2048,
      MM, 2048, 1, 512, 0, 0, 0, 0, 0, 0, 1, 2048, nullptr);
    G(hid_bf, 2048, w_ff2w2, 2048, nullptr, nullptr, nullptr, 0,
      MM, 512, 2, 1024, 1024, 0, 0, 0, 0, 0, 0, 0, part);
    // final: h = h + 0.5*v, then LN -> d_out (f32)
    redln_kernel<<<MM, 128, 0, stream>>>(part, 2, ff2_b2, h, 0.5f,
        nullptr, nullptr, ln_g, ln_b, (float*)d_out, nullptr);
}

// Round 13
// 377.120 us; speedup vs baseline: 6.5252x; 1.0417x over previous
//
#include <hip/hip_runtime.h>
#include <hip/hip_bf16.h>
#include <math.h>

#define LL   512
#define DD   512
#define DII  1024
#define NST  16
#define BB   8
#define MM   4096
#define CHL  32
#define NCH  16
#define MB_  (1024*1024)
#define Q_(n) ((size_t)(n)*262144)   // quarter-MiB units

typedef __attribute__((ext_vector_type(8))) short bf16x8;
typedef __attribute__((ext_vector_type(4))) float f32x4;

// Fast HW-native activations (v_exp/v_log/v_rcp): rel err ~1e-6.
__device__ __forceinline__ float fast_rcp(float x){ return __builtin_amdgcn_rcpf(x); }
__device__ __forceinline__ float sigmoidf_(float x){ return fast_rcp(1.0f + __expf(-x)); }
__device__ __forceinline__ float siluf_(float x){ return x * sigmoidf_(x); }
__device__ __forceinline__ float softplusf_(float x){
    return fmaxf(x, 0.0f) + __logf(1.0f + __expf(-fabsf(x)));
}

__device__ __forceinline__ short f2bf(float f) {
    union { float f; unsigned u; } v; v.f = f;
    unsigned r = v.u + 0x7fffu + ((v.u >> 16) & 1u);
    return (short)(r >> 16);
}
__device__ __forceinline__ float bf2f(short s) {
    union { unsigned u; float f; } v; v.u = ((unsigned)(unsigned short)s) << 16;
    return v.f;
}
__device__ __forceinline__ bf16x8 pack_bf8(float4 v0, float4 v1) {
    union { bf16x8 v; short e[8]; } pk;
    pk.e[0]=f2bf(v0.x); pk.e[1]=f2bf(v0.y); pk.e[2]=f2bf(v0.z); pk.e[3]=f2bf(v0.w);
    pk.e[4]=f2bf(v1.x); pk.e[5]=f2bf(v1.y); pk.e[6]=f2bf(v1.z); pk.e[7]=f2bf(v1.w);
    return pk.v;
}
__device__ __forceinline__ void gl_lds16(const short* g, short* l) {
    __builtin_amdgcn_global_load_lds(
        (const __attribute__((address_space(1))) void*)g,
        (__attribute__((address_space(3))) void*)l, 16, 0, 0);
}

// ---------------------------------------------------------------------------
// Batched fp32 -> bf16 weight conversion (10 segments).
// ---------------------------------------------------------------------------
struct WcvtArgs { const float* s[10]; short* d[10]; int n[10]; };
__global__ void __launch_bounds__(256) wcvt_kernel(WcvtArgs a) {
    const int seg = blockIdx.y;
    const int i = (blockIdx.x*256 + threadIdx.x) * 8;
    if (i >= a.n[seg]) return;
    const float* s = a.s[seg] + i;
    float4 v0 = *(const float4*)s;
    float4 v1 = *(const float4*)(s + 4);
    int di = i;
    if (seg == 8) di = ((i >> 5) << 6) | (i & 31);   // pad K 32 -> 64
    *(bf16x8*)(a.d[seg] + di) = pack_bf8(v0, v1);
}

// wout [2][512][1024] f32 -> [2][1024][512] bf16
__global__ void __launch_bounds__(256) woutT_kernel(
    const float* __restrict__ wout, short* __restrict__ outT)
{
    __shared__ float sh[64][65];
    const int o0 = blockIdx.x << 6;
    const int j0 = blockIdx.y << 6;
    const int d  = blockIdx.z;
    const float* in = wout + (size_t)d*512*1024;
    short* out = outT + (size_t)d*1024*512;
    const int t = threadIdx.x;
    const int c4 = (t & 15) << 2;
    const int r  = t >> 4;
    #pragma unroll
    for (int i = 0; i < 4; i++) {
        int orow = r + i*16;
        float4 v = *(const float4*)(in + (size_t)(o0 + orow)*1024 + j0 + c4);
        sh[orow][c4+0]=v.x; sh[orow][c4+1]=v.y; sh[orow][c4+2]=v.z; sh[orow][c4+3]=v.w;
    }
    __syncthreads();
    #pragma unroll
    for (int i = 0; i < 4; i++) {
        int jr = r + i*16;
        short4 o;
        o.x = f2bf(sh[c4+0][jr]); o.y = f2bf(sh[c4+1][jr]);
        o.z = f2bf(sh[c4+2][jr]); o.w = f2bf(sh[c4+3][jr]);
        *(short4*)(out + (size_t)(j0 + jr)*512 + o0 + c4) = o;
    }
}

// ---------------------------------------------------------------------------
// gemm9: 128x256 tile, BK=64, 512 thr = 8 waves (2Mx4N, wave tile 64x64),
// 2-phase counted-vmcnt pipeline + T2 source-pre-swizzle + XCD swizzle.
// 16 MFMA per 8 ds_read_b128 per wave per ks (2x the 64x128 ratio).
// LDS 96 KB -> 1 block/CU. Used for N>=2048 GEMMs (grid >= 256 blocks).
// ---------------------------------------------------------------------------
__global__ void __launch_bounds__(512) gemm9_kernel(
    const short* __restrict__ A, int lda,
    const short* __restrict__ W, int ldw,
    const float* __restrict__ bias,
    short* __restrict__ outB, int ldc,
    int kLen, int act)
{
    __shared__ short As[2][128*64];
    __shared__ short Ws[2][256*64];

    const int tid = threadIdx.x, lane = tid & 63, wid = tid >> 6;

    int nwg = gridDim.x * gridDim.y;
    int flat = blockIdx.y * gridDim.x + blockIdx.x;
    if (!(nwg & 7)) { int cpx = nwg >> 3; flat = (flat & 7)*cpx + (flat >> 3); }
    const int bx = flat % gridDim.x, by = flat / gridDim.x;
    const int rowBase = by << 7;
    const int colBase = bx << 8;

    size_t asrc[2];
    #pragma unroll
    for (int rd = 0; rd < 2; rd++) {
        int id = rd*512 + tid, row = id >> 3, u = id & 7;
        asrc[rd] = (size_t)(rowBase + row)*lda + ((u ^ (row & 7)) << 3);
    }
    size_t wsrc[4];
    #pragma unroll
    for (int rd = 0; rd < 4; rd++) {
        int id = rd*512 + tid, row = id >> 3, u = id & 7;
        wsrc[rd] = (size_t)(colBase + row)*ldw + ((u ^ (row & 7)) << 3);
    }

    const int fr = lane & 15;
    const int swz0 = ((((lane >> 4)    ) ^ (lane & 7)) << 3);
    const int swz1 = ((((lane >> 4) | 4) ^ (lane & 7)) << 3);
    const int wm = (wid >> 2) * 64, wn = (wid & 3) * 64;

    f32x4 acc[4][4] = {};

    auto STAGE = [&](int buf, int k0) {
        #pragma unroll
        for (int rd = 0; rd < 2; rd++)
            gl_lds16(A + asrc[rd] + k0, &As[buf][(rd*512 + tid)*8]);
        #pragma unroll
        for (int rd = 0; rd < 4; rd++)
            gl_lds16(W + wsrc[rd] + k0, &Ws[buf][(rd*512 + tid)*8]);
    };

    const int nT = kLen >> 6;
    STAGE(0, 0);
    int cur = 0;
    for (int t = 0; t < nT; ++t) {
        if (t + 1 < nT) {
            STAGE(cur ^ 1, (t+1)*64);
            asm volatile("s_waitcnt vmcnt(6)" ::: "memory");
        } else {
            asm volatile("s_waitcnt vmcnt(0)" ::: "memory");
        }
        __builtin_amdgcn_sched_barrier(0);
        __builtin_amdgcn_s_barrier();
        __builtin_amdgcn_sched_barrier(0);
        #pragma unroll
        for (int ks = 0; ks < 2; ks++) {
            const int so = ks ? swz1 : swz0;
            bf16x8 af[4], bfr[4];
            #pragma unroll
            for (int mi = 0; mi < 4; mi++)
                af[mi] = *(const bf16x8*)&As[cur][(wm + mi*16 + fr)*64 + so];
            #pragma unroll
            for (int ni = 0; ni < 4; ni++)
                bfr[ni] = *(const bf16x8*)&Ws[cur][(wn + ni*16 + fr)*64 + so];
            #pragma unroll
            for (int mi = 0; mi < 4; mi++)
                #pragma unroll
                for (int ni = 0; ni < 4; ni++)
                    acc[mi][ni] = __builtin_amdgcn_mfma_f32_16x16x32_bf16(af[mi], bfr[ni], acc[mi][ni], 0, 0, 0);
        }
        __builtin_amdgcn_sched_barrier(0);
        __builtin_amdgcn_s_barrier();
        __builtin_amdgcn_sched_barrier(0);
        cur ^= 1;
    }

    #pragma unroll
    for (int mi = 0; mi < 4; mi++)
        #pragma unroll
        for (int r = 0; r < 4; r++) {
            int orow = rowBase + wm + mi*16 + ((lane>>4)<<2) + r;
            #pragma unroll
            for (int ni = 0; ni < 4; ni++) {
                int gcol = colBase + wn + ni*16 + fr;
                float v = acc[mi][ni][r];
                if (bias) v += bias[gcol];
                if (act == 1) v = siluf_(v);
                outB[(size_t)orow*ldc + gcol] = f2bf(v);
            }
        }
}

// ---------------------------------------------------------------------------
// bf16 MFMA GEMM v8: 64xBN tile, BK=64, 4 waves, counted-vmcnt 2-deep
// pipeline, T2 source-pre-swizzle, XCD swizzle. Generalized batching.
// ---------------------------------------------------------------------------
template<int BN>
__global__ void __launch_bounds__(256) gemm3_kernel(
    const short* __restrict__ A, int lda,
    const short* __restrict__ W, int ldw,
    const float* __restrict__ bias,
    float* __restrict__ outF, short* __restrict__ outB, int ldc,
    int kLen, int kOff, int act, int actLim,
    size_t zA, size_t zW, int zB, size_t zO, int rowsPerW,
    float* __restrict__ partial, size_t pstride, int N)
{
    constexpr int WN = BN / 64;
    constexpr int WM = 4 / WN;
    constexpr int TM = 64 / WM;
    constexpr int FM = TM / 16;
    constexpr int WRW = BN / 32;

    __shared__ short As[2][64*64];
    __shared__ short Ws[2][BN*64];

    const int tid = threadIdx.x, lane = tid & 63, wid = tid >> 6;
    const int z = blockIdx.z;
    A += (size_t)z * zA;
    if (outF) outF += (size_t)z * zO;
    if (outB) outB += (size_t)z * zO;

    int nwg = gridDim.x * gridDim.y;
    int flat = blockIdx.y * gridDim.x + blockIdx.x;
    if (!(nwg & 7)) { int cpx = nwg >> 3; flat = (flat & 7)*cpx + (flat >> 3); }
    const int bx = flat % gridDim.x, by = flat / gridDim.x;

    const int rowBase = by << 6;
    const int colBase = bx * BN;
    const int kBase = z * kOff;

    const int dsel = rowsPerW ? (rowBase / rowsPerW) : z;
    W += (size_t)dsel * zW;
    if (bias) bias += (size_t)dsel * (size_t)zB;

    size_t asrc[2];
    #pragma unroll
    for (int rd = 0; rd < 2; rd++) {
        int id = rd*256 + tid, row = id >> 3, u = id & 7;
        asrc[rd] = (size_t)(rowBase + row)*lda + ((u ^ (row & 7)) << 3);
    }
    size_t wsrc[WRW];
    #pragma unroll
    for (int rd = 0; rd < WRW; rd++) {
        int id = rd*256 + tid, row = id >> 3, u = id & 7;
        wsrc[rd] = (size_t)(colBase + row)*ldw + ((u ^ (row & 7)) << 3);
    }

    const int fr = lane & 15;
    const int swz0 = ((((lane >> 4)    ) ^ (lane & 7)) << 3);
    const int swz1 = ((((lane >> 4) | 4) ^ (lane & 7)) << 3);
    const int wm = (wid / WN) * TM, wn = (wid % WN) * 64;

    f32x4 acc[FM][4] = {};

    auto STAGE = [&](int buf, int k0) {
        #pragma unroll
        for (int rd = 0; rd < 2; rd++)
            gl_lds16(A + asrc[rd] + k0, &As[buf][(rd*256 + tid)*8]);
        #pragma unroll
        for (int rd = 0; rd < WRW; rd++)
            gl_lds16(W + wsrc[rd] + k0, &Ws[buf][(rd*256 + tid)*8]);
    };

    const int nT = kLen >> 6;
    STAGE(0, kBase);
    int cur = 0;
    for (int t = 0; t < nT; ++t) {
        if (t + 1 < nT) {
            STAGE(cur ^ 1, kBase + (t+1)*64);
            asm volatile("s_waitcnt vmcnt(6)" ::: "memory");
        } else {
            asm volatile("s_waitcnt vmcnt(0)" ::: "memory");
        }
        __builtin_amdgcn_sched_barrier(0);
        __builtin_amdgcn_s_barrier();
        __builtin_amdgcn_sched_barrier(0);
        #pragma unroll
        for (int ks = 0; ks < 2; ks++) {
            const int so = ks ? swz1 : swz0;
            bf16x8 af[FM], bfr[4];
            #pragma unroll
            for (int mi = 0; mi < FM; mi++)
                af[mi] = *(const bf16x8*)&As[cur][(wm + mi*16 + fr)*64 + so];
            #pragma unroll
            for (int ni = 0; ni < 4; ni++)
                bfr[ni] = *(const bf16x8*)&Ws[cur][(wn + ni*16 + fr)*64 + so];
            #pragma unroll
            for (int mi = 0; mi < FM; mi++)
                #pragma unroll
                for (int ni = 0; ni < 4; ni++)
                    acc[mi][ni] = __builtin_amdgcn_mfma_f32_16x16x32_bf16(af[mi], bfr[ni], acc[mi][ni], 0, 0, 0);
        }
        __builtin_amdgcn_sched_barrier(0);
        __builtin_amdgcn_s_barrier();
        __builtin_amdgcn_sched_barrier(0);
        cur ^= 1;
    }

    if (partial) {
        float* pp = partial + (size_t)z * pstride;
        #pragma unroll
        for (int mi = 0; mi < FM; mi++)
            #pragma unroll
            for (int r = 0; r < 4; r++) {
                int orow = rowBase + wm + mi*16 + ((lane>>4)<<2) + r;
                #pragma unroll
                for (int ni = 0; ni < 4; ni++)
                    pp[(size_t)orow*N + colBase + wn + ni*16 + fr] = acc[mi][ni][r];
            }
    } else {
        #pragma unroll
        for (int mi = 0; mi < FM; mi++)
            #pragma unroll
            for (int r = 0; r < 4; r++) {
                int orow = rowBase + wm + mi*16 + ((lane>>4)<<2) + r;
                #pragma unroll
                for (int ni = 0; ni < 4; ni++) {
                    int gcol = colBase + wn + ni*16 + fr;
                    float v = acc[mi][ni][r];
                    if (bias) v += bias[gcol];
                    if (gcol < actLim) {
                        if (act == 1) v = siluf_(v);
                        else if (act == 2) v = softplusf_(v);
                    }
                    if (outF) outF[(size_t)orow*ldc + gcol] = v;
                    if (outB) outB[(size_t)orow*ldc + gcol] = f2bf(v);
                }
            }
    }
}

// ---------------------------------------------------------------------------
// Generic split-K reduce -> bf16 (xdb projection only).
// ---------------------------------------------------------------------------
__global__ void __launch_bounds__(256) reduce_kernel(
    const float* __restrict__ part, int S, size_t pstride, int N,
    short* __restrict__ outB, int ldc)
{
    const int i4 = blockIdx.x*256 + threadIdx.x;
    const int row = i4 / (N >> 2);
    const int c4  = (i4 - row*(N >> 2)) << 2;
    float4 s = *(const float4*)(part + (size_t)row*N + c4);
    for (int z = 1; z < S; z++) {
        float4 t = *(const float4*)(part + (size_t)z*pstride + (size_t)row*N + c4);
        s.x += t.x; s.y += t.y; s.z += t.z; s.w += t.w;
    }
    short4 o; o.x=f2bf(s.x); o.y=f2bf(s.y); o.z=f2bf(s.z); o.w=f2bf(s.w);
    *(short4*)(outB + (size_t)row*ldc + c4) = o;
}

// ---------------------------------------------------------------------------
// REDLN: sum S partials (N=512) + bias + resid*rscale -> h; optional fused
// LayerNorm -> bf16/f32.
// ---------------------------------------------------------------------------
__global__ void __launch_bounds__(128) redln_kernel(
    const float* __restrict__ part, int S,
    const float* __restrict__ bias,
    const float* __restrict__ resid, float rscale,
    float* __restrict__ houtF, short* __restrict__ houtB,
    const float* __restrict__ lng, const float* __restrict__ lnb2,
    float* __restrict__ lnoutF, short* __restrict__ lnoutB)
{
    const int row = blockIdx.x;
    const int t = threadIdx.x;
    const size_t pstride = (size_t)MM*512;
    float4 s = ((const float4*)(part + (size_t)row*512))[t];
    for (int z = 1; z < S; z++) {
        float4 v = ((const float4*)(part + z*pstride + (size_t)row*512))[t];
        s.x += v.x; s.y += v.y; s.z += v.z; s.w += v.w;
    }
    if (bias) { float4 b = ((const float4*)bias)[t]; s.x+=b.x; s.y+=b.y; s.z+=b.z; s.w+=b.w; }
    if (resid) {
        float4 r = ((const float4*)(resid + (size_t)row*512))[t];
        s.x = r.x + rscale*s.x; s.y = r.y + rscale*s.y;
        s.z = r.z + rscale*s.z; s.w = r.w + rscale*s.w;
    }
    if (houtF) ((float4*)(houtF + (size_t)row*512))[t] = s;
    if (houtB) {
        short4 o; o.x=f2bf(s.x); o.y=f2bf(s.y); o.z=f2bf(s.z); o.w=f2bf(s.w);
        *(short4*)(houtB + (size_t)row*512 + t*4) = o;
    }
    if (!lng) return;
    float sum = s.x+s.y+s.z+s.w;
    float sq  = s.x*s.x+s.y*s.y+s.z*s.z+s.w*s.w;
    #pragma unroll
    for (int off = 32; off >= 1; off >>= 1) {
        sum += __shfl_down(sum, off);
        sq  += __shfl_down(sq, off);
    }
    __shared__ float sh[4];
    if ((t & 63) == 0) { sh[(t>>6)*2] = sum; sh[(t>>6)*2+1] = sq; }
    __syncthreads();
    float mean = (sh[0]+sh[2]) * (1.0f/512.f);
    float var  = (sh[1]+sh[3]) * (1.0f/512.f) - mean*mean;
    float rstd = rsqrtf(var + 1e-5f);
    float4 gg = ((const float4*)lng)[t];
    float4 bb = ((const float4*)lnb2)[t];
    float4 o;
    o.x = (s.x-mean)*rstd*gg.x + bb.x;
    o.y = (s.y-mean)*rstd*gg.y + bb.y;
    o.z = (s.z-mean)*rstd*gg.z + bb.z;
    o.w = (s.w-mean)*rstd*gg.w + bb.w;
    if (lnoutF) ((float4*)(lnoutF + (size_t)row*512))[t] = o;
    if (lnoutB) {
        short4 ob; ob.x=f2bf(o.x); ob.y=f2bf(o.y); ob.z=f2bf(o.z); ob.w=f2bf(o.w);
        *(short4*)(lnoutB + (size_t)row*512 + t*4) = ob;
    }
}

// ---------------------------------------------------------------------------
// LayerNorm over 512 (pre-FFN1 only).
// ---------------------------------------------------------------------------
__global__ void __launch_bounds__(128) ln_kernel(
    const float* __restrict__ x, const float* __restrict__ g,
    const float* __restrict__ bta, short* __restrict__ outB)
{
    const int row = blockIdx.x;
    const int t = threadIdx.x;
    float4 v = ((const float4*)(x + (size_t)row*DD))[t];
    float s = v.x+v.y+v.z+v.w;
    float q = v.x*v.x+v.y*v.y+v.z*v.z+v.w*v.w;
    #pragma unroll
    for (int off = 32; off >= 1; off >>= 1) {
        s += __shfl_down(s, off);
        q += __shfl_down(q, off);
    }
    __shared__ float sh[4];
    if ((t & 63) == 0) { sh[(t>>6)*2] = s; sh[(t>>6)*2+1] = q; }
    __syncthreads();
    float mean = (sh[0]+sh[2]) * (1.0f/DD);
    float var  = (sh[1]+sh[3]) * (1.0f/DD) - mean*mean;
    float rstd = rsqrtf(var + 1e-5f);
    float4 gg = ((const float4*)g)[t];
    float4 bb = ((const float4*)bta)[t];
    short4 ob;
    ob.x = f2bf((v.x-mean)*rstd*gg.x + bb.x);
    ob.y = f2bf((v.y-mean)*rstd*gg.y + bb.y);
    ob.z = f2bf((v.z-mean)*rstd*gg.z + bb.z);
    ob.w = f2bf((v.w-mean)*rstd*gg.w + bb.w);
    *(short4*)(outB + (size_t)row*DD + t*4) = ob;
}

// ---------------------------------------------------------------------------
// Both-dir dwconv (K=4) + bias + SiLU, 4 channels/thread.
// ---------------------------------------------------------------------------
__global__ void __launch_bounds__(256) conv_both_kernel(
    const short* __restrict__ xz_all, const float* __restrict__ cw,
    const float* __restrict__ cb, short* __restrict__ xc_both)
{
    const int gid = blockIdx.x*256 + threadIdx.x;    // 2*MM*256 = 2^21
    const int c4  = (gid & 255) << 2;
    const int row = (gid >> 8) & (MM-1);
    const int dir = gid >> 20;
    const int l   = row & (LL-1);
    const short* base = xz_all + (size_t)(row - l)*4096 + dir*2048 + c4;
    float acc[4];
    #pragma unroll
    for (int j = 0; j < 4; j++) acc[j] = cb[dir*1024 + c4 + j];
    float wt[4][4];
    #pragma unroll
    for (int j = 0; j < 4; j++) {
        float4 w = *(const float4*)(cw + (size_t)dir*4096 + (c4 + j)*4);
        wt[j][0]=w.x; wt[j][1]=w.y; wt[j][2]=w.z; wt[j][3]=w.w;
    }
    #pragma unroll
    for (int t = 0; t < 4; t++) {
        int lt = dir ? (l + 3 - t) : (l - 3 + t);
        if (lt >= 0 && lt < LL) {
            short4 u = *(const short4*)(base + (size_t)lt*4096);
            acc[0] += wt[0][t]*bf2f(u.x);
            acc[1] += wt[1][t]*bf2f(u.y);
            acc[2] += wt[2][t]*bf2f(u.z);
            acc[3] += wt[3][t]*bf2f(u.w);
        }
    }
    short4 o;
    o.x = f2bf(siluf_(acc[0])); o.y = f2bf(siluf_(acc[1]));
    o.z = f2bf(siluf_(acc[2])); o.w = f2bf(siluf_(acc[3]));
    *(short4*)(xc_both + (size_t)dir*MM*1024 + (size_t)row*1024 + c4) = o;
}

// ---------------------------------------------------------------------------
// 3-pass scan, both dirs batched, CHL=32/NCH=16, exp-elim fast path.
// ---------------------------------------------------------------------------
__global__ void __launch_bounds__(256) scan_a_kernel(
    const short* __restrict__ dt_bf, const short* __restrict__ xc_both,
    const short* __restrict__ xdb_bf, const float* __restrict__ Alog,
    float* __restrict__ S_dt, float* __restrict__ H)
{
    const int bid = blockIdx.x;                // 1024
    const int dg  = bid & 3;
    const int c   = (bid >> 2) & (NCH-1);
    const int b   = (bid >> 6) & 7;
    const int dir = bid >> 9;
    const int d   = (dg << 8) + threadIdx.x;

    float Aexp[16];
    #pragma unroll
    for (int n = 0; n < 16; n++) Aexp[n] = -__expf(Alog[dir*16384 + d*16 + n]);
    const float A0 = Aexp[0];
    int fast = 1;
    #pragma unroll
    for (int n = 1; n < 16; n++)
        fast &= (fabsf(Aexp[n] - (float)(n+1)*A0) <= 1e-4f*fabsf(Aexp[n]) + 1e-6f);

    float h[16];
    #pragma unroll
    for (int n = 0; n < 16; n++) h[n] = 0.f;
    float S = 0.f;

    const size_t rbase = (size_t)b*LL + (size_t)c*CHL;
    const short* dtp = dt_bf + ((size_t)dir*MM + rbase)*1024 + d;
    const short* bcp = xdb_bf + ((size_t)dir*MM + rbase)*64 + 32;
    const short* xcp = xc_both + ((size_t)dir*MM + rbase)*1024 + d;

#define SCAN_A_BODY(FASTQ) \
    for (int i = 0; i < CHL; i++) { \
        int lp = dir ? (CHL-1-i) : i; \
        float dtv = bf2f(dtp[(size_t)lp*1024]); \
        float xcv = bf2f(xcp[(size_t)lp*1024]); \
        S += dtv; \
        float co = dtv*xcv; \
        union { bf16x8 v; short e[8]; } b0, b1; \
        b0.v = *(const bf16x8*)(bcp + (size_t)lp*64); \
        b1.v = *(const bf16x8*)(bcp + (size_t)lp*64 + 8); \
        float q[16]; \
        if (FASTQ) { \
            float p = __expf(dtv*A0); float qq = p; \
            _Pragma("unroll") for (int n = 0; n < 16; n++) { q[n] = qq; qq *= p; } \
        } else { \
            _Pragma("unroll") for (int n = 0; n < 16; n++) q[n] = __expf(dtv*Aexp[n]); \
        } \
        _Pragma("unroll") for (int n = 0; n < 16; n++) { \
            float Bv = bf2f(n < 8 ? b0.e[n] : b1.e[n & 7]); \
            h[n] = fmaf(q[n], h[n], co*Bv); \
        } \
    }
    if (fast) { SCAN_A_BODY(1) } else { SCAN_A_BODY(0) }
#undef SCAN_A_BODY

    S_dt[(((size_t)dir*BB + b)*NCH + c)*1024 + d] = S;
    const size_t hb = ((((size_t)dir*BB + b)*NCH + c)*16)*1024 + d;
    #pragma unroll
    for (int n = 0; n < 16; n++) H[hb + (size_t)n*1024] = h[n];
}

__global__ void __launch_bounds__(256) scan_b_kernel(
    const float* __restrict__ S_dt, float* H, const float* __restrict__ Alog)
{
    const int g = blockIdx.x*256 + threadIdx.x;  // 2*8*16*1024
    const int d = g & 1023;
    const int n = (g >> 10) & 15;
    const int b = (g >> 14) & 7;
    const int dir = g >> 17;
    const float Aexp = -__expf(Alog[dir*16384 + d*16 + n]);
    float h = 0.f;
    for (int ci = 0; ci < NCH; ci++) {
        int c = dir ? (NCH-1-ci) : ci;
        float S = S_dt[(((size_t)dir*BB + b)*NCH + c)*1024 + d];
        size_t i = ((((size_t)dir*BB + b)*NCH + c)*16 + n)*1024 + d;
        float q = __expf(Aexp*S);
        float hn = q*h + H[i];
        H[i] = h;
        h = hn;
    }
}

__global__ void __launch_bounds__(256) scan_c_kernel(
    const short* __restrict__ dt_bf, short* xc_ys,
    const short* __restrict__ xdb_bf, const float* __restrict__ Alog,
    const float* __restrict__ H, const short* __restrict__ xz_all,
    const float* __restrict__ Dp)
{
    const int bid = blockIdx.x;                // 1024
    const int dg  = bid & 3;
    const int c   = (bid >> 2) & (NCH-1);
    const int b   = (bid >> 6) & 7;
    const int dir = bid >> 9;
    const int d   = (dg << 8) + threadIdx.x;

    float Aexp[16];
    #pragma unroll
    for (int n = 0; n < 16; n++) Aexp[n] = -__expf(Alog[dir*16384 + d*16 + n]);
    const float A0 = Aexp[0];
    int fast = 1;
    #pragma unroll
    for (int n = 1; n < 16; n++)
        fast &= (fabsf(Aexp[n] - (float)(n+1)*A0) <= 1e-4f*fabsf(Aexp[n]) + 1e-6f);
    const float Dpv = Dp[dir*1024 + d];

    float h[16];
    const size_t hb = ((((size_t)dir*BB + b)*NCH + c)*16)*1024 + d;
    #pragma unroll
    for (int n = 0; n < 16; n++) h[n] = H[hb + (size_t)n*1024];

    const size_t rbase = (size_t)b*LL + (size_t)c*CHL;
    const short* dtp = dt_bf + ((size_t)dir*MM + rbase)*1024 + d;
    const short* bcp = xdb_bf + ((size_t)dir*MM + rbase)*64 + 32;
    short*       xcp = xc_ys + ((size_t)dir*MM + rbase)*1024 + d;
    const short* zp  = xz_all + rbase*4096 + dir*2048 + 1024 + d;

#define SCAN_C_BODY(FASTQ) \
    for (int i = 0; i < CHL; i++) { \
        int lp = dir ? (CHL-1-i) : i; \
        float dtv = bf2f(dtp[(size_t)lp*1024]); \
        float xcv = bf2f(xcp[(size_t)lp*1024]); \
        float zv  = bf2f(zp[(size_t)lp*4096]); \
        float co = dtv*xcv; \
        union { bf16x8 v; short e[8]; } b0, b1, c0, c1; \
        b0.v = *(const bf16x8*)(bcp + (size_t)lp*64); \
        b1.v = *(const bf16x8*)(bcp + (size_t)lp*64 + 8); \
        c0.v = *(const bf16x8*)(bcp + (size_t)lp*64 + 16); \
        c1.v = *(const bf16x8*)(bcp + (size_t)lp*64 + 24); \
        float q[16]; \
        if (FASTQ) { \
            float p = __expf(dtv*A0); float qq = p; \
            _Pragma("unroll") for (int n = 0; n < 16; n++) { q[n] = qq; qq *= p; } \
        } else { \
            _Pragma("unroll") for (int n = 0; n < 16; n++) q[n] = __expf(dtv*Aexp[n]); \
        } \
        float y = 0.f; \
        _Pragma("unroll") for (int n = 0; n < 16; n++) { \
            float Bv = bf2f(n < 8 ? b0.e[n] : b1.e[n & 7]); \
            float Cv = bf2f(n < 8 ? c0.e[n] : c1.e[n & 7]); \
            h[n] = fmaf(q[n], h[n], co*Bv); \
            y = fmaf(Cv, h[n], y); \
        } \
        float out = (y + Dpv*xcv) * siluf_(zv); \
        xcp[(size_t)lp*1024] = f2bf(out); \
    }
    if (fast) { SCAN_C_BODY(1) } else { SCAN_C_BODY(0) }
#undef SCAN_C_BODY
}

// ---------------------------------------------------------------------------
// GLU + transpose to [b, c, l] f32.
// ---------------------------------------------------------------------------
__global__ void __launch_bounds__(256) glu_transpose_kernel(
    const float* __restrict__ pw1, float* __restrict__ out_t)
{
    __shared__ float sh[64][65];
    const int c0 = blockIdx.x << 6;
    const int l0 = blockIdx.y << 6;
    const int b  = blockIdx.z;
    const int t  = threadIdx.x;
    const int c4 = (t & 15) << 2;
    const int r  = t >> 4;
    #pragma unroll
    for (int i = 0; i < 4; i++) {
        int lrow = r + i*16;
        size_t row = (size_t)(b << 9) + l0 + lrow;
        float4 a = *(const float4*)(pw1 + row*1024 + c0 + c4);
        float4 g = *(const float4*)(pw1 + row*1024 + 512 + c0 + c4);
        sh[lrow][c4+0] = a.x * sigmoidf_(g.x);
        sh[lrow][c4+1] = a.y * sigmoidf_(g.y);
        sh[lrow][c4+2] = a.z * sigmoidf_(g.z);
        sh[lrow][c4+3] = a.w * sigmoidf_(g.w);
    }
    __syncthreads();
    #pragma unroll
    for (int i = 0; i < 4; i++) {
        int crow = r + i*16;
        float4 o;
        o.x = sh[c4+0][crow];
        o.y = sh[c4+1][crow];
        o.z = sh[c4+2][crow];
        o.w = sh[c4+3][crow];
        *(float4*)(out_t + ((size_t)(b << 9) + c0 + crow)*512 + l0 + c4) = o;
    }
}

// ---------------------------------------------------------------------------
// Channel-major fused 3x dwconv avg + BN + SiLU.
// ---------------------------------------------------------------------------
__global__ void __launch_bounds__(256) multiconv_t_kernel(
    const float* __restrict__ gin_t,
    const float* __restrict__ w15, const float* __restrict__ w31,
    const float* __restrict__ w63,
    const float* __restrict__ bn_g, const float* __restrict__ bn_b,
    const float* __restrict__ bn_m, const float* __restrict__ bn_v,
    float* __restrict__ out_t)
{
    __shared__ float sh[574];
    const int c = blockIdx.x & (DD-1);
    const int b = blockIdx.x >> 9;
    const int t = threadIdx.x;
    const float* rowp = gin_t + ((size_t)(b << 9) + c)*512;
    sh[31 + t]       = rowp[t];
    sh[31 + t + 256] = rowp[t + 256];
    if (t < 31) { sh[t] = 0.f; sh[543 + t] = 0.f; }
    __syncthreads();

    const float bnscale = rsqrtf(bn_v[c] + 1e-5f) * bn_g[c];
    const float bnm = bn_m[c], bnb = bn_b[c];
    float* outp = out_t + ((size_t)(b << 9) + c)*512;
    #pragma unroll
    for (int half = 0; half < 2; half++) {
        int l = t + half*256;
        float s63 = 0.f, s31 = 0.f, s15 = 0.f;
        #pragma unroll
        for (int k = 0; k < 63; k++) s63 += w63[c*63 + k] * sh[l + k];
        #pragma unroll
        for (int k = 0; k < 31; k++) s31 += w31[c*31 + k] * sh[l + 16 + k];
        #pragma unroll
        for (int k = 0; k < 15; k++) s15 += w15[c*15 + k] * sh[l + 24 + k];
        float m = (s15 + s31 + s63) * (1.0f/3.0f);
        m = (m - bnm) * bnscale + bnb;
        outp[l] = siluf_(m);
    }
}

// ---------------------------------------------------------------------------
// Transpose [b, c, l] -> [b, l, c], bf16 out.
// ---------------------------------------------------------------------------
__global__ void __launch_bounds__(256) transpose_bcl_kernel(
    const float* __restrict__ in_t, short* __restrict__ out)
{
    __shared__ float sh[64][65];
    const int l0 = blockIdx.x << 6;
    const int c0 = blockIdx.y << 6;
    const int b  = blockIdx.z;
    const int t  = threadIdx.x;
    const int l4 = (t & 15) << 2;
    const int r  = t >> 4;
    #pragma unroll
    for (int i = 0; i < 4; i++) {
        int crow = r + i*16;
        float4 v = *(const float4*)(in_t + ((size_t)(b << 9) + c0 + crow)*512 + l0 + l4);
        sh[crow][l4+0] = v.x; sh[crow][l4+1] = v.y;
        sh[crow][l4+2] = v.z; sh[crow][l4+3] = v.w;
    }
    __syncthreads();
    #pragma unroll
    for (int i = 0; i < 4; i++) {
        int lrow = r + i*16;
        short4 o;
        o.x = f2bf(sh[l4+0][lrow]);
        o.y = f2bf(sh[l4+1][lrow]);
        o.z = f2bf(sh[l4+2][lrow]);
        o.w = f2bf(sh[l4+3][lrow]);
        *(short4*)(out + ((size_t)(b << 9) + l0 + lrow)*512 + c0 + l4) = o;
    }
}

// ---------------------------------------------------------------------------
extern "C" void kernel_launch(void* const* d_in, const int* in_sizes, int n_in,
                              void* d_out, int out_size, void* d_ws, size_t ws_size,
                              hipStream_t stream)
{
    const float* x        = (const float*)d_in[0];
    const float* ff1_ln_g = (const float*)d_in[1];
    const float* ff1_ln_b = (const float*)d_in[2];
    const float* ff1_w1   = (const float*)d_in[3];
    const float* ff1_b1   = (const float*)d_in[4];
    const float* ff1_w2   = (const float*)d_in[5];
    const float* ff1_b2   = (const float*)d_in[6];
    const float* ff2_ln_g = (const float*)d_in[7];
    const float* ff2_ln_b = (const float*)d_in[8];
    const float* ff2_w1   = (const float*)d_in[9];
    const float* ff2_b1   = (const float*)d_in[10];
    const float* ff2_w2   = (const float*)d_in[11];
    const float* ff2_b2   = (const float*)d_in[12];
    const float* m_win    = (const float*)d_in[13];
    const float* m_convw  = (const float*)d_in[14];
    const float* m_convb  = (const float*)d_in[15];
    const float* m_wx     = (const float*)d_in[16];
    const float* m_wdt    = (const float*)d_in[17];
    const float* m_bdt    = (const float*)d_in[18];
    const float* m_Alog   = (const float*)d_in[19];
    const float* m_Dp     = (const float*)d_in[20];
    const float* m_wout   = (const float*)d_in[21];
    const float* bi_wo    = (const float*)d_in[22];
    const float* bi_bo    = (const float*)d_in[23];
    const float* cv_ln_g  = (const float*)d_in[24];
    const float* cv_ln_b  = (const float*)d_in[25];
    const float* cv_pw1_w = (const float*)d_in[26];
    const float* cv_pw1_b = (const float*)d_in[27];
    const float* cv_dw15  = (const float*)d_in[28];
    const float* cv_dw31  = (const float*)d_in[29];
    const float* cv_dw63  = (const float*)d_in[30];
    const float* cv_bn_g  = (const float*)d_in[31];
    const float* cv_bn_b  = (const float*)d_in[32];
    const float* cv_bn_m  = (const float*)d_in[33];
    const float* cv_bn_v  = (const float*)d_in[34];
    const float* cv_pw2_w = (const float*)d_in[35];
    const float* cv_pw2_b = (const float*)d_in[36];
    const float* ln_g     = (const float*)d_in[37];
    const float* ln_b     = (const float*)d_in[38];

    // ---- Workspace (quarter-MiB offsets), total 105.5 MiB ----
    char* wsb = (char*)d_ws;
    float* h        = (float*)(wsb + Q_(0));     // 8 MB
    short* h_bf     = (short*)(wsb + Q_(32));    // 4 MB
    short* lnb_bf   = (short*)(wsb + Q_(48));    // 4 MB
    short* w_ff1w1  = (short*)(wsb + Q_(64));
    short* w_ff1w2  = (short*)(wsb + Q_(72));
    short* w_ff2w1  = (short*)(wsb + Q_(80));
    short* w_ff2w2  = (short*)(wsb + Q_(88));
    short* w_win    = (short*)(wsb + Q_(96));    // [4096,512] 4 MB
    short* w_pw1    = (short*)(wsb + Q_(112));
    short* w_pw2    = (short*)(wsb + Q_(116));
    short* w_Wc     = (short*)(wsb + Q_(118));   // [2][512][1024] 2 MB
    short* w_wdtp   = (short*)(wsb + Q_(126));   // [2][1024][64] 0.25 MB
    short* w_wx     = (short*)(wsb + Q_(127));   // [2][64][1024] 0.25 MB
    float* part     = (float*)(wsb + Q_(128));   // 16 MB partials / pw1out
    float* Hbuf     = (float*)(wsb + Q_(128));   // 16 MB scan H overlay
    float* S_dt     = (float*)(wsb + Q_(192));   // 1 MB
    short* xz_all   = (short*)(wsb + Q_(226));   // [MM,4096] 16 MB
    short* woutT_ov = (short*)(wsb + Q_(226));   // prep overlay 2 MB
    short* biwo_ov  = (short*)(wsb + Q_(234));   // prep overlay 1 MB
    float* glu_t    = (float*)(wsb + Q_(226));   // ConvMod overlay 8 MB
    short* xc_both  = (short*)(wsb + Q_(290));   // [2][MM,1024] 16 MB
    short* hid_bf   = (short*)(wsb + Q_(290));   // FFN overlay [MM,2048] 8 MB
    short* dt_bf    = (short*)(wsb + Q_(354));   // [2][MM,1024] 16 MB
    float* mconv_o  = (float*)(wsb + Q_(354));   // ConvMod overlay 8 MB
    short* xdb_bf   = (short*)(wsb + Q_(418));   // [2][MM,64] 1 MB -> ends 422

    if (ws_size < Q_(422)) return;

    // ---- Prep ----
    hipMemsetAsync(w_wdtp, 0, (size_t)2*1024*64*2, stream);
    WcvtArgs wa;
    wa.s[0]=ff1_w1;   wa.d[0]=w_ff1w1; wa.n[0]=1048576;
    wa.s[1]=ff1_w2;   wa.d[1]=w_ff1w2; wa.n[1]=1048576;
    wa.s[2]=ff2_w1;   wa.d[2]=w_ff2w1; wa.n[2]=1048576;
    wa.s[3]=ff2_w2;   wa.d[3]=w_ff2w2; wa.n[3]=1048576;
    wa.s[4]=m_win;    wa.d[4]=w_win;   wa.n[4]=2097152;
    wa.s[5]=bi_wo;    wa.d[5]=biwo_ov; wa.n[5]=524288;
    wa.s[6]=cv_pw1_w; wa.d[6]=w_pw1;   wa.n[6]=524288;
    wa.s[7]=cv_pw2_w; wa.d[7]=w_pw2;   wa.n[7]=262144;
    wa.s[8]=m_wdt;    wa.d[8]=w_wdtp;  wa.n[8]=65536;   // pad K 32->64
    wa.s[9]=m_wx;     wa.d[9]=w_wx;    wa.n[9]=131072;
    wcvt_kernel<<<dim3(1024,10), 256, 0, stream>>>(wa);
    woutT_kernel<<<dim3(8,16,2), 256, 0, stream>>>(m_wout, woutT_ov);

    auto G = [&](const short* A, int lda, const short* W, int ldw,
                 const float* bias, float* oF, short* oB, int ldc,
                 int M, int N, int nz, int kLen, int kOff,
                 size_t zA, size_t zW, int zB, size_t zO, int rowsPerW,
                 int act, int actLim, float* prt) {
        dim3 g(N/128, M/64, nz);
        gemm3_kernel<128><<<g, 256, 0, stream>>>(A, lda, W, ldw, bias, oF, oB, ldc,
            kLen, kOff, act, actLim, zA, zW, zB, zO, rowsPerW,
            prt, (size_t)M*N, N);
    };

    // Wc = biwo_half @ woutT -> [2][512][1024] bf16 (batched z=dir)
    G(biwo_ov, 1024, woutT_ov, 512, nullptr, nullptr, w_Wc, 1024,
      512, 1024, 2, 512, 0, 512, 524288, 0, 524288, 0, 0, 0, nullptr);

    // ---- FFN1 ----
    ln_kernel<<<MM, 128, 0, stream>>>(x, ff1_ln_g, ff1_ln_b, lnb_bf);
    gemm9_kernel<<<dim3(8, 32), 512, 0, stream>>>(lnb_bf, 512, w_ff1w1, 512,
        ff1_b1, hid_bf, 2048, 512, 1);
    G(hid_bf, 2048, w_ff1w2, 2048, nullptr, nullptr, nullptr, 0,
      MM, 512, 2, 1024, 1024, 0, 0, 0, 0, 0, 0, 0, part);
    redln_kernel<<<MM, 128, 0, stream>>>(part, 2, ff1_b2, x, 0.5f,
        h, h_bf, nullptr, nullptr, nullptr, nullptr);

    // ---- BiMamba ----
    gemm9_kernel<<<dim3(16, 32), 512, 0, stream>>>(h_bf, 512, w_win, 512,
        nullptr, xz_all, 4096, 512, 0);
    conv_both_kernel<<<8192, 256, 0, stream>>>(xz_all, m_convw, m_convb, xc_both);
    // xdb = xc @ wx^T : M=8192 (both dirs), N=64, split-K 4, W by row-dir
    {
        dim3 g(1, 128, 4);
        gemm3_kernel<64><<<g, 256, 0, stream>>>(xc_both, 1024, w_wx, 1024,
            nullptr, nullptr, nullptr, 0, 256, 256, 0, 0,
            0, 65536, 0, 0, 4096, part, (size_t)8192*64, 64);
    }
    reduce_kernel<<<512, 256, 0, stream>>>(part, 4, (size_t)8192*64, 64, xdb_bf, 64);
    // dt = softplus(xdb @ wdt_pad^T + bdt)
    G(xdb_bf, 64, w_wdtp, 64, m_bdt, nullptr, dt_bf, 1024,
      8192, 1024, 1, 64, 0, 0, 65536, 1024, 0, 4096, 2, 1024, nullptr);
    // 3-pass scan + fused ycombine (ys overwrites xc_both)
    scan_a_kernel<<<1024, 256, 0, stream>>>(dt_bf, xc_both, xdb_bf, m_Alog, S_dt, Hbuf);
    scan_b_kernel<<<1024, 256, 0, stream>>>(S_dt, Hbuf, m_Alog);
    scan_c_kernel<<<1024, 256, 0, stream>>>(dt_bf, xc_both, xdb_bf, m_Alog, Hbuf,
                                            xz_all, m_Dp);
    // h += ys0@Wc0 + ys1@Wc1 + bi_bo ; fused cv-LN
    G(xc_both, 1024, w_Wc, 1024, nullptr, nullptr, nullptr, 0,
      MM, 512, 2, 1024, 0, (size_t)MM*1024, 524288, 0, 0, 0, 0, 0, part);
    redln_kernel<<<MM, 128, 0, stream>>>(part, 2, bi_bo, h, 1.0f,
        h, nullptr, cv_ln_g, cv_ln_b, nullptr, lnb_bf);

    // ---- ConvMod ----
    G(lnb_bf, 512, w_pw1, 512, cv_pw1_b, part, nullptr, 1024,
      MM, 1024, 1, 512, 0, 0, 0, 0, 0, 0, 0, 0, nullptr);
    glu_transpose_kernel<<<dim3(8,8,8), 256, 0, stream>>>(part, glu_t);
    multiconv_t_kernel<<<BB*DD, 256, 0, stream>>>(glu_t,
        cv_dw15, cv_dw31, cv_dw63, cv_bn_g, cv_bn_b, cv_bn_m, cv_bn_v, mconv_o);
    transpose_bcl_kernel<<<dim3(8,8,8), 256, 0, stream>>>(mconv_o, lnb_bf);
    G(lnb_bf, 512, w_pw2, 512, nullptr, nullptr, nullptr, 0,
      MM, 512, 2, 256, 256, 0, 0, 0, 0, 0, 0, 0, part);
    redln_kernel<<<MM, 128, 0, stream>>>(part, 2, cv_pw2_b, h, 1.0f,
        h, nullptr, ff2_ln_g, ff2_ln_b, nullptr, lnb_bf);

    // ---- FFN2 ----
    gemm9_kernel<<<dim3(8, 32), 512, 0, stream>>>(lnb_bf, 512, w_ff2w1, 512,
        ff2_b1, hid_bf, 2048, 512, 1);
    G(hid_bf, 2048, w_ff2w2, 2048, nullptr, nullptr, nullptr, 0,
      MM, 512, 2, 1024, 1024, 0, 0, 0, 0, 0, 0, 0, part);
    // final: h = h + 0.5*v, then LN -> d_out (f32)
    redln_kernel<<<MM, 128, 0, stream>>>(part, 2, ff2_b2, h, 0.5f,
        nullptr, nullptr, ln_g, ln_b, (float*)d_out, nullptr);
}